// Round 2
// baseline (672.484 us; speedup 1.0000x reference)
//
#include <hip/hip_runtime.h>
#include <hip/hip_fp16.h>

#define TT 256
#define PP 88
#define CC 128
#define NN (TT * PP)          // 22528 positions
#define NPAD (NN + 32)
#define HEADS 4
#define HD 32
#define WIN 25
#define RPBW 49
#define RPBSZ (RPBW * RPBW)   // 2401
#define SCALE 0.17677669529663687f   // 1/sqrt(32)
#define LOG2E 1.4426950408889634f
#define QSC (SCALE * LOG2E)          // fold exp->exp2 into Q path

#if __has_builtin(__builtin_amdgcn_exp2f)
#define EXP2(x) __builtin_amdgcn_exp2f(x)
#else
#define EXP2(x) exp2f(x)
#endif

typedef _Float16 f16;
typedef f16 f16x8 __attribute__((ext_vector_type(8)));
typedef f16 f16x8u __attribute__((ext_vector_type(8), aligned(4)));
typedef f16 f16x4 __attribute__((ext_vector_type(4)));
typedef f16 f16x4u __attribute__((ext_vector_type(4), aligned(4)));
typedef float f32x4 __attribute__((ext_vector_type(4)));
typedef float f32x4u __attribute__((ext_vector_type(4), aligned(4)));
typedef __fp16 hf16x2 __attribute__((ext_vector_type(2)));
union PkU { hf16x2 h; unsigned u; };

// ---------- prep: repack (b<192) + parallel b2s (192<=b<216) + MFMA wcomb (216<=b<228) ----------
__global__ __launch_bounds__(256) void prep(
    const float* __restrict__ lw, const float* __restrict__ qw,
    const float* __restrict__ pw, const float* __restrict__ qb,
    const float* __restrict__ pb, const float* __restrict__ rpb,
    f16* __restrict__ lwh, f16* __restrict__ qwh, f16* __restrict__ pwh,
    f16* __restrict__ w2h, float* __restrict__ qbs, float* __restrict__ b2s,
    float* __restrict__ rpbp)
{
    const int b = blockIdx.x;
    if (b < 192) {
        int idx = b * 256 + threadIdx.x;              // covers 49152
        if (idx < 128 * 160) {                        // fusion W: [128][131] -> [128][160] pad
            int r = idx / 160, c = idx - r * 160;
            lwh[idx] = (f16)(c < 131 ? lw[r * 131 + c] : 0.f);
        }
        if (idx < 384 * 128) {                        // qkv W, Q rows scaled by QSC
            float v = qw[idx];
            if (idx < 128 * 128) v *= QSC;
            qwh[idx] = (f16)v;
        }
        if (idx < 128 * 128) pwh[idx] = (f16)pw[idx];
        if (idx < 384) qbs[idx] = qb[idx] * (idx < 128 ? QSC : 1.f);
        if (idx < 10240) rpbp[idx] = (idx < 4 * RPBSZ) ? rpb[idx] * LOG2E : 0.f;
    } else if (b < 216) {
        // b2s[i] = (qb[i] + qw[i,:]·pb) * sc_i ; 16 lanes per output, shuffle-reduce
        int t = (b - 192) * 256 + threadIdx.x;        // [0, 6144)
        int i = t >> 4, l = t & 15;
        if (i < 384) {
            float s = 0.f;
            #pragma unroll
            for (int j = l * 8; j < l * 8 + 8; j++) s += qw[i * 128 + j] * pb[j];
            s += __shfl_xor(s, 1); s += __shfl_xor(s, 2);
            s += __shfl_xor(s, 4); s += __shfl_xor(s, 8);
            if (l == 0) b2s[i] = (qb[i] + s) * (i < 128 ? QSC : 1.f);
        }
    } else {
        // w2h[i][k] = sc_i * sum_j qw[i][j] pw[j][k]
        const int bw = b - 216;                       // 0..11
        const int m0 = (bw & 1) * 64;                 // k-tile
        const int n0 = (bw >> 1) * 64;                // i-tile
        const int tid = threadIdx.x;
        const int w = tid >> 6, lane = tid & 63, quad = lane >> 4, nn = lane & 15;
        const int krow = m0 + w * 16 + nn;
        f16x8 af[4];
        #pragma unroll
        for (int ks = 0; ks < 4; ks++) {
            union { f16 e[8]; f16x8 v; } t;
            #pragma unroll
            for (int e = 0; e < 8; e++)
                t.e[e] = (f16)pw[(ks * 32 + quad * 8 + e) * 128 + krow];
            af[ks] = t.v;
        }
        f32x4 acc[4] = {};
        #pragma unroll
        for (int nt = 0; nt < 4; nt++) {
            int irow = n0 + nt * 16 + nn;
            #pragma unroll
            for (int ks = 0; ks < 4; ks++) {
                const float* qr = &qw[(size_t)irow * 128 + ks * 32 + quad * 8];
                float4 a = *(const float4*)qr, bq = *(const float4*)(qr + 4);
                PkU u0, u1, u2, u3;
                u0.h = __builtin_amdgcn_cvt_pkrtz(a.x, a.y);
                u1.h = __builtin_amdgcn_cvt_pkrtz(a.z, a.w);
                u2.h = __builtin_amdgcn_cvt_pkrtz(bq.x, bq.y);
                u3.h = __builtin_amdgcn_cvt_pkrtz(bq.z, bq.w);
                union { unsigned u[4]; f16x8 v; } bb;
                bb.u[0] = u0.u; bb.u[1] = u1.u; bb.u[2] = u2.u; bb.u[3] = u3.u;
                acc[nt] = __builtin_amdgcn_mfma_f32_16x16x32_f16(af[ks], bb.v, acc[nt], 0, 0, 0);
            }
        }
        #pragma unroll
        for (int nt = 0; nt < 4; nt++) {
            int i = n0 + nt * 16 + nn;
            float sc = (i < 128) ? QSC : 1.f;
            PkU p0, p1;
            p0.h = __builtin_amdgcn_cvt_pkrtz(acc[nt][0] * sc, acc[nt][1] * sc);
            p1.h = __builtin_amdgcn_cvt_pkrtz(acc[nt][2] * sc, acc[nt][3] * sc);
            *(uint2*)&w2h[(size_t)i * 128 + m0 + w * 16 + quad * 4] = make_uint2(p0.u, p1.u);
        }
    }
}

// ---------- fusion GEMM: yh = relu(cat @ lwh^T + lb); grid (352, 2) ----------
__global__ __launch_bounds__(256) void fusion_gemm(
    const float* __restrict__ x, const float* __restrict__ cond, const float* __restrict__ mask,
    const f16* __restrict__ lwh, const float* __restrict__ lb, f16* __restrict__ yh)
{
    __shared__ __align__(16) f16 Alds[64 * 168];
    const int m0 = blockIdx.x * 64, n0 = blockIdx.y * 64;
    const int tid = threadIdx.x;
    const int w = tid >> 6, lane = tid & 63, quad = lane >> 4, nn = lane & 15;

    {   // stage cat rows (f16)
        int r = tid >> 2, cpart = tid & 3;
        size_t pos = m0 + r;
        *(uint4*)&Alds[r * 168 + 128 + cpart * 8] = make_uint4(0, 0, 0, 0);
        const float* xr = x + pos * 128 + cpart * 32;
        #pragma unroll
        for (int t = 0; t < 4; t++) {
            float4 a = *(const float4*)(xr + t * 8);
            float4 b = *(const float4*)(xr + t * 8 + 4);
            PkU p0, p1, p2, p3;
            p0.h = __builtin_amdgcn_cvt_pkrtz(a.x, a.y);
            p1.h = __builtin_amdgcn_cvt_pkrtz(a.z, a.w);
            p2.h = __builtin_amdgcn_cvt_pkrtz(b.x, b.y);
            p3.h = __builtin_amdgcn_cvt_pkrtz(b.z, b.w);
            *(uint4*)&Alds[r * 168 + cpart * 32 + t * 8] = make_uint4(p0.u, p1.u, p2.u, p3.u);
        }
        if (cpart == 0) {
            Alds[r * 168 + 128] = (f16)cond[pos * 2];
            Alds[r * 168 + 129] = (f16)cond[pos * 2 + 1];
            Alds[r * 168 + 130] = (f16)mask[pos];
        }
    }
    __syncthreads();

    const int oc = n0 + w * 16 + nn;
    f16x8 af[5];
    #pragma unroll
    for (int ks = 0; ks < 5; ks++)
        af[ks] = *(const f16x8*)&lwh[(size_t)oc * 160 + ks * 32 + quad * 8];
    f32x4 acc[4] = {};
    #pragma unroll
    for (int ks = 0; ks < 5; ks++)
        #pragma unroll
        for (int nt = 0; nt < 4; nt++) {
            f16x8 bf = *(const f16x8*)&Alds[(nt * 16 + nn) * 168 + ks * 32 + quad * 8];
            acc[nt] = __builtin_amdgcn_mfma_f32_16x16x32_f16(af[ks], bf, acc[nt], 0, 0, 0);
        }
    float bv[4];
    #pragma unroll
    for (int r = 0; r < 4; r++) bv[r] = lb[n0 + w * 16 + quad * 4 + r];
    #pragma unroll
    for (int nt = 0; nt < 4; nt++) {
        int pos = m0 + nt * 16 + nn;
        PkU p0, p1;
        p0.h = __builtin_amdgcn_cvt_pkrtz(fmaxf(acc[nt][0] + bv[0], 0.f), fmaxf(acc[nt][1] + bv[1], 0.f));
        p1.h = __builtin_amdgcn_cvt_pkrtz(fmaxf(acc[nt][2] + bv[2], 0.f), fmaxf(acc[nt][3] + bv[3], 0.f));
        *(uint2*)&yh[(size_t)pos * 128 + n0 + w * 16 + quad * 4] = make_uint2(p0.u, p1.u);
    }
}

// ---------- qkv GEMM: grid (352, 6); Q|K rows stride 256, V transposed ----------
__global__ __launch_bounds__(256) void gemm_qkv(
    const f16* __restrict__ A, const f16* __restrict__ W, const float* __restrict__ bias,
    f16* __restrict__ qkh, f16* __restrict__ vt)
{
    __shared__ __align__(16) f16 Alds[64 * 136];
    const int m0 = blockIdx.x * 64, n0 = blockIdx.y * 64;
    const int tid = threadIdx.x;
    const int w = tid >> 6, lane = tid & 63, quad = lane >> 4, nn = lane & 15;

    for (int i = tid; i < 1024; i += 256) {
        int r = i >> 4, c = i & 15;
        *(uint4*)&Alds[r * 136 + c * 8] = *(const uint4*)&A[(size_t)(m0 + r) * 128 + c * 8];
    }
    __syncthreads();

    const int oc = n0 + w * 16 + nn;
    f16x8 af[4];
    #pragma unroll
    for (int ks = 0; ks < 4; ks++)
        af[ks] = *(const f16x8*)&W[(size_t)oc * 128 + ks * 32 + quad * 8];
    f32x4 acc[4] = {};
    #pragma unroll
    for (int ks = 0; ks < 4; ks++)
        #pragma unroll
        for (int nt = 0; nt < 4; nt++) {
            f16x8 bf = *(const f16x8*)&Alds[(nt * 16 + nn) * 136 + ks * 32 + quad * 8];
            acc[nt] = __builtin_amdgcn_mfma_f32_16x16x32_f16(af[ks], bf, acc[nt], 0, 0, 0);
        }
    float bv[4];
    #pragma unroll
    for (int r = 0; r < 4; r++) bv[r] = bias[n0 + w * 16 + quad * 4 + r];

    if (n0 < 256) {
        #pragma unroll
        for (int nt = 0; nt < 4; nt++) {
            int pos = m0 + nt * 16 + nn;
            PkU p0, p1;
            p0.h = __builtin_amdgcn_cvt_pkrtz(acc[nt][0] + bv[0], acc[nt][1] + bv[1]);
            p1.h = __builtin_amdgcn_cvt_pkrtz(acc[nt][2] + bv[2], acc[nt][3] + bv[3]);
            *(uint2*)&qkh[(size_t)pos * 256 + n0 + w * 16 + quad * 4] = make_uint2(p0.u, p1.u);
        }
    } else {
        #pragma unroll
        for (int nt = 0; nt < 4; nt++) {
            int pos = m0 + nt * 16 + nn;
            #pragma unroll
            for (int r = 0; r < 4; r++) {
                int chg = n0 - 256 + w * 16 + quad * 4 + r;
                vt[(size_t)chg * NPAD + pos] = (f16)(acc[nt][r] + bv[r]);
            }
        }
    }
}

// ---------- final projection: grid (352, 2), fp32 out ----------
__global__ __launch_bounds__(256) void gemm_out(
    const f16* __restrict__ A, const f16* __restrict__ W, const float* __restrict__ bias,
    float* __restrict__ outp)
{
    __shared__ __align__(16) f16 Alds[64 * 136];
    const int m0 = blockIdx.x * 64, n0 = blockIdx.y * 64;
    const int tid = threadIdx.x;
    const int w = tid >> 6, lane = tid & 63, quad = lane >> 4, nn = lane & 15;

    for (int i = tid; i < 1024; i += 256) {
        int r = i >> 4, c = i & 15;
        *(uint4*)&Alds[r * 136 + c * 8] = *(const uint4*)&A[(size_t)(m0 + r) * 128 + c * 8];
    }
    __syncthreads();

    const int oc = n0 + w * 16 + nn;
    f16x8 af[4];
    #pragma unroll
    for (int ks = 0; ks < 4; ks++)
        af[ks] = *(const f16x8*)&W[(size_t)oc * 128 + ks * 32 + quad * 8];
    f32x4 acc[4] = {};
    #pragma unroll
    for (int ks = 0; ks < 4; ks++)
        #pragma unroll
        for (int nt = 0; nt < 4; nt++) {
            f16x8 bf = *(const f16x8*)&Alds[(nt * 16 + nn) * 136 + ks * 32 + quad * 8];
            acc[nt] = __builtin_amdgcn_mfma_f32_16x16x32_f16(af[ks], bf, acc[nt], 0, 0, 0);
        }
    float bv[4];
    #pragma unroll
    for (int r = 0; r < 4; r++) bv[r] = bias[n0 + w * 16 + quad * 4 + r];
    #pragma unroll
    for (int nt = 0; nt < 4; nt++) {
        int pos = m0 + nt * 16 + nn;
        f32x4 vv;
        #pragma unroll
        for (int r = 0; r < 4; r++) vv[r] = acc[nt][r] + bv[r];
        *(f32x4*)&outp[(size_t)pos * 128 + n0 + w * 16 + quad * 4] = vv;
    }
}

// ---------- MFMA neighborhood attention v3: 4 waves split by KEY ROWS ONLY ----------
// Wave w owns key rows [ri0 + w*8, +8) and processes ALL 4 qsets per row:
// K/V/rpb loads amortized 4x (v2 halved this -> regressed; restored here) while
// keeping 4-wave concurrency (2x v1) and the register-direct PV path:
// PV uses v_mfma_f32_16x16x16f16 whose A-fragment layout (4 consecutive K-elems
// per quad) matches the S-MFMA C/D layout exactly, so packed exp2 probabilities
// feed PV in registers - no LDS transpose round-trip in the main loop.
// Masking: packed-f16 AND with precomputed per-qset column masks + per-row valid
// select (numerically = -1e30 poisoning). Rows fully outside a qset's window are
// skipped wave-uniformly (only waves 0/3 at tile edges hit this).
// Merge: symmetric 4-way exchange; wave w finalizes qset w (parallel epilogue).
// Olds layout [12][64][12] f32: lane stride 12 floats -> quarter-wave b128 is
// 2 lanes/bank = conflict-free.
__global__ __launch_bounds__(256, 3) void attn_mfma(
    const f16* __restrict__ qkh,   // [N][256] = Q|K, Q pre-scaled by QSC
    const f16* __restrict__ vt,    // [128][NPAD]
    const float* __restrict__ rpbp,
    f16* __restrict__ ao)          // [N][128]
{
    const int i0 = blockIdx.x * 8;
    const int j0 = blockIdx.y * 8;
    const int h  = blockIdx.z;
    const int tid = threadIdx.x;
    const int w = tid >> 6, lane = tid & 63;
    const int quad = lane >> 4, nn = lane & 15;

    const int ri0 = min(max(i0 - 12, 0), TT - 32);
    const int rj0 = min(max(j0 - 12, 0), PP - WIN) & ~1;

    __shared__ __align__(16) float Olds[12][64][12];   // [slot*4+qset][lane][8 O + 4 lacc]

    int si_[4];
    unsigned pm_[4][4];            // packed-f16 column masks per output word
    f16x8 qf[4];
    const float* rpq[4];
    const float* rp_h = rpbp + h * RPBSZ;
    const int aa0 = ri0 + w * 8;   // this wave's first key row

    #pragma unroll
    for (int q = 0; q < 4; q++) {
        int ql = q * 16 + nn;
        int qi = i0 + (ql >> 3), qj = j0 + (ql & 7);
        int si = min(max(qi - 12, 0), TT - WIN);
        int sj = min(max(qj - 12, 0), PP - WIN);
        si_[q] = si;
        unsigned cm = 0x1FFFFFFu << (sj - rj0);       // shift <= 7
        #pragma unroll
        for (int t = 0; t < 4; t++) {
            int k0 = (t >> 1) * 16 + quad * 4 + (t & 1) * 2;
            pm_[q][t] = (((cm >> k0) & 1u) ? 0xFFFFu : 0u)
                      | (((cm >> (k0 + 1)) & 1u) ? 0xFFFF0000u : 0u);
        }
        qf[q] = *(const f16x8*)&qkh[(size_t)(qi * PP + qj) * 256 + h * HD + quad * 8];
        rpq[q] = rp_h + (aa0 - qi + 24) * RPBW + (rj0 - qj + 24) + quad * 4;
    }

    const f16* vbase = vt + (size_t)(h * HD + nn) * NPAD;
    const int b0 = min(rj0 + nn, PP - 1);
    const int b1 = min(rj0 + 16 + nn, PP - 1);
    const size_t koff = 128 + h * HD + quad * 8;
    const f16x4 ones4 = {(f16)1.f, (f16)1.f, (f16)1.f, (f16)1.f};

    f32x4 O[4][2] = {};            // [qset][ch-half]; regs = queries, lane nn = channel
    f32x4 lacc[4] = {};

    // prologue: load row aa0
    int aa = aa0;
    const f16* rowK = qkh + (size_t)aa * PP * 256 + koff;
    f16x8 kf0 = *(const f16x8*)(rowK + (size_t)b0 * 256);
    f16x8 kf1 = *(const f16x8*)(rowK + (size_t)b1 * 256);
    const f16* vrow = vbase + aa * PP + rj0 + quad * 4;
    f16x4 vfA0 = *(const f16x4u*)vrow;                      // keys  0-15, ch lo
    f16x4 vfB0 = *(const f16x4u*)(vrow + 16);               // keys 16-31, ch lo
    f16x4 vfA1 = *(const f16x4u*)(vrow + (size_t)16 * NPAD);
    f16x4 vfB1 = *(const f16x4u*)(vrow + (size_t)16 * NPAD + 16);

    for (int c = 0; c < 8; c++) {
        // prefetch row aa+1 (last iteration overshoots into vt/ao workspace: in-bounds, unused)
        const f16* rowKn = qkh + (size_t)(aa + 1) * PP * 256 + koff;
        f16x8 nkf0 = *(const f16x8*)(rowKn + (size_t)b0 * 256);
        f16x8 nkf1 = *(const f16x8*)(rowKn + (size_t)b1 * 256);
        const f16* vrown = vbase + (aa + 1) * PP + rj0 + quad * 4;
        f16x4 nvfA0 = *(const f16x4u*)vrown;
        f16x4 nvfB0 = *(const f16x4u*)(vrown + 16);
        f16x4 nvfA1 = *(const f16x4u*)(vrown + (size_t)16 * NPAD);
        f16x4 nvfB1 = *(const f16x4u*)(vrown + (size_t)16 * NPAD + 16);

        #pragma unroll
        for (int q = 0; q < 4; q++) {
            bool rv = (unsigned)(aa - si_[q]) <= 24u;
            if (__any((int)rv)) {
                f32x4 za = *(const f32x4u*)rpq[q];
                f32x4 zb = *(const f32x4u*)(rpq[q] + 16);
                f32x4 s0 = __builtin_amdgcn_mfma_f32_16x16x32_f16(kf0, qf[q], za, 0, 0, 0);
                f32x4 s1 = __builtin_amdgcn_mfma_f32_16x16x32_f16(kf1, qf[q], zb, 0, 0, 0);

                float p[8];
                #pragma unroll
                for (int r = 0; r < 4; r++) {
                    p[r]     = EXP2(s0[r]);
                    p[r + 4] = EXP2(s1[r]);
                }
                PkU u0, u1, u2, u3;
                u0.h = __builtin_amdgcn_cvt_pkrtz(p[0], p[1]);
                u1.h = __builtin_amdgcn_cvt_pkrtz(p[2], p[3]);
                u2.h = __builtin_amdgcn_cvt_pkrtz(p[4], p[5]);
                u3.h = __builtin_amdgcn_cvt_pkrtz(p[6], p[7]);
                // mask: invalid columns / rows -> 0h (bitwise AND in packed-f16 domain)
                union { unsigned u[2]; f16x4 v; } pa, pb;
                pa.u[0] = rv ? (u0.u & pm_[q][0]) : 0u;
                pa.u[1] = rv ? (u1.u & pm_[q][1]) : 0u;
                pb.u[0] = rv ? (u2.u & pm_[q][2]) : 0u;
                pb.u[1] = rv ? (u3.u & pm_[q][3]) : 0u;

                O[q][0] = __builtin_amdgcn_mfma_f32_16x16x16f16(pa.v, vfA0, O[q][0], 0, 0, 0);
                O[q][0] = __builtin_amdgcn_mfma_f32_16x16x16f16(pb.v, vfB0, O[q][0], 0, 0, 0);
                O[q][1] = __builtin_amdgcn_mfma_f32_16x16x16f16(pa.v, vfA1, O[q][1], 0, 0, 0);
                O[q][1] = __builtin_amdgcn_mfma_f32_16x16x16f16(pb.v, vfB1, O[q][1], 0, 0, 0);
                lacc[q] = __builtin_amdgcn_mfma_f32_16x16x16f16(pa.v, ones4, lacc[q], 0, 0, 0);
                lacc[q] = __builtin_amdgcn_mfma_f32_16x16x16f16(pb.v, ones4, lacc[q], 0, 0, 0);
            }
            rpq[q] += RPBW;
        }
        kf0 = nkf0; kf1 = nkf1;
        vfA0 = nvfA0; vfB0 = nvfB0; vfA1 = nvfA1; vfB1 = nvfB1;
        aa++;
    }

    // ---- symmetric 4-way merge: wave w ships qsets q!=w, finalizes qset w ----
    #pragma unroll
    for (int q = 0; q < 4; q++) {
        if (q != w) {
            int slot = (w < q) ? w : w - 1;           // 0..2, distinct per storer
            float* ob = &Olds[slot * 4 + q][lane][0];
            *(f32x4*)&ob[0] = O[q][0];
            *(f32x4*)&ob[4] = O[q][1];
            *(f32x4*)&ob[8] = lacc[q];
        }
    }
    __syncthreads();
    {
        const int q = w;
        f32x4 o0 = O[q][0], o1 = O[q][1], la = lacc[q];
        #pragma unroll
        for (int s = 0; s < 3; s++) {
            const float* ob = &Olds[s * 4 + q][lane][0];
            o0 += *(const f32x4*)&ob[0];
            o1 += *(const f32x4*)&ob[4];
            la += *(const f32x4*)&ob[8];
        }
        #pragma unroll
        for (int r = 0; r < 4; r++) {
            float li = 1.f / la[r];
            int ql = q * 16 + quad * 4 + r;
            int qi = i0 + (ql >> 3), qj = j0 + (ql & 7);
            size_t base = (size_t)(qi * PP + qj) * CC + h * HD;
            ao[base + nn]      = (f16)(o0[r] * li);
            ao[base + 16 + nn] = (f16)(o1[r] * li);
        }
    }
}

extern "C" void kernel_launch(void* const* d_in, const int* in_sizes, int n_in,
                              void* d_out, int out_size, void* d_ws, size_t ws_size,
                              hipStream_t stream) {
    (void)in_sizes; (void)n_in; (void)out_size; (void)ws_size;
    const float* x    = (const float*)d_in[0];
    const float* cond = (const float*)d_in[1];
    const float* mask = (const float*)d_in[2];
    const float* lw   = (const float*)d_in[3];
    const float* lb   = (const float*)d_in[4];
    const float* qw   = (const float*)d_in[5];
    const float* qb   = (const float*)d_in[6];
    const float* rpb  = (const float*)d_in[7];
    const float* pw   = (const float*)d_in[8];
    const float* pb   = (const float*)d_in[9];
    float* outp       = (float*)d_out;

    float* ws   = (float*)d_ws;
    float* qbs  = ws;                 // 384
    float* b2s  = qbs + 384;          // 384
    float* rpbp = b2s + 384;          // 10240 padded
    f16* lwh  = (f16*)(rpbp + 10240);             // 128*160
    f16* qwh  = lwh + 20480;                      // 384*128
    f16* pwh  = qwh + 49152;                      // 128*128
    f16* w2h  = pwh + 16384;                      // 384*128
    f16* yh   = w2h + 49152;                      // NN*128
    f16* qkh  = yh + (size_t)NN * 128;            // NN*256 (Q|K)
    f16* vt   = qkh + (size_t)NN * 256;           // 128*NPAD
    f16* ao   = vt + (size_t)128 * NPAD;          // NN*128  (prefetch overshoot lands in vt/ao)

    prep<<<228, 256, 0, stream>>>(lw, qw, pw, qb, pb, rpb, lwh, qwh, pwh, w2h, qbs, b2s, rpbp);
    fusion_gemm<<<dim3(352, 2), 256, 0, stream>>>(x, cond, mask, lwh, lb, yh);
    gemm_qkv<<<dim3(352, 6), 256, 0, stream>>>(yh, qwh, qbs, qkh, vt);
    attn_mfma<<<dim3(TT / 8, PP / 8, HEADS), 256, 0, stream>>>(qkh, vt, rpbp, ao);
    gemm_qkv<<<dim3(352, 6), 256, 0, stream>>>(ao, w2h, b2s, qkh, vt);   // fused proj+qkv
    attn_mfma<<<dim3(TT / 8, PP / 8, HEADS), 256, 0, stream>>>(qkh, vt, rpbp, ao);
    gemm_out<<<dim3(352, 2), 256, 0, stream>>>(ao, pwh, pb, outp);
}

// Round 3
// 628.234 us; speedup vs baseline: 1.0704x; 1.0704x over previous
//
#include <hip/hip_runtime.h>
#include <hip/hip_fp16.h>

#define TT 256
#define PP 88
#define CC 128
#define NN (TT * PP)          // 22528 positions
#define NPAD (NN + 32)
#define HEADS 4
#define HD 32
#define WIN 25
#define RPBW 49
#define RPBSZ (RPBW * RPBW)   // 2401
#define SCALE 0.17677669529663687f   // 1/sqrt(32)
#define LOG2E 1.4426950408889634f
#define QSC (SCALE * LOG2E)          // fold exp->exp2 into Q path

#if __has_builtin(__builtin_amdgcn_exp2f)
#define EXP2(x) __builtin_amdgcn_exp2f(x)
#else
#define EXP2(x) exp2f(x)
#endif

typedef _Float16 f16;
typedef f16 f16x8 __attribute__((ext_vector_type(8)));
typedef f16 f16x8u __attribute__((ext_vector_type(8), aligned(4)));
typedef f16 f16x4 __attribute__((ext_vector_type(4)));
typedef f16 f16x4u __attribute__((ext_vector_type(4), aligned(4)));
typedef float f32x4 __attribute__((ext_vector_type(4)));
typedef float f32x4u __attribute__((ext_vector_type(4), aligned(4)));
typedef __fp16 hf16x2 __attribute__((ext_vector_type(2)));
union PkU { hf16x2 h; unsigned u; };

// ---------- prep: repack (b<192) + parallel b2s (192<=b<216) + MFMA wcomb (216<=b<228) ----------
__global__ __launch_bounds__(256) void prep(
    const float* __restrict__ lw, const float* __restrict__ qw,
    const float* __restrict__ pw, const float* __restrict__ qb,
    const float* __restrict__ pb, const float* __restrict__ rpb,
    f16* __restrict__ lwh, f16* __restrict__ qwh, f16* __restrict__ pwh,
    f16* __restrict__ w2h, float* __restrict__ qbs, float* __restrict__ b2s,
    float* __restrict__ rpbp)
{
    const int b = blockIdx.x;
    if (b < 192) {
        int idx = b * 256 + threadIdx.x;              // covers 49152
        if (idx < 128 * 160) {                        // fusion W: [128][131] -> [128][160] pad
            int r = idx / 160, c = idx - r * 160;
            lwh[idx] = (f16)(c < 131 ? lw[r * 131 + c] : 0.f);
        }
        if (idx < 384 * 128) {                        // qkv W, Q rows scaled by QSC
            float v = qw[idx];
            if (idx < 128 * 128) v *= QSC;
            qwh[idx] = (f16)v;
        }
        if (idx < 128 * 128) pwh[idx] = (f16)pw[idx];
        if (idx < 384) qbs[idx] = qb[idx] * (idx < 128 ? QSC : 1.f);
        if (idx < 10240) rpbp[idx] = (idx < 4 * RPBSZ) ? rpb[idx] * LOG2E : 0.f;
    } else if (b < 216) {
        // b2s[i] = (qb[i] + qw[i,:]·pb) * sc_i ; 16 lanes per output, shuffle-reduce
        int t = (b - 192) * 256 + threadIdx.x;        // [0, 6144)
        int i = t >> 4, l = t & 15;
        if (i < 384) {
            float s = 0.f;
            #pragma unroll
            for (int j = l * 8; j < l * 8 + 8; j++) s += qw[i * 128 + j] * pb[j];
            s += __shfl_xor(s, 1); s += __shfl_xor(s, 2);
            s += __shfl_xor(s, 4); s += __shfl_xor(s, 8);
            if (l == 0) b2s[i] = (qb[i] + s) * (i < 128 ? QSC : 1.f);
        }
    } else {
        // w2h[i][k] = sc_i * sum_j qw[i][j] pw[j][k]
        const int bw = b - 216;                       // 0..11
        const int m0 = (bw & 1) * 64;                 // k-tile
        const int n0 = (bw >> 1) * 64;                // i-tile
        const int tid = threadIdx.x;
        const int w = tid >> 6, lane = tid & 63, quad = lane >> 4, nn = lane & 15;
        const int krow = m0 + w * 16 + nn;
        f16x8 af[4];
        #pragma unroll
        for (int ks = 0; ks < 4; ks++) {
            union { f16 e[8]; f16x8 v; } t;
            #pragma unroll
            for (int e = 0; e < 8; e++)
                t.e[e] = (f16)pw[(ks * 32 + quad * 8 + e) * 128 + krow];
            af[ks] = t.v;
        }
        f32x4 acc[4] = {};
        #pragma unroll
        for (int nt = 0; nt < 4; nt++) {
            int irow = n0 + nt * 16 + nn;
            #pragma unroll
            for (int ks = 0; ks < 4; ks++) {
                const float* qr = &qw[(size_t)irow * 128 + ks * 32 + quad * 8];
                float4 a = *(const float4*)qr, bq = *(const float4*)(qr + 4);
                PkU u0, u1, u2, u3;
                u0.h = __builtin_amdgcn_cvt_pkrtz(a.x, a.y);
                u1.h = __builtin_amdgcn_cvt_pkrtz(a.z, a.w);
                u2.h = __builtin_amdgcn_cvt_pkrtz(bq.x, bq.y);
                u3.h = __builtin_amdgcn_cvt_pkrtz(bq.z, bq.w);
                union { unsigned u[4]; f16x8 v; } bb;
                bb.u[0] = u0.u; bb.u[1] = u1.u; bb.u[2] = u2.u; bb.u[3] = u3.u;
                acc[nt] = __builtin_amdgcn_mfma_f32_16x16x32_f16(af[ks], bb.v, acc[nt], 0, 0, 0);
            }
        }
        #pragma unroll
        for (int nt = 0; nt < 4; nt++) {
            int i = n0 + nt * 16 + nn;
            float sc = (i < 128) ? QSC : 1.f;
            PkU p0, p1;
            p0.h = __builtin_amdgcn_cvt_pkrtz(acc[nt][0] * sc, acc[nt][1] * sc);
            p1.h = __builtin_amdgcn_cvt_pkrtz(acc[nt][2] * sc, acc[nt][3] * sc);
            *(uint2*)&w2h[(size_t)i * 128 + m0 + w * 16 + quad * 4] = make_uint2(p0.u, p1.u);
        }
    }
}

// ---------- fusion GEMM: yh = relu(cat @ lwh^T + lb); grid (352, 2) ----------
__global__ __launch_bounds__(256) void fusion_gemm(
    const float* __restrict__ x, const float* __restrict__ cond, const float* __restrict__ mask,
    const f16* __restrict__ lwh, const float* __restrict__ lb, f16* __restrict__ yh)
{
    __shared__ __align__(16) f16 Alds[64 * 168];
    const int m0 = blockIdx.x * 64, n0 = blockIdx.y * 64;
    const int tid = threadIdx.x;
    const int w = tid >> 6, lane = tid & 63, quad = lane >> 4, nn = lane & 15;

    {   // stage cat rows (f16)
        int r = tid >> 2, cpart = tid & 3;
        size_t pos = m0 + r;
        *(uint4*)&Alds[r * 168 + 128 + cpart * 8] = make_uint4(0, 0, 0, 0);
        const float* xr = x + pos * 128 + cpart * 32;
        #pragma unroll
        for (int t = 0; t < 4; t++) {
            float4 a = *(const float4*)(xr + t * 8);
            float4 b = *(const float4*)(xr + t * 8 + 4);
            PkU p0, p1, p2, p3;
            p0.h = __builtin_amdgcn_cvt_pkrtz(a.x, a.y);
            p1.h = __builtin_amdgcn_cvt_pkrtz(a.z, a.w);
            p2.h = __builtin_amdgcn_cvt_pkrtz(b.x, b.y);
            p3.h = __builtin_amdgcn_cvt_pkrtz(b.z, b.w);
            *(uint4*)&Alds[r * 168 + cpart * 32 + t * 8] = make_uint4(p0.u, p1.u, p2.u, p3.u);
        }
        if (cpart == 0) {
            Alds[r * 168 + 128] = (f16)cond[pos * 2];
            Alds[r * 168 + 129] = (f16)cond[pos * 2 + 1];
            Alds[r * 168 + 130] = (f16)mask[pos];
        }
    }
    __syncthreads();

    const int oc = n0 + w * 16 + nn;
    f16x8 af[5];
    #pragma unroll
    for (int ks = 0; ks < 5; ks++)
        af[ks] = *(const f16x8*)&lwh[(size_t)oc * 160 + ks * 32 + quad * 8];
    f32x4 acc[4] = {};
    #pragma unroll
    for (int ks = 0; ks < 5; ks++)
        #pragma unroll
        for (int nt = 0; nt < 4; nt++) {
            f16x8 bf = *(const f16x8*)&Alds[(nt * 16 + nn) * 168 + ks * 32 + quad * 8];
            acc[nt] = __builtin_amdgcn_mfma_f32_16x16x32_f16(af[ks], bf, acc[nt], 0, 0, 0);
        }
    float bv[4];
    #pragma unroll
    for (int r = 0; r < 4; r++) bv[r] = lb[n0 + w * 16 + quad * 4 + r];
    #pragma unroll
    for (int nt = 0; nt < 4; nt++) {
        int pos = m0 + nt * 16 + nn;
        PkU p0, p1;
        p0.h = __builtin_amdgcn_cvt_pkrtz(fmaxf(acc[nt][0] + bv[0], 0.f), fmaxf(acc[nt][1] + bv[1], 0.f));
        p1.h = __builtin_amdgcn_cvt_pkrtz(fmaxf(acc[nt][2] + bv[2], 0.f), fmaxf(acc[nt][3] + bv[3], 0.f));
        *(uint2*)&yh[(size_t)pos * 128 + n0 + w * 16 + quad * 4] = make_uint2(p0.u, p1.u);
    }
}

// ---------- qkv GEMM: grid (352, 6); Q|K rows stride 256, V transposed ----------
__global__ __launch_bounds__(256) void gemm_qkv(
    const f16* __restrict__ A, const f16* __restrict__ W, const float* __restrict__ bias,
    f16* __restrict__ qkh, f16* __restrict__ vt)
{
    __shared__ __align__(16) f16 Alds[64 * 136];
    const int m0 = blockIdx.x * 64, n0 = blockIdx.y * 64;
    const int tid = threadIdx.x;
    const int w = tid >> 6, lane = tid & 63, quad = lane >> 4, nn = lane & 15;

    for (int i = tid; i < 1024; i += 256) {
        int r = i >> 4, c = i & 15;
        *(uint4*)&Alds[r * 136 + c * 8] = *(const uint4*)&A[(size_t)(m0 + r) * 128 + c * 8];
    }
    __syncthreads();

    const int oc = n0 + w * 16 + nn;
    f16x8 af[4];
    #pragma unroll
    for (int ks = 0; ks < 4; ks++)
        af[ks] = *(const f16x8*)&W[(size_t)oc * 128 + ks * 32 + quad * 8];
    f32x4 acc[4] = {};
    #pragma unroll
    for (int ks = 0; ks < 4; ks++)
        #pragma unroll
        for (int nt = 0; nt < 4; nt++) {
            f16x8 bf = *(const f16x8*)&Alds[(nt * 16 + nn) * 136 + ks * 32 + quad * 8];
            acc[nt] = __builtin_amdgcn_mfma_f32_16x16x32_f16(af[ks], bf, acc[nt], 0, 0, 0);
        }
    float bv[4];
    #pragma unroll
    for (int r = 0; r < 4; r++) bv[r] = bias[n0 + w * 16 + quad * 4 + r];

    if (n0 < 256) {
        #pragma unroll
        for (int nt = 0; nt < 4; nt++) {
            int pos = m0 + nt * 16 + nn;
            PkU p0, p1;
            p0.h = __builtin_amdgcn_cvt_pkrtz(acc[nt][0] + bv[0], acc[nt][1] + bv[1]);
            p1.h = __builtin_amdgcn_cvt_pkrtz(acc[nt][2] + bv[2], acc[nt][3] + bv[3]);
            *(uint2*)&qkh[(size_t)pos * 256 + n0 + w * 16 + quad * 4] = make_uint2(p0.u, p1.u);
        }
    } else {
        #pragma unroll
        for (int nt = 0; nt < 4; nt++) {
            int pos = m0 + nt * 16 + nn;
            #pragma unroll
            for (int r = 0; r < 4; r++) {
                int chg = n0 - 256 + w * 16 + quad * 4 + r;
                vt[(size_t)chg * NPAD + pos] = (f16)(acc[nt][r] + bv[r]);
            }
        }
    }
}

// ---------- final projection: grid (352, 2), fp32 out ----------
__global__ __launch_bounds__(256) void gemm_out(
    const f16* __restrict__ A, const f16* __restrict__ W, const float* __restrict__ bias,
    float* __restrict__ outp)
{
    __shared__ __align__(16) f16 Alds[64 * 136];
    const int m0 = blockIdx.x * 64, n0 = blockIdx.y * 64;
    const int tid = threadIdx.x;
    const int w = tid >> 6, lane = tid & 63, quad = lane >> 4, nn = lane & 15;

    for (int i = tid; i < 1024; i += 256) {
        int r = i >> 4, c = i & 15;
        *(uint4*)&Alds[r * 136 + c * 8] = *(const uint4*)&A[(size_t)(m0 + r) * 128 + c * 8];
    }
    __syncthreads();

    const int oc = n0 + w * 16 + nn;
    f16x8 af[4];
    #pragma unroll
    for (int ks = 0; ks < 4; ks++)
        af[ks] = *(const f16x8*)&W[(size_t)oc * 128 + ks * 32 + quad * 8];
    f32x4 acc[4] = {};
    #pragma unroll
    for (int ks = 0; ks < 4; ks++)
        #pragma unroll
        for (int nt = 0; nt < 4; nt++) {
            f16x8 bf = *(const f16x8*)&Alds[(nt * 16 + nn) * 136 + ks * 32 + quad * 8];
            acc[nt] = __builtin_amdgcn_mfma_f32_16x16x32_f16(af[ks], bf, acc[nt], 0, 0, 0);
        }
    float bv[4];
    #pragma unroll
    for (int r = 0; r < 4; r++) bv[r] = bias[n0 + w * 16 + quad * 4 + r];
    #pragma unroll
    for (int nt = 0; nt < 4; nt++) {
        int pos = m0 + nt * 16 + nn;
        f32x4 vv;
        #pragma unroll
        for (int r = 0; r < 4; r++) vv[r] = acc[nt][r] + bv[r];
        *(f32x4*)&outp[(size_t)pos * 128 + n0 + w * 16 + quad * 4] = vv;
    }
}

// ---------- MFMA neighborhood attention v4: key-row wave split, register PV ----------
// Wave w owns key rows [ri0 + w*8, +8) and processes ALL 4 qsets per row
// (K/V/rpb loads amortized 4x). PV uses v_mfma_f32_16x16x16f16 whose A-fragment
// layout (4 consecutive K-elems per quad) matches the S-MFMA C/D layout exactly,
// so packed exp2 probabilities feed PV in registers - no LDS in the main loop.
// v3 post-mortem: epilogue indexed O[w] with RUNTIME w -> entire accumulator
// array spilled to scratch (566 MB WRITE_SIZE, 285 us). v4: all register-array
// accesses are compile-time-indexed (unrolled q-loop + uniform `q == w` guard).
__global__ __launch_bounds__(256, 3) void attn_mfma(
    const f16* __restrict__ qkh,   // [N][256] = Q|K, Q pre-scaled by QSC
    const f16* __restrict__ vt,    // [128][NPAD]
    const float* __restrict__ rpbp,
    f16* __restrict__ ao)          // [N][128]
{
    const int i0 = blockIdx.x * 8;
    const int j0 = blockIdx.y * 8;
    const int h  = blockIdx.z;
    const int tid = threadIdx.x;
    const int w = tid >> 6, lane = tid & 63;
    const int quad = lane >> 4, nn = lane & 15;

    const int ri0 = min(max(i0 - 12, 0), TT - 32);
    const int rj0 = min(max(j0 - 12, 0), PP - WIN) & ~1;

    __shared__ __align__(16) float Olds[12][64][12];   // [slot*4+qset][lane][8 O + 4 lacc]

    int si_[4];
    unsigned pm_[4][4];            // packed-f16 column masks per output word
    f16x8 qf[4];
    const float* rpq[4];
    const float* rp_h = rpbp + h * RPBSZ;
    const int aa0 = ri0 + w * 8;   // this wave's first key row

    #pragma unroll
    for (int q = 0; q < 4; q++) {
        int ql = q * 16 + nn;
        int qi = i0 + (ql >> 3), qj = j0 + (ql & 7);
        int si = min(max(qi - 12, 0), TT - WIN);
        int sj = min(max(qj - 12, 0), PP - WIN);
        si_[q] = si;
        unsigned cm = 0x1FFFFFFu << (sj - rj0);       // shift <= 7
        #pragma unroll
        for (int t = 0; t < 4; t++) {
            int k0 = (t >> 1) * 16 + quad * 4 + (t & 1) * 2;
            pm_[q][t] = (((cm >> k0) & 1u) ? 0xFFFFu : 0u)
                      | (((cm >> (k0 + 1)) & 1u) ? 0xFFFF0000u : 0u);
        }
        qf[q] = *(const f16x8*)&qkh[(size_t)(qi * PP + qj) * 256 + h * HD + quad * 8];
        rpq[q] = rp_h + (aa0 - qi + 24) * RPBW + (rj0 - qj + 24) + quad * 4;
    }

    const f16* vbase = vt + (size_t)(h * HD + nn) * NPAD;
    const int b0 = min(rj0 + nn, PP - 1);
    const int b1 = min(rj0 + 16 + nn, PP - 1);
    const size_t koff = 128 + h * HD + quad * 8;
    const f16x4 ones4 = {(f16)1.f, (f16)1.f, (f16)1.f, (f16)1.f};

    f32x4 O[4][2] = {};            // [qset][ch-half]; regs = queries, lane nn = channel
    f32x4 lacc[4] = {};

    // prologue: load row aa0
    int aa = aa0;
    const f16* rowK = qkh + (size_t)aa * PP * 256 + koff;
    f16x8 kf0 = *(const f16x8*)(rowK + (size_t)b0 * 256);
    f16x8 kf1 = *(const f16x8*)(rowK + (size_t)b1 * 256);
    const f16* vrow = vbase + aa * PP + rj0 + quad * 4;
    f16x4 vfA0 = *(const f16x4u*)vrow;                      // keys  0-15, ch lo
    f16x4 vfB0 = *(const f16x4u*)(vrow + 16);               // keys 16-31, ch lo
    f16x4 vfA1 = *(const f16x4u*)(vrow + (size_t)16 * NPAD);
    f16x4 vfB1 = *(const f16x4u*)(vrow + (size_t)16 * NPAD + 16);

    for (int c = 0; c < 8; c++) {
        // prefetch row aa+1 (last iteration overshoots into vt/ao workspace: in-bounds, unused)
        const f16* rowKn = qkh + (size_t)(aa + 1) * PP * 256 + koff;
        f16x8 nkf0 = *(const f16x8*)(rowKn + (size_t)b0 * 256);
        f16x8 nkf1 = *(const f16x8*)(rowKn + (size_t)b1 * 256);
        const f16* vrown = vbase + (aa + 1) * PP + rj0 + quad * 4;
        f16x4 nvfA0 = *(const f16x4u*)vrown;
        f16x4 nvfB0 = *(const f16x4u*)(vrown + 16);
        f16x4 nvfA1 = *(const f16x4u*)(vrown + (size_t)16 * NPAD);
        f16x4 nvfB1 = *(const f16x4u*)(vrown + (size_t)16 * NPAD + 16);

        #pragma unroll
        for (int q = 0; q < 4; q++) {
            bool rv = (unsigned)(aa - si_[q]) <= 24u;
            if (__any((int)rv)) {
                f32x4 za = *(const f32x4u*)rpq[q];
                f32x4 zb = *(const f32x4u*)(rpq[q] + 16);
                f32x4 s0 = __builtin_amdgcn_mfma_f32_16x16x32_f16(kf0, qf[q], za, 0, 0, 0);
                f32x4 s1 = __builtin_amdgcn_mfma_f32_16x16x32_f16(kf1, qf[q], zb, 0, 0, 0);

                float p[8];
                #pragma unroll
                for (int r = 0; r < 4; r++) {
                    p[r]     = EXP2(s0[r]);
                    p[r + 4] = EXP2(s1[r]);
                }
                PkU u0, u1, u2, u3;
                u0.h = __builtin_amdgcn_cvt_pkrtz(p[0], p[1]);
                u1.h = __builtin_amdgcn_cvt_pkrtz(p[2], p[3]);
                u2.h = __builtin_amdgcn_cvt_pkrtz(p[4], p[5]);
                u3.h = __builtin_amdgcn_cvt_pkrtz(p[6], p[7]);
                // mask: invalid columns / rows -> 0h (bitwise AND in packed-f16 domain)
                union { unsigned u[2]; f16x4 v; } pa, pb;
                pa.u[0] = rv ? (u0.u & pm_[q][0]) : 0u;
                pa.u[1] = rv ? (u1.u & pm_[q][1]) : 0u;
                pb.u[0] = rv ? (u2.u & pm_[q][2]) : 0u;
                pb.u[1] = rv ? (u3.u & pm_[q][3]) : 0u;

                O[q][0] = __builtin_amdgcn_mfma_f32_16x16x16f16(pa.v, vfA0, O[q][0], 0, 0, 0);
                O[q][0] = __builtin_amdgcn_mfma_f32_16x16x16f16(pb.v, vfB0, O[q][0], 0, 0, 0);
                O[q][1] = __builtin_amdgcn_mfma_f32_16x16x16f16(pa.v, vfA1, O[q][1], 0, 0, 0);
                O[q][1] = __builtin_amdgcn_mfma_f32_16x16x16f16(pb.v, vfB1, O[q][1], 0, 0, 0);
                lacc[q] = __builtin_amdgcn_mfma_f32_16x16x16f16(pa.v, ones4, lacc[q], 0, 0, 0);
                lacc[q] = __builtin_amdgcn_mfma_f32_16x16x16f16(pb.v, ones4, lacc[q], 0, 0, 0);
            }
            rpq[q] += RPBW;
        }
        kf0 = nkf0; kf1 = nkf1;
        vfA0 = nvfA0; vfB0 = nvfB0; vfA1 = nvfA1; vfB1 = nvfB1;
        aa++;
    }

    // ---- symmetric 4-way merge: wave w ships qsets q!=w, finalizes qset w ----
    // ALL register-array indices compile-time (v3 spilled via runtime O[w]).
    #pragma unroll
    for (int q = 0; q < 4; q++) {
        if (q != w) {
            int slot = (w < q) ? w : w - 1;           // 0..2, distinct per storer
            float* ob = &Olds[slot * 4 + q][lane][0];
            *(f32x4*)&ob[0] = O[q][0];
            *(f32x4*)&ob[4] = O[q][1];
            *(f32x4*)&ob[8] = lacc[q];
        }
    }
    __syncthreads();
    #pragma unroll
    for (int q = 0; q < 4; q++) {
        if (q == w) {                                 // wave-uniform; q stays constant
            f32x4 o0 = O[q][0], o1 = O[q][1], la = lacc[q];
            #pragma unroll
            for (int s = 0; s < 3; s++) {
                const float* ob = &Olds[s * 4 + q][lane][0];
                o0 += *(const f32x4*)&ob[0];
                o1 += *(const f32x4*)&ob[4];
                la += *(const f32x4*)&ob[8];
            }
            #pragma unroll
            for (int r = 0; r < 4; r++) {
                float li = 1.f / la[r];
                int ql = q * 16 + quad * 4 + r;
                int qi = i0 + (ql >> 3), qj = j0 + (ql & 7);
                size_t base = (size_t)(qi * PP + qj) * CC + h * HD;
                ao[base + nn]      = (f16)(o0[r] * li);
                ao[base + 16 + nn] = (f16)(o1[r] * li);
            }
        }
    }
}

extern "C" void kernel_launch(void* const* d_in, const int* in_sizes, int n_in,
                              void* d_out, int out_size, void* d_ws, size_t ws_size,
                              hipStream_t stream) {
    (void)in_sizes; (void)n_in; (void)out_size; (void)ws_size;
    const float* x    = (const float*)d_in[0];
    const float* cond = (const float*)d_in[1];
    const float* mask = (const float*)d_in[2];
    const float* lw   = (const float*)d_in[3];
    const float* lb   = (const float*)d_in[4];
    const float* qw   = (const float*)d_in[5];
    const float* qb   = (const float*)d_in[6];
    const float* rpb  = (const float*)d_in[7];
    const float* pw   = (const float*)d_in[8];
    const float* pb   = (const float*)d_in[9];
    float* outp       = (float*)d_out;

    float* ws   = (float*)d_ws;
    float* qbs  = ws;                 // 384
    float* b2s  = qbs + 384;          // 384
    float* rpbp = b2s + 384;          // 10240 padded
    f16* lwh  = (f16*)(rpbp + 10240);             // 128*160
    f16* qwh  = lwh + 20480;                      // 384*128
    f16* pwh  = qwh + 49152;                      // 128*128
    f16* w2h  = pwh + 16384;                      // 384*128
    f16* yh   = w2h + 49152;                      // NN*128
    f16* qkh  = yh + (size_t)NN * 128;            // NN*256 (Q|K)
    f16* vt   = qkh + (size_t)NN * 256;           // 128*NPAD
    f16* ao   = vt + (size_t)128 * NPAD;          // NN*128  (prefetch overshoot lands in vt/ao)

    prep<<<228, 256, 0, stream>>>(lw, qw, pw, qb, pb, rpb, lwh, qwh, pwh, w2h, qbs, b2s, rpbp);
    fusion_gemm<<<dim3(352, 2), 256, 0, stream>>>(x, cond, mask, lwh, lb, yh);
    gemm_qkv<<<dim3(352, 6), 256, 0, stream>>>(yh, qwh, qbs, qkh, vt);
    attn_mfma<<<dim3(TT / 8, PP / 8, HEADS), 256, 0, stream>>>(qkh, vt, rpbp, ao);
    gemm_qkv<<<dim3(352, 6), 256, 0, stream>>>(ao, w2h, b2s, qkh, vt);   // fused proj+qkv
    attn_mfma<<<dim3(TT / 8, PP / 8, HEADS), 256, 0, stream>>>(qkh, vt, rpbp, ao);
    gemm_out<<<dim3(352, 2), 256, 0, stream>>>(ao, pwh, pb, outp);
}

// Round 4
// 261.815 us; speedup vs baseline: 2.5685x; 2.3995x over previous
//
#include <hip/hip_runtime.h>
#include <hip/hip_fp16.h>

#define TT 256
#define PP 88
#define CC 128
#define NN (TT * PP)          // 22528 positions
#define NPAD (NN + 32)
#define HEADS 4
#define HD 32
#define WIN 25
#define RPBW 49
#define RPBSZ (RPBW * RPBW)   // 2401
#define SCALE 0.17677669529663687f   // 1/sqrt(32)
#define LOG2E 1.4426950408889634f
#define QSC (SCALE * LOG2E)          // fold exp->exp2 into Q path

#if __has_builtin(__builtin_amdgcn_exp2f)
#define EXP2(x) __builtin_amdgcn_exp2f(x)
#else
#define EXP2(x) exp2f(x)
#endif

typedef _Float16 f16;
typedef f16 f16x8 __attribute__((ext_vector_type(8)));
typedef f16 f16x8u __attribute__((ext_vector_type(8), aligned(4)));
typedef f16 f16x4 __attribute__((ext_vector_type(4)));
typedef f16 f16x4u __attribute__((ext_vector_type(4), aligned(4)));
typedef float f32x4 __attribute__((ext_vector_type(4)));
typedef float f32x4u __attribute__((ext_vector_type(4), aligned(4)));
typedef __fp16 hf16x2 __attribute__((ext_vector_type(2)));
union PkU { hf16x2 h; unsigned u; };

// ---------- prep: repack (b<192) + parallel b2s (192<=b<216) + MFMA wcomb (216<=b<228) ----------
__global__ __launch_bounds__(256) void prep(
    const float* __restrict__ lw, const float* __restrict__ qw,
    const float* __restrict__ pw, const float* __restrict__ qb,
    const float* __restrict__ pb, const float* __restrict__ rpb,
    f16* __restrict__ lwh, f16* __restrict__ qwh, f16* __restrict__ pwh,
    f16* __restrict__ w2h, float* __restrict__ qbs, float* __restrict__ b2s,
    float* __restrict__ rpbp)
{
    const int b = blockIdx.x;
    if (b < 192) {
        int idx = b * 256 + threadIdx.x;              // covers 49152
        if (idx < 128 * 160) {                        // fusion W: [128][131] -> [128][160] pad
            int r = idx / 160, c = idx - r * 160;
            lwh[idx] = (f16)(c < 131 ? lw[r * 131 + c] : 0.f);
        }
        if (idx < 384 * 128) {                        // qkv W, Q rows scaled by QSC
            float v = qw[idx];
            if (idx < 128 * 128) v *= QSC;
            qwh[idx] = (f16)v;
        }
        if (idx < 128 * 128) pwh[idx] = (f16)pw[idx];
        if (idx < 384) qbs[idx] = qb[idx] * (idx < 128 ? QSC : 1.f);
        if (idx < 10240) rpbp[idx] = (idx < 4 * RPBSZ) ? rpb[idx] * LOG2E : 0.f;
    } else if (b < 216) {
        // b2s[i] = (qb[i] + qw[i,:]·pb) * sc_i ; 16 lanes per output, shuffle-reduce
        int t = (b - 192) * 256 + threadIdx.x;        // [0, 6144)
        int i = t >> 4, l = t & 15;
        if (i < 384) {
            float s = 0.f;
            #pragma unroll
            for (int j = l * 8; j < l * 8 + 8; j++) s += qw[i * 128 + j] * pb[j];
            s += __shfl_xor(s, 1); s += __shfl_xor(s, 2);
            s += __shfl_xor(s, 4); s += __shfl_xor(s, 8);
            if (l == 0) b2s[i] = (qb[i] + s) * (i < 128 ? QSC : 1.f);
        }
    } else {
        // w2h[i][k] = sc_i * sum_j qw[i][j] pw[j][k]
        const int bw = b - 216;                       // 0..11
        const int m0 = (bw & 1) * 64;                 // k-tile
        const int n0 = (bw >> 1) * 64;                // i-tile
        const int tid = threadIdx.x;
        const int w = tid >> 6, lane = tid & 63, quad = lane >> 4, nn = lane & 15;
        const int krow = m0 + w * 16 + nn;
        f16x8 af[4];
        #pragma unroll
        for (int ks = 0; ks < 4; ks++) {
            union { f16 e[8]; f16x8 v; } t;
            #pragma unroll
            for (int e = 0; e < 8; e++)
                t.e[e] = (f16)pw[(ks * 32 + quad * 8 + e) * 128 + krow];
            af[ks] = t.v;
        }
        f32x4 acc[4] = {};
        #pragma unroll
        for (int nt = 0; nt < 4; nt++) {
            int irow = n0 + nt * 16 + nn;
            #pragma unroll
            for (int ks = 0; ks < 4; ks++) {
                const float* qr = &qw[(size_t)irow * 128 + ks * 32 + quad * 8];
                float4 a = *(const float4*)qr, bq = *(const float4*)(qr + 4);
                PkU u0, u1, u2, u3;
                u0.h = __builtin_amdgcn_cvt_pkrtz(a.x, a.y);
                u1.h = __builtin_amdgcn_cvt_pkrtz(a.z, a.w);
                u2.h = __builtin_amdgcn_cvt_pkrtz(bq.x, bq.y);
                u3.h = __builtin_amdgcn_cvt_pkrtz(bq.z, bq.w);
                union { unsigned u[4]; f16x8 v; } bb;
                bb.u[0] = u0.u; bb.u[1] = u1.u; bb.u[2] = u2.u; bb.u[3] = u3.u;
                acc[nt] = __builtin_amdgcn_mfma_f32_16x16x32_f16(af[ks], bb.v, acc[nt], 0, 0, 0);
            }
        }
        #pragma unroll
        for (int nt = 0; nt < 4; nt++) {
            int i = n0 + nt * 16 + nn;
            float sc = (i < 128) ? QSC : 1.f;
            PkU p0, p1;
            p0.h = __builtin_amdgcn_cvt_pkrtz(acc[nt][0] * sc, acc[nt][1] * sc);
            p1.h = __builtin_amdgcn_cvt_pkrtz(acc[nt][2] * sc, acc[nt][3] * sc);
            *(uint2*)&w2h[(size_t)i * 128 + m0 + w * 16 + quad * 4] = make_uint2(p0.u, p1.u);
        }
    }
}

// ---------- fusion GEMM: yh = relu(cat @ lwh^T + lb); grid (352, 2) ----------
__global__ __launch_bounds__(256) void fusion_gemm(
    const float* __restrict__ x, const float* __restrict__ cond, const float* __restrict__ mask,
    const f16* __restrict__ lwh, const float* __restrict__ lb, f16* __restrict__ yh)
{
    __shared__ __align__(16) f16 Alds[64 * 168];
    const int m0 = blockIdx.x * 64, n0 = blockIdx.y * 64;
    const int tid = threadIdx.x;
    const int w = tid >> 6, lane = tid & 63, quad = lane >> 4, nn = lane & 15;

    {   // stage cat rows (f16)
        int r = tid >> 2, cpart = tid & 3;
        size_t pos = m0 + r;
        *(uint4*)&Alds[r * 168 + 128 + cpart * 8] = make_uint4(0, 0, 0, 0);
        const float* xr = x + pos * 128 + cpart * 32;
        #pragma unroll
        for (int t = 0; t < 4; t++) {
            float4 a = *(const float4*)(xr + t * 8);
            float4 b = *(const float4*)(xr + t * 8 + 4);
            PkU p0, p1, p2, p3;
            p0.h = __builtin_amdgcn_cvt_pkrtz(a.x, a.y);
            p1.h = __builtin_amdgcn_cvt_pkrtz(a.z, a.w);
            p2.h = __builtin_amdgcn_cvt_pkrtz(b.x, b.y);
            p3.h = __builtin_amdgcn_cvt_pkrtz(b.z, b.w);
            *(uint4*)&Alds[r * 168 + cpart * 32 + t * 8] = make_uint4(p0.u, p1.u, p2.u, p3.u);
        }
        if (cpart == 0) {
            Alds[r * 168 + 128] = (f16)cond[pos * 2];
            Alds[r * 168 + 129] = (f16)cond[pos * 2 + 1];
            Alds[r * 168 + 130] = (f16)mask[pos];
        }
    }
    __syncthreads();

    const int oc = n0 + w * 16 + nn;
    f16x8 af[5];
    #pragma unroll
    for (int ks = 0; ks < 5; ks++)
        af[ks] = *(const f16x8*)&lwh[(size_t)oc * 160 + ks * 32 + quad * 8];
    f32x4 acc[4] = {};
    #pragma unroll
    for (int ks = 0; ks < 5; ks++)
        #pragma unroll
        for (int nt = 0; nt < 4; nt++) {
            f16x8 bf = *(const f16x8*)&Alds[(nt * 16 + nn) * 168 + ks * 32 + quad * 8];
            acc[nt] = __builtin_amdgcn_mfma_f32_16x16x32_f16(af[ks], bf, acc[nt], 0, 0, 0);
        }
    float bv[4];
    #pragma unroll
    for (int r = 0; r < 4; r++) bv[r] = lb[n0 + w * 16 + quad * 4 + r];
    #pragma unroll
    for (int nt = 0; nt < 4; nt++) {
        int pos = m0 + nt * 16 + nn;
        PkU p0, p1;
        p0.h = __builtin_amdgcn_cvt_pkrtz(fmaxf(acc[nt][0] + bv[0], 0.f), fmaxf(acc[nt][1] + bv[1], 0.f));
        p1.h = __builtin_amdgcn_cvt_pkrtz(fmaxf(acc[nt][2] + bv[2], 0.f), fmaxf(acc[nt][3] + bv[3], 0.f));
        *(uint2*)&yh[(size_t)pos * 128 + n0 + w * 16 + quad * 4] = make_uint2(p0.u, p1.u);
    }
}

// ---------- qkv GEMM: grid (352, 6); Q|K rows stride 256, V transposed ----------
__global__ __launch_bounds__(256) void gemm_qkv(
    const f16* __restrict__ A, const f16* __restrict__ W, const float* __restrict__ bias,
    f16* __restrict__ qkh, f16* __restrict__ vt)
{
    __shared__ __align__(16) f16 Alds[64 * 136];
    const int m0 = blockIdx.x * 64, n0 = blockIdx.y * 64;
    const int tid = threadIdx.x;
    const int w = tid >> 6, lane = tid & 63, quad = lane >> 4, nn = lane & 15;

    for (int i = tid; i < 1024; i += 256) {
        int r = i >> 4, c = i & 15;
        *(uint4*)&Alds[r * 136 + c * 8] = *(const uint4*)&A[(size_t)(m0 + r) * 128 + c * 8];
    }
    __syncthreads();

    const int oc = n0 + w * 16 + nn;
    f16x8 af[4];
    #pragma unroll
    for (int ks = 0; ks < 4; ks++)
        af[ks] = *(const f16x8*)&W[(size_t)oc * 128 + ks * 32 + quad * 8];
    f32x4 acc[4] = {};
    #pragma unroll
    for (int ks = 0; ks < 4; ks++)
        #pragma unroll
        for (int nt = 0; nt < 4; nt++) {
            f16x8 bf = *(const f16x8*)&Alds[(nt * 16 + nn) * 136 + ks * 32 + quad * 8];
            acc[nt] = __builtin_amdgcn_mfma_f32_16x16x32_f16(af[ks], bf, acc[nt], 0, 0, 0);
        }
    float bv[4];
    #pragma unroll
    for (int r = 0; r < 4; r++) bv[r] = bias[n0 + w * 16 + quad * 4 + r];

    if (n0 < 256) {
        #pragma unroll
        for (int nt = 0; nt < 4; nt++) {
            int pos = m0 + nt * 16 + nn;
            PkU p0, p1;
            p0.h = __builtin_amdgcn_cvt_pkrtz(acc[nt][0] + bv[0], acc[nt][1] + bv[1]);
            p1.h = __builtin_amdgcn_cvt_pkrtz(acc[nt][2] + bv[2], acc[nt][3] + bv[3]);
            *(uint2*)&qkh[(size_t)pos * 256 + n0 + w * 16 + quad * 4] = make_uint2(p0.u, p1.u);
        }
    } else {
        #pragma unroll
        for (int nt = 0; nt < 4; nt++) {
            int pos = m0 + nt * 16 + nn;
            #pragma unroll
            for (int r = 0; r < 4; r++) {
                int chg = n0 - 256 + w * 16 + quad * 4 + r;
                vt[(size_t)chg * NPAD + pos] = (f16)(acc[nt][r] + bv[r]);
            }
        }
    }
}

// ---------- final projection: grid (352, 2), fp32 out ----------
__global__ __launch_bounds__(256) void gemm_out(
    const f16* __restrict__ A, const f16* __restrict__ W, const float* __restrict__ bias,
    float* __restrict__ outp)
{
    __shared__ __align__(16) f16 Alds[64 * 136];
    const int m0 = blockIdx.x * 64, n0 = blockIdx.y * 64;
    const int tid = threadIdx.x;
    const int w = tid >> 6, lane = tid & 63, quad = lane >> 4, nn = lane & 15;

    for (int i = tid; i < 1024; i += 256) {
        int r = i >> 4, c = i & 15;
        *(uint4*)&Alds[r * 136 + c * 8] = *(const uint4*)&A[(size_t)(m0 + r) * 128 + c * 8];
    }
    __syncthreads();

    const int oc = n0 + w * 16 + nn;
    f16x8 af[4];
    #pragma unroll
    for (int ks = 0; ks < 4; ks++)
        af[ks] = *(const f16x8*)&W[(size_t)oc * 128 + ks * 32 + quad * 8];
    f32x4 acc[4] = {};
    #pragma unroll
    for (int ks = 0; ks < 4; ks++)
        #pragma unroll
        for (int nt = 0; nt < 4; nt++) {
            f16x8 bf = *(const f16x8*)&Alds[(nt * 16 + nn) * 136 + ks * 32 + quad * 8];
            acc[nt] = __builtin_amdgcn_mfma_f32_16x16x32_f16(af[ks], bf, acc[nt], 0, 0, 0);
        }
    float bv[4];
    #pragma unroll
    for (int r = 0; r < 4; r++) bv[r] = bias[n0 + w * 16 + quad * 4 + r];
    #pragma unroll
    for (int nt = 0; nt < 4; nt++) {
        int pos = m0 + nt * 16 + nn;
        f32x4 vv;
        #pragma unroll
        for (int r = 0; r < 4; r++) vv[r] = acc[nt][r] + bv[r];
        *(f32x4*)&outp[(size_t)pos * 128 + n0 + w * 16 + quad * 4] = vv;
    }
}

// ---------- MFMA neighborhood attention v5: v1 shape + register-direct PV ----------
// 128 threads, 2 waves; wave w owns key rows [ri0+w*16, +16), ALL 4 qsets per row
// (4x K/V/rpb amortization, the proven 55us v1 decomposition). The one change vs
// v1: PV uses v_mfma_f32_16x16x16f16 whose A-fragment layout (4 consecutive
// K-elems per quad) matches the S-MFMA C/D layout exactly, so packed exp2
// probabilities feed PV directly in registers - the per-qset serial LDS
// round-trip (pack -> ds_write -> ds_read -> PV, ~130cy) is deleted.
// NO __launch_bounds__ minimum: v3/v4's (256,3) put the ~165-reg live set right
// at the 170-reg cap and the allocator dumped the accumulators to scratch
// (387 MB WRITE_SIZE). Default cap leaves headroom; v1 shape compiled to 84.
// Merge LDS re-strided to [64][60]: lane stride 60 dwords -> bank starts step
// 28 mod 32 -> 2 lanes/bank on b128 = conflict-free (kills v1's 2.77M conflicts).
__global__ __launch_bounds__(128) void attn_mfma(
    const f16* __restrict__ qkh,   // [N][256] = Q|K, Q pre-scaled by QSC
    const f16* __restrict__ vt,    // [128][NPAD]
    const float* __restrict__ rpbp,
    f16* __restrict__ ao)          // [N][128]
{
    const int i0 = blockIdx.x * 8;
    const int j0 = blockIdx.y * 8;
    const int h  = blockIdx.z;
    const int tid = threadIdx.x;
    const int w = tid >> 6, lane = tid & 63;
    const int quad = lane >> 4, nn = lane & 15;

    const int ri0 = min(max(i0 - 12, 0), TT - 32);
    const int rj0 = min(max(j0 - 12, 0), PP - WIN) & ~1;

    __shared__ __align__(16) float Olds[64][60];   // wave-1 partials, conflict-free stride

    int si_[4];
    unsigned pm_[4][4];            // packed-f16 column masks per output word
    f16x8 qf[4];
    const float* rpq[4];
    const float* rp_h = rpbp + h * RPBSZ;
    const int aa0 = ri0 + w * 16;  // this wave's first key row

    #pragma unroll
    for (int q = 0; q < 4; q++) {
        int ql = q * 16 + nn;
        int qi = i0 + (ql >> 3), qj = j0 + (ql & 7);
        int si = min(max(qi - 12, 0), TT - WIN);
        int sj = min(max(qj - 12, 0), PP - WIN);
        si_[q] = si;
        unsigned cm = 0x1FFFFFFu << (sj - rj0);       // shift <= 7
        #pragma unroll
        for (int t = 0; t < 4; t++) {
            int k0 = (t >> 1) * 16 + quad * 4 + (t & 1) * 2;
            pm_[q][t] = (((cm >> k0) & 1u) ? 0xFFFFu : 0u)
                      | (((cm >> (k0 + 1)) & 1u) ? 0xFFFF0000u : 0u);
        }
        qf[q] = *(const f16x8*)&qkh[(size_t)(qi * PP + qj) * 256 + h * HD + quad * 8];
        rpq[q] = rp_h + (aa0 - qi + 24) * RPBW + (rj0 - qj + 24) + quad * 4;
    }

    const f16* vbase = vt + (size_t)(h * HD + nn) * NPAD;
    const int b0 = min(rj0 + nn, PP - 1);
    const int b1 = min(rj0 + 16 + nn, PP - 1);
    const size_t koff = 128 + h * HD + quad * 8;
    const f16x4 ones4 = {(f16)1.f, (f16)1.f, (f16)1.f, (f16)1.f};

    f32x4 O[4][2] = {};            // [qset][ch-half]; regs = queries, lane nn = channel
    f32x4 lacc[4] = {};

    // prologue: load row aa0
    int aa = aa0;
    const f16* rowK = qkh + (size_t)aa * PP * 256 + koff;
    f16x8 kf0 = *(const f16x8*)(rowK + (size_t)b0 * 256);
    f16x8 kf1 = *(const f16x8*)(rowK + (size_t)b1 * 256);
    const f16* vrow = vbase + aa * PP + rj0 + quad * 4;
    f16x4 vfA0 = *(const f16x4u*)vrow;                      // keys  0-15, ch lo
    f16x4 vfB0 = *(const f16x4u*)(vrow + 16);               // keys 16-31, ch lo
    f16x4 vfA1 = *(const f16x4u*)(vrow + (size_t)16 * NPAD);
    f16x4 vfB1 = *(const f16x4u*)(vrow + (size_t)16 * NPAD + 16);

    for (int c = 0; c < 16; c++) {
        // prefetch row aa+1 (last iteration overshoots into vt/ao workspace: in-bounds, unused)
        const f16* rowKn = qkh + (size_t)(aa + 1) * PP * 256 + koff;
        f16x8 nkf0 = *(const f16x8*)(rowKn + (size_t)b0 * 256);
        f16x8 nkf1 = *(const f16x8*)(rowKn + (size_t)b1 * 256);
        const f16* vrown = vbase + (aa + 1) * PP + rj0 + quad * 4;
        f16x4 nvfA0 = *(const f16x4u*)vrown;
        f16x4 nvfB0 = *(const f16x4u*)(vrown + 16);
        f16x4 nvfA1 = *(const f16x4u*)(vrown + (size_t)16 * NPAD);
        f16x4 nvfB1 = *(const f16x4u*)(vrown + (size_t)16 * NPAD + 16);

        #pragma unroll
        for (int q = 0; q < 4; q++) {
            bool rv = (unsigned)(aa - si_[q]) <= 24u;
            if (__any((int)rv)) {
                f32x4 za = *(const f32x4u*)rpq[q];
                f32x4 zb = *(const f32x4u*)(rpq[q] + 16);
                f32x4 s0 = __builtin_amdgcn_mfma_f32_16x16x32_f16(kf0, qf[q], za, 0, 0, 0);
                f32x4 s1 = __builtin_amdgcn_mfma_f32_16x16x32_f16(kf1, qf[q], zb, 0, 0, 0);

                float p[8];
                #pragma unroll
                for (int r = 0; r < 4; r++) {
                    p[r]     = EXP2(s0[r]);
                    p[r + 4] = EXP2(s1[r]);
                }
                PkU u0, u1, u2, u3;
                u0.h = __builtin_amdgcn_cvt_pkrtz(p[0], p[1]);
                u1.h = __builtin_amdgcn_cvt_pkrtz(p[2], p[3]);
                u2.h = __builtin_amdgcn_cvt_pkrtz(p[4], p[5]);
                u3.h = __builtin_amdgcn_cvt_pkrtz(p[6], p[7]);
                // mask: invalid columns / rows -> 0h (bitwise AND in packed-f16 domain)
                union { unsigned u[2]; f16x4 v; } pa, pb;
                pa.u[0] = rv ? (u0.u & pm_[q][0]) : 0u;
                pa.u[1] = rv ? (u1.u & pm_[q][1]) : 0u;
                pb.u[0] = rv ? (u2.u & pm_[q][2]) : 0u;
                pb.u[1] = rv ? (u3.u & pm_[q][3]) : 0u;

                O[q][0] = __builtin_amdgcn_mfma_f32_16x16x16f16(pa.v, vfA0, O[q][0], 0, 0, 0);
                O[q][0] = __builtin_amdgcn_mfma_f32_16x16x16f16(pb.v, vfB0, O[q][0], 0, 0, 0);
                O[q][1] = __builtin_amdgcn_mfma_f32_16x16x16f16(pa.v, vfA1, O[q][1], 0, 0, 0);
                O[q][1] = __builtin_amdgcn_mfma_f32_16x16x16f16(pb.v, vfB1, O[q][1], 0, 0, 0);
                lacc[q] = __builtin_amdgcn_mfma_f32_16x16x16f16(pa.v, ones4, lacc[q], 0, 0, 0);
                lacc[q] = __builtin_amdgcn_mfma_f32_16x16x16f16(pb.v, ones4, lacc[q], 0, 0, 0);
            }
            rpq[q] += RPBW;
        }
        kf0 = nkf0; kf1 = nkf1;
        vfA0 = nvfA0; vfB0 = nvfB0; vfA1 = nvfA1; vfB1 = nvfB1;
        aa++;
    }

    // ---- merge: wave1 stores partials, wave0 adds and finishes ----
    if (w == 1) {
        float* ob = &Olds[lane][0];
        #pragma unroll
        for (int q = 0; q < 4; q++) {
            *(f32x4*)&ob[q * 12]     = O[q][0];
            *(f32x4*)&ob[q * 12 + 4] = O[q][1];
            *(f32x4*)&ob[q * 12 + 8] = lacc[q];
        }
    }
    __syncthreads();
    if (w == 0) {
        const float* ob = &Olds[lane][0];
        #pragma unroll
        for (int q = 0; q < 4; q++) {
            f32x4 o0 = O[q][0] + *(const f32x4*)&ob[q * 12];
            f32x4 o1 = O[q][1] + *(const f32x4*)&ob[q * 12 + 4];
            f32x4 la = lacc[q] + *(const f32x4*)&ob[q * 12 + 8];
            #pragma unroll
            for (int r = 0; r < 4; r++) {
                float li = 1.f / la[r];
                int ql = q * 16 + quad * 4 + r;
                int qi = i0 + (ql >> 3), qj = j0 + (ql & 7);
                size_t base = (size_t)(qi * PP + qj) * CC + h * HD;
                ao[base + nn]      = (f16)(o0[r] * li);
                ao[base + 16 + nn] = (f16)(o1[r] * li);
            }
        }
    }
}

extern "C" void kernel_launch(void* const* d_in, const int* in_sizes, int n_in,
                              void* d_out, int out_size, void* d_ws, size_t ws_size,
                              hipStream_t stream) {
    (void)in_sizes; (void)n_in; (void)out_size; (void)ws_size;
    const float* x    = (const float*)d_in[0];
    const float* cond = (const float*)d_in[1];
    const float* mask = (const float*)d_in[2];
    const float* lw   = (const float*)d_in[3];
    const float* lb   = (const float*)d_in[4];
    const float* qw   = (const float*)d_in[5];
    const float* qb   = (const float*)d_in[6];
    const float* rpb  = (const float*)d_in[7];
    const float* pw   = (const float*)d_in[8];
    const float* pb   = (const float*)d_in[9];
    float* outp       = (float*)d_out;

    float* ws   = (float*)d_ws;
    float* qbs  = ws;                 // 384
    float* b2s  = qbs + 384;          // 384
    float* rpbp = b2s + 384;          // 10240 padded
    f16* lwh  = (f16*)(rpbp + 10240);             // 128*160
    f16* qwh  = lwh + 20480;                      // 384*128
    f16* pwh  = qwh + 49152;                      // 128*128
    f16* w2h  = pwh + 16384;                      // 384*128
    f16* yh   = w2h + 49152;                      // NN*128
    f16* qkh  = yh + (size_t)NN * 128;            // NN*256 (Q|K)
    f16* vt   = qkh + (size_t)NN * 256;           // 128*NPAD
    f16* ao   = vt + (size_t)128 * NPAD;          // NN*128  (prefetch overshoot lands in vt/ao)

    prep<<<228, 256, 0, stream>>>(lw, qw, pw, qb, pb, rpb, lwh, qwh, pwh, w2h, qbs, b2s, rpbp);
    fusion_gemm<<<dim3(352, 2), 256, 0, stream>>>(x, cond, mask, lwh, lb, yh);
    gemm_qkv<<<dim3(352, 6), 256, 0, stream>>>(yh, qwh, qbs, qkh, vt);
    attn_mfma<<<dim3(TT / 8, PP / 8, HEADS), 128, 0, stream>>>(qkh, vt, rpbp, ao);
    gemm_qkv<<<dim3(352, 6), 256, 0, stream>>>(ao, w2h, b2s, qkh, vt);   // fused proj+qkv
    attn_mfma<<<dim3(TT / 8, PP / 8, HEADS), 128, 0, stream>>>(qkh, vt, rpbp, ao);
    gemm_out<<<dim3(352, 2), 256, 0, stream>>>(ao, pwh, pb, outp);
}

// Round 5
// 221.133 us; speedup vs baseline: 3.0411x; 1.1840x over previous
//
#include <hip/hip_runtime.h>
#include <hip/hip_fp16.h>

#define TT 256
#define PP 88
#define CC 128
#define NN (TT * PP)          // 22528 positions
#define NPAD (NN + 32)
#define HEADS 4
#define HD 32
#define WIN 25
#define RPBW 49
#define RPBSZ (RPBW * RPBW)   // 2401
#define SCALE 0.17677669529663687f   // 1/sqrt(32)
#define LOG2E 1.4426950408889634f
#define QSC (SCALE * LOG2E)          // fold exp->exp2 into Q path

#if __has_builtin(__builtin_amdgcn_exp2f)
#define EXP2(x) __builtin_amdgcn_exp2f(x)
#else
#define EXP2(x) exp2f(x)
#endif

typedef _Float16 f16;
typedef f16 f16x8 __attribute__((ext_vector_type(8)));
typedef f16 f16x8u __attribute__((ext_vector_type(8), aligned(4)));
typedef f16 f16x4 __attribute__((ext_vector_type(4)));
typedef f16 f16x4u __attribute__((ext_vector_type(4), aligned(4)));
typedef float f32x4 __attribute__((ext_vector_type(4)));
typedef float f32x4u __attribute__((ext_vector_type(4), aligned(4)));
typedef __fp16 hf16x2 __attribute__((ext_vector_type(2)));
union PkU { hf16x2 h; unsigned u; };

// ---------- prep: repack (b<192) + parallel b2s (192<=b<216) + MFMA wcomb (216<=b<228) ----------
__global__ __launch_bounds__(256) void prep(
    const float* __restrict__ lw, const float* __restrict__ qw,
    const float* __restrict__ pw, const float* __restrict__ qb,
    const float* __restrict__ pb, const float* __restrict__ rpb,
    f16* __restrict__ lwh, f16* __restrict__ qwh, f16* __restrict__ pwh,
    f16* __restrict__ w2h, float* __restrict__ qbs, float* __restrict__ b2s,
    float* __restrict__ rpbp)
{
    const int b = blockIdx.x;
    if (b < 192) {
        int idx = b * 256 + threadIdx.x;              // covers 49152
        if (idx < 128 * 160) {                        // fusion W: [128][131] -> [128][160] pad
            int r = idx / 160, c = idx - r * 160;
            lwh[idx] = (f16)(c < 131 ? lw[r * 131 + c] : 0.f);
        }
        if (idx < 384 * 128) {                        // qkv W, Q rows scaled by QSC
            float v = qw[idx];
            if (idx < 128 * 128) v *= QSC;
            qwh[idx] = (f16)v;
        }
        if (idx < 128 * 128) pwh[idx] = (f16)pw[idx];
        if (idx < 384) qbs[idx] = qb[idx] * (idx < 128 ? QSC : 1.f);
        if (idx < 10240) rpbp[idx] = (idx < 4 * RPBSZ) ? rpb[idx] * LOG2E : 0.f;
    } else if (b < 216) {
        // b2s[i] = (qb[i] + qw[i,:]·pb) * sc_i ; 16 lanes per output, shuffle-reduce
        int t = (b - 192) * 256 + threadIdx.x;        // [0, 6144)
        int i = t >> 4, l = t & 15;
        if (i < 384) {
            float s = 0.f;
            #pragma unroll
            for (int j = l * 8; j < l * 8 + 8; j++) s += qw[i * 128 + j] * pb[j];
            s += __shfl_xor(s, 1); s += __shfl_xor(s, 2);
            s += __shfl_xor(s, 4); s += __shfl_xor(s, 8);
            if (l == 0) b2s[i] = (qb[i] + s) * (i < 128 ? QSC : 1.f);
        }
    } else {
        // w2h[i][k] = sc_i * sum_j qw[i][j] pw[j][k]
        const int bw = b - 216;                       // 0..11
        const int m0 = (bw & 1) * 64;                 // k-tile
        const int n0 = (bw >> 1) * 64;                // i-tile
        const int tid = threadIdx.x;
        const int w = tid >> 6, lane = tid & 63, quad = lane >> 4, nn = lane & 15;
        const int krow = m0 + w * 16 + nn;
        f16x8 af[4];
        #pragma unroll
        for (int ks = 0; ks < 4; ks++) {
            union { f16 e[8]; f16x8 v; } t;
            #pragma unroll
            for (int e = 0; e < 8; e++)
                t.e[e] = (f16)pw[(ks * 32 + quad * 8 + e) * 128 + krow];
            af[ks] = t.v;
        }
        f32x4 acc[4] = {};
        #pragma unroll
        for (int nt = 0; nt < 4; nt++) {
            int irow = n0 + nt * 16 + nn;
            #pragma unroll
            for (int ks = 0; ks < 4; ks++) {
                const float* qr = &qw[(size_t)irow * 128 + ks * 32 + quad * 8];
                float4 a = *(const float4*)qr, bq = *(const float4*)(qr + 4);
                PkU u0, u1, u2, u3;
                u0.h = __builtin_amdgcn_cvt_pkrtz(a.x, a.y);
                u1.h = __builtin_amdgcn_cvt_pkrtz(a.z, a.w);
                u2.h = __builtin_amdgcn_cvt_pkrtz(bq.x, bq.y);
                u3.h = __builtin_amdgcn_cvt_pkrtz(bq.z, bq.w);
                union { unsigned u[4]; f16x8 v; } bb;
                bb.u[0] = u0.u; bb.u[1] = u1.u; bb.u[2] = u2.u; bb.u[3] = u3.u;
                acc[nt] = __builtin_amdgcn_mfma_f32_16x16x32_f16(af[ks], bb.v, acc[nt], 0, 0, 0);
            }
        }
        #pragma unroll
        for (int nt = 0; nt < 4; nt++) {
            int i = n0 + nt * 16 + nn;
            float sc = (i < 128) ? QSC : 1.f;
            PkU p0, p1;
            p0.h = __builtin_amdgcn_cvt_pkrtz(acc[nt][0] * sc, acc[nt][1] * sc);
            p1.h = __builtin_amdgcn_cvt_pkrtz(acc[nt][2] * sc, acc[nt][3] * sc);
            *(uint2*)&w2h[(size_t)i * 128 + m0 + w * 16 + quad * 4] = make_uint2(p0.u, p1.u);
        }
    }
}

// ---------- fusion GEMM: yh = relu(cat @ lwh^T + lb); grid (352, 2) ----------
__global__ __launch_bounds__(256) void fusion_gemm(
    const float* __restrict__ x, const float* __restrict__ cond, const float* __restrict__ mask,
    const f16* __restrict__ lwh, const float* __restrict__ lb, f16* __restrict__ yh)
{
    __shared__ __align__(16) f16 Alds[64 * 168];
    const int m0 = blockIdx.x * 64, n0 = blockIdx.y * 64;
    const int tid = threadIdx.x;
    const int w = tid >> 6, lane = tid & 63, quad = lane >> 4, nn = lane & 15;

    {   // stage cat rows (f16)
        int r = tid >> 2, cpart = tid & 3;
        size_t pos = m0 + r;
        *(uint4*)&Alds[r * 168 + 128 + cpart * 8] = make_uint4(0, 0, 0, 0);
        const float* xr = x + pos * 128 + cpart * 32;
        #pragma unroll
        for (int t = 0; t < 4; t++) {
            float4 a = *(const float4*)(xr + t * 8);
            float4 b = *(const float4*)(xr + t * 8 + 4);
            PkU p0, p1, p2, p3;
            p0.h = __builtin_amdgcn_cvt_pkrtz(a.x, a.y);
            p1.h = __builtin_amdgcn_cvt_pkrtz(a.z, a.w);
            p2.h = __builtin_amdgcn_cvt_pkrtz(b.x, b.y);
            p3.h = __builtin_amdgcn_cvt_pkrtz(b.z, b.w);
            *(uint4*)&Alds[r * 168 + cpart * 32 + t * 8] = make_uint4(p0.u, p1.u, p2.u, p3.u);
        }
        if (cpart == 0) {
            Alds[r * 168 + 128] = (f16)cond[pos * 2];
            Alds[r * 168 + 129] = (f16)cond[pos * 2 + 1];
            Alds[r * 168 + 130] = (f16)mask[pos];
        }
    }
    __syncthreads();

    const int oc = n0 + w * 16 + nn;
    f16x8 af[5];
    #pragma unroll
    for (int ks = 0; ks < 5; ks++)
        af[ks] = *(const f16x8*)&lwh[(size_t)oc * 160 + ks * 32 + quad * 8];
    f32x4 acc[4] = {};
    #pragma unroll
    for (int ks = 0; ks < 5; ks++)
        #pragma unroll
        for (int nt = 0; nt < 4; nt++) {
            f16x8 bf = *(const f16x8*)&Alds[(nt * 16 + nn) * 168 + ks * 32 + quad * 8];
            acc[nt] = __builtin_amdgcn_mfma_f32_16x16x32_f16(af[ks], bf, acc[nt], 0, 0, 0);
        }
    float bv[4];
    #pragma unroll
    for (int r = 0; r < 4; r++) bv[r] = lb[n0 + w * 16 + quad * 4 + r];
    #pragma unroll
    for (int nt = 0; nt < 4; nt++) {
        int pos = m0 + nt * 16 + nn;
        PkU p0, p1;
        p0.h = __builtin_amdgcn_cvt_pkrtz(fmaxf(acc[nt][0] + bv[0], 0.f), fmaxf(acc[nt][1] + bv[1], 0.f));
        p1.h = __builtin_amdgcn_cvt_pkrtz(fmaxf(acc[nt][2] + bv[2], 0.f), fmaxf(acc[nt][3] + bv[3], 0.f));
        *(uint2*)&yh[(size_t)pos * 128 + n0 + w * 16 + quad * 4] = make_uint2(p0.u, p1.u);
    }
}

// ---------- qkv GEMM: grid (352, 6); Q|K rows stride 256, V transposed ----------
__global__ __launch_bounds__(256) void gemm_qkv(
    const f16* __restrict__ A, const f16* __restrict__ W, const float* __restrict__ bias,
    f16* __restrict__ qkh, f16* __restrict__ vt)
{
    __shared__ __align__(16) f16 Alds[64 * 136];
    const int m0 = blockIdx.x * 64, n0 = blockIdx.y * 64;
    const int tid = threadIdx.x;
    const int w = tid >> 6, lane = tid & 63, quad = lane >> 4, nn = lane & 15;

    for (int i = tid; i < 1024; i += 256) {
        int r = i >> 4, c = i & 15;
        *(uint4*)&Alds[r * 136 + c * 8] = *(const uint4*)&A[(size_t)(m0 + r) * 128 + c * 8];
    }
    __syncthreads();

    const int oc = n0 + w * 16 + nn;
    f16x8 af[4];
    #pragma unroll
    for (int ks = 0; ks < 4; ks++)
        af[ks] = *(const f16x8*)&W[(size_t)oc * 128 + ks * 32 + quad * 8];
    f32x4 acc[4] = {};
    #pragma unroll
    for (int ks = 0; ks < 4; ks++)
        #pragma unroll
        for (int nt = 0; nt < 4; nt++) {
            f16x8 bf = *(const f16x8*)&Alds[(nt * 16 + nn) * 136 + ks * 32 + quad * 8];
            acc[nt] = __builtin_amdgcn_mfma_f32_16x16x32_f16(af[ks], bf, acc[nt], 0, 0, 0);
        }
    float bv[4];
    #pragma unroll
    for (int r = 0; r < 4; r++) bv[r] = bias[n0 + w * 16 + quad * 4 + r];

    if (n0 < 256) {
        #pragma unroll
        for (int nt = 0; nt < 4; nt++) {
            int pos = m0 + nt * 16 + nn;
            PkU p0, p1;
            p0.h = __builtin_amdgcn_cvt_pkrtz(acc[nt][0] + bv[0], acc[nt][1] + bv[1]);
            p1.h = __builtin_amdgcn_cvt_pkrtz(acc[nt][2] + bv[2], acc[nt][3] + bv[3]);
            *(uint2*)&qkh[(size_t)pos * 256 + n0 + w * 16 + quad * 4] = make_uint2(p0.u, p1.u);
        }
    } else {
        #pragma unroll
        for (int nt = 0; nt < 4; nt++) {
            int pos = m0 + nt * 16 + nn;
            #pragma unroll
            for (int r = 0; r < 4; r++) {
                int chg = n0 - 256 + w * 16 + quad * 4 + r;
                vt[(size_t)chg * NPAD + pos] = (f16)(acc[nt][r] + bv[r]);
            }
        }
    }
}

// ---------- final projection: grid (352, 2), fp32 out ----------
__global__ __launch_bounds__(256) void gemm_out(
    const f16* __restrict__ A, const f16* __restrict__ W, const float* __restrict__ bias,
    float* __restrict__ outp)
{
    __shared__ __align__(16) f16 Alds[64 * 136];
    const int m0 = blockIdx.x * 64, n0 = blockIdx.y * 64;
    const int tid = threadIdx.x;
    const int w = tid >> 6, lane = tid & 63, quad = lane >> 4, nn = lane & 15;

    for (int i = tid; i < 1024; i += 256) {
        int r = i >> 4, c = i & 15;
        *(uint4*)&Alds[r * 136 + c * 8] = *(const uint4*)&A[(size_t)(m0 + r) * 128 + c * 8];
    }
    __syncthreads();

    const int oc = n0 + w * 16 + nn;
    f16x8 af[4];
    #pragma unroll
    for (int ks = 0; ks < 4; ks++)
        af[ks] = *(const f16x8*)&W[(size_t)oc * 128 + ks * 32 + quad * 8];
    f32x4 acc[4] = {};
    #pragma unroll
    for (int ks = 0; ks < 4; ks++)
        #pragma unroll
        for (int nt = 0; nt < 4; nt++) {
            f16x8 bf = *(const f16x8*)&Alds[(nt * 16 + nn) * 136 + ks * 32 + quad * 8];
            acc[nt] = __builtin_amdgcn_mfma_f32_16x16x32_f16(af[ks], bf, acc[nt], 0, 0, 0);
        }
    float bv[4];
    #pragma unroll
    for (int r = 0; r < 4; r++) bv[r] = bias[n0 + w * 16 + quad * 4 + r];
    #pragma unroll
    for (int nt = 0; nt < 4; nt++) {
        int pos = m0 + nt * 16 + nn;
        f32x4 vv;
        #pragma unroll
        for (int r = 0; r < 4; r++) vv[r] = acc[nt][r] + bv[r];
        *(f32x4*)&outp[(size_t)pos * 128 + n0 + w * 16 + quad * 4] = vv;
    }
}

// ---------- MFMA neighborhood attention v6: row-pipelined register PV ----------
// v5 shape (2 waves x 16 key rows x 4 qsets, 4x K/V/rpb amortization, register
// PV via 16x16x16 layout match) + three latency fixes:
// 1. PV of row aa-1 is deferred one iteration: each iter issues the rpb loads
//    FIRST, runs the previous row's 24 PV MFMAs (latency cover), then V/K load
//    issues, then S+exp of the current row. Every load now has >=1 phase of
//    cover (v5 had rpb -> S-MFMA back-to-back = exposed L2 latency x16 iters).
// 2. Branchless: __any dropped; masks already zero invalid keys. Out-of-window
//    rpb reads land in the zero-padded rpbp (max offset 9953 < 10240, verified).
//    One straight-line body lets the scheduler interleave all 4 qsets.
// 3. XCD swizzle: bx=(x&7)*4+(x>>3) gives each XCD a contiguous 32-row i-range
//    (K/V working set ~2.5MB fits the 4MB per-XCD L2).
__global__ __launch_bounds__(128) void attn_mfma(
    const f16* __restrict__ qkh,   // [N][256] = Q|K, Q pre-scaled by QSC
    const f16* __restrict__ vt,    // [128][NPAD]
    const float* __restrict__ rpbp,
    f16* __restrict__ ao)          // [N][128]
{
    const int bx = ((blockIdx.x & 7) << 2) + (blockIdx.x >> 3);   // XCD-contiguous i-tiles
    const int i0 = bx * 8;
    const int j0 = blockIdx.y * 8;
    const int h  = blockIdx.z;
    const int tid = threadIdx.x;
    const int w = tid >> 6, lane = tid & 63;
    const int quad = lane >> 4, nn = lane & 15;

    const int ri0 = min(max(i0 - 12, 0), TT - 32);
    const int rj0 = min(max(j0 - 12, 0), PP - WIN) & ~1;

    __shared__ __align__(16) float Olds[64][60];   // wave-1 partials (stride 60: 0 conflicts, v5)

    int si_[4];
    unsigned pm_[4][4];            // packed-f16 column masks per output word
    f16x8 qf[4];
    const float* rpq[4];
    const float* rp_h = rpbp + h * RPBSZ;
    const int aa0 = ri0 + w * 16;  // this wave's first key row

    #pragma unroll
    for (int q = 0; q < 4; q++) {
        int ql = q * 16 + nn;
        int qi = i0 + (ql >> 3), qj = j0 + (ql & 7);
        int si = min(max(qi - 12, 0), TT - WIN);
        int sj = min(max(qj - 12, 0), PP - WIN);
        si_[q] = si;
        unsigned cm = 0x1FFFFFFu << (sj - rj0);       // shift <= 7
        #pragma unroll
        for (int t = 0; t < 4; t++) {
            int k0 = (t >> 1) * 16 + quad * 4 + (t & 1) * 2;
            pm_[q][t] = (((cm >> k0) & 1u) ? 0xFFFFu : 0u)
                      | (((cm >> (k0 + 1)) & 1u) ? 0xFFFF0000u : 0u);
        }
        qf[q] = *(const f16x8*)&qkh[(size_t)(qi * PP + qj) * 256 + h * HD + quad * 8];
        rpq[q] = rp_h + (aa0 - qi + 24) * RPBW + (rj0 - qj + 24) + quad * 4;
    }

    const f16* vbase = vt + (size_t)(h * HD + nn) * NPAD;
    const int b0 = min(rj0 + nn, PP - 1);
    const int b1 = min(rj0 + 16 + nn, PP - 1);
    const size_t koff = 128 + h * HD + quad * 8;
    const f16x4 ones4 = {(f16)1.f, (f16)1.f, (f16)1.f, (f16)1.f};

    f32x4 O[4][2] = {};            // [qset][ch-half]; regs = queries, lane nn = channel
    f32x4 lacc[4] = {};
    union PB { unsigned u[2]; f16x4 v; };
    PB pa_[4], pb_[4];             // pending P (row aa-1), masked, packed
    f32x4 za_[4], zb_[4];          // rpb C-init for current row

    // ---- prologue: row aa0 -> S/exp only (its PV runs in iter c=1) ----
    int aa = aa0;
    const f16* rowK = qkh + (size_t)aa * (PP * 256) + koff;
    f16x8 kf0 = *(const f16x8*)(rowK + (size_t)b0 * 256);
    f16x8 kf1 = *(const f16x8*)(rowK + (size_t)b1 * 256);
    const f16* vrow = vbase + aa * PP + rj0 + quad * 4;
    f16x4 vfA0 = *(const f16x4u*)vrow;                      // keys  0-15, ch lo
    f16x4 vfB0 = *(const f16x4u*)(vrow + 16);               // keys 16-31, ch lo
    f16x4 vfA1 = *(const f16x4u*)(vrow + (size_t)16 * NPAD);
    f16x4 vfB1 = *(const f16x4u*)(vrow + (size_t)16 * NPAD + 16);
    #pragma unroll
    for (int q = 0; q < 4; q++) {
        za_[q] = *(const f32x4u*)rpq[q];
        zb_[q] = *(const f32x4u*)(rpq[q] + 16);
        rpq[q] += RPBW;
    }
    #pragma unroll
    for (int q = 0; q < 4; q++) {
        f32x4 s0 = __builtin_amdgcn_mfma_f32_16x16x32_f16(kf0, qf[q], za_[q], 0, 0, 0);
        f32x4 s1 = __builtin_amdgcn_mfma_f32_16x16x32_f16(kf1, qf[q], zb_[q], 0, 0, 0);
        bool rv = (unsigned)(aa - si_[q]) <= 24u;
        float p[8];
        #pragma unroll
        for (int r = 0; r < 4; r++) { p[r] = EXP2(s0[r]); p[r + 4] = EXP2(s1[r]); }
        PkU u0, u1, u2, u3;
        u0.h = __builtin_amdgcn_cvt_pkrtz(p[0], p[1]);
        u1.h = __builtin_amdgcn_cvt_pkrtz(p[2], p[3]);
        u2.h = __builtin_amdgcn_cvt_pkrtz(p[4], p[5]);
        u3.h = __builtin_amdgcn_cvt_pkrtz(p[6], p[7]);
        pa_[q].u[0] = rv ? (u0.u & pm_[q][0]) : 0u;
        pa_[q].u[1] = rv ? (u1.u & pm_[q][1]) : 0u;
        pb_[q].u[0] = rv ? (u2.u & pm_[q][2]) : 0u;
        pb_[q].u[1] = rv ? (u3.u & pm_[q][3]) : 0u;
    }
    // prefetch K for row aa0+1
    const f16* rowKn = qkh + (size_t)(aa + 1) * (PP * 256) + koff;
    f16x8 nkf0 = *(const f16x8*)(rowKn + (size_t)b0 * 256);
    f16x8 nkf1 = *(const f16x8*)(rowKn + (size_t)b1 * 256);

    // ---- pipelined main loop: rows aa0+1 .. aa0+15 ----
    #pragma unroll 1
    for (int c = 1; c < 16; ++c) {
        aa = aa0 + c;
        kf0 = nkf0; kf1 = nkf1;                       // K(aa), prefetched last iter

        // (a) issue rpb loads for row aa (oldest in VMEM queue -> S wait is cheap)
        #pragma unroll
        for (int q = 0; q < 4; q++) {
            za_[q] = *(const f32x4u*)rpq[q];
            zb_[q] = *(const f32x4u*)(rpq[q] + 16);
            rpq[q] += RPBW;
        }

        // (b) PV for row aa-1 (covers the rpb latency with 24 MFMAs)
        #pragma unroll
        for (int q = 0; q < 4; q++) {
            O[q][0] = __builtin_amdgcn_mfma_f32_16x16x16f16(pa_[q].v, vfA0, O[q][0], 0, 0, 0);
            O[q][0] = __builtin_amdgcn_mfma_f32_16x16x16f16(pb_[q].v, vfB0, O[q][0], 0, 0, 0);
            O[q][1] = __builtin_amdgcn_mfma_f32_16x16x16f16(pa_[q].v, vfA1, O[q][1], 0, 0, 0);
            O[q][1] = __builtin_amdgcn_mfma_f32_16x16x16f16(pb_[q].v, vfB1, O[q][1], 0, 0, 0);
            lacc[q] = __builtin_amdgcn_mfma_f32_16x16x16f16(pa_[q].v, ones4, lacc[q], 0, 0, 0);
            lacc[q] = __builtin_amdgcn_mfma_f32_16x16x16f16(pb_[q].v, ones4, lacc[q], 0, 0, 0);
        }

        // (c) issue V loads for row aa (consumed by next iter's PV)
        const f16* vr = vbase + aa * PP + rj0 + quad * 4;
        vfA0 = *(const f16x4u*)vr;
        vfB0 = *(const f16x4u*)(vr + 16);
        vfA1 = *(const f16x4u*)(vr + (size_t)16 * NPAD);
        vfB1 = *(const f16x4u*)(vr + (size_t)16 * NPAD + 16);

        // (d) issue K prefetch for row aa+1 (last iter overshoots into vt workspace: unused)
        const f16* rkn = qkh + (size_t)(aa + 1) * (PP * 256) + koff;
        nkf0 = *(const f16x8*)(rkn + (size_t)b0 * 256);
        nkf1 = *(const f16x8*)(rkn + (size_t)b1 * 256);

        // (e) S + exp for row aa -> pending P (pa_/pb_ free: consumed in (b))
        #pragma unroll
        for (int q = 0; q < 4; q++) {
            f32x4 s0 = __builtin_amdgcn_mfma_f32_16x16x32_f16(kf0, qf[q], za_[q], 0, 0, 0);
            f32x4 s1 = __builtin_amdgcn_mfma_f32_16x16x32_f16(kf1, qf[q], zb_[q], 0, 0, 0);
            bool rv = (unsigned)(aa - si_[q]) <= 24u;
            float p[8];
            #pragma unroll
            for (int r = 0; r < 4; r++) { p[r] = EXP2(s0[r]); p[r + 4] = EXP2(s1[r]); }
            PkU u0, u1, u2, u3;
            u0.h = __builtin_amdgcn_cvt_pkrtz(p[0], p[1]);
            u1.h = __builtin_amdgcn_cvt_pkrtz(p[2], p[3]);
            u2.h = __builtin_amdgcn_cvt_pkrtz(p[4], p[5]);
            u3.h = __builtin_amdgcn_cvt_pkrtz(p[6], p[7]);
            pa_[q].u[0] = rv ? (u0.u & pm_[q][0]) : 0u;
            pa_[q].u[1] = rv ? (u1.u & pm_[q][1]) : 0u;
            pb_[q].u[0] = rv ? (u2.u & pm_[q][2]) : 0u;
            pb_[q].u[1] = rv ? (u3.u & pm_[q][3]) : 0u;
        }
    }

    // ---- epilogue PV: last row (aa0+15) ----
    #pragma unroll
    for (int q = 0; q < 4; q++) {
        O[q][0] = __builtin_amdgcn_mfma_f32_16x16x16f16(pa_[q].v, vfA0, O[q][0], 0, 0, 0);
        O[q][0] = __builtin_amdgcn_mfma_f32_16x16x16f16(pb_[q].v, vfB0, O[q][0], 0, 0, 0);
        O[q][1] = __builtin_amdgcn_mfma_f32_16x16x16f16(pa_[q].v, vfA1, O[q][1], 0, 0, 0);
        O[q][1] = __builtin_amdgcn_mfma_f32_16x16x16f16(pb_[q].v, vfB1, O[q][1], 0, 0, 0);
        lacc[q] = __builtin_amdgcn_mfma_f32_16x16x16f16(pa_[q].v, ones4, lacc[q], 0, 0, 0);
        lacc[q] = __builtin_amdgcn_mfma_f32_16x16x16f16(pb_[q].v, ones4, lacc[q], 0, 0, 0);
    }

    // ---- merge: wave1 stores partials, wave0 adds and finishes ----
    if (w == 1) {
        float* ob = &Olds[lane][0];
        #pragma unroll
        for (int q = 0; q < 4; q++) {
            *(f32x4*)&ob[q * 12]     = O[q][0];
            *(f32x4*)&ob[q * 12 + 4] = O[q][1];
            *(f32x4*)&ob[q * 12 + 8] = lacc[q];
        }
    }
    __syncthreads();
    if (w == 0) {
        const float* ob = &Olds[lane][0];
        #pragma unroll
        for (int q = 0; q < 4; q++) {
            f32x4 o0 = O[q][0] + *(const f32x4*)&ob[q * 12];
            f32x4 o1 = O[q][1] + *(const f32x4*)&ob[q * 12 + 4];
            f32x4 la = lacc[q] + *(const f32x4*)&ob[q * 12 + 8];
            #pragma unroll
            for (int r = 0; r < 4; r++) {
                float li = 1.f / la[r];
                int ql = q * 16 + quad * 4 + r;
                int qi = i0 + (ql >> 3), qj = j0 + (ql & 7);
                size_t base = (size_t)(qi * PP + qj) * CC + h * HD;
                ao[base + nn]      = (f16)(o0[r] * li);
                ao[base + 16 + nn] = (f16)(o1[r] * li);
            }
        }
    }
}

extern "C" void kernel_launch(void* const* d_in, const int* in_sizes, int n_in,
                              void* d_out, int out_size, void* d_ws, size_t ws_size,
                              hipStream_t stream) {
    (void)in_sizes; (void)n_in; (void)out_size; (void)ws_size;
    const float* x    = (const float*)d_in[0];
    const float* cond = (const float*)d_in[1];
    const float* mask = (const float*)d_in[2];
    const float* lw   = (const float*)d_in[3];
    const float* lb   = (const float*)d_in[4];
    const float* qw   = (const float*)d_in[5];
    const float* qb   = (const float*)d_in[6];
    const float* rpb  = (const float*)d_in[7];
    const float* pw   = (const float*)d_in[8];
    const float* pb   = (const float*)d_in[9];
    float* outp       = (float*)d_out;

    float* ws   = (float*)d_ws;
    float* qbs  = ws;                 // 384
    float* b2s  = qbs + 384;          // 384
    float* rpbp = b2s + 384;          // 10240 padded
    f16* lwh  = (f16*)(rpbp + 10240);             // 128*160
    f16* qwh  = lwh + 20480;                      // 384*128
    f16* pwh  = qwh + 49152;                      // 128*128
    f16* w2h  = pwh + 16384;                      // 384*128
    f16* yh   = w2h + 49152;                      // NN*128
    f16* qkh  = yh + (size_t)NN * 128;            // NN*256 (Q|K)
    f16* vt   = qkh + (size_t)NN * 256;           // 128*NPAD
    f16* ao   = vt + (size_t)128 * NPAD;          // NN*128  (prefetch overshoot lands in vt/ao)

    prep<<<228, 256, 0, stream>>>(lw, qw, pw, qb, pb, rpb, lwh, qwh, pwh, w2h, qbs, b2s, rpbp);
    fusion_gemm<<<dim3(352, 2), 256, 0, stream>>>(x, cond, mask, lwh, lb, yh);
    gemm_qkv<<<dim3(352, 6), 256, 0, stream>>>(yh, qwh, qbs, qkh, vt);
    attn_mfma<<<dim3(TT / 8, PP / 8, HEADS), 128, 0, stream>>>(qkh, vt, rpbp, ao);
    gemm_qkv<<<dim3(352, 6), 256, 0, stream>>>(ao, w2h, b2s, qkh, vt);   // fused proj+qkv
    attn_mfma<<<dim3(TT / 8, PP / 8, HEADS), 128, 0, stream>>>(qkh, vt, rpbp, ao);
    gemm_out<<<dim3(352, 2), 256, 0, stream>>>(ao, pwh, pb, outp);
}

// Round 6
// 207.503 us; speedup vs baseline: 3.2408x; 1.0657x over previous
//
#include <hip/hip_runtime.h>
#include <hip/hip_fp16.h>

#define TT 256
#define PP 88
#define CC 128
#define NN (TT * PP)          // 22528 positions
#define HEADS 4
#define HD 32
#define WIN 25
#define RPBW 49
#define RPBSZ (RPBW * RPBW)   // 2401
#define SCALE 0.17677669529663687f   // 1/sqrt(32)
#define LOG2E 1.4426950408889634f
#define QSC (SCALE * LOG2E)          // fold exp->exp2 into Q path

// K layout: kh2[aa][h][j:88][ch32]   -> row stride (aa) = 11264, (aa,h) block = 2816
// V layout: vh2[aa][h][half:2][g:22][ch16][jr:4] -> same strides; dense 512B per attn load
#define KVROW 11264           // f16 elems per aa row (4 heads x 2816)
#define KVAARWS 258           // aa rows allocated (256 + prefetch/overshoot pad)

#if __has_builtin(__builtin_amdgcn_exp2f)
#define EXP2(x) __builtin_amdgcn_exp2f(x)
#else
#define EXP2(x) exp2f(x)
#endif

typedef _Float16 f16;
typedef f16 f16x8 __attribute__((ext_vector_type(8)));
typedef f16 f16x8u __attribute__((ext_vector_type(8), aligned(4)));
typedef f16 f16x4 __attribute__((ext_vector_type(4)));
typedef f16 f16x4u __attribute__((ext_vector_type(4), aligned(4)));
typedef float f32x4 __attribute__((ext_vector_type(4)));
typedef float f32x4u __attribute__((ext_vector_type(4), aligned(4)));
typedef __fp16 hf16x2 __attribute__((ext_vector_type(2)));
union PkU { hf16x2 h; unsigned u; };

// ---------- prep: repack (b<192) + parallel b2s (192<=b<216) + MFMA wcomb (216<=b<228) ----------
__global__ __launch_bounds__(256) void prep(
    const float* __restrict__ lw, const float* __restrict__ qw,
    const float* __restrict__ pw, const float* __restrict__ qb,
    const float* __restrict__ pb, const float* __restrict__ rpb,
    f16* __restrict__ lwh, f16* __restrict__ qwh, f16* __restrict__ pwh,
    f16* __restrict__ w2h, float* __restrict__ qbs, float* __restrict__ b2s,
    float* __restrict__ rpbp)
{
    const int b = blockIdx.x;
    if (b < 192) {
        int idx = b * 256 + threadIdx.x;              // covers 49152
        if (idx < 128 * 160) {                        // fusion W: [128][131] -> [128][160] pad
            int r = idx / 160, c = idx - r * 160;
            lwh[idx] = (f16)(c < 131 ? lw[r * 131 + c] : 0.f);
        }
        if (idx < 384 * 128) {                        // qkv W, Q rows scaled by QSC
            float v = qw[idx];
            if (idx < 128 * 128) v *= QSC;
            qwh[idx] = (f16)v;
        }
        if (idx < 128 * 128) pwh[idx] = (f16)pw[idx];
        if (idx < 384) qbs[idx] = qb[idx] * (idx < 128 ? QSC : 1.f);
        if (idx < 10240) rpbp[idx] = (idx < 4 * RPBSZ) ? rpb[idx] * LOG2E : 0.f;
    } else if (b < 216) {
        // b2s[i] = (qb[i] + qw[i,:]·pb) * sc_i ; 16 lanes per output, shuffle-reduce
        int t = (b - 192) * 256 + threadIdx.x;        // [0, 6144)
        int i = t >> 4, l = t & 15;
        if (i < 384) {
            float s = 0.f;
            #pragma unroll
            for (int j = l * 8; j < l * 8 + 8; j++) s += qw[i * 128 + j] * pb[j];
            s += __shfl_xor(s, 1); s += __shfl_xor(s, 2);
            s += __shfl_xor(s, 4); s += __shfl_xor(s, 8);
            if (l == 0) b2s[i] = (qb[i] + s) * (i < 128 ? QSC : 1.f);
        }
    } else {
        // w2h[i][k] = sc_i * sum_j qw[i][j] pw[j][k]
        const int bw = b - 216;                       // 0..11
        const int m0 = (bw & 1) * 64;                 // k-tile
        const int n0 = (bw >> 1) * 64;                // i-tile
        const int tid = threadIdx.x;
        const int w = tid >> 6, lane = tid & 63, quad = lane >> 4, nn = lane & 15;
        const int krow = m0 + w * 16 + nn;
        f16x8 af[4];
        #pragma unroll
        for (int ks = 0; ks < 4; ks++) {
            union { f16 e[8]; f16x8 v; } t;
            #pragma unroll
            for (int e = 0; e < 8; e++)
                t.e[e] = (f16)pw[(ks * 32 + quad * 8 + e) * 128 + krow];
            af[ks] = t.v;
        }
        f32x4 acc[4] = {};
        #pragma unroll
        for (int nt = 0; nt < 4; nt++) {
            int irow = n0 + nt * 16 + nn;
            #pragma unroll
            for (int ks = 0; ks < 4; ks++) {
                const float* qr = &qw[(size_t)irow * 128 + ks * 32 + quad * 8];
                float4 a = *(const float4*)qr, bq = *(const float4*)(qr + 4);
                PkU u0, u1, u2, u3;
                u0.h = __builtin_amdgcn_cvt_pkrtz(a.x, a.y);
                u1.h = __builtin_amdgcn_cvt_pkrtz(a.z, a.w);
                u2.h = __builtin_amdgcn_cvt_pkrtz(bq.x, bq.y);
                u3.h = __builtin_amdgcn_cvt_pkrtz(bq.z, bq.w);
                union { unsigned u[4]; f16x8 v; } bb;
                bb.u[0] = u0.u; bb.u[1] = u1.u; bb.u[2] = u2.u; bb.u[3] = u3.u;
                acc[nt] = __builtin_amdgcn_mfma_f32_16x16x32_f16(af[ks], bb.v, acc[nt], 0, 0, 0);
            }
        }
        #pragma unroll
        for (int nt = 0; nt < 4; nt++) {
            int i = n0 + nt * 16 + nn;
            float sc = (i < 128) ? QSC : 1.f;
            PkU p0, p1;
            p0.h = __builtin_amdgcn_cvt_pkrtz(acc[nt][0] * sc, acc[nt][1] * sc);
            p1.h = __builtin_amdgcn_cvt_pkrtz(acc[nt][2] * sc, acc[nt][3] * sc);
            *(uint2*)&w2h[(size_t)i * 128 + m0 + w * 16 + quad * 4] = make_uint2(p0.u, p1.u);
        }
    }
}

// ---------- fusion GEMM: yh = relu(cat @ lwh^T + lb); grid (352, 2) ----------
__global__ __launch_bounds__(256) void fusion_gemm(
    const float* __restrict__ x, const float* __restrict__ cond, const float* __restrict__ mask,
    const f16* __restrict__ lwh, const float* __restrict__ lb, f16* __restrict__ yh)
{
    __shared__ __align__(16) f16 Alds[64 * 168];
    const int m0 = blockIdx.x * 64, n0 = blockIdx.y * 64;
    const int tid = threadIdx.x;
    const int w = tid >> 6, lane = tid & 63, quad = lane >> 4, nn = lane & 15;

    {   // stage cat rows (f16)
        int r = tid >> 2, cpart = tid & 3;
        size_t pos = m0 + r;
        *(uint4*)&Alds[r * 168 + 128 + cpart * 8] = make_uint4(0, 0, 0, 0);
        const float* xr = x + pos * 128 + cpart * 32;
        #pragma unroll
        for (int t = 0; t < 4; t++) {
            float4 a = *(const float4*)(xr + t * 8);
            float4 b = *(const float4*)(xr + t * 8 + 4);
            PkU p0, p1, p2, p3;
            p0.h = __builtin_amdgcn_cvt_pkrtz(a.x, a.y);
            p1.h = __builtin_amdgcn_cvt_pkrtz(a.z, a.w);
            p2.h = __builtin_amdgcn_cvt_pkrtz(b.x, b.y);
            p3.h = __builtin_amdgcn_cvt_pkrtz(b.z, b.w);
            *(uint4*)&Alds[r * 168 + cpart * 32 + t * 8] = make_uint4(p0.u, p1.u, p2.u, p3.u);
        }
        if (cpart == 0) {
            Alds[r * 168 + 128] = (f16)cond[pos * 2];
            Alds[r * 168 + 129] = (f16)cond[pos * 2 + 1];
            Alds[r * 168 + 130] = (f16)mask[pos];
        }
    }
    __syncthreads();

    const int oc = n0 + w * 16 + nn;
    f16x8 af[5];
    #pragma unroll
    for (int ks = 0; ks < 5; ks++)
        af[ks] = *(const f16x8*)&lwh[(size_t)oc * 160 + ks * 32 + quad * 8];
    f32x4 acc[4] = {};
    #pragma unroll
    for (int ks = 0; ks < 5; ks++)
        #pragma unroll
        for (int nt = 0; nt < 4; nt++) {
            f16x8 bf = *(const f16x8*)&Alds[(nt * 16 + nn) * 168 + ks * 32 + quad * 8];
            acc[nt] = __builtin_amdgcn_mfma_f32_16x16x32_f16(af[ks], bf, acc[nt], 0, 0, 0);
        }
    float bv[4];
    #pragma unroll
    for (int r = 0; r < 4; r++) bv[r] = lb[n0 + w * 16 + quad * 4 + r];
    #pragma unroll
    for (int nt = 0; nt < 4; nt++) {
        int pos = m0 + nt * 16 + nn;
        PkU p0, p1;
        p0.h = __builtin_amdgcn_cvt_pkrtz(fmaxf(acc[nt][0] + bv[0], 0.f), fmaxf(acc[nt][1] + bv[1], 0.f));
        p1.h = __builtin_amdgcn_cvt_pkrtz(fmaxf(acc[nt][2] + bv[2], 0.f), fmaxf(acc[nt][3] + bv[3], 0.f));
        *(uint2*)&yh[(size_t)pos * 128 + n0 + w * 16 + quad * 4] = make_uint2(p0.u, p1.u);
    }
}

// ---------- qkv GEMM: grid (352, 6); Q -> qh[pos][128], K -> kh2, V -> vh2 ----------
// Read-side coalescing for attn: scatter cost moved to the (once-per-element)
// write side; attn reads each element ~16x from dense windows.
__global__ __launch_bounds__(256) void gemm_qkv(
    const f16* __restrict__ A, const f16* __restrict__ W, const float* __restrict__ bias,
    f16* __restrict__ qh, f16* __restrict__ kh2, f16* __restrict__ vh2)
{
    __shared__ __align__(16) f16 Alds[64 * 136];
    const int m0 = blockIdx.x * 64, n0 = blockIdx.y * 64;
    const int tid = threadIdx.x;
    const int w = tid >> 6, lane = tid & 63, quad = lane >> 4, nn = lane & 15;

    for (int i = tid; i < 1024; i += 256) {
        int r = i >> 4, c = i & 15;
        *(uint4*)&Alds[r * 136 + c * 8] = *(const uint4*)&A[(size_t)(m0 + r) * 128 + c * 8];
    }
    __syncthreads();

    const int oc = n0 + w * 16 + nn;
    f16x8 af[4];
    #pragma unroll
    for (int ks = 0; ks < 4; ks++)
        af[ks] = *(const f16x8*)&W[(size_t)oc * 128 + ks * 32 + quad * 8];
    f32x4 acc[4] = {};
    #pragma unroll
    for (int ks = 0; ks < 4; ks++)
        #pragma unroll
        for (int nt = 0; nt < 4; nt++) {
            f16x8 bf = *(const f16x8*)&Alds[(nt * 16 + nn) * 136 + ks * 32 + quad * 8];
            acc[nt] = __builtin_amdgcn_mfma_f32_16x16x32_f16(af[ks], bf, acc[nt], 0, 0, 0);
        }
    float bv[4];
    #pragma unroll
    for (int r = 0; r < 4; r++) bv[r] = bias[n0 + w * 16 + quad * 4 + r];

    if (n0 < 128) {                                   // ---- Q: qh[pos][128]
        #pragma unroll
        for (int nt = 0; nt < 4; nt++) {
            int pos = m0 + nt * 16 + nn;
            PkU p0, p1;
            p0.h = __builtin_amdgcn_cvt_pkrtz(acc[nt][0] + bv[0], acc[nt][1] + bv[1]);
            p1.h = __builtin_amdgcn_cvt_pkrtz(acc[nt][2] + bv[2], acc[nt][3] + bv[3]);
            *(uint2*)&qh[(size_t)pos * 128 + n0 + w * 16 + quad * 4] = make_uint2(p0.u, p1.u);
        }
    } else if (n0 < 256) {                            // ---- K: kh2[aa][h][j][ch32]
        const int ch = n0 - 128 + w * 16 + quad * 4;  // 4 consecutive, same ch32 block
        const int hh = ch >> 5, c32 = ch & 31;
        #pragma unroll
        for (int nt = 0; nt < 4; nt++) {
            int pos = m0 + nt * 16 + nn;
            int aa = pos / 88, j = pos - aa * 88;
            PkU p0, p1;
            p0.h = __builtin_amdgcn_cvt_pkrtz(acc[nt][0] + bv[0], acc[nt][1] + bv[1]);
            p1.h = __builtin_amdgcn_cvt_pkrtz(acc[nt][2] + bv[2], acc[nt][3] + bv[3]);
            *(uint2*)&kh2[((size_t)(aa * 4 + hh) * 88 + j) * 32 + c32] = make_uint2(p0.u, p1.u);
        }
    } else {                                          // ---- V: vh2[aa][h][half][g][ch16][jr]
        const int chb = n0 - 256 + w * 16 + quad * 4;
        #pragma unroll
        for (int nt = 0; nt < 4; nt++) {
            int pos = m0 + nt * 16 + nn;
            int aa = pos / 88, j = pos - aa * 88;
            size_t vb = (size_t)(aa * 4) * 2816 + (j >> 2) * 64 + (j & 3);
            #pragma unroll
            for (int r = 0; r < 4; r++) {
                int chg = chb + r;
                int hh = chg >> 5, c = chg & 31;
                vh2[vb + (size_t)hh * 2816 + (c >> 4) * 1408 + (c & 15) * 4] =
                    (f16)(acc[nt][r] + bv[r]);
            }
        }
    }
}

// ---------- final projection: grid (352, 2), fp32 out ----------
__global__ __launch_bounds__(256) void gemm_out(
    const f16* __restrict__ A, const f16* __restrict__ W, const float* __restrict__ bias,
    float* __restrict__ outp)
{
    __shared__ __align__(16) f16 Alds[64 * 136];
    const int m0 = blockIdx.x * 64, n0 = blockIdx.y * 64;
    const int tid = threadIdx.x;
    const int w = tid >> 6, lane = tid & 63, quad = lane >> 4, nn = lane & 15;

    for (int i = tid; i < 1024; i += 256) {
        int r = i >> 4, c = i & 15;
        *(uint4*)&Alds[r * 136 + c * 8] = *(const uint4*)&A[(size_t)(m0 + r) * 128 + c * 8];
    }
    __syncthreads();

    const int oc = n0 + w * 16 + nn;
    f16x8 af[4];
    #pragma unroll
    for (int ks = 0; ks < 4; ks++)
        af[ks] = *(const f16x8*)&W[(size_t)oc * 128 + ks * 32 + quad * 8];
    f32x4 acc[4] = {};
    #pragma unroll
    for (int ks = 0; ks < 4; ks++)
        #pragma unroll
        for (int nt = 0; nt < 4; nt++) {
            f16x8 bf = *(const f16x8*)&Alds[(nt * 16 + nn) * 136 + ks * 32 + quad * 8];
            acc[nt] = __builtin_amdgcn_mfma_f32_16x16x32_f16(af[ks], bf, acc[nt], 0, 0, 0);
        }
    float bv[4];
    #pragma unroll
    for (int r = 0; r < 4; r++) bv[r] = bias[n0 + w * 16 + quad * 4 + r];
    #pragma unroll
    for (int nt = 0; nt < 4; nt++) {
        int pos = m0 + nt * 16 + nn;
        f32x4 vv;
        #pragma unroll
        for (int r = 0; r < 4; r++) vv[r] = acc[nt][r] + bv[r];
        *(f32x4*)&outp[(size_t)pos * 128 + n0 + w * 16 + quad * 4] = vv;
    }
}

// ---------- MFMA neighborhood attention v7: v6 pipeline + coalesced K/V ----------
// Identical schedule to v6 (2 waves x 16 key rows x 4 qsets, row-pipelined
// register PV, branchless masks, XCD swizzle). Only change: K/V loads now hit
// the re-laid-out kh2/vh2 buffers, so every main-loop load is ONE dense region
// (K: 1KB window; V: 512B window, lane l <-> l*8B) instead of a 16-line gather
// strided 512B / 45KB. rj0 is 4-aligned for the V layout (window invariant
// sj-7 <= rj0 <= sj verified for all 11 j-tiles; mask shift stays <= 7; the
// g=22 overshoot at rj0=60 is always column-masked and lands in padding).
__global__ __launch_bounds__(128) void attn_mfma(
    const f16* __restrict__ qh,    // [N][128] Q, pre-scaled by QSC
    const f16* __restrict__ kh2,   // [aa][h][j][ch32]
    const f16* __restrict__ vh2,   // [aa][h][half][g][ch16][jr]
    const float* __restrict__ rpbp,
    f16* __restrict__ ao)          // [N][128]
{
    const int bx = ((blockIdx.x & 7) << 2) + (blockIdx.x >> 3);   // XCD-contiguous i-tiles
    const int i0 = bx * 8;
    const int j0 = blockIdx.y * 8;
    const int h  = blockIdx.z;
    const int tid = threadIdx.x;
    const int w = tid >> 6, lane = tid & 63;
    const int quad = lane >> 4, nn = lane & 15;

    const int ri0 = min(max(i0 - 12, 0), TT - 32);
    const int rj0 = min(max(j0 - 12, 0), PP - WIN) & ~3;   // 4-aligned for vh2

    __shared__ __align__(16) float Olds[64][60];   // wave-1 partials (stride 60: 0 conflicts)

    int si_[4];
    unsigned pm_[4][4];            // packed-f16 column masks per output word
    f16x8 qf[4];
    const float* rpq[4];
    const float* rp_h = rpbp + h * RPBSZ;
    const int aa0 = ri0 + w * 16;  // this wave's first key row

    #pragma unroll
    for (int q = 0; q < 4; q++) {
        int ql = q * 16 + nn;
        int qi = i0 + (ql >> 3), qj = j0 + (ql & 7);
        int si = min(max(qi - 12, 0), TT - WIN);
        int sj = min(max(qj - 12, 0), PP - WIN);
        si_[q] = si;
        unsigned cm = 0x1FFFFFFu << (sj - rj0);       // shift <= 7
        #pragma unroll
        for (int t = 0; t < 4; t++) {
            int k0 = (t >> 1) * 16 + quad * 4 + (t & 1) * 2;
            pm_[q][t] = (((cm >> k0) & 1u) ? 0xFFFFu : 0u)
                      | (((cm >> (k0 + 1)) & 1u) ? 0xFFFF0000u : 0u);
        }
        qf[q] = *(const f16x8*)&qh[(size_t)(qi * PP + qj) * 128 + h * HD + quad * 8];
        rpq[q] = rp_h + (aa0 - qi + 24) * RPBW + (rj0 - qj + 24) + quad * 4;
    }

    const int b0 = min(rj0 + nn, PP - 1);
    const int b1 = min(rj0 + 16 + nn, PP - 1);
    const f16x4 ones4 = {(f16)1.f, (f16)1.f, (f16)1.f, (f16)1.f};

    // dense per-lane base pointers (advance by KVROW per key row)
    const f16* kb = kh2 + (size_t)(aa0 * 4 + h) * 2816 + quad * 8;
    const f16* vb = vh2 + (size_t)(aa0 * 4 + h) * 2816 + ((rj0 >> 2) + quad) * 64 + nn * 4;

    f32x4 O[4][2] = {};            // [qset][ch-half]; regs = queries, lane nn = channel
    f32x4 lacc[4] = {};
    union PB { unsigned u[2]; f16x4 v; };
    PB pa_[4], pb_[4];             // pending P (row aa-1), masked, packed
    f32x4 za_[4], zb_[4];          // rpb C-init for current row

    // ---- prologue: row aa0 -> S/exp only (its PV runs in iter c=1) ----
    int aa = aa0;
    f16x8 kf0 = *(const f16x8*)(kb + (size_t)b0 * 32);
    f16x8 kf1 = *(const f16x8*)(kb + (size_t)b1 * 32);
    f16x4 vfA0 = *(const f16x4u*)vb;                  // keys  0-15, ch lo
    f16x4 vfB0 = *(const f16x4u*)(vb + 256);          // keys 16-31, ch lo
    f16x4 vfA1 = *(const f16x4u*)(vb + 1408);         // keys  0-15, ch hi
    f16x4 vfB1 = *(const f16x4u*)(vb + 1664);         // keys 16-31, ch hi
    #pragma unroll
    for (int q = 0; q < 4; q++) {
        za_[q] = *(const f32x4u*)rpq[q];
        zb_[q] = *(const f32x4u*)(rpq[q] + 16);
        rpq[q] += RPBW;
    }
    #pragma unroll
    for (int q = 0; q < 4; q++) {
        f32x4 s0 = __builtin_amdgcn_mfma_f32_16x16x32_f16(kf0, qf[q], za_[q], 0, 0, 0);
        f32x4 s1 = __builtin_amdgcn_mfma_f32_16x16x32_f16(kf1, qf[q], zb_[q], 0, 0, 0);
        bool rv = (unsigned)(aa - si_[q]) <= 24u;
        float p[8];
        #pragma unroll
        for (int r = 0; r < 4; r++) { p[r] = EXP2(s0[r]); p[r + 4] = EXP2(s1[r]); }
        PkU u0, u1, u2, u3;
        u0.h = __builtin_amdgcn_cvt_pkrtz(p[0], p[1]);
        u1.h = __builtin_amdgcn_cvt_pkrtz(p[2], p[3]);
        u2.h = __builtin_amdgcn_cvt_pkrtz(p[4], p[5]);
        u3.h = __builtin_amdgcn_cvt_pkrtz(p[6], p[7]);
        pa_[q].u[0] = rv ? (u0.u & pm_[q][0]) : 0u;
        pa_[q].u[1] = rv ? (u1.u & pm_[q][1]) : 0u;
        pb_[q].u[0] = rv ? (u2.u & pm_[q][2]) : 0u;
        pb_[q].u[1] = rv ? (u3.u & pm_[q][3]) : 0u;
    }
    // prefetch K for row aa0+1
    kb += KVROW;
    f16x8 nkf0 = *(const f16x8*)(kb + (size_t)b0 * 32);
    f16x8 nkf1 = *(const f16x8*)(kb + (size_t)b1 * 32);

    // ---- pipelined main loop: rows aa0+1 .. aa0+15 ----
    #pragma unroll 1
    for (int c = 1; c < 16; ++c) {
        aa = aa0 + c;
        kf0 = nkf0; kf1 = nkf1;                       // K(aa), prefetched last iter

        // (a) issue rpb loads for row aa (oldest in VMEM queue -> S wait is cheap)
        #pragma unroll
        for (int q = 0; q < 4; q++) {
            za_[q] = *(const f32x4u*)rpq[q];
            zb_[q] = *(const f32x4u*)(rpq[q] + 16);
            rpq[q] += RPBW;
        }

        // (b) PV for row aa-1 (covers the rpb latency with 24 MFMAs)
        #pragma unroll
        for (int q = 0; q < 4; q++) {
            O[q][0] = __builtin_amdgcn_mfma_f32_16x16x16f16(pa_[q].v, vfA0, O[q][0], 0, 0, 0);
            O[q][0] = __builtin_amdgcn_mfma_f32_16x16x16f16(pb_[q].v, vfB0, O[q][0], 0, 0, 0);
            O[q][1] = __builtin_amdgcn_mfma_f32_16x16x16f16(pa_[q].v, vfA1, O[q][1], 0, 0, 0);
            O[q][1] = __builtin_amdgcn_mfma_f32_16x16x16f16(pb_[q].v, vfB1, O[q][1], 0, 0, 0);
            lacc[q] = __builtin_amdgcn_mfma_f32_16x16x16f16(pa_[q].v, ones4, lacc[q], 0, 0, 0);
            lacc[q] = __builtin_amdgcn_mfma_f32_16x16x16f16(pb_[q].v, ones4, lacc[q], 0, 0, 0);
        }

        // (c) issue V loads for row aa (consumed by next iter's PV) - dense 512B each
        vb += KVROW;
        vfA0 = *(const f16x4u*)vb;
        vfB0 = *(const f16x4u*)(vb + 256);
        vfA1 = *(const f16x4u*)(vb + 1408);
        vfB1 = *(const f16x4u*)(vb + 1664);

        // (d) issue K prefetch for row aa+1 (last iter reads padded row: unused)
        kb += KVROW;
        nkf0 = *(const f16x8*)(kb + (size_t)b0 * 32);
        nkf1 = *(const f16x8*)(kb + (size_t)b1 * 32);

        // (e) S + exp for row aa -> pending P (pa_/pb_ free: consumed in (b))
        #pragma unroll
        for (int q = 0; q < 4; q++) {
            f32x4 s0 = __builtin_amdgcn_mfma_f32_16x16x32_f16(kf0, qf[q], za_[q], 0, 0, 0);
            f32x4 s1 = __builtin_amdgcn_mfma_f32_16x16x32_f16(kf1, qf[q], zb_[q], 0, 0, 0);
            bool rv = (unsigned)(aa - si_[q]) <= 24u;
            float p[8];
            #pragma unroll
            for (int r = 0; r < 4; r++) { p[r] = EXP2(s0[r]); p[r + 4] = EXP2(s1[r]); }
            PkU u0, u1, u2, u3;
            u0.h = __builtin_amdgcn_cvt_pkrtz(p[0], p[1]);
            u1.h = __builtin_amdgcn_cvt_pkrtz(p[2], p[3]);
            u2.h = __builtin_amdgcn_cvt_pkrtz(p[4], p[5]);
            u3.h = __builtin_amdgcn_cvt_pkrtz(p[6], p[7]);
            pa_[q].u[0] = rv ? (u0.u & pm_[q][0]) : 0u;
            pa_[q].u[1] = rv ? (u1.u & pm_[q][1]) : 0u;
            pb_[q].u[0] = rv ? (u2.u & pm_[q][2]) : 0u;
            pb_[q].u[1] = rv ? (u3.u & pm_[q][3]) : 0u;
        }
    }

    // ---- epilogue PV: last row (aa0+15) ----
    #pragma unroll
    for (int q = 0; q < 4; q++) {
        O[q][0] = __builtin_amdgcn_mfma_f32_16x16x16f16(pa_[q].v, vfA0, O[q][0], 0, 0, 0);
        O[q][0] = __builtin_amdgcn_mfma_f32_16x16x16f16(pb_[q].v, vfB0, O[q][0], 0, 0, 0);
        O[q][1] = __builtin_amdgcn_mfma_f32_16x16x16f16(pa_[q].v, vfA1, O[q][1], 0, 0, 0);
        O[q][1] = __builtin_amdgcn_mfma_f32_16x16x16f16(pb_[q].v, vfB1, O[q][1], 0, 0, 0);
        lacc[q] = __builtin_amdgcn_mfma_f32_16x16x16f16(pa_[q].v, ones4, lacc[q], 0, 0, 0);
        lacc[q] = __builtin_amdgcn_mfma_f32_16x16x16f16(pb_[q].v, ones4, lacc[q], 0, 0, 0);
    }

    // ---- merge: wave1 stores partials, wave0 adds and finishes ----
    if (w == 1) {
        float* ob = &Olds[lane][0];
        #pragma unroll
        for (int q = 0; q < 4; q++) {
            *(f32x4*)&ob[q * 12]     = O[q][0];
            *(f32x4*)&ob[q * 12 + 4] = O[q][1];
            *(f32x4*)&ob[q * 12 + 8] = lacc[q];
        }
    }
    __syncthreads();
    if (w == 0) {
        const float* ob = &Olds[lane][0];
        #pragma unroll
        for (int q = 0; q < 4; q++) {
            f32x4 o0 = O[q][0] + *(const f32x4*)&ob[q * 12];
            f32x4 o1 = O[q][1] + *(const f32x4*)&ob[q * 12 + 4];
            f32x4 la = lacc[q] + *(const f32x4*)&ob[q * 12 + 8];
            #pragma unroll
            for (int r = 0; r < 4; r++) {
                float li = 1.f / la[r];
                int ql = q * 16 + quad * 4 + r;
                int qi = i0 + (ql >> 3), qj = j0 + (ql & 7);
                size_t base = (size_t)(qi * PP + qj) * CC + h * HD;
                ao[base + nn]      = (f16)(o0[r] * li);
                ao[base + 16 + nn] = (f16)(o1[r] * li);
            }
        }
    }
}

extern "C" void kernel_launch(void* const* d_in, const int* in_sizes, int n_in,
                              void* d_out, int out_size, void* d_ws, size_t ws_size,
                              hipStream_t stream) {
    (void)in_sizes; (void)n_in; (void)out_size; (void)ws_size;
    const float* x    = (const float*)d_in[0];
    const float* cond = (const float*)d_in[1];
    const float* mask = (const float*)d_in[2];
    const float* lw   = (const float*)d_in[3];
    const float* lb   = (const float*)d_in[4];
    const float* qw   = (const float*)d_in[5];
    const float* qb   = (const float*)d_in[6];
    const float* rpb  = (const float*)d_in[7];
    const float* pw   = (const float*)d_in[8];
    const float* pb   = (const float*)d_in[9];
    float* outp       = (float*)d_out;

    float* ws   = (float*)d_ws;
    float* qbs  = ws;                 // 384
    float* b2s  = qbs + 384;          // 384
    float* rpbp = b2s + 384;          // 10240 padded
    f16* lwh  = (f16*)(rpbp + 10240);             // 128*160
    f16* qwh  = lwh + 20480;                      // 384*128
    f16* pwh  = qwh + 49152;                      // 128*128
    f16* w2h  = pwh + 16384;                      // 384*128
    f16* yh   = w2h + 49152;                      // NN*128
    f16* qh   = yh + (size_t)NN * 128;            // NN*128 Q
    f16* kh2  = qh + (size_t)NN * 128;            // 258 rows * 11264
    f16* vh2  = kh2 + (size_t)KVAARWS * KVROW;    // 258 rows * 11264
    f16* ao   = vh2 + (size_t)KVAARWS * KVROW;    // NN*128

    prep<<<228, 256, 0, stream>>>(lw, qw, pw, qb, pb, rpb, lwh, qwh, pwh, w2h, qbs, b2s, rpbp);
    fusion_gemm<<<dim3(352, 2), 256, 0, stream>>>(x, cond, mask, lwh, lb, yh);
    gemm_qkv<<<dim3(352, 6), 256, 0, stream>>>(yh, qwh, qbs, qh, kh2, vh2);
    attn_mfma<<<dim3(TT / 8, PP / 8, HEADS), 128, 0, stream>>>(qh, kh2, vh2, rpbp, ao);
    gemm_qkv<<<dim3(352, 6), 256, 0, stream>>>(ao, w2h, b2s, qh, kh2, vh2);   // fused proj+qkv
    attn_mfma<<<dim3(TT / 8, PP / 8, HEADS), 128, 0, stream>>>(qh, kh2, vh2, rpbp, ao);
    gemm_out<<<dim3(352, 2), 256, 0, stream>>>(ao, pwh, pb, outp);
}

// Round 7
// 197.525 us; speedup vs baseline: 3.4045x; 1.0505x over previous
//
#include <hip/hip_runtime.h>
#include <hip/hip_fp16.h>

#define TT 256
#define PP 88
#define CC 128
#define NN (TT * PP)          // 22528 positions
#define HEADS 4
#define HD 32
#define WIN 25
#define RPBW 49
#define RPBSZ (RPBW * RPBW)   // 2401
#define SCALE 0.17677669529663687f   // 1/sqrt(32)
#define LOG2E 1.4426950408889634f
#define QSC (SCALE * LOG2E)          // fold exp->exp2 into Q path

// K layout: kh2[aa][h][j:88][ch32]   -> row stride (aa) = 11264, (aa,h) block = 2816
// V layout: vh2[aa][h][half:2][g:22][ch16][jr:4] -> same strides; dense 512B per attn load
#define KVROW 11264           // f16 elems per aa row (4 heads x 2816)
#define KVAARWS 258           // aa rows allocated (256 + prefetch/overshoot pad)

#if __has_builtin(__builtin_amdgcn_exp2f)
#define EXP2(x) __builtin_amdgcn_exp2f(x)
#else
#define EXP2(x) exp2f(x)
#endif

typedef _Float16 f16;
typedef f16 f16x8 __attribute__((ext_vector_type(8)));
typedef f16 f16x8u __attribute__((ext_vector_type(8), aligned(4)));
typedef f16 f16x4 __attribute__((ext_vector_type(4)));
typedef f16 f16x4u __attribute__((ext_vector_type(4), aligned(4)));
typedef float f32x4 __attribute__((ext_vector_type(4)));
typedef float f32x4u __attribute__((ext_vector_type(4), aligned(4)));
typedef __fp16 hf16x2 __attribute__((ext_vector_type(2)));
union PkU { hf16x2 h; unsigned u; };

// ---------- prep: repack (b<192) + parallel b2s (192<=b<216) + MFMA wcomb (216<=b<228) ----------
__global__ __launch_bounds__(256) void prep(
    const float* __restrict__ lw, const float* __restrict__ qw,
    const float* __restrict__ pw, const float* __restrict__ qb,
    const float* __restrict__ pb, const float* __restrict__ rpb,
    f16* __restrict__ lwh, f16* __restrict__ qwh, f16* __restrict__ pwh,
    f16* __restrict__ w2h, float* __restrict__ qbs, float* __restrict__ b2s,
    float* __restrict__ rpbp)
{
    const int b = blockIdx.x;
    if (b < 192) {
        int idx = b * 256 + threadIdx.x;              // covers 49152
        if (idx < 128 * 160) {                        // fusion W: [128][131] -> [128][160] pad
            int r = idx / 160, c = idx - r * 160;
            lwh[idx] = (f16)(c < 131 ? lw[r * 131 + c] : 0.f);
        }
        if (idx < 384 * 128) {                        // qkv W, Q rows scaled by QSC
            float v = qw[idx];
            if (idx < 128 * 128) v *= QSC;
            qwh[idx] = (f16)v;
        }
        if (idx < 128 * 128) pwh[idx] = (f16)pw[idx];
        if (idx < 384) qbs[idx] = qb[idx] * (idx < 128 ? QSC : 1.f);
        if (idx < 10240) rpbp[idx] = (idx < 4 * RPBSZ) ? rpb[idx] * LOG2E : 0.f;
    } else if (b < 216) {
        // b2s[i] = (qb[i] + qw[i,:]·pb) * sc_i ; 16 lanes per output, shuffle-reduce
        int t = (b - 192) * 256 + threadIdx.x;        // [0, 6144)
        int i = t >> 4, l = t & 15;
        if (i < 384) {
            float s = 0.f;
            #pragma unroll
            for (int j = l * 8; j < l * 8 + 8; j++) s += qw[i * 128 + j] * pb[j];
            s += __shfl_xor(s, 1); s += __shfl_xor(s, 2);
            s += __shfl_xor(s, 4); s += __shfl_xor(s, 8);
            if (l == 0) b2s[i] = (qb[i] + s) * (i < 128 ? QSC : 1.f);
        }
    } else {
        // w2h[i][k] = sc_i * sum_j qw[i][j] pw[j][k]
        const int bw = b - 216;                       // 0..11
        const int m0 = (bw & 1) * 64;                 // k-tile
        const int n0 = (bw >> 1) * 64;                // i-tile
        const int tid = threadIdx.x;
        const int w = tid >> 6, lane = tid & 63, quad = lane >> 4, nn = lane & 15;
        const int krow = m0 + w * 16 + nn;
        f16x8 af[4];
        #pragma unroll
        for (int ks = 0; ks < 4; ks++) {
            union { f16 e[8]; f16x8 v; } t;
            #pragma unroll
            for (int e = 0; e < 8; e++)
                t.e[e] = (f16)pw[(ks * 32 + quad * 8 + e) * 128 + krow];
            af[ks] = t.v;
        }
        f32x4 acc[4] = {};
        #pragma unroll
        for (int nt = 0; nt < 4; nt++) {
            int irow = n0 + nt * 16 + nn;
            #pragma unroll
            for (int ks = 0; ks < 4; ks++) {
                const float* qr = &qw[(size_t)irow * 128 + ks * 32 + quad * 8];
                float4 a = *(const float4*)qr, bq = *(const float4*)(qr + 4);
                PkU u0, u1, u2, u3;
                u0.h = __builtin_amdgcn_cvt_pkrtz(a.x, a.y);
                u1.h = __builtin_amdgcn_cvt_pkrtz(a.z, a.w);
                u2.h = __builtin_amdgcn_cvt_pkrtz(bq.x, bq.y);
                u3.h = __builtin_amdgcn_cvt_pkrtz(bq.z, bq.w);
                union { unsigned u[4]; f16x8 v; } bb;
                bb.u[0] = u0.u; bb.u[1] = u1.u; bb.u[2] = u2.u; bb.u[3] = u3.u;
                acc[nt] = __builtin_amdgcn_mfma_f32_16x16x32_f16(af[ks], bb.v, acc[nt], 0, 0, 0);
            }
        }
        #pragma unroll
        for (int nt = 0; nt < 4; nt++) {
            int i = n0 + nt * 16 + nn;
            float sc = (i < 128) ? QSC : 1.f;
            PkU p0, p1;
            p0.h = __builtin_amdgcn_cvt_pkrtz(acc[nt][0] * sc, acc[nt][1] * sc);
            p1.h = __builtin_amdgcn_cvt_pkrtz(acc[nt][2] * sc, acc[nt][3] * sc);
            *(uint2*)&w2h[(size_t)i * 128 + m0 + w * 16 + quad * 4] = make_uint2(p0.u, p1.u);
        }
    }
}

// ---------- fusion GEMM: yh = relu(cat @ lwh^T + lb); grid (352, 2) ----------
__global__ __launch_bounds__(256) void fusion_gemm(
    const float* __restrict__ x, const float* __restrict__ cond, const float* __restrict__ mask,
    const f16* __restrict__ lwh, const float* __restrict__ lb, f16* __restrict__ yh)
{
    __shared__ __align__(16) f16 Alds[64 * 168];
    const int m0 = blockIdx.x * 64, n0 = blockIdx.y * 64;
    const int tid = threadIdx.x;
    const int w = tid >> 6, lane = tid & 63, quad = lane >> 4, nn = lane & 15;

    {   // stage cat rows (f16)
        int r = tid >> 2, cpart = tid & 3;
        size_t pos = m0 + r;
        *(uint4*)&Alds[r * 168 + 128 + cpart * 8] = make_uint4(0, 0, 0, 0);
        const float* xr = x + pos * 128 + cpart * 32;
        #pragma unroll
        for (int t = 0; t < 4; t++) {
            float4 a = *(const float4*)(xr + t * 8);
            float4 b = *(const float4*)(xr + t * 8 + 4);
            PkU p0, p1, p2, p3;
            p0.h = __builtin_amdgcn_cvt_pkrtz(a.x, a.y);
            p1.h = __builtin_amdgcn_cvt_pkrtz(a.z, a.w);
            p2.h = __builtin_amdgcn_cvt_pkrtz(b.x, b.y);
            p3.h = __builtin_amdgcn_cvt_pkrtz(b.z, b.w);
            *(uint4*)&Alds[r * 168 + cpart * 32 + t * 8] = make_uint4(p0.u, p1.u, p2.u, p3.u);
        }
        if (cpart == 0) {
            Alds[r * 168 + 128] = (f16)cond[pos * 2];
            Alds[r * 168 + 129] = (f16)cond[pos * 2 + 1];
            Alds[r * 168 + 130] = (f16)mask[pos];
        }
    }
    __syncthreads();

    const int oc = n0 + w * 16 + nn;
    f16x8 af[5];
    #pragma unroll
    for (int ks = 0; ks < 5; ks++)
        af[ks] = *(const f16x8*)&lwh[(size_t)oc * 160 + ks * 32 + quad * 8];
    f32x4 acc[4] = {};
    #pragma unroll
    for (int ks = 0; ks < 5; ks++)
        #pragma unroll
        for (int nt = 0; nt < 4; nt++) {
            f16x8 bf = *(const f16x8*)&Alds[(nt * 16 + nn) * 168 + ks * 32 + quad * 8];
            acc[nt] = __builtin_amdgcn_mfma_f32_16x16x32_f16(af[ks], bf, acc[nt], 0, 0, 0);
        }
    float bv[4];
    #pragma unroll
    for (int r = 0; r < 4; r++) bv[r] = lb[n0 + w * 16 + quad * 4 + r];
    #pragma unroll
    for (int nt = 0; nt < 4; nt++) {
        int pos = m0 + nt * 16 + nn;
        PkU p0, p1;
        p0.h = __builtin_amdgcn_cvt_pkrtz(fmaxf(acc[nt][0] + bv[0], 0.f), fmaxf(acc[nt][1] + bv[1], 0.f));
        p1.h = __builtin_amdgcn_cvt_pkrtz(fmaxf(acc[nt][2] + bv[2], 0.f), fmaxf(acc[nt][3] + bv[3], 0.f));
        *(uint2*)&yh[(size_t)pos * 128 + n0 + w * 16 + quad * 4] = make_uint2(p0.u, p1.u);
    }
}

// ---------- qkv GEMM: grid (352, 6); Q -> qh[pos][128], K -> kh2, V -> vh2 ----------
// Read-side coalescing for attn: scatter cost moved to the (once-per-element)
// write side; attn reads each element ~16x from dense windows.
__global__ __launch_bounds__(256) void gemm_qkv(
    const f16* __restrict__ A, const f16* __restrict__ W, const float* __restrict__ bias,
    f16* __restrict__ qh, f16* __restrict__ kh2, f16* __restrict__ vh2)
{
    __shared__ __align__(16) f16 Alds[64 * 136];
    const int m0 = blockIdx.x * 64, n0 = blockIdx.y * 64;
    const int tid = threadIdx.x;
    const int w = tid >> 6, lane = tid & 63, quad = lane >> 4, nn = lane & 15;

    for (int i = tid; i < 1024; i += 256) {
        int r = i >> 4, c = i & 15;
        *(uint4*)&Alds[r * 136 + c * 8] = *(const uint4*)&A[(size_t)(m0 + r) * 128 + c * 8];
    }
    __syncthreads();

    const int oc = n0 + w * 16 + nn;
    f16x8 af[4];
    #pragma unroll
    for (int ks = 0; ks < 4; ks++)
        af[ks] = *(const f16x8*)&W[(size_t)oc * 128 + ks * 32 + quad * 8];
    f32x4 acc[4] = {};
    #pragma unroll
    for (int ks = 0; ks < 4; ks++)
        #pragma unroll
        for (int nt = 0; nt < 4; nt++) {
            f16x8 bf = *(const f16x8*)&Alds[(nt * 16 + nn) * 136 + ks * 32 + quad * 8];
            acc[nt] = __builtin_amdgcn_mfma_f32_16x16x32_f16(af[ks], bf, acc[nt], 0, 0, 0);
        }
    float bv[4];
    #pragma unroll
    for (int r = 0; r < 4; r++) bv[r] = bias[n0 + w * 16 + quad * 4 + r];

    if (n0 < 128) {                                   // ---- Q: qh[pos][128]
        #pragma unroll
        for (int nt = 0; nt < 4; nt++) {
            int pos = m0 + nt * 16 + nn;
            PkU p0, p1;
            p0.h = __builtin_amdgcn_cvt_pkrtz(acc[nt][0] + bv[0], acc[nt][1] + bv[1]);
            p1.h = __builtin_amdgcn_cvt_pkrtz(acc[nt][2] + bv[2], acc[nt][3] + bv[3]);
            *(uint2*)&qh[(size_t)pos * 128 + n0 + w * 16 + quad * 4] = make_uint2(p0.u, p1.u);
        }
    } else if (n0 < 256) {                            // ---- K: kh2[aa][h][j][ch32]
        const int ch = n0 - 128 + w * 16 + quad * 4;  // 4 consecutive, same ch32 block
        const int hh = ch >> 5, c32 = ch & 31;
        #pragma unroll
        for (int nt = 0; nt < 4; nt++) {
            int pos = m0 + nt * 16 + nn;
            int aa = pos / 88, j = pos - aa * 88;
            PkU p0, p1;
            p0.h = __builtin_amdgcn_cvt_pkrtz(acc[nt][0] + bv[0], acc[nt][1] + bv[1]);
            p1.h = __builtin_amdgcn_cvt_pkrtz(acc[nt][2] + bv[2], acc[nt][3] + bv[3]);
            *(uint2*)&kh2[((size_t)(aa * 4 + hh) * 88 + j) * 32 + c32] = make_uint2(p0.u, p1.u);
        }
    } else {                                          // ---- V: vh2[aa][h][half][g][ch16][jr]
        const int chb = n0 - 256 + w * 16 + quad * 4;
        #pragma unroll
        for (int nt = 0; nt < 4; nt++) {
            int pos = m0 + nt * 16 + nn;
            int aa = pos / 88, j = pos - aa * 88;
            size_t vb = (size_t)(aa * 4) * 2816 + (j >> 2) * 64 + (j & 3);
            #pragma unroll
            for (int r = 0; r < 4; r++) {
                int chg = chb + r;
                int hh = chg >> 5, c = chg & 31;
                vh2[vb + (size_t)hh * 2816 + (c >> 4) * 1408 + (c & 15) * 4] =
                    (f16)(acc[nt][r] + bv[r]);
            }
        }
    }
}

// ---------- final projection: grid (352, 2), fp32 out ----------
__global__ __launch_bounds__(256) void gemm_out(
    const f16* __restrict__ A, const f16* __restrict__ W, const float* __restrict__ bias,
    float* __restrict__ outp)
{
    __shared__ __align__(16) f16 Alds[64 * 136];
    const int m0 = blockIdx.x * 64, n0 = blockIdx.y * 64;
    const int tid = threadIdx.x;
    const int w = tid >> 6, lane = tid & 63, quad = lane >> 4, nn = lane & 15;

    for (int i = tid; i < 1024; i += 256) {
        int r = i >> 4, c = i & 15;
        *(uint4*)&Alds[r * 136 + c * 8] = *(const uint4*)&A[(size_t)(m0 + r) * 128 + c * 8];
    }
    __syncthreads();

    const int oc = n0 + w * 16 + nn;
    f16x8 af[4];
    #pragma unroll
    for (int ks = 0; ks < 4; ks++)
        af[ks] = *(const f16x8*)&W[(size_t)oc * 128 + ks * 32 + quad * 8];
    f32x4 acc[4] = {};
    #pragma unroll
    for (int ks = 0; ks < 4; ks++)
        #pragma unroll
        for (int nt = 0; nt < 4; nt++) {
            f16x8 bf = *(const f16x8*)&Alds[(nt * 16 + nn) * 136 + ks * 32 + quad * 8];
            acc[nt] = __builtin_amdgcn_mfma_f32_16x16x32_f16(af[ks], bf, acc[nt], 0, 0, 0);
        }
    float bv[4];
    #pragma unroll
    for (int r = 0; r < 4; r++) bv[r] = bias[n0 + w * 16 + quad * 4 + r];
    #pragma unroll
    for (int nt = 0; nt < 4; nt++) {
        int pos = m0 + nt * 16 + nn;
        f32x4 vv;
        #pragma unroll
        for (int r = 0; r < 4; r++) vv[r] = acc[nt][r] + bv[r];
        *(f32x4*)&outp[(size_t)pos * 128 + n0 + w * 16 + quad * 4] = vv;
    }
}

// ---------- MFMA neighborhood attention v8: 4-row i-tiles, 2x wave supply ----------
// v7 schedule kept verbatim (row-pipelined register PV, branchless masks,
// coalesced kh2/vh2, XCD chunking); the i-tile shrinks 8->4 query rows:
//   grid 2816 blocks x 2 waves (5632 waves, ~5.5/SIMD nominal vs v7's 2.75);
//   per block: 32 queries = 2 qsets, key-row span 28, 14 rows/wave;
//   per-wave register state halves -> high residency, no spill risk;
//   total work SHRINKS (S-MFMAs/query -12%, rpb loads -12%) since the key-row
//   pad is 28 vs 32 for half the queries; each key row still loaded by exactly
//   one wave (not the v2 mistake). Cost: K/V refetched across 2x blocks
//   (FETCH ~12->~19 MB, L2-absorbed). rpb overshoot reads (row idx -3..51,
//   col to 55) stay inside the zero-padded rpbp/workspace and are row-masked.
__global__ __launch_bounds__(128) void attn_mfma(
    const f16* __restrict__ qh,    // [N][128] Q, pre-scaled by QSC
    const f16* __restrict__ kh2,   // [aa][h][j][ch32]
    const f16* __restrict__ vh2,   // [aa][h][half][g][ch16][jr]
    const float* __restrict__ rpbp,
    f16* __restrict__ ao)          // [N][128]
{
    const int bx = ((blockIdx.x & 7) << 3) + (blockIdx.x >> 3);   // XCD-contiguous i-tiles
    const int i0 = bx * 4;
    const int j0 = blockIdx.y * 8;
    const int h  = blockIdx.z;
    const int tid = threadIdx.x;
    const int w = tid >> 6, lane = tid & 63;
    const int quad = lane >> 4, nn = lane & 15;

    const int ri0 = min(max(i0 - 12, 0), TT - 28);         // 28-row key span
    const int rj0 = min(max(j0 - 12, 0), PP - WIN) & ~3;   // 4-aligned for vh2

    __shared__ __align__(16) float Olds[64][28];   // wave-1 partials (2-way/quarter = free)

    int si_[2];
    unsigned pm_[2][4];            // packed-f16 column masks per output word
    f16x8 qf[2];
    const float* rpq[2];
    const float* rp_h = rpbp + h * RPBSZ;
    const int aa0 = ri0 + w * 14;  // this wave's first key row (14 rows/wave)

    #pragma unroll
    for (int q = 0; q < 2; q++) {
        int ql = q * 16 + nn;
        int qi = i0 + (ql >> 3), qj = j0 + (ql & 7);
        int si = min(max(qi - 12, 0), TT - WIN);
        int sj = min(max(qj - 12, 0), PP - WIN);
        si_[q] = si;
        unsigned cm = 0x1FFFFFFu << (sj - rj0);       // shift <= 7
        #pragma unroll
        for (int t = 0; t < 4; t++) {
            int k0 = (t >> 1) * 16 + quad * 4 + (t & 1) * 2;
            pm_[q][t] = (((cm >> k0) & 1u) ? 0xFFFFu : 0u)
                      | (((cm >> (k0 + 1)) & 1u) ? 0xFFFF0000u : 0u);
        }
        qf[q] = *(const f16x8*)&qh[(size_t)(qi * PP + qj) * 128 + h * HD + quad * 8];
        rpq[q] = rp_h + (aa0 - qi + 24) * RPBW + (rj0 - qj + 24) + quad * 4;
    }

    const int b0 = min(rj0 + nn, PP - 1);
    const int b1 = min(rj0 + 16 + nn, PP - 1);
    const f16x4 ones4 = {(f16)1.f, (f16)1.f, (f16)1.f, (f16)1.f};

    // dense per-lane base pointers (advance by KVROW per key row)
    const f16* kb = kh2 + (size_t)(aa0 * 4 + h) * 2816 + quad * 8;
    const f16* vb = vh2 + (size_t)(aa0 * 4 + h) * 2816 + ((rj0 >> 2) + quad) * 64 + nn * 4;

    f32x4 O[2][2] = {};            // [qset][ch-half]; regs = queries, lane nn = channel
    f32x4 lacc[2] = {};
    union PB { unsigned u[2]; f16x4 v; };
    PB pa_[2], pb_[2];             // pending P (row aa-1), masked, packed
    f32x4 za_[2], zb_[2];          // rpb C-init for current row

    // ---- prologue: row aa0 -> S/exp only (its PV runs in iter c=1) ----
    int aa = aa0;
    f16x8 kf0 = *(const f16x8*)(kb + (size_t)b0 * 32);
    f16x8 kf1 = *(const f16x8*)(kb + (size_t)b1 * 32);
    f16x4 vfA0 = *(const f16x4u*)vb;                  // keys  0-15, ch lo
    f16x4 vfB0 = *(const f16x4u*)(vb + 256);          // keys 16-31, ch lo
    f16x4 vfA1 = *(const f16x4u*)(vb + 1408);         // keys  0-15, ch hi
    f16x4 vfB1 = *(const f16x4u*)(vb + 1664);         // keys 16-31, ch hi
    #pragma unroll
    for (int q = 0; q < 2; q++) {
        za_[q] = *(const f32x4u*)rpq[q];
        zb_[q] = *(const f32x4u*)(rpq[q] + 16);
        rpq[q] += RPBW;
    }
    #pragma unroll
    for (int q = 0; q < 2; q++) {
        f32x4 s0 = __builtin_amdgcn_mfma_f32_16x16x32_f16(kf0, qf[q], za_[q], 0, 0, 0);
        f32x4 s1 = __builtin_amdgcn_mfma_f32_16x16x32_f16(kf1, qf[q], zb_[q], 0, 0, 0);
        bool rv = (unsigned)(aa - si_[q]) <= 24u;
        float p[8];
        #pragma unroll
        for (int r = 0; r < 4; r++) { p[r] = EXP2(s0[r]); p[r + 4] = EXP2(s1[r]); }
        PkU u0, u1, u2, u3;
        u0.h = __builtin_amdgcn_cvt_pkrtz(p[0], p[1]);
        u1.h = __builtin_amdgcn_cvt_pkrtz(p[2], p[3]);
        u2.h = __builtin_amdgcn_cvt_pkrtz(p[4], p[5]);
        u3.h = __builtin_amdgcn_cvt_pkrtz(p[6], p[7]);
        pa_[q].u[0] = rv ? (u0.u & pm_[q][0]) : 0u;
        pa_[q].u[1] = rv ? (u1.u & pm_[q][1]) : 0u;
        pb_[q].u[0] = rv ? (u2.u & pm_[q][2]) : 0u;
        pb_[q].u[1] = rv ? (u3.u & pm_[q][3]) : 0u;
    }
    // prefetch K for row aa0+1
    kb += KVROW;
    f16x8 nkf0 = *(const f16x8*)(kb + (size_t)b0 * 32);
    f16x8 nkf1 = *(const f16x8*)(kb + (size_t)b1 * 32);

    // ---- pipelined main loop: rows aa0+1 .. aa0+13 ----
    #pragma unroll 1
    for (int c = 1; c < 14; ++c) {
        aa = aa0 + c;
        kf0 = nkf0; kf1 = nkf1;                       // K(aa), prefetched last iter

        // (a) issue rpb loads for row aa (oldest in VMEM queue -> S wait is cheap)
        #pragma unroll
        for (int q = 0; q < 2; q++) {
            za_[q] = *(const f32x4u*)rpq[q];
            zb_[q] = *(const f32x4u*)(rpq[q] + 16);
            rpq[q] += RPBW;
        }

        // (b) PV for row aa-1 (covers the rpb latency with 12 MFMAs)
        #pragma unroll
        for (int q = 0; q < 2; q++) {
            O[q][0] = __builtin_amdgcn_mfma_f32_16x16x16f16(pa_[q].v, vfA0, O[q][0], 0, 0, 0);
            O[q][0] = __builtin_amdgcn_mfma_f32_16x16x16f16(pb_[q].v, vfB0, O[q][0], 0, 0, 0);
            O[q][1] = __builtin_amdgcn_mfma_f32_16x16x16f16(pa_[q].v, vfA1, O[q][1], 0, 0, 0);
            O[q][1] = __builtin_amdgcn_mfma_f32_16x16x16f16(pb_[q].v, vfB1, O[q][1], 0, 0, 0);
            lacc[q] = __builtin_amdgcn_mfma_f32_16x16x16f16(pa_[q].v, ones4, lacc[q], 0, 0, 0);
            lacc[q] = __builtin_amdgcn_mfma_f32_16x16x16f16(pb_[q].v, ones4, lacc[q], 0, 0, 0);
        }

        // (c) issue V loads for row aa (consumed by next iter's PV) - dense 512B each
        vb += KVROW;
        vfA0 = *(const f16x4u*)vb;
        vfB0 = *(const f16x4u*)(vb + 256);
        vfA1 = *(const f16x4u*)(vb + 1408);
        vfB1 = *(const f16x4u*)(vb + 1664);

        // (d) issue K prefetch for row aa+1 (last iter reads padded row: unused)
        kb += KVROW;
        nkf0 = *(const f16x8*)(kb + (size_t)b0 * 32);
        nkf1 = *(const f16x8*)(kb + (size_t)b1 * 32);

        // (e) S + exp for row aa -> pending P (pa_/pb_ free: consumed in (b))
        #pragma unroll
        for (int q = 0; q < 2; q++) {
            f32x4 s0 = __builtin_amdgcn_mfma_f32_16x16x32_f16(kf0, qf[q], za_[q], 0, 0, 0);
            f32x4 s1 = __builtin_amdgcn_mfma_f32_16x16x32_f16(kf1, qf[q], zb_[q], 0, 0, 0);
            bool rv = (unsigned)(aa - si_[q]) <= 24u;
            float p[8];
            #pragma unroll
            for (int r = 0; r < 4; r++) { p[r] = EXP2(s0[r]); p[r + 4] = EXP2(s1[r]); }
            PkU u0, u1, u2, u3;
            u0.h = __builtin_amdgcn_cvt_pkrtz(p[0], p[1]);
            u1.h = __builtin_amdgcn_cvt_pkrtz(p[2], p[3]);
            u2.h = __builtin_amdgcn_cvt_pkrtz(p[4], p[5]);
            u3.h = __builtin_amdgcn_cvt_pkrtz(p[6], p[7]);
            pa_[q].u[0] = rv ? (u0.u & pm_[q][0]) : 0u;
            pa_[q].u[1] = rv ? (u1.u & pm_[q][1]) : 0u;
            pb_[q].u[0] = rv ? (u2.u & pm_[q][2]) : 0u;
            pb_[q].u[1] = rv ? (u3.u & pm_[q][3]) : 0u;
        }
    }

    // ---- epilogue PV: last row (aa0+13) ----
    #pragma unroll
    for (int q = 0; q < 2; q++) {
        O[q][0] = __builtin_amdgcn_mfma_f32_16x16x16f16(pa_[q].v, vfA0, O[q][0], 0, 0, 0);
        O[q][0] = __builtin_amdgcn_mfma_f32_16x16x16f16(pb_[q].v, vfB0, O[q][0], 0, 0, 0);
        O[q][1] = __builtin_amdgcn_mfma_f32_16x16x16f16(pa_[q].v, vfA1, O[q][1], 0, 0, 0);
        O[q][1] = __builtin_amdgcn_mfma_f32_16x16x16f16(pb_[q].v, vfB1, O[q][1], 0, 0, 0);
        lacc[q] = __builtin_amdgcn_mfma_f32_16x16x16f16(pa_[q].v, ones4, lacc[q], 0, 0, 0);
        lacc[q] = __builtin_amdgcn_mfma_f32_16x16x16f16(pb_[q].v, ones4, lacc[q], 0, 0, 0);
    }

    // ---- merge: wave1 stores partials, wave0 adds and finishes ----
    if (w == 1) {
        float* ob = &Olds[lane][0];
        #pragma unroll
        for (int q = 0; q < 2; q++) {
            *(f32x4*)&ob[q * 12]     = O[q][0];
            *(f32x4*)&ob[q * 12 + 4] = O[q][1];
            *(f32x4*)&ob[q * 12 + 8] = lacc[q];
        }
    }
    __syncthreads();
    if (w == 0) {
        const float* ob = &Olds[lane][0];
        #pragma unroll
        for (int q = 0; q < 2; q++) {
            f32x4 o0 = O[q][0] + *(const f32x4*)&ob[q * 12];
            f32x4 o1 = O[q][1] + *(const f32x4*)&ob[q * 12 + 4];
            f32x4 la = lacc[q] + *(const f32x4*)&ob[q * 12 + 8];
            #pragma unroll
            for (int r = 0; r < 4; r++) {
                float li = 1.f / la[r];
                int ql = q * 16 + quad * 4 + r;
                int qi = i0 + (ql >> 3), qj = j0 + (ql & 7);
                size_t base = (size_t)(qi * PP + qj) * CC + h * HD;
                ao[base + nn]      = (f16)(o0[r] * li);
                ao[base + 16 + nn] = (f16)(o1[r] * li);
            }
        }
    }
}

extern "C" void kernel_launch(void* const* d_in, const int* in_sizes, int n_in,
                              void* d_out, int out_size, void* d_ws, size_t ws_size,
                              hipStream_t stream) {
    (void)in_sizes; (void)n_in; (void)out_size; (void)ws_size;
    const float* x    = (const float*)d_in[0];
    const float* cond = (const float*)d_in[1];
    const float* mask = (const float*)d_in[2];
    const float* lw   = (const float*)d_in[3];
    const float* lb   = (const float*)d_in[4];
    const float* qw   = (const float*)d_in[5];
    const float* qb   = (const float*)d_in[6];
    const float* rpb  = (const float*)d_in[7];
    const float* pw   = (const float*)d_in[8];
    const float* pb   = (const float*)d_in[9];
    float* outp       = (float*)d_out;

    float* ws   = (float*)d_ws;
    float* qbs  = ws;                 // 384
    float* b2s  = qbs + 384;          // 384
    float* rpbp = b2s + 384;          // 10240 padded
    f16* lwh  = (f16*)(rpbp + 10240);             // 128*160
    f16* qwh  = lwh + 20480;                      // 384*128
    f16* pwh  = qwh + 49152;                      // 128*128
    f16* w2h  = pwh + 16384;                      // 384*128
    f16* yh   = w2h + 49152;                      // NN*128
    f16* qh   = yh + (size_t)NN * 128;            // NN*128 Q
    f16* kh2  = qh + (size_t)NN * 128;            // 258 rows * 11264
    f16* vh2  = kh2 + (size_t)KVAARWS * KVROW;    // 258 rows * 11264
    f16* ao   = vh2 + (size_t)KVAARWS * KVROW;    // NN*128

    prep<<<228, 256, 0, stream>>>(lw, qw, pw, qb, pb, rpb, lwh, qwh, pwh, w2h, qbs, b2s, rpbp);
    fusion_gemm<<<dim3(352, 2), 256, 0, stream>>>(x, cond, mask, lwh, lb, yh);
    gemm_qkv<<<dim3(352, 6), 256, 0, stream>>>(yh, qwh, qbs, qh, kh2, vh2);
    attn_mfma<<<dim3(TT / 4, PP / 8, HEADS), 128, 0, stream>>>(qh, kh2, vh2, rpbp, ao);
    gemm_qkv<<<dim3(352, 6), 256, 0, stream>>>(ao, w2h, b2s, qh, kh2, vh2);   // fused proj+qkv
    attn_mfma<<<dim3(TT / 4, PP / 8, HEADS), 128, 0, stream>>>(qh, kh2, vh2, rpbp, ao);
    gemm_out<<<dim3(352, 2), 256, 0, stream>>>(ao, pwh, pb, outp);
}

// Round 8
// 193.705 us; speedup vs baseline: 3.4717x; 1.0197x over previous
//
#include <hip/hip_runtime.h>
#include <hip/hip_fp16.h>

#define TT 256
#define PP 88
#define CC 128
#define NN (TT * PP)          // 22528 positions
#define HEADS 4
#define HD 32
#define WIN 25
#define RPBW 49
#define RPBSZ (RPBW * RPBW)   // 2401
#define SCALE 0.17677669529663687f   // 1/sqrt(32)
#define LOG2E 1.4426950408889634f
#define QSC (SCALE * LOG2E)          // fold exp->exp2 into Q path

// K layout: kh2[aa][h][j:88][ch32]   -> row stride (aa) = 11264, (aa,h) block = 2816
// V layout: vh2[aa][h][half:2][g:22][ch16][jr:4] -> same strides; dense 512B per attn load
#define KVROW 11264           // f16 elems per aa row (4 heads x 2816)
#define KVAARWS 258           // aa rows allocated (256 + prefetch/overshoot pad)

#if __has_builtin(__builtin_amdgcn_exp2f)
#define EXP2(x) __builtin_amdgcn_exp2f(x)
#else
#define EXP2(x) exp2f(x)
#endif

typedef _Float16 f16;
typedef f16 f16x8 __attribute__((ext_vector_type(8)));
typedef f16 f16x8u __attribute__((ext_vector_type(8), aligned(4)));
typedef f16 f16x4 __attribute__((ext_vector_type(4)));
typedef f16 f16x4u __attribute__((ext_vector_type(4), aligned(4)));
typedef float f32x4 __attribute__((ext_vector_type(4)));
typedef float f32x4u __attribute__((ext_vector_type(4), aligned(4)));
typedef __fp16 hf16x2 __attribute__((ext_vector_type(2)));
union PkU { hf16x2 h; unsigned u; };

// ---------- prep: repack (b<192) + parallel b2s (192<=b<216) + MFMA wcomb (216<=b<228) ----------
__global__ __launch_bounds__(256) void prep(
    const float* __restrict__ lw, const float* __restrict__ qw,
    const float* __restrict__ pw, const float* __restrict__ qb,
    const float* __restrict__ pb, const float* __restrict__ rpb,
    f16* __restrict__ lwh, f16* __restrict__ qwh, f16* __restrict__ pwh,
    f16* __restrict__ w2h, float* __restrict__ qbs, float* __restrict__ b2s,
    float* __restrict__ rpbp)
{
    const int b = blockIdx.x;
    if (b < 192) {
        int idx = b * 256 + threadIdx.x;              // covers 49152
        if (idx < 128 * 160) {                        // fusion W: [128][131] -> [128][160] pad
            int r = idx / 160, c = idx - r * 160;
            lwh[idx] = (f16)(c < 131 ? lw[r * 131 + c] : 0.f);
        }
        if (idx < 384 * 128) {                        // qkv W, Q rows scaled by QSC
            float v = qw[idx];
            if (idx < 128 * 128) v *= QSC;
            qwh[idx] = (f16)v;
        }
        if (idx < 128 * 128) pwh[idx] = (f16)pw[idx];
        if (idx < 384) qbs[idx] = qb[idx] * (idx < 128 ? QSC : 1.f);
        if (idx < 10240) rpbp[idx] = (idx < 4 * RPBSZ) ? rpb[idx] * LOG2E : 0.f;
    } else if (b < 216) {
        // b2s[i] = (qb[i] + qw[i,:]·pb) * sc_i ; 16 lanes per output, shuffle-reduce
        int t = (b - 192) * 256 + threadIdx.x;        // [0, 6144)
        int i = t >> 4, l = t & 15;
        if (i < 384) {
            float s = 0.f;
            #pragma unroll
            for (int j = l * 8; j < l * 8 + 8; j++) s += qw[i * 128 + j] * pb[j];
            s += __shfl_xor(s, 1); s += __shfl_xor(s, 2);
            s += __shfl_xor(s, 4); s += __shfl_xor(s, 8);
            if (l == 0) b2s[i] = (qb[i] + s) * (i < 128 ? QSC : 1.f);
        }
    } else {
        // w2h[i][k] = sc_i * sum_j qw[i][j] pw[j][k]
        const int bw = b - 216;                       // 0..11
        const int m0 = (bw & 1) * 64;                 // k-tile
        const int n0 = (bw >> 1) * 64;                // i-tile
        const int tid = threadIdx.x;
        const int w = tid >> 6, lane = tid & 63, quad = lane >> 4, nn = lane & 15;
        const int krow = m0 + w * 16 + nn;
        f16x8 af[4];
        #pragma unroll
        for (int ks = 0; ks < 4; ks++) {
            union { f16 e[8]; f16x8 v; } t;
            #pragma unroll
            for (int e = 0; e < 8; e++)
                t.e[e] = (f16)pw[(ks * 32 + quad * 8 + e) * 128 + krow];
            af[ks] = t.v;
        }
        f32x4 acc[4] = {};
        #pragma unroll
        for (int nt = 0; nt < 4; nt++) {
            int irow = n0 + nt * 16 + nn;
            #pragma unroll
            for (int ks = 0; ks < 4; ks++) {
                const float* qr = &qw[(size_t)irow * 128 + ks * 32 + quad * 8];
                float4 a = *(const float4*)qr, bq = *(const float4*)(qr + 4);
                PkU u0, u1, u2, u3;
                u0.h = __builtin_amdgcn_cvt_pkrtz(a.x, a.y);
                u1.h = __builtin_amdgcn_cvt_pkrtz(a.z, a.w);
                u2.h = __builtin_amdgcn_cvt_pkrtz(bq.x, bq.y);
                u3.h = __builtin_amdgcn_cvt_pkrtz(bq.z, bq.w);
                union { unsigned u[4]; f16x8 v; } bb;
                bb.u[0] = u0.u; bb.u[1] = u1.u; bb.u[2] = u2.u; bb.u[3] = u3.u;
                acc[nt] = __builtin_amdgcn_mfma_f32_16x16x32_f16(af[ks], bb.v, acc[nt], 0, 0, 0);
            }
        }
        #pragma unroll
        for (int nt = 0; nt < 4; nt++) {
            int i = n0 + nt * 16 + nn;
            float sc = (i < 128) ? QSC : 1.f;
            PkU p0, p1;
            p0.h = __builtin_amdgcn_cvt_pkrtz(acc[nt][0] * sc, acc[nt][1] * sc);
            p1.h = __builtin_amdgcn_cvt_pkrtz(acc[nt][2] * sc, acc[nt][3] * sc);
            *(uint2*)&w2h[(size_t)i * 128 + m0 + w * 16 + quad * 4] = make_uint2(p0.u, p1.u);
        }
    }
}

// ---------- fusion GEMM: yh = relu(cat @ lwh^T + lb); grid (352, 2) ----------
__global__ __launch_bounds__(256) void fusion_gemm(
    const float* __restrict__ x, const float* __restrict__ cond, const float* __restrict__ mask,
    const f16* __restrict__ lwh, const float* __restrict__ lb, f16* __restrict__ yh)
{
    __shared__ __align__(16) f16 Alds[64 * 168];
    const int m0 = blockIdx.x * 64, n0 = blockIdx.y * 64;
    const int tid = threadIdx.x;
    const int w = tid >> 6, lane = tid & 63, quad = lane >> 4, nn = lane & 15;

    {   // stage cat rows (f16)
        int r = tid >> 2, cpart = tid & 3;
        size_t pos = m0 + r;
        *(uint4*)&Alds[r * 168 + 128 + cpart * 8] = make_uint4(0, 0, 0, 0);
        const float* xr = x + pos * 128 + cpart * 32;
        #pragma unroll
        for (int t = 0; t < 4; t++) {
            float4 a = *(const float4*)(xr + t * 8);
            float4 b = *(const float4*)(xr + t * 8 + 4);
            PkU p0, p1, p2, p3;
            p0.h = __builtin_amdgcn_cvt_pkrtz(a.x, a.y);
            p1.h = __builtin_amdgcn_cvt_pkrtz(a.z, a.w);
            p2.h = __builtin_amdgcn_cvt_pkrtz(b.x, b.y);
            p3.h = __builtin_amdgcn_cvt_pkrtz(b.z, b.w);
            *(uint4*)&Alds[r * 168 + cpart * 32 + t * 8] = make_uint4(p0.u, p1.u, p2.u, p3.u);
        }
        if (cpart == 0) {
            Alds[r * 168 + 128] = (f16)cond[pos * 2];
            Alds[r * 168 + 129] = (f16)cond[pos * 2 + 1];
            Alds[r * 168 + 130] = (f16)mask[pos];
        }
    }
    __syncthreads();

    const int oc = n0 + w * 16 + nn;
    f16x8 af[5];
    #pragma unroll
    for (int ks = 0; ks < 5; ks++)
        af[ks] = *(const f16x8*)&lwh[(size_t)oc * 160 + ks * 32 + quad * 8];
    f32x4 acc[4] = {};
    #pragma unroll
    for (int ks = 0; ks < 5; ks++)
        #pragma unroll
        for (int nt = 0; nt < 4; nt++) {
            f16x8 bf = *(const f16x8*)&Alds[(nt * 16 + nn) * 168 + ks * 32 + quad * 8];
            acc[nt] = __builtin_amdgcn_mfma_f32_16x16x32_f16(af[ks], bf, acc[nt], 0, 0, 0);
        }
    float bv[4];
    #pragma unroll
    for (int r = 0; r < 4; r++) bv[r] = lb[n0 + w * 16 + quad * 4 + r];
    #pragma unroll
    for (int nt = 0; nt < 4; nt++) {
        int pos = m0 + nt * 16 + nn;
        PkU p0, p1;
        p0.h = __builtin_amdgcn_cvt_pkrtz(fmaxf(acc[nt][0] + bv[0], 0.f), fmaxf(acc[nt][1] + bv[1], 0.f));
        p1.h = __builtin_amdgcn_cvt_pkrtz(fmaxf(acc[nt][2] + bv[2], 0.f), fmaxf(acc[nt][3] + bv[3], 0.f));
        *(uint2*)&yh[(size_t)pos * 128 + n0 + w * 16 + quad * 4] = make_uint2(p0.u, p1.u);
    }
}

// ---------- qkv GEMM: grid (352, 6); Q -> qh[pos][128], K -> kh2, V -> vh2 ----------
// Read-side coalescing for attn: scatter cost moved to the (once-per-element)
// write side; attn reads each element ~16x from dense windows.
__global__ __launch_bounds__(256) void gemm_qkv(
    const f16* __restrict__ A, const f16* __restrict__ W, const float* __restrict__ bias,
    f16* __restrict__ qh, f16* __restrict__ kh2, f16* __restrict__ vh2)
{
    __shared__ __align__(16) f16 Alds[64 * 136];
    const int m0 = blockIdx.x * 64, n0 = blockIdx.y * 64;
    const int tid = threadIdx.x;
    const int w = tid >> 6, lane = tid & 63, quad = lane >> 4, nn = lane & 15;

    for (int i = tid; i < 1024; i += 256) {
        int r = i >> 4, c = i & 15;
        *(uint4*)&Alds[r * 136 + c * 8] = *(const uint4*)&A[(size_t)(m0 + r) * 128 + c * 8];
    }
    __syncthreads();

    const int oc = n0 + w * 16 + nn;
    f16x8 af[4];
    #pragma unroll
    for (int ks = 0; ks < 4; ks++)
        af[ks] = *(const f16x8*)&W[(size_t)oc * 128 + ks * 32 + quad * 8];
    f32x4 acc[4] = {};
    #pragma unroll
    for (int ks = 0; ks < 4; ks++)
        #pragma unroll
        for (int nt = 0; nt < 4; nt++) {
            f16x8 bf = *(const f16x8*)&Alds[(nt * 16 + nn) * 136 + ks * 32 + quad * 8];
            acc[nt] = __builtin_amdgcn_mfma_f32_16x16x32_f16(af[ks], bf, acc[nt], 0, 0, 0);
        }
    float bv[4];
    #pragma unroll
    for (int r = 0; r < 4; r++) bv[r] = bias[n0 + w * 16 + quad * 4 + r];

    if (n0 < 128) {                                   // ---- Q: qh[pos][128]
        #pragma unroll
        for (int nt = 0; nt < 4; nt++) {
            int pos = m0 + nt * 16 + nn;
            PkU p0, p1;
            p0.h = __builtin_amdgcn_cvt_pkrtz(acc[nt][0] + bv[0], acc[nt][1] + bv[1]);
            p1.h = __builtin_amdgcn_cvt_pkrtz(acc[nt][2] + bv[2], acc[nt][3] + bv[3]);
            *(uint2*)&qh[(size_t)pos * 128 + n0 + w * 16 + quad * 4] = make_uint2(p0.u, p1.u);
        }
    } else if (n0 < 256) {                            // ---- K: kh2[aa][h][j][ch32]
        const int ch = n0 - 128 + w * 16 + quad * 4;  // 4 consecutive, same ch32 block
        const int hh = ch >> 5, c32 = ch & 31;
        #pragma unroll
        for (int nt = 0; nt < 4; nt++) {
            int pos = m0 + nt * 16 + nn;
            int aa = pos / 88, j = pos - aa * 88;
            PkU p0, p1;
            p0.h = __builtin_amdgcn_cvt_pkrtz(acc[nt][0] + bv[0], acc[nt][1] + bv[1]);
            p1.h = __builtin_amdgcn_cvt_pkrtz(acc[nt][2] + bv[2], acc[nt][3] + bv[3]);
            *(uint2*)&kh2[((size_t)(aa * 4 + hh) * 88 + j) * 32 + c32] = make_uint2(p0.u, p1.u);
        }
    } else {                                          // ---- V: vh2[aa][h][half][g][ch16][jr]
        const int chb = n0 - 256 + w * 16 + quad * 4;
        #pragma unroll
        for (int nt = 0; nt < 4; nt++) {
            int pos = m0 + nt * 16 + nn;
            int aa = pos / 88, j = pos - aa * 88;
            size_t vb = (size_t)(aa * 4) * 2816 + (j >> 2) * 64 + (j & 3);
            #pragma unroll
            for (int r = 0; r < 4; r++) {
                int chg = chb + r;
                int hh = chg >> 5, c = chg & 31;
                vh2[vb + (size_t)hh * 2816 + (c >> 4) * 1408 + (c & 15) * 4] =
                    (f16)(acc[nt][r] + bv[r]);
            }
        }
    }
}

// ---------- final projection: grid (352, 2), fp32 out ----------
__global__ __launch_bounds__(256) void gemm_out(
    const f16* __restrict__ A, const f16* __restrict__ W, const float* __restrict__ bias,
    float* __restrict__ outp)
{
    __shared__ __align__(16) f16 Alds[64 * 136];
    const int m0 = blockIdx.x * 64, n0 = blockIdx.y * 64;
    const int tid = threadIdx.x;
    const int w = tid >> 6, lane = tid & 63, quad = lane >> 4, nn = lane & 15;

    for (int i = tid; i < 1024; i += 256) {
        int r = i >> 4, c = i & 15;
        *(uint4*)&Alds[r * 136 + c * 8] = *(const uint4*)&A[(size_t)(m0 + r) * 128 + c * 8];
    }
    __syncthreads();

    const int oc = n0 + w * 16 + nn;
    f16x8 af[4];
    #pragma unroll
    for (int ks = 0; ks < 4; ks++)
        af[ks] = *(const f16x8*)&W[(size_t)oc * 128 + ks * 32 + quad * 8];
    f32x4 acc[4] = {};
    #pragma unroll
    for (int ks = 0; ks < 4; ks++)
        #pragma unroll
        for (int nt = 0; nt < 4; nt++) {
            f16x8 bf = *(const f16x8*)&Alds[(nt * 16 + nn) * 136 + ks * 32 + quad * 8];
            acc[nt] = __builtin_amdgcn_mfma_f32_16x16x32_f16(af[ks], bf, acc[nt], 0, 0, 0);
        }
    float bv[4];
    #pragma unroll
    for (int r = 0; r < 4; r++) bv[r] = bias[n0 + w * 16 + quad * 4 + r];
    #pragma unroll
    for (int nt = 0; nt < 4; nt++) {
        int pos = m0 + nt * 16 + nn;
        f32x4 vv;
        #pragma unroll
        for (int r = 0; r < 4; r++) vv[r] = acc[nt][r] + bv[r];
        *(f32x4*)&outp[(size_t)pos * 128 + n0 + w * 16 + quad * 4] = vv;
    }
}

// ---------- MFMA neighborhood attention v9: fully-unrolled deep pipeline ----------
// v8 structure kept (4-row i-tiles, 2 waves x 14 key rows x 2 qsets, register
// PV, coalesced kh2/vh2, branchless masks, XCD chunking). Two changes:
// 1. Row loop FULLY UNROLLED: v8's depth-1 pipeline left the rpb->S gap covered
//    only by the 12-MFMA PV block (~100cy < L2 latency); unrolling lets the
//    compiler hoist each row's K/V/rpb loads 1-2 full iterations ahead
//    (register renaming instead of rotation movs; rpb pointer bumps fold into
//    13-bit imm offsets). v8 showed extra waves don't hide this (5.5 waves/SIMD
//    bought ~5%) -> trade occupancy for per-wave ILP depth.
// 2. __launch_bounds__(128, 3): caps VGPR at ~170 so the allocator can't
//    overshoot into 2-waves/SIMD territory (live set ~120-140 w/ 2-qset state;
//    v3/v4's spill was the same cap with DOUBLE the state - headroom verified).
//    Spill tripwire: WRITE_SIZE must stay ~5.8 MB.
// Plus T5 s_setprio(1/0) around the pure-MFMA PV cluster (attn +4-7%, m191).
__global__ __launch_bounds__(128, 3) void attn_mfma(
    const f16* __restrict__ qh,    // [N][128] Q, pre-scaled by QSC
    const f16* __restrict__ kh2,   // [aa][h][j][ch32]
    const f16* __restrict__ vh2,   // [aa][h][half][g][ch16][jr]
    const float* __restrict__ rpbp,
    f16* __restrict__ ao)          // [N][128]
{
    const int bx = ((blockIdx.x & 7) << 3) + (blockIdx.x >> 3);   // XCD-contiguous i-tiles
    const int i0 = bx * 4;
    const int j0 = blockIdx.y * 8;
    const int h  = blockIdx.z;
    const int tid = threadIdx.x;
    const int w = tid >> 6, lane = tid & 63;
    const int quad = lane >> 4, nn = lane & 15;

    const int ri0 = min(max(i0 - 12, 0), TT - 28);         // 28-row key span
    const int rj0 = min(max(j0 - 12, 0), PP - WIN) & ~3;   // 4-aligned for vh2

    __shared__ __align__(16) float Olds[64][28];   // wave-1 partials (2-way/quarter = free)

    int si_[2];
    unsigned pm_[2][4];            // packed-f16 column masks per output word
    f16x8 qf[2];
    const float* rpq[2];
    const float* rp_h = rpbp + h * RPBSZ;
    const int aa0 = ri0 + w * 14;  // this wave's first key row (14 rows/wave)

    #pragma unroll
    for (int q = 0; q < 2; q++) {
        int ql = q * 16 + nn;
        int qi = i0 + (ql >> 3), qj = j0 + (ql & 7);
        int si = min(max(qi - 12, 0), TT - WIN);
        int sj = min(max(qj - 12, 0), PP - WIN);
        si_[q] = si;
        unsigned cm = 0x1FFFFFFu << (sj - rj0);       // shift <= 7
        #pragma unroll
        for (int t = 0; t < 4; t++) {
            int k0 = (t >> 1) * 16 + quad * 4 + (t & 1) * 2;
            pm_[q][t] = (((cm >> k0) & 1u) ? 0xFFFFu : 0u)
                      | (((cm >> (k0 + 1)) & 1u) ? 0xFFFF0000u : 0u);
        }
        qf[q] = *(const f16x8*)&qh[(size_t)(qi * PP + qj) * 128 + h * HD + quad * 8];
        rpq[q] = rp_h + (aa0 - qi + 24) * RPBW + (rj0 - qj + 24) + quad * 4;
    }

    const int b0 = min(rj0 + nn, PP - 1);
    const int b1 = min(rj0 + 16 + nn, PP - 1);
    const f16x4 ones4 = {(f16)1.f, (f16)1.f, (f16)1.f, (f16)1.f};

    // dense per-lane base pointers (advance by KVROW per key row)
    const f16* kb = kh2 + (size_t)(aa0 * 4 + h) * 2816 + quad * 8;
    const f16* vb = vh2 + (size_t)(aa0 * 4 + h) * 2816 + ((rj0 >> 2) + quad) * 64 + nn * 4;

    f32x4 O[2][2] = {};            // [qset][ch-half]; regs = queries, lane nn = channel
    f32x4 lacc[2] = {};
    union PB { unsigned u[2]; f16x4 v; };
    PB pa_[2], pb_[2];             // pending P (row aa-1), masked, packed
    f32x4 za_[2], zb_[2];          // rpb C-init for current row

    // ---- prologue: row aa0 -> S/exp only (its PV runs in iter c=1) ----
    int aa = aa0;
    f16x8 kf0 = *(const f16x8*)(kb + (size_t)b0 * 32);
    f16x8 kf1 = *(const f16x8*)(kb + (size_t)b1 * 32);
    f16x4 vfA0 = *(const f16x4u*)vb;                  // keys  0-15, ch lo
    f16x4 vfB0 = *(const f16x4u*)(vb + 256);          // keys 16-31, ch lo
    f16x4 vfA1 = *(const f16x4u*)(vb + 1408);         // keys  0-15, ch hi
    f16x4 vfB1 = *(const f16x4u*)(vb + 1664);         // keys 16-31, ch hi
    #pragma unroll
    for (int q = 0; q < 2; q++) {
        za_[q] = *(const f32x4u*)rpq[q];
        zb_[q] = *(const f32x4u*)(rpq[q] + 16);
        rpq[q] += RPBW;
    }
    #pragma unroll
    for (int q = 0; q < 2; q++) {
        f32x4 s0 = __builtin_amdgcn_mfma_f32_16x16x32_f16(kf0, qf[q], za_[q], 0, 0, 0);
        f32x4 s1 = __builtin_amdgcn_mfma_f32_16x16x32_f16(kf1, qf[q], zb_[q], 0, 0, 0);
        bool rv = (unsigned)(aa - si_[q]) <= 24u;
        float p[8];
        #pragma unroll
        for (int r = 0; r < 4; r++) { p[r] = EXP2(s0[r]); p[r + 4] = EXP2(s1[r]); }
        PkU u0, u1, u2, u3;
        u0.h = __builtin_amdgcn_cvt_pkrtz(p[0], p[1]);
        u1.h = __builtin_amdgcn_cvt_pkrtz(p[2], p[3]);
        u2.h = __builtin_amdgcn_cvt_pkrtz(p[4], p[5]);
        u3.h = __builtin_amdgcn_cvt_pkrtz(p[6], p[7]);
        pa_[q].u[0] = rv ? (u0.u & pm_[q][0]) : 0u;
        pa_[q].u[1] = rv ? (u1.u & pm_[q][1]) : 0u;
        pb_[q].u[0] = rv ? (u2.u & pm_[q][2]) : 0u;
        pb_[q].u[1] = rv ? (u3.u & pm_[q][3]) : 0u;
    }
    // prefetch K for row aa0+1
    kb += KVROW;
    f16x8 nkf0 = *(const f16x8*)(kb + (size_t)b0 * 32);
    f16x8 nkf1 = *(const f16x8*)(kb + (size_t)b1 * 32);

    // ---- fully-unrolled pipelined loop: rows aa0+1 .. aa0+13 ----
    #pragma unroll
    for (int c = 1; c < 14; ++c) {
        aa = aa0 + c;
        kf0 = nkf0; kf1 = nkf1;                       // K(aa), prefetched last iter

        // (a) issue rpb loads for row aa (oldest in VMEM queue -> S wait is cheap)
        #pragma unroll
        for (int q = 0; q < 2; q++) {
            za_[q] = *(const f32x4u*)rpq[q];
            zb_[q] = *(const f32x4u*)(rpq[q] + 16);
            rpq[q] += RPBW;
        }

        // (b) PV for row aa-1 (pure-MFMA cluster; setprio keeps the pipe fed)
        __builtin_amdgcn_s_setprio(1);
        #pragma unroll
        for (int q = 0; q < 2; q++) {
            O[q][0] = __builtin_amdgcn_mfma_f32_16x16x16f16(pa_[q].v, vfA0, O[q][0], 0, 0, 0);
            O[q][0] = __builtin_amdgcn_mfma_f32_16x16x16f16(pb_[q].v, vfB0, O[q][0], 0, 0, 0);
            O[q][1] = __builtin_amdgcn_mfma_f32_16x16x16f16(pa_[q].v, vfA1, O[q][1], 0, 0, 0);
            O[q][1] = __builtin_amdgcn_mfma_f32_16x16x16f16(pb_[q].v, vfB1, O[q][1], 0, 0, 0);
            lacc[q] = __builtin_amdgcn_mfma_f32_16x16x16f16(pa_[q].v, ones4, lacc[q], 0, 0, 0);
            lacc[q] = __builtin_amdgcn_mfma_f32_16x16x16f16(pb_[q].v, ones4, lacc[q], 0, 0, 0);
        }
        __builtin_amdgcn_s_setprio(0);

        // (c) issue V loads for row aa (consumed by next iter's PV) - dense 512B each
        vb += KVROW;
        vfA0 = *(const f16x4u*)vb;
        vfB0 = *(const f16x4u*)(vb + 256);
        vfA1 = *(const f16x4u*)(vb + 1408);
        vfB1 = *(const f16x4u*)(vb + 1664);

        // (d) issue K prefetch for row aa+1 (last iter reads padded row: unused)
        kb += KVROW;
        nkf0 = *(const f16x8*)(kb + (size_t)b0 * 32);
        nkf1 = *(const f16x8*)(kb + (size_t)b1 * 32);

        // (e) S + exp for row aa -> pending P (pa_/pb_ free: consumed in (b))
        #pragma unroll
        for (int q = 0; q < 2; q++) {
            f32x4 s0 = __builtin_amdgcn_mfma_f32_16x16x32_f16(kf0, qf[q], za_[q], 0, 0, 0);
            f32x4 s1 = __builtin_amdgcn_mfma_f32_16x16x32_f16(kf1, qf[q], zb_[q], 0, 0, 0);
            bool rv = (unsigned)(aa - si_[q]) <= 24u;
            float p[8];
            #pragma unroll
            for (int r = 0; r < 4; r++) { p[r] = EXP2(s0[r]); p[r + 4] = EXP2(s1[r]); }
            PkU u0, u1, u2, u3;
            u0.h = __builtin_amdgcn_cvt_pkrtz(p[0], p[1]);
            u1.h = __builtin_amdgcn_cvt_pkrtz(p[2], p[3]);
            u2.h = __builtin_amdgcn_cvt_pkrtz(p[4], p[5]);
            u3.h = __builtin_amdgcn_cvt_pkrtz(p[6], p[7]);
            pa_[q].u[0] = rv ? (u0.u & pm_[q][0]) : 0u;
            pa_[q].u[1] = rv ? (u1.u & pm_[q][1]) : 0u;
            pb_[q].u[0] = rv ? (u2.u & pm_[q][2]) : 0u;
            pb_[q].u[1] = rv ? (u3.u & pm_[q][3]) : 0u;
        }
    }

    // ---- epilogue PV: last row (aa0+13) ----
    #pragma unroll
    for (int q = 0; q < 2; q++) {
        O[q][0] = __builtin_amdgcn_mfma_f32_16x16x16f16(pa_[q].v, vfA0, O[q][0], 0, 0, 0);
        O[q][0] = __builtin_amdgcn_mfma_f32_16x16x16f16(pb_[q].v, vfB0, O[q][0], 0, 0, 0);
        O[q][1] = __builtin_amdgcn_mfma_f32_16x16x16f16(pa_[q].v, vfA1, O[q][1], 0, 0, 0);
        O[q][1] = __builtin_amdgcn_mfma_f32_16x16x16f16(pb_[q].v, vfB1, O[q][1], 0, 0, 0);
        lacc[q] = __builtin_amdgcn_mfma_f32_16x16x16f16(pa_[q].v, ones4, lacc[q], 0, 0, 0);
        lacc[q] = __builtin_amdgcn_mfma_f32_16x16x16f16(pb_[q].v, ones4, lacc[q], 0, 0, 0);
    }

    // ---- merge: wave1 stores partials, wave0 adds and finishes ----
    if (w == 1) {
        float* ob = &Olds[lane][0];
        #pragma unroll
        for (int q = 0; q < 2; q++) {
            *(f32x4*)&ob[q * 12]     = O[q][0];
            *(f32x4*)&ob[q * 12 + 4] = O[q][1];
            *(f32x4*)&ob[q * 12 + 8] = lacc[q];
        }
    }
    __syncthreads();
    if (w == 0) {
        const float* ob = &Olds[lane][0];
        #pragma unroll
        for (int q = 0; q < 2; q++) {
            f32x4 o0 = O[q][0] + *(const f32x4*)&ob[q * 12];
            f32x4 o1 = O[q][1] + *(const f32x4*)&ob[q * 12 + 4];
            f32x4 la = lacc[q] + *(const f32x4*)&ob[q * 12 + 8];
            #pragma unroll
            for (int r = 0; r < 4; r++) {
                float li = 1.f / la[r];
                int ql = q * 16 + quad * 4 + r;
                int qi = i0 + (ql >> 3), qj = j0 + (ql & 7);
                size_t base = (size_t)(qi * PP + qj) * CC + h * HD;
                ao[base + nn]      = (f16)(o0[r] * li);
                ao[base + 16 + nn] = (f16)(o1[r] * li);
            }
        }
    }
}

extern "C" void kernel_launch(void* const* d_in, const int* in_sizes, int n_in,
                              void* d_out, int out_size, void* d_ws, size_t ws_size,
                              hipStream_t stream) {
    (void)in_sizes; (void)n_in; (void)out_size; (void)ws_size;
    const float* x    = (const float*)d_in[0];
    const float* cond = (const float*)d_in[1];
    const float* mask = (const float*)d_in[2];
    const float* lw   = (const float*)d_in[3];
    const float* lb   = (const float*)d_in[4];
    const float* qw   = (const float*)d_in[5];
    const float* qb   = (const float*)d_in[6];
    const float* rpb  = (const float*)d_in[7];
    const float* pw   = (const float*)d_in[8];
    const float* pb   = (const float*)d_in[9];
    float* outp       = (float*)d_out;

    float* ws   = (float*)d_ws;
    float* qbs  = ws;                 // 384
    float* b2s  = qbs + 384;          // 384
    float* rpbp = b2s + 384;          // 10240 padded
    f16* lwh  = (f16*)(rpbp + 10240);             // 128*160
    f16* qwh  = lwh + 20480;                      // 384*128
    f16* pwh  = qwh + 49152;                      // 128*128
    f16* w2h  = pwh + 16384;                      // 384*128
    f16* yh   = w2h + 49152;                      // NN*128
    f16* qh   = yh + (size_t)NN * 128;            // NN*128 Q
    f16* kh2  = qh + (size_t)NN * 128;            // 258 rows * 11264
    f16* vh2  = kh2 + (size_t)KVAARWS * KVROW;    // 258 rows * 11264
    f16* ao   = vh2 + (size_t)KVAARWS * KVROW;    // NN*128

    prep<<<228, 256, 0, stream>>>(lw, qw, pw, qb, pb, rpb, lwh, qwh, pwh, w2h, qbs, b2s, rpbp);
    fusion_gemm<<<dim3(352, 2), 256, 0, stream>>>(x, cond, mask, lwh, lb, yh);
    gemm_qkv<<<dim3(352, 6), 256, 0, stream>>>(yh, qwh, qbs, qh, kh2, vh2);
    attn_mfma<<<dim3(TT / 4, PP / 8, HEADS), 128, 0, stream>>>(qh, kh2, vh2, rpbp, ao);
    gemm_qkv<<<dim3(352, 6), 256, 0, stream>>>(ao, w2h, b2s, qh, kh2, vh2);   // fused proj+qkv
    attn_mfma<<<dim3(TT / 4, PP / 8, HEADS), 128, 0, stream>>>(qh, kh2, vh2, rpbp, ao);
    gemm_out<<<dim3(352, 2), 256, 0, stream>>>(ao, pwh, pb, outp);
}

// Round 9
// 184.409 us; speedup vs baseline: 3.6467x; 1.0504x over previous
//
#include <hip/hip_runtime.h>
#include <hip/hip_fp16.h>

#define TT 256
#define PP 88
#define CC 128
#define NN (TT * PP)          // 22528 positions
#define HEADS 4
#define HD 32
#define WIN 25
#define RPBW 49
#define RPBSZ (RPBW * RPBW)   // 2401
#define SCALE 0.17677669529663687f   // 1/sqrt(32)
#define LOG2E 1.4426950408889634f
#define QSC (SCALE * LOG2E)          // fold exp->exp2 into Q path

// K layout: kh2[aa][h][j:88][ch32]   -> row stride (aa) = 11264, (aa,h) block = 2816
// V layout: vh2[aa][h][half:2][g:22][ch16][jr:4] -> same strides; dense 512B per attn load
#define KVROW 11264           // f16 elems per aa row (4 heads x 2816)
#define KVAARWS 258           // aa rows allocated (256 + prefetch/overshoot pad)

#if __has_builtin(__builtin_amdgcn_exp2f)
#define EXP2(x) __builtin_amdgcn_exp2f(x)
#else
#define EXP2(x) exp2f(x)
#endif

typedef _Float16 f16;
typedef f16 f16x8 __attribute__((ext_vector_type(8)));
typedef f16 f16x8u __attribute__((ext_vector_type(8), aligned(4)));
typedef f16 f16x4 __attribute__((ext_vector_type(4)));
typedef f16 f16x4u __attribute__((ext_vector_type(4), aligned(4)));
typedef float f32x4 __attribute__((ext_vector_type(4)));
typedef float f32x4u __attribute__((ext_vector_type(4), aligned(4)));
typedef __fp16 hf16x2 __attribute__((ext_vector_type(2)));
union PkU { hf16x2 h; unsigned u; };

// Fragment-packed W layout (for gemm_qkv af loads): for output row i and col k,
//   ntile=i>>6, w=(i>>4)&3, nn=i&15, ks=k>>5, quad=(k&31)>>3, e=k&7, lane=quad*16+nn
//   faddr = (ntile*4 + w)*2048 + ks*512 + lane*8 + e
// -> af[ks] load = one dense 1KB window per (ntile,w,ks) instead of a 16-row gather.

// ---------- prep: repack (b<192) + parallel b2s (192<=b<216) + MFMA wcomb (216<=b<228) ----------
__global__ __launch_bounds__(256) void prep(
    const float* __restrict__ lw, const float* __restrict__ qw,
    const float* __restrict__ pw, const float* __restrict__ qb,
    const float* __restrict__ pb, const float* __restrict__ rpb,
    f16* __restrict__ lwh, f16* __restrict__ qwf, f16* __restrict__ pwh,
    f16* __restrict__ w2f, float* __restrict__ qbs, float* __restrict__ b2s,
    float* __restrict__ rpbp)
{
    const int b = blockIdx.x;
    if (b < 192) {
        int idx = b * 256 + threadIdx.x;              // covers 49152
        if (idx < 128 * 160) {                        // fusion W: [128][131] -> [128][160] pad
            int r = idx / 160, c = idx - r * 160;
            lwh[idx] = (f16)(c < 131 ? lw[r * 131 + c] : 0.f);
        }
        if (idx < 384 * 128) {                        // qkv W -> FRAGMENT-PACKED qwf
            float v = qw[idx];
            if (idx < 128 * 128) v *= QSC;            // Q rows scaled
            int i = idx >> 7, k = idx & 127;
            int lane = (((k & 31) >> 3) << 4) + (i & 15);
            int faddr = (((i >> 6) << 2) + ((i >> 4) & 3)) * 2048 + (k >> 5) * 512 + lane * 8 + (k & 7);
            qwf[faddr] = (f16)v;
        }
        if (idx < 128 * 128) pwh[idx] = (f16)pw[idx];
        if (idx < 384) qbs[idx] = qb[idx] * (idx < 128 ? QSC : 1.f);
        if (idx < 10240) rpbp[idx] = (idx < 4 * RPBSZ) ? rpb[idx] * LOG2E : 0.f;
    } else if (b < 216) {
        // b2s[i] = (qb[i] + qw[i,:]·pb) * sc_i ; 16 lanes per output, shuffle-reduce
        int t = (b - 192) * 256 + threadIdx.x;        // [0, 6144)
        int i = t >> 4, l = t & 15;
        if (i < 384) {
            float s = 0.f;
            #pragma unroll
            for (int j = l * 8; j < l * 8 + 8; j++) s += qw[i * 128 + j] * pb[j];
            s += __shfl_xor(s, 1); s += __shfl_xor(s, 2);
            s += __shfl_xor(s, 4); s += __shfl_xor(s, 8);
            if (l == 0) b2s[i] = (qb[i] + s) * (i < 128 ? QSC : 1.f);
        }
    } else {
        // w2f[i][k] = sc_i * sum_j qw[i][j] pw[j][k]  (fragment-packed output)
        const int bw = b - 216;                       // 0..11
        const int m0 = (bw & 1) * 64;                 // k-tile
        const int n0 = (bw >> 1) * 64;                // i-tile
        const int tid = threadIdx.x;
        const int w = tid >> 6, lane = tid & 63, quad = lane >> 4, nn = lane & 15;
        const int krow = m0 + w * 16 + nn;
        f16x8 af[4];
        #pragma unroll
        for (int ks = 0; ks < 4; ks++) {
            union { f16 e[8]; f16x8 v; } t;
            #pragma unroll
            for (int e = 0; e < 8; e++)
                t.e[e] = (f16)pw[(ks * 32 + quad * 8 + e) * 128 + krow];
            af[ks] = t.v;
        }
        f32x4 acc[4] = {};
        #pragma unroll
        for (int nt = 0; nt < 4; nt++) {
            int irow = n0 + nt * 16 + nn;
            #pragma unroll
            for (int ks = 0; ks < 4; ks++) {
                const float* qr = &qw[(size_t)irow * 128 + ks * 32 + quad * 8];
                float4 a = *(const float4*)qr, bq = *(const float4*)(qr + 4);
                PkU u0, u1, u2, u3;
                u0.h = __builtin_amdgcn_cvt_pkrtz(a.x, a.y);
                u1.h = __builtin_amdgcn_cvt_pkrtz(a.z, a.w);
                u2.h = __builtin_amdgcn_cvt_pkrtz(bq.x, bq.y);
                u3.h = __builtin_amdgcn_cvt_pkrtz(bq.z, bq.w);
                union { unsigned u[4]; f16x8 v; } bb;
                bb.u[0] = u0.u; bb.u[1] = u1.u; bb.u[2] = u2.u; bb.u[3] = u3.u;
                acc[nt] = __builtin_amdgcn_mfma_f32_16x16x32_f16(af[ks], bb.v, acc[nt], 0, 0, 0);
            }
        }
        #pragma unroll
        for (int nt = 0; nt < 4; nt++) {
            int i = n0 + nt * 16 + nn;
            int k = m0 + w * 16 + quad * 4;           // 4 consecutive cols, k&7 in {0,4}
            float sc = (i < 128) ? QSC : 1.f;
            PkU p0, p1;
            p0.h = __builtin_amdgcn_cvt_pkrtz(acc[nt][0] * sc, acc[nt][1] * sc);
            p1.h = __builtin_amdgcn_cvt_pkrtz(acc[nt][2] * sc, acc[nt][3] * sc);
            int lane2 = (((k & 31) >> 3) << 4) + (i & 15);
            int faddr = (((i >> 6) << 2) + ((i >> 4) & 3)) * 2048 + (k >> 5) * 512 + lane2 * 8 + (k & 7);
            *(uint2*)&w2f[faddr] = make_uint2(p0.u, p1.u);
        }
    }
}

// ---------- fusion GEMM: yh = relu(cat @ lwh^T + lb); grid (352, 2) ----------
__global__ __launch_bounds__(256) void fusion_gemm(
    const float* __restrict__ x, const float* __restrict__ cond, const float* __restrict__ mask,
    const f16* __restrict__ lwh, const float* __restrict__ lb, f16* __restrict__ yh)
{
    __shared__ __align__(16) f16 Alds[64 * 168];
    const int m0 = blockIdx.x * 64, n0 = blockIdx.y * 64;
    const int tid = threadIdx.x;
    const int w = tid >> 6, lane = tid & 63, quad = lane >> 4, nn = lane & 15;

    {   // stage cat rows (f16)
        int r = tid >> 2, cpart = tid & 3;
        size_t pos = m0 + r;
        *(uint4*)&Alds[r * 168 + 128 + cpart * 8] = make_uint4(0, 0, 0, 0);
        const float* xr = x + pos * 128 + cpart * 32;
        #pragma unroll
        for (int t = 0; t < 4; t++) {
            float4 a = *(const float4*)(xr + t * 8);
            float4 b = *(const float4*)(xr + t * 8 + 4);
            PkU p0, p1, p2, p3;
            p0.h = __builtin_amdgcn_cvt_pkrtz(a.x, a.y);
            p1.h = __builtin_amdgcn_cvt_pkrtz(a.z, a.w);
            p2.h = __builtin_amdgcn_cvt_pkrtz(b.x, b.y);
            p3.h = __builtin_amdgcn_cvt_pkrtz(b.z, b.w);
            *(uint4*)&Alds[r * 168 + cpart * 32 + t * 8] = make_uint4(p0.u, p1.u, p2.u, p3.u);
        }
        if (cpart == 0) {
            Alds[r * 168 + 128] = (f16)cond[pos * 2];
            Alds[r * 168 + 129] = (f16)cond[pos * 2 + 1];
            Alds[r * 168 + 130] = (f16)mask[pos];
        }
    }
    __syncthreads();

    const int oc = n0 + w * 16 + nn;
    f16x8 af[5];
    #pragma unroll
    for (int ks = 0; ks < 5; ks++)
        af[ks] = *(const f16x8*)&lwh[(size_t)oc * 160 + ks * 32 + quad * 8];
    f32x4 acc[4] = {};
    #pragma unroll
    for (int ks = 0; ks < 5; ks++)
        #pragma unroll
        for (int nt = 0; nt < 4; nt++) {
            f16x8 bf = *(const f16x8*)&Alds[(nt * 16 + nn) * 168 + ks * 32 + quad * 8];
            acc[nt] = __builtin_amdgcn_mfma_f32_16x16x32_f16(af[ks], bf, acc[nt], 0, 0, 0);
        }
    float bv[4];
    #pragma unroll
    for (int r = 0; r < 4; r++) bv[r] = lb[n0 + w * 16 + quad * 4 + r];
    #pragma unroll
    for (int nt = 0; nt < 4; nt++) {
        int pos = m0 + nt * 16 + nn;
        PkU p0, p1;
        p0.h = __builtin_amdgcn_cvt_pkrtz(fmaxf(acc[nt][0] + bv[0], 0.f), fmaxf(acc[nt][1] + bv[1], 0.f));
        p1.h = __builtin_amdgcn_cvt_pkrtz(fmaxf(acc[nt][2] + bv[2], 0.f), fmaxf(acc[nt][3] + bv[3], 0.f));
        *(uint2*)&yh[(size_t)pos * 128 + n0 + w * 16 + quad * 4] = make_uint2(p0.u, p1.u);
    }
}

// ---------- qkv GEMM v10: fragment-packed W loads + LDS-staged coalesced stores ----------
// grid (352, 6); Q -> qh[pos][128], K -> kh2, V -> vh2.
// v9 pathologies fixed: (1) af was a 16-row x 256B gather -> now one dense 1KB
// window from qwf/w2f; (2) Q/K stores were 8B pieces strided 256B, V was 16
// SCALAR 2B stores/thread -> all now stage the 64x64 tile in Rlds and emit
// exactly 2 dense uint4 stores/thread along the output buffer's contiguous axis
// (runs verified not to cross j-row/head/half boundaries; j%4==0 alignment from
// m0%4==0 and 88%4==0). Q/K keep RTZ pack, V keeps RNE cast (numerics as v9).
__global__ __launch_bounds__(256) void gemm_qkv(
    const f16* __restrict__ A, const f16* __restrict__ Wf, const float* __restrict__ bias,
    f16* __restrict__ qh, f16* __restrict__ kh2, f16* __restrict__ vh2)
{
    __shared__ __align__(16) f16 Alds[64 * 136];
    __shared__ __align__(16) f16 Rlds[64][72];
    const int m0 = blockIdx.x * 64, n0 = blockIdx.y * 64;
    const int tid = threadIdx.x;
    const int w = tid >> 6, lane = tid & 63, quad = lane >> 4, nn = lane & 15;

    for (int i = tid; i < 1024; i += 256) {
        int r = i >> 4, c = i & 15;
        *(uint4*)&Alds[r * 136 + c * 8] = *(const uint4*)&A[(size_t)(m0 + r) * 128 + c * 8];
    }
    __syncthreads();

    const f16* wfb = Wf + ((size_t)(n0 >> 6) * 4 + w) * 2048 + lane * 8;
    f16x8 af[4];
    #pragma unroll
    for (int ks = 0; ks < 4; ks++)
        af[ks] = *(const f16x8*)(wfb + ks * 512);
    f32x4 acc[4] = {};
    #pragma unroll
    for (int ks = 0; ks < 4; ks++)
        #pragma unroll
        for (int nt = 0; nt < 4; nt++) {
            f16x8 bf = *(const f16x8*)&Alds[(nt * 16 + nn) * 136 + ks * 32 + quad * 8];
            acc[nt] = __builtin_amdgcn_mfma_f32_16x16x32_f16(af[ks], bf, acc[nt], 0, 0, 0);
        }
    float bv[4];
    #pragma unroll
    for (int r = 0; r < 4; r++) bv[r] = bias[n0 + w * 16 + quad * 4 + r];

    // ---- stage output tile to Rlds[pos_local][ch_local] ----
    if (n0 < 256) {   // Q/K: RTZ pack (as v9)
        #pragma unroll
        for (int nt = 0; nt < 4; nt++) {
            PkU p0, p1;
            p0.h = __builtin_amdgcn_cvt_pkrtz(acc[nt][0] + bv[0], acc[nt][1] + bv[1]);
            p1.h = __builtin_amdgcn_cvt_pkrtz(acc[nt][2] + bv[2], acc[nt][3] + bv[3]);
            *(uint2*)&Rlds[nt * 16 + nn][w * 16 + quad * 4] = make_uint2(p0.u, p1.u);
        }
    } else {          // V: RNE casts (as v9)
        #pragma unroll
        for (int nt = 0; nt < 4; nt++) {
            union { f16 e[4]; uint2 u; } t;
            #pragma unroll
            for (int r = 0; r < 4; r++) t.e[r] = (f16)(acc[nt][r] + bv[r]);
            *(uint2*)&Rlds[nt * 16 + nn][w * 16 + quad * 4] = t.u;
        }
    }
    __syncthreads();

    // ---- 512 dense uint4 runs, 2 per thread ----
    if (n0 < 128) {                                   // ---- Q: qh[pos][128]
        #pragma unroll
        for (int it = 0; it < 2; it++) {
            int idx = it * 256 + tid;                 // [0,512)
            int pl = idx >> 3, oct = idx & 7;
            f16x8 v = *(const f16x8*)&Rlds[pl][oct * 8];
            *(uint4*)&qh[(size_t)(m0 + pl) * 128 + n0 + oct * 8] = *(uint4*)&v;
        }
    } else if (n0 < 256) {                            // ---- K: kh2[aa][h][j][ch32]
        #pragma unroll
        for (int it = 0; it < 2; it++) {
            int idx = it * 256 + tid;
            int pl = idx >> 3, oct = idx & 7;
            f16x8 v = *(const f16x8*)&Rlds[pl][oct * 8];
            int pos = m0 + pl, aa = pos / 88, j = pos - aa * 88;
            int ch = n0 - 128 + oct * 8;              // octet never crosses a 32-ch head
            int h = ch >> 5, c32 = ch & 31;
            *(uint4*)&kh2[((size_t)(aa * 4 + h) * 88 + j) * 32 + c32] = *(uint4*)&v;
        }
    } else {                                          // ---- V: vh2[aa][h][half][g][ch16][jr]
        #pragma unroll
        for (int it = 0; it < 2; it++) {
            int idx = it * 256 + tid;
            int pq = idx >> 5, cp = idx & 31;         // pos quad, ch pair
            union { f16 e[8]; uint4 u; } t;
            #pragma unroll
            for (int cc = 0; cc < 2; cc++)
                #pragma unroll
                for (int jj = 0; jj < 4; jj++)
                    t.e[cc * 4 + jj] = Rlds[pq * 4 + jj][cp * 2 + cc];
            int pos = m0 + pq * 4, aa = pos / 88, j = pos - aa * 88;   // j%4==0
            int ch = n0 - 256 + cp * 2;               // even pair: same h/half/c16-pair
            int h = ch >> 5, c = ch & 31, half = c >> 4, c16 = c & 15;
            *(uint4*)&vh2[(size_t)(aa * 4 + h) * 2816 + half * 1408 + (j >> 2) * 64 + c16 * 4] = t.u;
        }
    }
}

// ---------- final projection: grid (352, 2), fp32 out ----------
__global__ __launch_bounds__(256) void gemm_out(
    const f16* __restrict__ A, const f16* __restrict__ W, const float* __restrict__ bias,
    float* __restrict__ outp)
{
    __shared__ __align__(16) f16 Alds[64 * 136];
    const int m0 = blockIdx.x * 64, n0 = blockIdx.y * 64;
    const int tid = threadIdx.x;
    const int w = tid >> 6, lane = tid & 63, quad = lane >> 4, nn = lane & 15;

    for (int i = tid; i < 1024; i += 256) {
        int r = i >> 4, c = i & 15;
        *(uint4*)&Alds[r * 136 + c * 8] = *(const uint4*)&A[(size_t)(m0 + r) * 128 + c * 8];
    }
    __syncthreads();

    const int oc = n0 + w * 16 + nn;
    f16x8 af[4];
    #pragma unroll
    for (int ks = 0; ks < 4; ks++)
        af[ks] = *(const f16x8*)&W[(size_t)oc * 128 + ks * 32 + quad * 8];
    f32x4 acc[4] = {};
    #pragma unroll
    for (int ks = 0; ks < 4; ks++)
        #pragma unroll
        for (int nt = 0; nt < 4; nt++) {
            f16x8 bf = *(const f16x8*)&Alds[(nt * 16 + nn) * 136 + ks * 32 + quad * 8];
            acc[nt] = __builtin_amdgcn_mfma_f32_16x16x32_f16(af[ks], bf, acc[nt], 0, 0, 0);
        }
    float bv[4];
    #pragma unroll
    for (int r = 0; r < 4; r++) bv[r] = bias[n0 + w * 16 + quad * 4 + r];
    #pragma unroll
    for (int nt = 0; nt < 4; nt++) {
        int pos = m0 + nt * 16 + nn;
        f32x4 vv;
        #pragma unroll
        for (int r = 0; r < 4; r++) vv[r] = acc[nt][r] + bv[r];
        *(f32x4*)&outp[(size_t)pos * 128 + n0 + w * 16 + quad * 4] = vv;
    }
}

// ---------- MFMA neighborhood attention v9 (unchanged): fully-unrolled deep pipeline ----------
__global__ __launch_bounds__(128, 3) void attn_mfma(
    const f16* __restrict__ qh,    // [N][128] Q, pre-scaled by QSC
    const f16* __restrict__ kh2,   // [aa][h][j][ch32]
    const f16* __restrict__ vh2,   // [aa][h][half][g][ch16][jr]
    const float* __restrict__ rpbp,
    f16* __restrict__ ao)          // [N][128]
{
    const int bx = ((blockIdx.x & 7) << 3) + (blockIdx.x >> 3);   // XCD-contiguous i-tiles
    const int i0 = bx * 4;
    const int j0 = blockIdx.y * 8;
    const int h  = blockIdx.z;
    const int tid = threadIdx.x;
    const int w = tid >> 6, lane = tid & 63;
    const int quad = lane >> 4, nn = lane & 15;

    const int ri0 = min(max(i0 - 12, 0), TT - 28);         // 28-row key span
    const int rj0 = min(max(j0 - 12, 0), PP - WIN) & ~3;   // 4-aligned for vh2

    __shared__ __align__(16) float Olds[64][28];   // wave-1 partials (2-way/quarter = free)

    int si_[2];
    unsigned pm_[2][4];            // packed-f16 column masks per output word
    f16x8 qf[2];
    const float* rpq[2];
    const float* rp_h = rpbp + h * RPBSZ;
    const int aa0 = ri0 + w * 14;  // this wave's first key row (14 rows/wave)

    #pragma unroll
    for (int q = 0; q < 2; q++) {
        int ql = q * 16 + nn;
        int qi = i0 + (ql >> 3), qj = j0 + (ql & 7);
        int si = min(max(qi - 12, 0), TT - WIN);
        int sj = min(max(qj - 12, 0), PP - WIN);
        si_[q] = si;
        unsigned cm = 0x1FFFFFFu << (sj - rj0);       // shift <= 7
        #pragma unroll
        for (int t = 0; t < 4; t++) {
            int k0 = (t >> 1) * 16 + quad * 4 + (t & 1) * 2;
            pm_[q][t] = (((cm >> k0) & 1u) ? 0xFFFFu : 0u)
                      | (((cm >> (k0 + 1)) & 1u) ? 0xFFFF0000u : 0u);
        }
        qf[q] = *(const f16x8*)&qh[(size_t)(qi * PP + qj) * 128 + h * HD + quad * 8];
        rpq[q] = rp_h + (aa0 - qi + 24) * RPBW + (rj0 - qj + 24) + quad * 4;
    }

    const int b0 = min(rj0 + nn, PP - 1);
    const int b1 = min(rj0 + 16 + nn, PP - 1);
    const f16x4 ones4 = {(f16)1.f, (f16)1.f, (f16)1.f, (f16)1.f};

    // dense per-lane base pointers (advance by KVROW per key row)
    const f16* kb = kh2 + (size_t)(aa0 * 4 + h) * 2816 + quad * 8;
    const f16* vb = vh2 + (size_t)(aa0 * 4 + h) * 2816 + ((rj0 >> 2) + quad) * 64 + nn * 4;

    f32x4 O[2][2] = {};            // [qset][ch-half]; regs = queries, lane nn = channel
    f32x4 lacc[2] = {};
    union PB { unsigned u[2]; f16x4 v; };
    PB pa_[2], pb_[2];             // pending P (row aa-1), masked, packed
    f32x4 za_[2], zb_[2];          // rpb C-init for current row

    // ---- prologue: row aa0 -> S/exp only (its PV runs in iter c=1) ----
    int aa = aa0;
    f16x8 kf0 = *(const f16x8*)(kb + (size_t)b0 * 32);
    f16x8 kf1 = *(const f16x8*)(kb + (size_t)b1 * 32);
    f16x4 vfA0 = *(const f16x4u*)vb;                  // keys  0-15, ch lo
    f16x4 vfB0 = *(const f16x4u*)(vb + 256);          // keys 16-31, ch lo
    f16x4 vfA1 = *(const f16x4u*)(vb + 1408);         // keys  0-15, ch hi
    f16x4 vfB1 = *(const f16x4u*)(vb + 1664);         // keys 16-31, ch hi
    #pragma unroll
    for (int q = 0; q < 2; q++) {
        za_[q] = *(const f32x4u*)rpq[q];
        zb_[q] = *(const f32x4u*)(rpq[q] + 16);
        rpq[q] += RPBW;
    }
    #pragma unroll
    for (int q = 0; q < 2; q++) {
        f32x4 s0 = __builtin_amdgcn_mfma_f32_16x16x32_f16(kf0, qf[q], za_[q], 0, 0, 0);
        f32x4 s1 = __builtin_amdgcn_mfma_f32_16x16x32_f16(kf1, qf[q], zb_[q], 0, 0, 0);
        bool rv = (unsigned)(aa - si_[q]) <= 24u;
        float p[8];
        #pragma unroll
        for (int r = 0; r < 4; r++) { p[r] = EXP2(s0[r]); p[r + 4] = EXP2(s1[r]); }
        PkU u0, u1, u2, u3;
        u0.h = __builtin_amdgcn_cvt_pkrtz(p[0], p[1]);
        u1.h = __builtin_amdgcn_cvt_pkrtz(p[2], p[3]);
        u2.h = __builtin_amdgcn_cvt_pkrtz(p[4], p[5]);
        u3.h = __builtin_amdgcn_cvt_pkrtz(p[6], p[7]);
        pa_[q].u[0] = rv ? (u0.u & pm_[q][0]) : 0u;
        pa_[q].u[1] = rv ? (u1.u & pm_[q][1]) : 0u;
        pb_[q].u[0] = rv ? (u2.u & pm_[q][2]) : 0u;
        pb_[q].u[1] = rv ? (u3.u & pm_[q][3]) : 0u;
    }
    // prefetch K for row aa0+1
    kb += KVROW;
    f16x8 nkf0 = *(const f16x8*)(kb + (size_t)b0 * 32);
    f16x8 nkf1 = *(const f16x8*)(kb + (size_t)b1 * 32);

    // ---- fully-unrolled pipelined loop: rows aa0+1 .. aa0+13 ----
    #pragma unroll
    for (int c = 1; c < 14; ++c) {
        aa = aa0 + c;
        kf0 = nkf0; kf1 = nkf1;                       // K(aa), prefetched last iter

        // (a) issue rpb loads for row aa (oldest in VMEM queue -> S wait is cheap)
        #pragma unroll
        for (int q = 0; q < 2; q++) {
            za_[q] = *(const f32x4u*)rpq[q];
            zb_[q] = *(const f32x4u*)(rpq[q] + 16);
            rpq[q] += RPBW;
        }

        // (b) PV for row aa-1 (pure-MFMA cluster; setprio keeps the pipe fed)
        __builtin_amdgcn_s_setprio(1);
        #pragma unroll
        for (int q = 0; q < 2; q++) {
            O[q][0] = __builtin_amdgcn_mfma_f32_16x16x16f16(pa_[q].v, vfA0, O[q][0], 0, 0, 0);
            O[q][0] = __builtin_amdgcn_mfma_f32_16x16x16f16(pb_[q].v, vfB0, O[q][0], 0, 0, 0);
            O[q][1] = __builtin_amdgcn_mfma_f32_16x16x16f16(pa_[q].v, vfA1, O[q][1], 0, 0, 0);
            O[q][1] = __builtin_amdgcn_mfma_f32_16x16x16f16(pb_[q].v, vfB1, O[q][1], 0, 0, 0);
            lacc[q] = __builtin_amdgcn_mfma_f32_16x16x16f16(pa_[q].v, ones4, lacc[q], 0, 0, 0);
            lacc[q] = __builtin_amdgcn_mfma_f32_16x16x16f16(pb_[q].v, ones4, lacc[q], 0, 0, 0);
        }
        __builtin_amdgcn_s_setprio(0);

        // (c) issue V loads for row aa (consumed by next iter's PV) - dense 512B each
        vb += KVROW;
        vfA0 = *(const f16x4u*)vb;
        vfB0 = *(const f16x4u*)(vb + 256);
        vfA1 = *(const f16x4u*)(vb + 1408);
        vfB1 = *(const f16x4u*)(vb + 1664);

        // (d) issue K prefetch for row aa+1 (last iter reads padded row: unused)
        kb += KVROW;
        nkf0 = *(const f16x8*)(kb + (size_t)b0 * 32);
        nkf1 = *(const f16x8*)(kb + (size_t)b1 * 32);

        // (e) S + exp for row aa -> pending P (pa_/pb_ free: consumed in (b))
        #pragma unroll
        for (int q = 0; q < 2; q++) {
            f32x4 s0 = __builtin_amdgcn_mfma_f32_16x16x32_f16(kf0, qf[q], za_[q], 0, 0, 0);
            f32x4 s1 = __builtin_amdgcn_mfma_f32_16x16x32_f16(kf1, qf[q], zb_[q], 0, 0, 0);
            bool rv = (unsigned)(aa - si_[q]) <= 24u;
            float p[8];
            #pragma unroll
            for (int r = 0; r < 4; r++) { p[r] = EXP2(s0[r]); p[r + 4] = EXP2(s1[r]); }
            PkU u0, u1, u2, u3;
            u0.h = __builtin_amdgcn_cvt_pkrtz(p[0], p[1]);
            u1.h = __builtin_amdgcn_cvt_pkrtz(p[2], p[3]);
            u2.h = __builtin_amdgcn_cvt_pkrtz(p[4], p[5]);
            u3.h = __builtin_amdgcn_cvt_pkrtz(p[6], p[7]);
            pa_[q].u[0] = rv ? (u0.u & pm_[q][0]) : 0u;
            pa_[q].u[1] = rv ? (u1.u & pm_[q][1]) : 0u;
            pb_[q].u[0] = rv ? (u2.u & pm_[q][2]) : 0u;
            pb_[q].u[1] = rv ? (u3.u & pm_[q][3]) : 0u;
        }
    }

    // ---- epilogue PV: last row (aa0+13) ----
    #pragma unroll
    for (int q = 0; q < 2; q++) {
        O[q][0] = __builtin_amdgcn_mfma_f32_16x16x16f16(pa_[q].v, vfA0, O[q][0], 0, 0, 0);
        O[q][0] = __builtin_amdgcn_mfma_f32_16x16x16f16(pb_[q].v, vfB0, O[q][0], 0, 0, 0);
        O[q][1] = __builtin_amdgcn_mfma_f32_16x16x16f16(pa_[q].v, vfA1, O[q][1], 0, 0, 0);
        O[q][1] = __builtin_amdgcn_mfma_f32_16x16x16f16(pb_[q].v, vfB1, O[q][1], 0, 0, 0);
        lacc[q] = __builtin_amdgcn_mfma_f32_16x16x16f16(pa_[q].v, ones4, lacc[q], 0, 0, 0);
        lacc[q] = __builtin_amdgcn_mfma_f32_16x16x16f16(pb_[q].v, ones4, lacc[q], 0, 0, 0);
    }

    // ---- merge: wave1 stores partials, wave0 adds and finishes ----
    if (w == 1) {
        float* ob = &Olds[lane][0];
        #pragma unroll
        for (int q = 0; q < 2; q++) {
            *(f32x4*)&ob[q * 12]     = O[q][0];
            *(f32x4*)&ob[q * 12 + 4] = O[q][1];
            *(f32x4*)&ob[q * 12 + 8] = lacc[q];
        }
    }
    __syncthreads();
    if (w == 0) {
        const float* ob = &Olds[lane][0];
        #pragma unroll
        for (int q = 0; q < 2; q++) {
            f32x4 o0 = O[q][0] + *(const f32x4*)&ob[q * 12];
            f32x4 o1 = O[q][1] + *(const f32x4*)&ob[q * 12 + 4];
            f32x4 la = lacc[q] + *(const f32x4*)&ob[q * 12 + 8];
            #pragma unroll
            for (int r = 0; r < 4; r++) {
                float li = 1.f / la[r];
                int ql = q * 16 + quad * 4 + r;
                int qi = i0 + (ql >> 3), qj = j0 + (ql & 7);
                size_t base = (size_t)(qi * PP + qj) * CC + h * HD;
                ao[base + nn]      = (f16)(o0[r] * li);
                ao[base + 16 + nn] = (f16)(o1[r] * li);
            }
        }
    }
}

extern "C" void kernel_launch(void* const* d_in, const int* in_sizes, int n_in,
                              void* d_out, int out_size, void* d_ws, size_t ws_size,
                              hipStream_t stream) {
    (void)in_sizes; (void)n_in; (void)out_size; (void)ws_size;
    const float* x    = (const float*)d_in[0];
    const float* cond = (const float*)d_in[1];
    const float* mask = (const float*)d_in[2];
    const float* lw   = (const float*)d_in[3];
    const float* lb   = (const float*)d_in[4];
    const float* qw   = (const float*)d_in[5];
    const float* qb   = (const float*)d_in[6];
    const float* rpb  = (const float*)d_in[7];
    const float* pw   = (const float*)d_in[8];
    const float* pb   = (const float*)d_in[9];
    float* outp       = (float*)d_out;

    float* ws   = (float*)d_ws;
    float* qbs  = ws;                 // 384
    float* b2s  = qbs + 384;          // 384
    float* rpbp = b2s + 384;          // 10240 padded
    f16* lwh  = (f16*)(rpbp + 10240);             // 128*160
    f16* qwf  = lwh + 20480;                      // 384*128 fragment-packed
    f16* pwh  = qwf + 49152;                      // 128*128
    f16* w2f  = pwh + 16384;                      // 384*128 fragment-packed
    f16* yh   = w2f + 49152;                      // NN*128
    f16* qh   = yh + (size_t)NN * 128;            // NN*128 Q
    f16* kh2  = qh + (size_t)NN * 128;            // 258 rows * 11264
    f16* vh2  = kh2 + (size_t)KVAARWS * KVROW;    // 258 rows * 11264
    f16* ao   = vh2 + (size_t)KVAARWS * KVROW;    // NN*128

    prep<<<228, 256, 0, stream>>>(lw, qw, pw, qb, pb, rpb, lwh, qwf, pwh, w2f, qbs, b2s, rpbp);
    fusion_gemm<<<dim3(352, 2), 256, 0, stream>>>(x, cond, mask, lwh, lb, yh);
    gemm_qkv<<<dim3(352, 6), 256, 0, stream>>>(yh, qwf, qbs, qh, kh2, vh2);
    attn_mfma<<<dim3(TT / 4, PP / 8, HEADS), 128, 0, stream>>>(qh, kh2, vh2, rpbp, ao);
    gemm_qkv<<<dim3(352, 6), 256, 0, stream>>>(ao, w2f, b2s, qh, kh2, vh2);   // fused proj+qkv
    attn_mfma<<<dim3(TT / 4, PP / 8, HEADS), 128, 0, stream>>>(qh, kh2, vh2, rpbp, ao);
    gemm_out<<<dim3(352, 2), 256, 0, stream>>>(ao, pwh, pb, outp);
}

// Round 10
// 183.626 us; speedup vs baseline: 3.6623x; 1.0043x over previous
//
#include <hip/hip_runtime.h>
#include <hip/hip_fp16.h>

#define TT 256
#define PP 88
#define CC 128
#define NN (TT * PP)          // 22528 positions
#define HEADS 4
#define HD 32
#define WIN 25
#define RPBW 49
#define RPBSZ (RPBW * RPBW)   // 2401
#define SCALE 0.17677669529663687f   // 1/sqrt(32)
#define LOG2E 1.4426950408889634f
#define QSC (SCALE * LOG2E)          // fold exp->exp2 into Q path

// K layout: kh2[aa][h][j:88][ch32]   -> row stride (aa) = 11264, (aa,h) block = 2816
// V layout: vh2[aa][h][half:2][g:22][ch16][jr:4] -> same strides; dense 512B per attn load
#define KVROW 11264           // f16 elems per aa row (4 heads x 2816)
#define KVAARWS 258           // aa rows allocated (256 + prefetch/overshoot pad)

#if __has_builtin(__builtin_amdgcn_exp2f)
#define EXP2(x) __builtin_amdgcn_exp2f(x)
#else
#define EXP2(x) exp2f(x)
#endif

typedef _Float16 f16;
typedef f16 f16x8 __attribute__((ext_vector_type(8)));
typedef f16 f16x8u __attribute__((ext_vector_type(8), aligned(4)));
typedef f16 f16x4 __attribute__((ext_vector_type(4)));
typedef f16 f16x4u __attribute__((ext_vector_type(4), aligned(4)));
typedef float f32x4 __attribute__((ext_vector_type(4)));
typedef float f32x4u __attribute__((ext_vector_type(4), aligned(4)));
typedef __fp16 hf16x2 __attribute__((ext_vector_type(2)));
union PkU { hf16x2 h; unsigned u; };

// Fragment-packed W layout (for all MFMA af loads): output row i, col k:
//   group = (i>>6)*4 + ((i>>4)&3), ks = k>>5, lane = ((k&31)>>3)*16 + (i&15)
//   faddr = group*(KS*512) + ks*512 + lane*8 + (k&7)      [KS = #32-col blocks]
// -> af[ks] load = one dense 1KB window instead of a 16-row x 256B gather.

// ---------- prep: repack (b<192) + parallel b2s (192<=b<216) + MFMA wcomb (216<=b<228) ----------
__global__ __launch_bounds__(256) void prep(
    const float* __restrict__ lw, const float* __restrict__ qw,
    const float* __restrict__ pw, const float* __restrict__ qb,
    const float* __restrict__ pb, const float* __restrict__ rpb,
    f16* __restrict__ lwf, f16* __restrict__ qwf, f16* __restrict__ pwf,
    f16* __restrict__ w2f, float* __restrict__ qbs, float* __restrict__ b2s,
    float* __restrict__ rpbp)
{
    const int b = blockIdx.x;
    if (b < 192) {
        int idx = b * 256 + threadIdx.x;              // covers 49152
        if (idx < 128 * 160) {                        // fusion W -> FRAGMENT-PACKED lwf (KS=5)
            int r = idx / 160, c = idx - r * 160;
            float v = (c < 131) ? lw[r * 131 + c] : 0.f;
            int lane = (((c & 31) >> 3) << 4) + (r & 15);
            int faddr = (((r >> 6) << 2) + ((r >> 4) & 3)) * 2560 + (c >> 5) * 512 + lane * 8 + (c & 7);
            lwf[faddr] = (f16)v;
        }
        if (idx < 384 * 128) {                        // qkv W -> FRAGMENT-PACKED qwf (KS=4)
            float v = qw[idx];
            if (idx < 128 * 128) v *= QSC;            // Q rows scaled
            int i = idx >> 7, k = idx & 127;
            int lane = (((k & 31) >> 3) << 4) + (i & 15);
            int faddr = (((i >> 6) << 2) + ((i >> 4) & 3)) * 2048 + (k >> 5) * 512 + lane * 8 + (k & 7);
            qwf[faddr] = (f16)v;
        }
        if (idx < 128 * 128) {                        // proj W -> FRAGMENT-PACKED pwf (KS=4)
            int i = idx >> 7, k = idx & 127;
            int lane = (((k & 31) >> 3) << 4) + (i & 15);
            int faddr = (((i >> 6) << 2) + ((i >> 4) & 3)) * 2048 + (k >> 5) * 512 + lane * 8 + (k & 7);
            pwf[faddr] = (f16)pw[idx];
        }
        if (idx < 384) qbs[idx] = qb[idx] * (idx < 128 ? QSC : 1.f);
        if (idx < 10240) rpbp[idx] = (idx < 4 * RPBSZ) ? rpb[idx] * LOG2E : 0.f;
    } else if (b < 216) {
        // b2s[i] = (qb[i] + qw[i,:]·pb) * sc_i ; 16 lanes per output, shuffle-reduce
        int t = (b - 192) * 256 + threadIdx.x;        // [0, 6144)
        int i = t >> 4, l = t & 15;
        if (i < 384) {
            float s = 0.f;
            #pragma unroll
            for (int j = l * 8; j < l * 8 + 8; j++) s += qw[i * 128 + j] * pb[j];
            s += __shfl_xor(s, 1); s += __shfl_xor(s, 2);
            s += __shfl_xor(s, 4); s += __shfl_xor(s, 8);
            if (l == 0) b2s[i] = (qb[i] + s) * (i < 128 ? QSC : 1.f);
        }
    } else {
        // w2f[i][k] = sc_i * sum_j qw[i][j] pw[j][k]  (fragment-packed output)
        const int bw = b - 216;                       // 0..11
        const int m0 = (bw & 1) * 64;                 // k-tile
        const int n0 = (bw >> 1) * 64;                // i-tile
        const int tid = threadIdx.x;
        const int w = tid >> 6, lane = tid & 63, quad = lane >> 4, nn = lane & 15;
        const int krow = m0 + w * 16 + nn;
        f16x8 af[4];
        #pragma unroll
        for (int ks = 0; ks < 4; ks++) {
            union { f16 e[8]; f16x8 v; } t;
            #pragma unroll
            for (int e = 0; e < 8; e++)
                t.e[e] = (f16)pw[(ks * 32 + quad * 8 + e) * 128 + krow];
            af[ks] = t.v;
        }
        f32x4 acc[4] = {};
        #pragma unroll
        for (int nt = 0; nt < 4; nt++) {
            int irow = n0 + nt * 16 + nn;
            #pragma unroll
            for (int ks = 0; ks < 4; ks++) {
                const float* qr = &qw[(size_t)irow * 128 + ks * 32 + quad * 8];
                float4 a = *(const float4*)qr, bq = *(const float4*)(qr + 4);
                PkU u0, u1, u2, u3;
                u0.h = __builtin_amdgcn_cvt_pkrtz(a.x, a.y);
                u1.h = __builtin_amdgcn_cvt_pkrtz(a.z, a.w);
                u2.h = __builtin_amdgcn_cvt_pkrtz(bq.x, bq.y);
                u3.h = __builtin_amdgcn_cvt_pkrtz(bq.z, bq.w);
                union { unsigned u[4]; f16x8 v; } bb;
                bb.u[0] = u0.u; bb.u[1] = u1.u; bb.u[2] = u2.u; bb.u[3] = u3.u;
                acc[nt] = __builtin_amdgcn_mfma_f32_16x16x32_f16(af[ks], bb.v, acc[nt], 0, 0, 0);
            }
        }
        #pragma unroll
        for (int nt = 0; nt < 4; nt++) {
            int i = n0 + nt * 16 + nn;
            int k = m0 + w * 16 + quad * 4;           // 4 consecutive cols, k&7 in {0,4}
            float sc = (i < 128) ? QSC : 1.f;
            PkU p0, p1;
            p0.h = __builtin_amdgcn_cvt_pkrtz(acc[nt][0] * sc, acc[nt][1] * sc);
            p1.h = __builtin_amdgcn_cvt_pkrtz(acc[nt][2] * sc, acc[nt][3] * sc);
            int lane2 = (((k & 31) >> 3) << 4) + (i & 15);
            int faddr = (((i >> 6) << 2) + ((i >> 4) & 3)) * 2048 + (k >> 5) * 512 + lane2 * 8 + (k & 7);
            *(uint2*)&w2f[faddr] = make_uint2(p0.u, p1.u);
        }
    }
}

// ---------- fusion GEMM v11: frag-packed W + LDS-staged dense stores; grid (352, 2) ----------
__global__ __launch_bounds__(256) void fusion_gemm(
    const float* __restrict__ x, const float* __restrict__ cond, const float* __restrict__ mask,
    const f16* __restrict__ lwf, const float* __restrict__ lb, f16* __restrict__ yh)
{
    __shared__ __align__(16) f16 Alds[64 * 168];
    __shared__ __align__(16) f16 Rlds[64][72];
    const int m0 = blockIdx.x * 64, n0 = blockIdx.y * 64;
    const int tid = threadIdx.x;
    const int w = tid >> 6, lane = tid & 63, quad = lane >> 4, nn = lane & 15;

    {   // stage cat rows (f16)
        int r = tid >> 2, cpart = tid & 3;
        size_t pos = m0 + r;
        *(uint4*)&Alds[r * 168 + 128 + cpart * 8] = make_uint4(0, 0, 0, 0);
        const float* xr = x + pos * 128 + cpart * 32;
        #pragma unroll
        for (int t = 0; t < 4; t++) {
            float4 a = *(const float4*)(xr + t * 8);
            float4 b = *(const float4*)(xr + t * 8 + 4);
            PkU p0, p1, p2, p3;
            p0.h = __builtin_amdgcn_cvt_pkrtz(a.x, a.y);
            p1.h = __builtin_amdgcn_cvt_pkrtz(a.z, a.w);
            p2.h = __builtin_amdgcn_cvt_pkrtz(b.x, b.y);
            p3.h = __builtin_amdgcn_cvt_pkrtz(b.z, b.w);
            *(uint4*)&Alds[r * 168 + cpart * 32 + t * 8] = make_uint4(p0.u, p1.u, p2.u, p3.u);
        }
        if (cpart == 0) {
            Alds[r * 168 + 128] = (f16)cond[pos * 2];
            Alds[r * 168 + 129] = (f16)cond[pos * 2 + 1];
            Alds[r * 168 + 130] = (f16)mask[pos];
        }
    }
    __syncthreads();

    const f16* wfb = lwf + ((size_t)(n0 >> 6) * 4 + w) * 2560 + lane * 8;
    f16x8 af[5];
    #pragma unroll
    for (int ks = 0; ks < 5; ks++)
        af[ks] = *(const f16x8*)(wfb + ks * 512);
    f32x4 acc[4] = {};
    #pragma unroll
    for (int ks = 0; ks < 5; ks++)
        #pragma unroll
        for (int nt = 0; nt < 4; nt++) {
            f16x8 bf = *(const f16x8*)&Alds[(nt * 16 + nn) * 168 + ks * 32 + quad * 8];
            acc[nt] = __builtin_amdgcn_mfma_f32_16x16x32_f16(af[ks], bf, acc[nt], 0, 0, 0);
        }
    float bv[4];
    #pragma unroll
    for (int r = 0; r < 4; r++) bv[r] = lb[n0 + w * 16 + quad * 4 + r];
    #pragma unroll
    for (int nt = 0; nt < 4; nt++) {
        PkU p0, p1;
        p0.h = __builtin_amdgcn_cvt_pkrtz(fmaxf(acc[nt][0] + bv[0], 0.f), fmaxf(acc[nt][1] + bv[1], 0.f));
        p1.h = __builtin_amdgcn_cvt_pkrtz(fmaxf(acc[nt][2] + bv[2], 0.f), fmaxf(acc[nt][3] + bv[3], 0.f));
        *(uint2*)&Rlds[nt * 16 + nn][w * 16 + quad * 4] = make_uint2(p0.u, p1.u);
    }
    __syncthreads();
    #pragma unroll
    for (int it = 0; it < 2; it++) {                  // 512 dense uint4 runs
        int idx = it * 256 + tid;
        int pl = idx >> 3, oct = idx & 7;
        *(uint4*)&yh[(size_t)(m0 + pl) * 128 + n0 + oct * 8] = *(uint4*)&Rlds[pl][oct * 8];
    }
}

// ---------- qkv GEMM v10 (unchanged): fragment-packed W + LDS-staged coalesced stores ----------
__global__ __launch_bounds__(256) void gemm_qkv(
    const f16* __restrict__ A, const f16* __restrict__ Wf, const float* __restrict__ bias,
    f16* __restrict__ qh, f16* __restrict__ kh2, f16* __restrict__ vh2)
{
    __shared__ __align__(16) f16 Alds[64 * 136];
    __shared__ __align__(16) f16 Rlds[64][72];
    const int m0 = blockIdx.x * 64, n0 = blockIdx.y * 64;
    const int tid = threadIdx.x;
    const int w = tid >> 6, lane = tid & 63, quad = lane >> 4, nn = lane & 15;

    for (int i = tid; i < 1024; i += 256) {
        int r = i >> 4, c = i & 15;
        *(uint4*)&Alds[r * 136 + c * 8] = *(const uint4*)&A[(size_t)(m0 + r) * 128 + c * 8];
    }
    __syncthreads();

    const f16* wfb = Wf + ((size_t)(n0 >> 6) * 4 + w) * 2048 + lane * 8;
    f16x8 af[4];
    #pragma unroll
    for (int ks = 0; ks < 4; ks++)
        af[ks] = *(const f16x8*)(wfb + ks * 512);
    f32x4 acc[4] = {};
    #pragma unroll
    for (int ks = 0; ks < 4; ks++)
        #pragma unroll
        for (int nt = 0; nt < 4; nt++) {
            f16x8 bf = *(const f16x8*)&Alds[(nt * 16 + nn) * 136 + ks * 32 + quad * 8];
            acc[nt] = __builtin_amdgcn_mfma_f32_16x16x32_f16(af[ks], bf, acc[nt], 0, 0, 0);
        }
    float bv[4];
    #pragma unroll
    for (int r = 0; r < 4; r++) bv[r] = bias[n0 + w * 16 + quad * 4 + r];

    // ---- stage output tile to Rlds[pos_local][ch_local] ----
    if (n0 < 256) {   // Q/K: RTZ pack
        #pragma unroll
        for (int nt = 0; nt < 4; nt++) {
            PkU p0, p1;
            p0.h = __builtin_amdgcn_cvt_pkrtz(acc[nt][0] + bv[0], acc[nt][1] + bv[1]);
            p1.h = __builtin_amdgcn_cvt_pkrtz(acc[nt][2] + bv[2], acc[nt][3] + bv[3]);
            *(uint2*)&Rlds[nt * 16 + nn][w * 16 + quad * 4] = make_uint2(p0.u, p1.u);
        }
    } else {          // V: RNE casts
        #pragma unroll
        for (int nt = 0; nt < 4; nt++) {
            union { f16 e[4]; uint2 u; } t;
            #pragma unroll
            for (int r = 0; r < 4; r++) t.e[r] = (f16)(acc[nt][r] + bv[r]);
            *(uint2*)&Rlds[nt * 16 + nn][w * 16 + quad * 4] = t.u;
        }
    }
    __syncthreads();

    // ---- 512 dense uint4 runs, 2 per thread ----
    if (n0 < 128) {                                   // ---- Q: qh[pos][128]
        #pragma unroll
        for (int it = 0; it < 2; it++) {
            int idx = it * 256 + tid;                 // [0,512)
            int pl = idx >> 3, oct = idx & 7;
            f16x8 v = *(const f16x8*)&Rlds[pl][oct * 8];
            *(uint4*)&qh[(size_t)(m0 + pl) * 128 + n0 + oct * 8] = *(uint4*)&v;
        }
    } else if (n0 < 256) {                            // ---- K: kh2[aa][h][j][ch32]
        #pragma unroll
        for (int it = 0; it < 2; it++) {
            int idx = it * 256 + tid;
            int pl = idx >> 3, oct = idx & 7;
            f16x8 v = *(const f16x8*)&Rlds[pl][oct * 8];
            int pos = m0 + pl, aa = pos / 88, j = pos - aa * 88;
            int ch = n0 - 128 + oct * 8;              // octet never crosses a 32-ch head
            int h = ch >> 5, c32 = ch & 31;
            *(uint4*)&kh2[((size_t)(aa * 4 + h) * 88 + j) * 32 + c32] = *(uint4*)&v;
        }
    } else {                                          // ---- V: vh2[aa][h][half][g][ch16][jr]
        #pragma unroll
        for (int it = 0; it < 2; it++) {
            int idx = it * 256 + tid;
            int pq = idx >> 5, cp = idx & 31;         // pos quad, ch pair
            union { f16 e[8]; uint4 u; } t;
            #pragma unroll
            for (int cc = 0; cc < 2; cc++)
                #pragma unroll
                for (int jj = 0; jj < 4; jj++)
                    t.e[cc * 4 + jj] = Rlds[pq * 4 + jj][cp * 2 + cc];
            int pos = m0 + pq * 4, aa = pos / 88, j = pos - aa * 88;   // j%4==0
            int ch = n0 - 256 + cp * 2;               // even pair: same h/half/c16-pair
            int h = ch >> 5, c = ch & 31, half = c >> 4, c16 = c & 15;
            *(uint4*)&vh2[(size_t)(aa * 4 + h) * 2816 + half * 1408 + (j >> 2) * 64 + c16 * 4] = t.u;
        }
    }
}

// ---------- final projection v11: frag-packed W + LDS-staged dense f32 stores ----------
__global__ __launch_bounds__(256) void gemm_out(
    const f16* __restrict__ A, const f16* __restrict__ Wf, const float* __restrict__ bias,
    float* __restrict__ outp)
{
    __shared__ __align__(16) f16 Alds[64 * 136];
    __shared__ __align__(16) float Rldsf[64][68];
    const int m0 = blockIdx.x * 64, n0 = blockIdx.y * 64;
    const int tid = threadIdx.x;
    const int w = tid >> 6, lane = tid & 63, quad = lane >> 4, nn = lane & 15;

    for (int i = tid; i < 1024; i += 256) {
        int r = i >> 4, c = i & 15;
        *(uint4*)&Alds[r * 136 + c * 8] = *(const uint4*)&A[(size_t)(m0 + r) * 128 + c * 8];
    }
    __syncthreads();

    const f16* wfb = Wf + ((size_t)(n0 >> 6) * 4 + w) * 2048 + lane * 8;
    f16x8 af[4];
    #pragma unroll
    for (int ks = 0; ks < 4; ks++)
        af[ks] = *(const f16x8*)(wfb + ks * 512);
    f32x4 acc[4] = {};
    #pragma unroll
    for (int ks = 0; ks < 4; ks++)
        #pragma unroll
        for (int nt = 0; nt < 4; nt++) {
            f16x8 bf = *(const f16x8*)&Alds[(nt * 16 + nn) * 136 + ks * 32 + quad * 8];
            acc[nt] = __builtin_amdgcn_mfma_f32_16x16x32_f16(af[ks], bf, acc[nt], 0, 0, 0);
        }
    float bv[4];
    #pragma unroll
    for (int r = 0; r < 4; r++) bv[r] = bias[n0 + w * 16 + quad * 4 + r];
    #pragma unroll
    for (int nt = 0; nt < 4; nt++) {
        f32x4 vv;
        #pragma unroll
        for (int r = 0; r < 4; r++) vv[r] = acc[nt][r] + bv[r];
        *(f32x4*)&Rldsf[nt * 16 + nn][w * 16 + quad * 4] = vv;
    }
    __syncthreads();
    #pragma unroll
    for (int it = 0; it < 4; it++) {                  // 1024 dense f32x4 runs
        int idx = it * 256 + tid;
        int pl = idx >> 4, part = idx & 15;
        *(f32x4*)&outp[(size_t)(m0 + pl) * 128 + n0 + part * 4] = *(const f32x4*)&Rldsf[pl][part * 4];
    }
}

// ---------- MFMA neighborhood attention v9 (unchanged): fully-unrolled deep pipeline ----------
__global__ __launch_bounds__(128, 3) void attn_mfma(
    const f16* __restrict__ qh,    // [N][128] Q, pre-scaled by QSC
    const f16* __restrict__ kh2,   // [aa][h][j][ch32]
    const f16* __restrict__ vh2,   // [aa][h][half][g][ch16][jr]
    const float* __restrict__ rpbp,
    f16* __restrict__ ao)          // [N][128]
{
    const int bx = ((blockIdx.x & 7) << 3) + (blockIdx.x >> 3);   // XCD-contiguous i-tiles
    const int i0 = bx * 4;
    const int j0 = blockIdx.y * 8;
    const int h  = blockIdx.z;
    const int tid = threadIdx.x;
    const int w = tid >> 6, lane = tid & 63;
    const int quad = lane >> 4, nn = lane & 15;

    const int ri0 = min(max(i0 - 12, 0), TT - 28);         // 28-row key span
    const int rj0 = min(max(j0 - 12, 0), PP - WIN) & ~3;   // 4-aligned for vh2

    __shared__ __align__(16) float Olds[64][28];   // wave-1 partials (2-way/quarter = free)

    int si_[2];
    unsigned pm_[2][4];            // packed-f16 column masks per output word
    f16x8 qf[2];
    const float* rpq[2];
    const float* rp_h = rpbp + h * RPBSZ;
    const int aa0 = ri0 + w * 14;  // this wave's first key row (14 rows/wave)

    #pragma unroll
    for (int q = 0; q < 2; q++) {
        int ql = q * 16 + nn;
        int qi = i0 + (ql >> 3), qj = j0 + (ql & 7);
        int si = min(max(qi - 12, 0), TT - WIN);
        int sj = min(max(qj - 12, 0), PP - WIN);
        si_[q] = si;
        unsigned cm = 0x1FFFFFFu << (sj - rj0);       // shift <= 7
        #pragma unroll
        for (int t = 0; t < 4; t++) {
            int k0 = (t >> 1) * 16 + quad * 4 + (t & 1) * 2;
            pm_[q][t] = (((cm >> k0) & 1u) ? 0xFFFFu : 0u)
                      | (((cm >> (k0 + 1)) & 1u) ? 0xFFFF0000u : 0u);
        }
        qf[q] = *(const f16x8*)&qh[(size_t)(qi * PP + qj) * 128 + h * HD + quad * 8];
        rpq[q] = rp_h + (aa0 - qi + 24) * RPBW + (rj0 - qj + 24) + quad * 4;
    }

    const int b0 = min(rj0 + nn, PP - 1);
    const int b1 = min(rj0 + 16 + nn, PP - 1);
    const f16x4 ones4 = {(f16)1.f, (f16)1.f, (f16)1.f, (f16)1.f};

    // dense per-lane base pointers (advance by KVROW per key row)
    const f16* kb = kh2 + (size_t)(aa0 * 4 + h) * 2816 + quad * 8;
    const f16* vb = vh2 + (size_t)(aa0 * 4 + h) * 2816 + ((rj0 >> 2) + quad) * 64 + nn * 4;

    f32x4 O[2][2] = {};            // [qset][ch-half]; regs = queries, lane nn = channel
    f32x4 lacc[2] = {};
    union PB { unsigned u[2]; f16x4 v; };
    PB pa_[2], pb_[2];             // pending P (row aa-1), masked, packed
    f32x4 za_[2], zb_[2];          // rpb C-init for current row

    // ---- prologue: row aa0 -> S/exp only (its PV runs in iter c=1) ----
    int aa = aa0;
    f16x8 kf0 = *(const f16x8*)(kb + (size_t)b0 * 32);
    f16x8 kf1 = *(const f16x8*)(kb + (size_t)b1 * 32);
    f16x4 vfA0 = *(const f16x4u*)vb;                  // keys  0-15, ch lo
    f16x4 vfB0 = *(const f16x4u*)(vb + 256);          // keys 16-31, ch lo
    f16x4 vfA1 = *(const f16x4u*)(vb + 1408);         // keys  0-15, ch hi
    f16x4 vfB1 = *(const f16x4u*)(vb + 1664);         // keys 16-31, ch hi
    #pragma unroll
    for (int q = 0; q < 2; q++) {
        za_[q] = *(const f32x4u*)rpq[q];
        zb_[q] = *(const f32x4u*)(rpq[q] + 16);
        rpq[q] += RPBW;
    }
    #pragma unroll
    for (int q = 0; q < 2; q++) {
        f32x4 s0 = __builtin_amdgcn_mfma_f32_16x16x32_f16(kf0, qf[q], za_[q], 0, 0, 0);
        f32x4 s1 = __builtin_amdgcn_mfma_f32_16x16x32_f16(kf1, qf[q], zb_[q], 0, 0, 0);
        bool rv = (unsigned)(aa - si_[q]) <= 24u;
        float p[8];
        #pragma unroll
        for (int r = 0; r < 4; r++) { p[r] = EXP2(s0[r]); p[r + 4] = EXP2(s1[r]); }
        PkU u0, u1, u2, u3;
        u0.h = __builtin_amdgcn_cvt_pkrtz(p[0], p[1]);
        u1.h = __builtin_amdgcn_cvt_pkrtz(p[2], p[3]);
        u2.h = __builtin_amdgcn_cvt_pkrtz(p[4], p[5]);
        u3.h = __builtin_amdgcn_cvt_pkrtz(p[6], p[7]);
        pa_[q].u[0] = rv ? (u0.u & pm_[q][0]) : 0u;
        pa_[q].u[1] = rv ? (u1.u & pm_[q][1]) : 0u;
        pb_[q].u[0] = rv ? (u2.u & pm_[q][2]) : 0u;
        pb_[q].u[1] = rv ? (u3.u & pm_[q][3]) : 0u;
    }
    // prefetch K for row aa0+1
    kb += KVROW;
    f16x8 nkf0 = *(const f16x8*)(kb + (size_t)b0 * 32);
    f16x8 nkf1 = *(const f16x8*)(kb + (size_t)b1 * 32);

    // ---- fully-unrolled pipelined loop: rows aa0+1 .. aa0+13 ----
    #pragma unroll
    for (int c = 1; c < 14; ++c) {
        aa = aa0 + c;
        kf0 = nkf0; kf1 = nkf1;                       // K(aa), prefetched last iter

        // (a) issue rpb loads for row aa (oldest in VMEM queue -> S wait is cheap)
        #pragma unroll
        for (int q = 0; q < 2; q++) {
            za_[q] = *(const f32x4u*)rpq[q];
            zb_[q] = *(const f32x4u*)(rpq[q] + 16);
            rpq[q] += RPBW;
        }

        // (b) PV for row aa-1 (pure-MFMA cluster; setprio keeps the pipe fed)
        __builtin_amdgcn_s_setprio(1);
        #pragma unroll
        for (int q = 0; q < 2; q++) {
            O[q][0] = __builtin_amdgcn_mfma_f32_16x16x16f16(pa_[q].v, vfA0, O[q][0], 0, 0, 0);
            O[q][0] = __builtin_amdgcn_mfma_f32_16x16x16f16(pb_[q].v, vfB0, O[q][0], 0, 0, 0);
            O[q][1] = __builtin_amdgcn_mfma_f32_16x16x16f16(pa_[q].v, vfA1, O[q][1], 0, 0, 0);
            O[q][1] = __builtin_amdgcn_mfma_f32_16x16x16f16(pb_[q].v, vfB1, O[q][1], 0, 0, 0);
            lacc[q] = __builtin_amdgcn_mfma_f32_16x16x16f16(pa_[q].v, ones4, lacc[q], 0, 0, 0);
            lacc[q] = __builtin_amdgcn_mfma_f32_16x16x16f16(pb_[q].v, ones4, lacc[q], 0, 0, 0);
        }
        __builtin_amdgcn_s_setprio(0);

        // (c) issue V loads for row aa (consumed by next iter's PV) - dense 512B each
        vb += KVROW;
        vfA0 = *(const f16x4u*)vb;
        vfB0 = *(const f16x4u*)(vb + 256);
        vfA1 = *(const f16x4u*)(vb + 1408);
        vfB1 = *(const f16x4u*)(vb + 1664);

        // (d) issue K prefetch for row aa+1 (last iter reads padded row: unused)
        kb += KVROW;
        nkf0 = *(const f16x8*)(kb + (size_t)b0 * 32);
        nkf1 = *(const f16x8*)(kb + (size_t)b1 * 32);

        // (e) S + exp for row aa -> pending P (pa_/pb_ free: consumed in (b))
        #pragma unroll
        for (int q = 0; q < 2; q++) {
            f32x4 s0 = __builtin_amdgcn_mfma_f32_16x16x32_f16(kf0, qf[q], za_[q], 0, 0, 0);
            f32x4 s1 = __builtin_amdgcn_mfma_f32_16x16x32_f16(kf1, qf[q], zb_[q], 0, 0, 0);
            bool rv = (unsigned)(aa - si_[q]) <= 24u;
            float p[8];
            #pragma unroll
            for (int r = 0; r < 4; r++) { p[r] = EXP2(s0[r]); p[r + 4] = EXP2(s1[r]); }
            PkU u0, u1, u2, u3;
            u0.h = __builtin_amdgcn_cvt_pkrtz(p[0], p[1]);
            u1.h = __builtin_amdgcn_cvt_pkrtz(p[2], p[3]);
            u2.h = __builtin_amdgcn_cvt_pkrtz(p[4], p[5]);
            u3.h = __builtin_amdgcn_cvt_pkrtz(p[6], p[7]);
            pa_[q].u[0] = rv ? (u0.u & pm_[q][0]) : 0u;
            pa_[q].u[1] = rv ? (u1.u & pm_[q][1]) : 0u;
            pb_[q].u[0] = rv ? (u2.u & pm_[q][2]) : 0u;
            pb_[q].u[1] = rv ? (u3.u & pm_[q][3]) : 0u;
        }
    }

    // ---- epilogue PV: last row (aa0+13) ----
    #pragma unroll
    for (int q = 0; q < 2; q++) {
        O[q][0] = __builtin_amdgcn_mfma_f32_16x16x16f16(pa_[q].v, vfA0, O[q][0], 0, 0, 0);
        O[q][0] = __builtin_amdgcn_mfma_f32_16x16x16f16(pb_[q].v, vfB0, O[q][0], 0, 0, 0);
        O[q][1] = __builtin_amdgcn_mfma_f32_16x16x16f16(pa_[q].v, vfA1, O[q][1], 0, 0, 0);
        O[q][1] = __builtin_amdgcn_mfma_f32_16x16x16f16(pb_[q].v, vfB1, O[q][1], 0, 0, 0);
        lacc[q] = __builtin_amdgcn_mfma_f32_16x16x16f16(pa_[q].v, ones4, lacc[q], 0, 0, 0);
        lacc[q] = __builtin_amdgcn_mfma_f32_16x16x16f16(pb_[q].v, ones4, lacc[q], 0, 0, 0);
    }

    // ---- merge: wave1 stores partials, wave0 adds and finishes ----
    if (w == 1) {
        float* ob = &Olds[lane][0];
        #pragma unroll
        for (int q = 0; q < 2; q++) {
            *(f32x4*)&ob[q * 12]     = O[q][0];
            *(f32x4*)&ob[q * 12 + 4] = O[q][1];
            *(f32x4*)&ob[q * 12 + 8] = lacc[q];
        }
    }
    __syncthreads();
    if (w == 0) {
        const float* ob = &Olds[lane][0];
        #pragma unroll
        for (int q = 0; q < 2; q++) {
            f32x4 o0 = O[q][0] + *(const f32x4*)&ob[q * 12];
            f32x4 o1 = O[q][1] + *(const f32x4*)&ob[q * 12 + 4];
            f32x4 la = lacc[q] + *(const f32x4*)&ob[q * 12 + 8];
            #pragma unroll
            for (int r = 0; r < 4; r++) {
                float li = 1.f / la[r];
                int ql = q * 16 + quad * 4 + r;
                int qi = i0 + (ql >> 3), qj = j0 + (ql & 7);
                size_t base = (size_t)(qi * PP + qj) * CC + h * HD;
                ao[base + nn]      = (f16)(o0[r] * li);
                ao[base + 16 + nn] = (f16)(o1[r] * li);
            }
        }
    }
}

extern "C" void kernel_launch(void* const* d_in, const int* in_sizes, int n_in,
                              void* d_out, int out_size, void* d_ws, size_t ws_size,
                              hipStream_t stream) {
    (void)in_sizes; (void)n_in; (void)out_size; (void)ws_size;
    const float* x    = (const float*)d_in[0];
    const float* cond = (const float*)d_in[1];
    const float* mask = (const float*)d_in[2];
    const float* lw   = (const float*)d_in[3];
    const float* lb   = (const float*)d_in[4];
    const float* qw   = (const float*)d_in[5];
    const float* qb   = (const float*)d_in[6];
    const float* rpb  = (const float*)d_in[7];
    const float* pw   = (const float*)d_in[8];
    const float* pb   = (const float*)d_in[9];
    float* outp       = (float*)d_out;

    float* ws   = (float*)d_ws;
    float* qbs  = ws;                 // 384
    float* b2s  = qbs + 384;          // 384
    float* rpbp = b2s + 384;          // 10240 padded
    f16* lwf  = (f16*)(rpbp + 10240);             // 128*160 fragment-packed
    f16* qwf  = lwf + 20480;                      // 384*128 fragment-packed
    f16* pwf  = qwf + 49152;                      // 128*128 fragment-packed
    f16* w2f  = pwf + 16384;                      // 384*128 fragment-packed
    f16* yh   = w2f + 49152;                      // NN*128
    f16* qh   = yh + (size_t)NN * 128;            // NN*128 Q
    f16* kh2  = qh + (size_t)NN * 128;            // 258 rows * 11264
    f16* vh2  = kh2 + (size_t)KVAARWS * KVROW;    // 258 rows * 11264
    f16* ao   = vh2 + (size_t)KVAARWS * KVROW;    // NN*128

    prep<<<228, 256, 0, stream>>>(lw, qw, pw, qb, pb, rpb, lwf, qwf, pwf, w2f, qbs, b2s, rpbp);
    fusion_gemm<<<dim3(352, 2), 256, 0, stream>>>(x, cond, mask, lwf, lb, yh);
    gemm_qkv<<<dim3(352, 6), 256, 0, stream>>>(yh, qwf, qbs, qh, kh2, vh2);
    attn_mfma<<<dim3(TT / 4, PP / 8, HEADS), 128, 0, stream>>>(qh, kh2, vh2, rpbp, ao);
    gemm_qkv<<<dim3(352, 6), 256, 0, stream>>>(ao, w2f, b2s, qh, kh2, vh2);   // fused proj+qkv
    attn_mfma<<<dim3(TT / 4, PP / 8, HEADS), 128, 0, stream>>>(qh, kh2, vh2, rpbp, ao);
    gemm_out<<<dim3(352, 2), 256, 0, stream>>>(ao, pwf, pb, outp);
}

// Round 11
// 181.547 us; speedup vs baseline: 3.7042x; 1.0115x over previous
//
#include <hip/hip_runtime.h>
#include <hip/hip_fp16.h>

#define TT 256
#define PP 88
#define CC 128
#define NN (TT * PP)          // 22528 positions
#define HEADS 4
#define HD 32
#define WIN 25
#define RPBW 49
#define RPBSZ (RPBW * RPBW)   // 2401
#define SCALE 0.17677669529663687f   // 1/sqrt(32)
#define LOG2E 1.4426950408889634f
#define QSC (SCALE * LOG2E)          // fold exp->exp2 into Q path

// K layout: kh2[aa][h][j:88][ch32]   -> row stride (aa) = 11264, (aa,h) block = 2816
// V layout: vh2[aa][h][half:2][g:22][ch16][jr:4] -> same strides; dense 512B per attn load
#define KVROW 11264           // f16 elems per aa row (4 heads x 2816)
#define KVAARWS 258           // aa rows allocated (256 + prefetch/overshoot pad)

#if __has_builtin(__builtin_amdgcn_exp2f)
#define EXP2(x) __builtin_amdgcn_exp2f(x)
#else
#define EXP2(x) exp2f(x)
#endif

typedef _Float16 f16;
typedef f16 f16x8 __attribute__((ext_vector_type(8)));
typedef f16 f16x8u __attribute__((ext_vector_type(8), aligned(4)));
typedef f16 f16x4 __attribute__((ext_vector_type(4)));
typedef f16 f16x4u __attribute__((ext_vector_type(4), aligned(4)));
typedef float f32x4 __attribute__((ext_vector_type(4)));
typedef float f32x4u __attribute__((ext_vector_type(4), aligned(4)));
typedef __fp16 hf16x2 __attribute__((ext_vector_type(2)));
union PkU { hf16x2 h; unsigned u; };

// Fragment-packed W layout (for all MFMA af loads): output row i, col k:
//   group = (i>>6)*4 + ((i>>4)&3), ks = k>>5, lane = ((k&31)>>3)*16 + (i&15)
//   faddr = group*(KS*512) + ks*512 + lane*8 + (k&7)      [KS = #32-col blocks]
// -> af[ks] load = one dense 1KB window instead of a 16-row x 256B gather.

// ---------- prep: repack (b<192) + parallel b2s (192<=b<216) + MFMA wcomb (216<=b<228) ----------
__global__ __launch_bounds__(256) void prep(
    const float* __restrict__ lw, const float* __restrict__ qw,
    const float* __restrict__ pw, const float* __restrict__ qb,
    const float* __restrict__ pb, const float* __restrict__ rpb,
    f16* __restrict__ lwf, f16* __restrict__ qwf, f16* __restrict__ pwf,
    f16* __restrict__ w2f, float* __restrict__ qbs, float* __restrict__ b2s,
    float* __restrict__ rpbp)
{
    const int b = blockIdx.x;
    if (b < 192) {
        int idx = b * 256 + threadIdx.x;              // covers 49152
        if (idx < 128 * 160) {                        // fusion W -> FRAGMENT-PACKED lwf (KS=5)
            int r = idx / 160, c = idx - r * 160;
            float v = (c < 131) ? lw[r * 131 + c] : 0.f;
            int lane = (((c & 31) >> 3) << 4) + (r & 15);
            int faddr = (((r >> 6) << 2) + ((r >> 4) & 3)) * 2560 + (c >> 5) * 512 + lane * 8 + (c & 7);
            lwf[faddr] = (f16)v;
        }
        if (idx < 384 * 128) {                        // qkv W -> FRAGMENT-PACKED qwf (KS=4)
            float v = qw[idx];
            if (idx < 128 * 128) v *= QSC;            // Q rows scaled
            int i = idx >> 7, k = idx & 127;
            int lane = (((k & 31) >> 3) << 4) + (i & 15);
            int faddr = (((i >> 6) << 2) + ((i >> 4) & 3)) * 2048 + (k >> 5) * 512 + lane * 8 + (k & 7);
            qwf[faddr] = (f16)v;
        }
        if (idx < 128 * 128) {                        // proj W -> FRAGMENT-PACKED pwf (KS=4)
            int i = idx >> 7, k = idx & 127;
            int lane = (((k & 31) >> 3) << 4) + (i & 15);
            int faddr = (((i >> 6) << 2) + ((i >> 4) & 3)) * 2048 + (k >> 5) * 512 + lane * 8 + (k & 7);
            pwf[faddr] = (f16)pw[idx];
        }
        if (idx < 384) qbs[idx] = qb[idx] * (idx < 128 ? QSC : 1.f);
        if (idx < 10240) rpbp[idx] = (idx < 4 * RPBSZ) ? rpb[idx] * LOG2E : 0.f;
    } else if (b < 216) {
        // b2s[i] = (qb[i] + qw[i,:]·pb) * sc_i ; 16 lanes per output, shuffle-reduce
        int t = (b - 192) * 256 + threadIdx.x;        // [0, 6144)
        int i = t >> 4, l = t & 15;
        if (i < 384) {
            float s = 0.f;
            #pragma unroll
            for (int j = l * 8; j < l * 8 + 8; j++) s += qw[i * 128 + j] * pb[j];
            s += __shfl_xor(s, 1); s += __shfl_xor(s, 2);
            s += __shfl_xor(s, 4); s += __shfl_xor(s, 8);
            if (l == 0) b2s[i] = (qb[i] + s) * (i < 128 ? QSC : 1.f);
        }
    } else {
        // w2f[i][k] = sc_i * sum_j qw[i][j] pw[j][k]  (fragment-packed output)
        const int bw = b - 216;                       // 0..11
        const int m0 = (bw & 1) * 64;                 // k-tile
        const int n0 = (bw >> 1) * 64;                // i-tile
        const int tid = threadIdx.x;
        const int w = tid >> 6, lane = tid & 63, quad = lane >> 4, nn = lane & 15;
        const int krow = m0 + w * 16 + nn;
        f16x8 af[4];
        #pragma unroll
        for (int ks = 0; ks < 4; ks++) {
            union { f16 e[8]; f16x8 v; } t;
            #pragma unroll
            for (int e = 0; e < 8; e++)
                t.e[e] = (f16)pw[(ks * 32 + quad * 8 + e) * 128 + krow];
            af[ks] = t.v;
        }
        f32x4 acc[4] = {};
        #pragma unroll
        for (int nt = 0; nt < 4; nt++) {
            int irow = n0 + nt * 16 + nn;
            #pragma unroll
            for (int ks = 0; ks < 4; ks++) {
                const float* qr = &qw[(size_t)irow * 128 + ks * 32 + quad * 8];
                float4 a = *(const float4*)qr, bq = *(const float4*)(qr + 4);
                PkU u0, u1, u2, u3;
                u0.h = __builtin_amdgcn_cvt_pkrtz(a.x, a.y);
                u1.h = __builtin_amdgcn_cvt_pkrtz(a.z, a.w);
                u2.h = __builtin_amdgcn_cvt_pkrtz(bq.x, bq.y);
                u3.h = __builtin_amdgcn_cvt_pkrtz(bq.z, bq.w);
                union { unsigned u[4]; f16x8 v; } bb;
                bb.u[0] = u0.u; bb.u[1] = u1.u; bb.u[2] = u2.u; bb.u[3] = u3.u;
                acc[nt] = __builtin_amdgcn_mfma_f32_16x16x32_f16(af[ks], bb.v, acc[nt], 0, 0, 0);
            }
        }
        #pragma unroll
        for (int nt = 0; nt < 4; nt++) {
            int i = n0 + nt * 16 + nn;
            int k = m0 + w * 16 + quad * 4;           // 4 consecutive cols, k&7 in {0,4}
            float sc = (i < 128) ? QSC : 1.f;
            PkU p0, p1;
            p0.h = __builtin_amdgcn_cvt_pkrtz(acc[nt][0] * sc, acc[nt][1] * sc);
            p1.h = __builtin_amdgcn_cvt_pkrtz(acc[nt][2] * sc, acc[nt][3] * sc);
            int lane2 = (((k & 31) >> 3) << 4) + (i & 15);
            int faddr = (((i >> 6) << 2) + ((i >> 4) & 3)) * 2048 + (k >> 5) * 512 + lane2 * 8 + (k & 7);
            *(uint2*)&w2f[faddr] = make_uint2(p0.u, p1.u);
        }
    }
}

// ---------- fusion GEMM v11: frag-packed W + LDS-staged dense stores; grid (352, 2) ----------
__global__ __launch_bounds__(256) void fusion_gemm(
    const float* __restrict__ x, const float* __restrict__ cond, const float* __restrict__ mask,
    const f16* __restrict__ lwf, const float* __restrict__ lb, f16* __restrict__ yh)
{
    __shared__ __align__(16) f16 Alds[64 * 168];
    __shared__ __align__(16) f16 Rlds[64][72];
    const int m0 = blockIdx.x * 64, n0 = blockIdx.y * 64;
    const int tid = threadIdx.x;
    const int w = tid >> 6, lane = tid & 63, quad = lane >> 4, nn = lane & 15;

    {   // stage cat rows (f16)
        int r = tid >> 2, cpart = tid & 3;
        size_t pos = m0 + r;
        *(uint4*)&Alds[r * 168 + 128 + cpart * 8] = make_uint4(0, 0, 0, 0);
        const float* xr = x + pos * 128 + cpart * 32;
        #pragma unroll
        for (int t = 0; t < 4; t++) {
            float4 a = *(const float4*)(xr + t * 8);
            float4 b = *(const float4*)(xr + t * 8 + 4);
            PkU p0, p1, p2, p3;
            p0.h = __builtin_amdgcn_cvt_pkrtz(a.x, a.y);
            p1.h = __builtin_amdgcn_cvt_pkrtz(a.z, a.w);
            p2.h = __builtin_amdgcn_cvt_pkrtz(b.x, b.y);
            p3.h = __builtin_amdgcn_cvt_pkrtz(b.z, b.w);
            *(uint4*)&Alds[r * 168 + cpart * 32 + t * 8] = make_uint4(p0.u, p1.u, p2.u, p3.u);
        }
        if (cpart == 0) {
            Alds[r * 168 + 128] = (f16)cond[pos * 2];
            Alds[r * 168 + 129] = (f16)cond[pos * 2 + 1];
            Alds[r * 168 + 130] = (f16)mask[pos];
        }
    }
    __syncthreads();

    const f16* wfb = lwf + ((size_t)(n0 >> 6) * 4 + w) * 2560 + lane * 8;
    f16x8 af[5];
    #pragma unroll
    for (int ks = 0; ks < 5; ks++)
        af[ks] = *(const f16x8*)(wfb + ks * 512);
    f32x4 acc[4] = {};
    #pragma unroll
    for (int ks = 0; ks < 5; ks++)
        #pragma unroll
        for (int nt = 0; nt < 4; nt++) {
            f16x8 bf = *(const f16x8*)&Alds[(nt * 16 + nn) * 168 + ks * 32 + quad * 8];
            acc[nt] = __builtin_amdgcn_mfma_f32_16x16x32_f16(af[ks], bf, acc[nt], 0, 0, 0);
        }
    float bv[4];
    #pragma unroll
    for (int r = 0; r < 4; r++) bv[r] = lb[n0 + w * 16 + quad * 4 + r];
    #pragma unroll
    for (int nt = 0; nt < 4; nt++) {
        PkU p0, p1;
        p0.h = __builtin_amdgcn_cvt_pkrtz(fmaxf(acc[nt][0] + bv[0], 0.f), fmaxf(acc[nt][1] + bv[1], 0.f));
        p1.h = __builtin_amdgcn_cvt_pkrtz(fmaxf(acc[nt][2] + bv[2], 0.f), fmaxf(acc[nt][3] + bv[3], 0.f));
        *(uint2*)&Rlds[nt * 16 + nn][w * 16 + quad * 4] = make_uint2(p0.u, p1.u);
    }
    __syncthreads();
    #pragma unroll
    for (int it = 0; it < 2; it++) {                  // 512 dense uint4 runs
        int idx = it * 256 + tid;
        int pl = idx >> 3, oct = idx & 7;
        *(uint4*)&yh[(size_t)(m0 + pl) * 128 + n0 + oct * 8] = *(uint4*)&Rlds[pl][oct * 8];
    }
}

// ---------- qkv GEMM v10 (unchanged): fragment-packed W + LDS-staged coalesced stores ----------
__global__ __launch_bounds__(256) void gemm_qkv(
    const f16* __restrict__ A, const f16* __restrict__ Wf, const float* __restrict__ bias,
    f16* __restrict__ qh, f16* __restrict__ kh2, f16* __restrict__ vh2)
{
    __shared__ __align__(16) f16 Alds[64 * 136];
    __shared__ __align__(16) f16 Rlds[64][72];
    const int m0 = blockIdx.x * 64, n0 = blockIdx.y * 64;
    const int tid = threadIdx.x;
    const int w = tid >> 6, lane = tid & 63, quad = lane >> 4, nn = lane & 15;

    for (int i = tid; i < 1024; i += 256) {
        int r = i >> 4, c = i & 15;
        *(uint4*)&Alds[r * 136 + c * 8] = *(const uint4*)&A[(size_t)(m0 + r) * 128 + c * 8];
    }
    __syncthreads();

    const f16* wfb = Wf + ((size_t)(n0 >> 6) * 4 + w) * 2048 + lane * 8;
    f16x8 af[4];
    #pragma unroll
    for (int ks = 0; ks < 4; ks++)
        af[ks] = *(const f16x8*)(wfb + ks * 512);
    f32x4 acc[4] = {};
    #pragma unroll
    for (int ks = 0; ks < 4; ks++)
        #pragma unroll
        for (int nt = 0; nt < 4; nt++) {
            f16x8 bf = *(const f16x8*)&Alds[(nt * 16 + nn) * 136 + ks * 32 + quad * 8];
            acc[nt] = __builtin_amdgcn_mfma_f32_16x16x32_f16(af[ks], bf, acc[nt], 0, 0, 0);
        }
    float bv[4];
    #pragma unroll
    for (int r = 0; r < 4; r++) bv[r] = bias[n0 + w * 16 + quad * 4 + r];

    // ---- stage output tile to Rlds[pos_local][ch_local] ----
    if (n0 < 256) {   // Q/K: RTZ pack
        #pragma unroll
        for (int nt = 0; nt < 4; nt++) {
            PkU p0, p1;
            p0.h = __builtin_amdgcn_cvt_pkrtz(acc[nt][0] + bv[0], acc[nt][1] + bv[1]);
            p1.h = __builtin_amdgcn_cvt_pkrtz(acc[nt][2] + bv[2], acc[nt][3] + bv[3]);
            *(uint2*)&Rlds[nt * 16 + nn][w * 16 + quad * 4] = make_uint2(p0.u, p1.u);
        }
    } else {          // V: RNE casts
        #pragma unroll
        for (int nt = 0; nt < 4; nt++) {
            union { f16 e[4]; uint2 u; } t;
            #pragma unroll
            for (int r = 0; r < 4; r++) t.e[r] = (f16)(acc[nt][r] + bv[r]);
            *(uint2*)&Rlds[nt * 16 + nn][w * 16 + quad * 4] = t.u;
        }
    }
    __syncthreads();

    // ---- 512 dense uint4 runs, 2 per thread ----
    if (n0 < 128) {                                   // ---- Q: qh[pos][128]
        #pragma unroll
        for (int it = 0; it < 2; it++) {
            int idx = it * 256 + tid;                 // [0,512)
            int pl = idx >> 3, oct = idx & 7;
            f16x8 v = *(const f16x8*)&Rlds[pl][oct * 8];
            *(uint4*)&qh[(size_t)(m0 + pl) * 128 + n0 + oct * 8] = *(uint4*)&v;
        }
    } else if (n0 < 256) {                            // ---- K: kh2[aa][h][j][ch32]
        #pragma unroll
        for (int it = 0; it < 2; it++) {
            int idx = it * 256 + tid;
            int pl = idx >> 3, oct = idx & 7;
            f16x8 v = *(const f16x8*)&Rlds[pl][oct * 8];
            int pos = m0 + pl, aa = pos / 88, j = pos - aa * 88;
            int ch = n0 - 128 + oct * 8;              // octet never crosses a 32-ch head
            int h = ch >> 5, c32 = ch & 31;
            *(uint4*)&kh2[((size_t)(aa * 4 + h) * 88 + j) * 32 + c32] = *(uint4*)&v;
        }
    } else {                                          // ---- V: vh2[aa][h][half][g][ch16][jr]
        #pragma unroll
        for (int it = 0; it < 2; it++) {
            int idx = it * 256 + tid;
            int pq = idx >> 5, cp = idx & 31;         // pos quad, ch pair
            union { f16 e[8]; uint4 u; } t;
            #pragma unroll
            for (int cc = 0; cc < 2; cc++)
                #pragma unroll
                for (int jj = 0; jj < 4; jj++)
                    t.e[cc * 4 + jj] = Rlds[pq * 4 + jj][cp * 2 + cc];
            int pos = m0 + pq * 4, aa = pos / 88, j = pos - aa * 88;   // j%4==0
            int ch = n0 - 256 + cp * 2;               // even pair: same h/half/c16-pair
            int h = ch >> 5, c = ch & 31, half = c >> 4, c16 = c & 15;
            *(uint4*)&vh2[(size_t)(aa * 4 + h) * 2816 + half * 1408 + (j >> 2) * 64 + c16 * 4] = t.u;
        }
    }
}

// ---------- final projection v11: frag-packed W + LDS-staged dense f32 stores ----------
__global__ __launch_bounds__(256) void gemm_out(
    const f16* __restrict__ A, const f16* __restrict__ Wf, const float* __restrict__ bias,
    float* __restrict__ outp)
{
    __shared__ __align__(16) f16 Alds[64 * 136];
    __shared__ __align__(16) float Rldsf[64][68];
    const int m0 = blockIdx.x * 64, n0 = blockIdx.y * 64;
    const int tid = threadIdx.x;
    const int w = tid >> 6, lane = tid & 63, quad = lane >> 4, nn = lane & 15;

    for (int i = tid; i < 1024; i += 256) {
        int r = i >> 4, c = i & 15;
        *(uint4*)&Alds[r * 136 + c * 8] = *(const uint4*)&A[(size_t)(m0 + r) * 128 + c * 8];
    }
    __syncthreads();

    const f16* wfb = Wf + ((size_t)(n0 >> 6) * 4 + w) * 2048 + lane * 8;
    f16x8 af[4];
    #pragma unroll
    for (int ks = 0; ks < 4; ks++)
        af[ks] = *(const f16x8*)(wfb + ks * 512);
    f32x4 acc[4] = {};
    #pragma unroll
    for (int ks = 0; ks < 4; ks++)
        #pragma unroll
        for (int nt = 0; nt < 4; nt++) {
            f16x8 bf = *(const f16x8*)&Alds[(nt * 16 + nn) * 136 + ks * 32 + quad * 8];
            acc[nt] = __builtin_amdgcn_mfma_f32_16x16x32_f16(af[ks], bf, acc[nt], 0, 0, 0);
        }
    float bv[4];
    #pragma unroll
    for (int r = 0; r < 4; r++) bv[r] = bias[n0 + w * 16 + quad * 4 + r];
    #pragma unroll
    for (int nt = 0; nt < 4; nt++) {
        f32x4 vv;
        #pragma unroll
        for (int r = 0; r < 4; r++) vv[r] = acc[nt][r] + bv[r];
        *(f32x4*)&Rldsf[nt * 16 + nn][w * 16 + quad * 4] = vv;
    }
    __syncthreads();
    #pragma unroll
    for (int it = 0; it < 4; it++) {                  // 1024 dense f32x4 runs
        int idx = it * 256 + tid;
        int pl = idx >> 4, part = idx & 15;
        *(f32x4*)&outp[(size_t)(m0 + pl) * 128 + n0 + part * 4] = *(const f32x4*)&Rldsf[pl][part * 4];
    }
}

// ---------- MFMA neighborhood attention v12: 2 heads per block (4 waves) ----------
// v9/v11 per-wave pipeline kept byte-identical (14 key rows x 2 qsets, register
// PV, coalesced kh2/vh2, branchless masks, full unroll, setprio). Change: each
// block hosts TWO heads - wave w: head = blockIdx.z*2 + (w>>1), key-half = w&1.
// Rationale: measured OccupancyPercent ~13% (=~2 blocks/CU) despite VGPR/LDS
// allowing 10; v2's 256-thread variant measured 31% - evidence of a per-block
// residency cap. Doubling waves/block doubles resident waves under that cap;
// per-wave work/loads unchanged (each (head,key-half) still loaded once per
// block - not the v2 amortization mistake, which halved K/V reuse per WAVE).
// Merge: per head-pair in Olds[2][64][28] (kh=1 stores, kh=0 finalizes).
__global__ __launch_bounds__(256, 3) void attn_mfma(
    const f16* __restrict__ qh,    // [N][128] Q, pre-scaled by QSC
    const f16* __restrict__ kh2,   // [aa][h][j][ch32]
    const f16* __restrict__ vh2,   // [aa][h][half][g][ch16][jr]
    const float* __restrict__ rpbp,
    f16* __restrict__ ao)          // [N][128]
{
    const int bx = ((blockIdx.x & 7) << 3) + (blockIdx.x >> 3);   // XCD-contiguous i-tiles
    const int i0 = bx * 4;
    const int j0 = blockIdx.y * 8;
    const int tid = threadIdx.x;
    const int w = tid >> 6, lane = tid & 63;
    const int quad = lane >> 4, nn = lane & 15;
    const int kh = w & 1;                  // key-row half within head-group
    const int hs = w >> 1;                 // head-sub within block
    const int h  = blockIdx.z * 2 + hs;

    const int ri0 = min(max(i0 - 12, 0), TT - 28);         // 28-row key span
    const int rj0 = min(max(j0 - 12, 0), PP - WIN) & ~3;   // 4-aligned for vh2

    __shared__ __align__(16) float Olds[2][64][28];   // [head-sub] kh=1 partials

    int si_[2];
    unsigned pm_[2][4];            // packed-f16 column masks per output word
    f16x8 qf[2];
    const float* rpq[2];
    const float* rp_h = rpbp + h * RPBSZ;
    const int aa0 = ri0 + kh * 14; // this wave's first key row (14 rows/wave)

    #pragma unroll
    for (int q = 0; q < 2; q++) {
        int ql = q * 16 + nn;
        int qi = i0 + (ql >> 3), qj = j0 + (ql & 7);
        int si = min(max(qi - 12, 0), TT - WIN);
        int sj = min(max(qj - 12, 0), PP - WIN);
        si_[q] = si;
        unsigned cm = 0x1FFFFFFu << (sj - rj0);       // shift <= 7
        #pragma unroll
        for (int t = 0; t < 4; t++) {
            int k0 = (t >> 1) * 16 + quad * 4 + (t & 1) * 2;
            pm_[q][t] = (((cm >> k0) & 1u) ? 0xFFFFu : 0u)
                      | (((cm >> (k0 + 1)) & 1u) ? 0xFFFF0000u : 0u);
        }
        qf[q] = *(const f16x8*)&qh[(size_t)(qi * PP + qj) * 128 + h * HD + quad * 8];
        rpq[q] = rp_h + (aa0 - qi + 24) * RPBW + (rj0 - qj + 24) + quad * 4;
    }

    const int b0 = min(rj0 + nn, PP - 1);
    const int b1 = min(rj0 + 16 + nn, PP - 1);
    const f16x4 ones4 = {(f16)1.f, (f16)1.f, (f16)1.f, (f16)1.f};

    // dense per-lane base pointers (advance by KVROW per key row)
    const f16* kb = kh2 + (size_t)(aa0 * 4 + h) * 2816 + quad * 8;
    const f16* vb = vh2 + (size_t)(aa0 * 4 + h) * 2816 + ((rj0 >> 2) + quad) * 64 + nn * 4;

    f32x4 O[2][2] = {};            // [qset][ch-half]; regs = queries, lane nn = channel
    f32x4 lacc[2] = {};
    union PB { unsigned u[2]; f16x4 v; };
    PB pa_[2], pb_[2];             // pending P (row aa-1), masked, packed
    f32x4 za_[2], zb_[2];          // rpb C-init for current row

    // ---- prologue: row aa0 -> S/exp only (its PV runs in iter c=1) ----
    int aa = aa0;
    f16x8 kf0 = *(const f16x8*)(kb + (size_t)b0 * 32);
    f16x8 kf1 = *(const f16x8*)(kb + (size_t)b1 * 32);
    f16x4 vfA0 = *(const f16x4u*)vb;                  // keys  0-15, ch lo
    f16x4 vfB0 = *(const f16x4u*)(vb + 256);          // keys 16-31, ch lo
    f16x4 vfA1 = *(const f16x4u*)(vb + 1408);         // keys  0-15, ch hi
    f16x4 vfB1 = *(const f16x4u*)(vb + 1664);         // keys 16-31, ch hi
    #pragma unroll
    for (int q = 0; q < 2; q++) {
        za_[q] = *(const f32x4u*)rpq[q];
        zb_[q] = *(const f32x4u*)(rpq[q] + 16);
        rpq[q] += RPBW;
    }
    #pragma unroll
    for (int q = 0; q < 2; q++) {
        f32x4 s0 = __builtin_amdgcn_mfma_f32_16x16x32_f16(kf0, qf[q], za_[q], 0, 0, 0);
        f32x4 s1 = __builtin_amdgcn_mfma_f32_16x16x32_f16(kf1, qf[q], zb_[q], 0, 0, 0);
        bool rv = (unsigned)(aa - si_[q]) <= 24u;
        float p[8];
        #pragma unroll
        for (int r = 0; r < 4; r++) { p[r] = EXP2(s0[r]); p[r + 4] = EXP2(s1[r]); }
        PkU u0, u1, u2, u3;
        u0.h = __builtin_amdgcn_cvt_pkrtz(p[0], p[1]);
        u1.h = __builtin_amdgcn_cvt_pkrtz(p[2], p[3]);
        u2.h = __builtin_amdgcn_cvt_pkrtz(p[4], p[5]);
        u3.h = __builtin_amdgcn_cvt_pkrtz(p[6], p[7]);
        pa_[q].u[0] = rv ? (u0.u & pm_[q][0]) : 0u;
        pa_[q].u[1] = rv ? (u1.u & pm_[q][1]) : 0u;
        pb_[q].u[0] = rv ? (u2.u & pm_[q][2]) : 0u;
        pb_[q].u[1] = rv ? (u3.u & pm_[q][3]) : 0u;
    }
    // prefetch K for row aa0+1
    kb += KVROW;
    f16x8 nkf0 = *(const f16x8*)(kb + (size_t)b0 * 32);
    f16x8 nkf1 = *(const f16x8*)(kb + (size_t)b1 * 32);

    // ---- fully-unrolled pipelined loop: rows aa0+1 .. aa0+13 ----
    #pragma unroll
    for (int c = 1; c < 14; ++c) {
        aa = aa0 + c;
        kf0 = nkf0; kf1 = nkf1;                       // K(aa), prefetched last iter

        // (a) issue rpb loads for row aa (oldest in VMEM queue -> S wait is cheap)
        #pragma unroll
        for (int q = 0; q < 2; q++) {
            za_[q] = *(const f32x4u*)rpq[q];
            zb_[q] = *(const f32x4u*)(rpq[q] + 16);
            rpq[q] += RPBW;
        }

        // (b) PV for row aa-1 (pure-MFMA cluster; setprio keeps the pipe fed)
        __builtin_amdgcn_s_setprio(1);
        #pragma unroll
        for (int q = 0; q < 2; q++) {
            O[q][0] = __builtin_amdgcn_mfma_f32_16x16x16f16(pa_[q].v, vfA0, O[q][0], 0, 0, 0);
            O[q][0] = __builtin_amdgcn_mfma_f32_16x16x16f16(pb_[q].v, vfB0, O[q][0], 0, 0, 0);
            O[q][1] = __builtin_amdgcn_mfma_f32_16x16x16f16(pa_[q].v, vfA1, O[q][1], 0, 0, 0);
            O[q][1] = __builtin_amdgcn_mfma_f32_16x16x16f16(pb_[q].v, vfB1, O[q][1], 0, 0, 0);
            lacc[q] = __builtin_amdgcn_mfma_f32_16x16x16f16(pa_[q].v, ones4, lacc[q], 0, 0, 0);
            lacc[q] = __builtin_amdgcn_mfma_f32_16x16x16f16(pb_[q].v, ones4, lacc[q], 0, 0, 0);
        }
        __builtin_amdgcn_s_setprio(0);

        // (c) issue V loads for row aa (consumed by next iter's PV) - dense 512B each
        vb += KVROW;
        vfA0 = *(const f16x4u*)vb;
        vfB0 = *(const f16x4u*)(vb + 256);
        vfA1 = *(const f16x4u*)(vb + 1408);
        vfB1 = *(const f16x4u*)(vb + 1664);

        // (d) issue K prefetch for row aa+1 (last iter reads padded row: unused)
        kb += KVROW;
        nkf0 = *(const f16x8*)(kb + (size_t)b0 * 32);
        nkf1 = *(const f16x8*)(kb + (size_t)b1 * 32);

        // (e) S + exp for row aa -> pending P (pa_/pb_ free: consumed in (b))
        #pragma unroll
        for (int q = 0; q < 2; q++) {
            f32x4 s0 = __builtin_amdgcn_mfma_f32_16x16x32_f16(kf0, qf[q], za_[q], 0, 0, 0);
            f32x4 s1 = __builtin_amdgcn_mfma_f32_16x16x32_f16(kf1, qf[q], zb_[q], 0, 0, 0);
            bool rv = (unsigned)(aa - si_[q]) <= 24u;
            float p[8];
            #pragma unroll
            for (int r = 0; r < 4; r++) { p[r] = EXP2(s0[r]); p[r + 4] = EXP2(s1[r]); }
            PkU u0, u1, u2, u3;
            u0.h = __builtin_amdgcn_cvt_pkrtz(p[0], p[1]);
            u1.h = __builtin_amdgcn_cvt_pkrtz(p[2], p[3]);
            u2.h = __builtin_amdgcn_cvt_pkrtz(p[4], p[5]);
            u3.h = __builtin_amdgcn_cvt_pkrtz(p[6], p[7]);
            pa_[q].u[0] = rv ? (u0.u & pm_[q][0]) : 0u;
            pa_[q].u[1] = rv ? (u1.u & pm_[q][1]) : 0u;
            pb_[q].u[0] = rv ? (u2.u & pm_[q][2]) : 0u;
            pb_[q].u[1] = rv ? (u3.u & pm_[q][3]) : 0u;
        }
    }

    // ---- epilogue PV: last row (aa0+13) ----
    #pragma unroll
    for (int q = 0; q < 2; q++) {
        O[q][0] = __builtin_amdgcn_mfma_f32_16x16x16f16(pa_[q].v, vfA0, O[q][0], 0, 0, 0);
        O[q][0] = __builtin_amdgcn_mfma_f32_16x16x16f16(pb_[q].v, vfB0, O[q][0], 0, 0, 0);
        O[q][1] = __builtin_amdgcn_mfma_f32_16x16x16f16(pa_[q].v, vfA1, O[q][1], 0, 0, 0);
        O[q][1] = __builtin_amdgcn_mfma_f32_16x16x16f16(pb_[q].v, vfB1, O[q][1], 0, 0, 0);
        lacc[q] = __builtin_amdgcn_mfma_f32_16x16x16f16(pa_[q].v, ones4, lacc[q], 0, 0, 0);
        lacc[q] = __builtin_amdgcn_mfma_f32_16x16x16f16(pb_[q].v, ones4, lacc[q], 0, 0, 0);
    }

    // ---- merge (per head-pair): kh=1 wave stores, kh=0 wave adds and finishes ----
    if (kh) {
        float* ob = &Olds[hs][lane][0];
        #pragma unroll
        for (int q = 0; q < 2; q++) {
            *(f32x4*)&ob[q * 12]     = O[q][0];
            *(f32x4*)&ob[q * 12 + 4] = O[q][1];
            *(f32x4*)&ob[q * 12 + 8] = lacc[q];
        }
    }
    __syncthreads();
    if (!kh) {
        const float* ob = &Olds[hs][lane][0];
        #pragma unroll
        for (int q = 0; q < 2; q++) {
            f32x4 o0 = O[q][0] + *(const f32x4*)&ob[q * 12];
            f32x4 o1 = O[q][1] + *(const f32x4*)&ob[q * 12 + 4];
            f32x4 la = lacc[q] + *(const f32x4*)&ob[q * 12 + 8];
            #pragma unroll
            for (int r = 0; r < 4; r++) {
                float li = 1.f / la[r];
                int ql = q * 16 + quad * 4 + r;
                int qi = i0 + (ql >> 3), qj = j0 + (ql & 7);
                size_t base = (size_t)(qi * PP + qj) * CC + h * HD;
                ao[base + nn]      = (f16)(o0[r] * li);
                ao[base + 16 + nn] = (f16)(o1[r] * li);
            }
        }
    }
}

extern "C" void kernel_launch(void* const* d_in, const int* in_sizes, int n_in,
                              void* d_out, int out_size, void* d_ws, size_t ws_size,
                              hipStream_t stream) {
    (void)in_sizes; (void)n_in; (void)out_size; (void)ws_size;
    const float* x    = (const float*)d_in[0];
    const float* cond = (const float*)d_in[1];
    const float* mask = (const float*)d_in[2];
    const float* lw   = (const float*)d_in[3];
    const float* lb   = (const float*)d_in[4];
    const float* qw   = (const float*)d_in[5];
    const float* qb   = (const float*)d_in[6];
    const float* rpb  = (const float*)d_in[7];
    const float* pw   = (const float*)d_in[8];
    const float* pb   = (const float*)d_in[9];
    float* outp       = (float*)d_out;

    float* ws   = (float*)d_ws;
    float* qbs  = ws;                 // 384
    float* b2s  = qbs + 384;          // 384
    float* rpbp = b2s + 384;          // 10240 padded
    f16* lwf  = (f16*)(rpbp + 10240);             // 128*160 fragment-packed
    f16* qwf  = lwf + 20480;                      // 384*128 fragment-packed
    f16* pwf  = qwf + 49152;                      // 128*128 fragment-packed
    f16* w2f  = pwf + 16384;                      // 384*128 fragment-packed
    f16* yh   = w2f + 49152;                      // NN*128
    f16* qh   = yh + (size_t)NN * 128;            // NN*128 Q
    f16* kh2  = qh + (size_t)NN * 128;            // 258 rows * 11264
    f16* vh2  = kh2 + (size_t)KVAARWS * KVROW;    // 258 rows * 11264
    f16* ao   = vh2 + (size_t)KVAARWS * KVROW;    // NN*128

    prep<<<228, 256, 0, stream>>>(lw, qw, pw, qb, pb, rpb, lwf, qwf, pwf, w2f, qbs, b2s, rpbp);
    fusion_gemm<<<dim3(352, 2), 256, 0, stream>>>(x, cond, mask, lwf, lb, yh);
    gemm_qkv<<<dim3(352, 6), 256, 0, stream>>>(yh, qwf, qbs, qh, kh2, vh2);
    attn_mfma<<<dim3(TT / 4, PP / 8, HEADS / 2), 256, 0, stream>>>(qh, kh2, vh2, rpbp, ao);
    gemm_qkv<<<dim3(352, 6), 256, 0, stream>>>(ao, w2f, b2s, qh, kh2, vh2);   // fused proj+qkv
    attn_mfma<<<dim3(TT / 4, PP / 8, HEADS / 2), 256, 0, stream>>>(qh, kh2, vh2, rpbp, ao);
    gemm_out<<<dim3(352, 2), 256, 0, stream>>>(ao, pwf, pb, outp);
}

// Round 12
// 180.850 us; speedup vs baseline: 3.7185x; 1.0039x over previous
//
#include <hip/hip_runtime.h>
#include <hip/hip_fp16.h>

#define TT 256
#define PP 88
#define CC 128
#define NN (TT * PP)          // 22528 positions
#define HEADS 4
#define HD 32
#define WIN 25
#define RPBW 49
#define RPBSZ (RPBW * RPBW)   // 2401
#define SCALE 0.17677669529663687f   // 1/sqrt(32)
#define LOG2E 1.4426950408889634f
#define QSC (SCALE * LOG2E)          // fold exp->exp2 into Q path

// K layout: kh2[aa][h][j:88][ch32]   -> row stride (aa) = 11264, (aa,h) block = 2816
// V layout: vh2[aa][h][half:2][g:22][ch16][jr:4] -> same strides; dense 512B per attn load
#define KVROW 11264           // f16 elems per aa row (4 heads x 2816)
#define KVAARWS 258           // aa rows allocated (256 + prefetch/overshoot pad)

#if __has_builtin(__builtin_amdgcn_exp2f)
#define EXP2(x) __builtin_amdgcn_exp2f(x)
#else
#define EXP2(x) exp2f(x)
#endif

typedef _Float16 f16;
typedef f16 f16x8 __attribute__((ext_vector_type(8)));
typedef f16 f16x8u __attribute__((ext_vector_type(8), aligned(4)));
typedef f16 f16x4 __attribute__((ext_vector_type(4)));
typedef f16 f16x4u __attribute__((ext_vector_type(4), aligned(4)));
typedef float f32x4 __attribute__((ext_vector_type(4)));
typedef float f32x4u __attribute__((ext_vector_type(4), aligned(4)));
typedef __fp16 hf16x2 __attribute__((ext_vector_type(2)));
union PkU { hf16x2 h; unsigned u; };

// Fragment-packed W layout (for all MFMA af loads): output row i, col k:
//   group = (i>>6)*4 + ((i>>4)&3), ks = k>>5, lane = ((k&31)>>3)*16 + (i&15)
//   faddr = group*(KS*512) + ks*512 + lane*8 + (k&7)      [KS = #32-col blocks]
// Inverse (used by vectorized prep): i = (group>>2)*64 + (group&3)*16 + (lane&15),
//   k = ks*32 + (lane>>4)*8 + e, e=0..7  -> 8 consecutive k = 8 consecutive faddr.

// ---------- prep v13: VECTORIZED repack (dense uint4 stores) + b2s + MFMA wcomb ----------
__global__ __launch_bounds__(256) void prep(
    const float* __restrict__ lw, const float* __restrict__ qw,
    const float* __restrict__ pw, const float* __restrict__ qb,
    const float* __restrict__ pb, const float* __restrict__ rpb,
    f16* __restrict__ lwf, f16* __restrict__ qwf, f16* __restrict__ pwf,
    f16* __restrict__ w2f, float* __restrict__ qbs, float* __restrict__ b2s,
    float* __restrict__ rpbp)
{
    const int b = blockIdx.x;
    if (b < 192) {
        int idx = b * 256 + threadIdx.x;              // [0, 49152)
        if (idx < 6144) {                             // qwf: 24 groups x 4 ks x 64 lanes
            int group = idx >> 8, ks = (idx >> 6) & 3, lane = idx & 63;
            int i = (group >> 2) * 64 + (group & 3) * 16 + (lane & 15);
            int k0 = ks * 32 + (lane >> 4) * 8;
            float sc = (i < 128) ? QSC : 1.f;
            union { f16 e[8]; uint4 u; } t;
            #pragma unroll
            for (int e = 0; e < 8; e++) t.e[e] = (f16)(qw[i * 128 + k0 + e] * sc);
            *(uint4*)&qwf[group * 2048 + ks * 512 + lane * 8] = t.u;
        } else if (idx < 8704) {                      // lwf: 8 groups x 5 ks x 64 lanes
            int j = idx - 6144;
            int group = j >> 8, rem = j & 255;        // rem = ks*64 + lane, ks<5 when j<2560
            if (j < 2560) { }                         // (group<8 guaranteed: 2560 = 8*5*64... )
            int ks = rem >> 6, lane = rem & 63;
            // j in [0,2560): group = j/320? -- use direct decomposition instead:
            group = j / 320; int r2 = j - group * 320; ks = r2 >> 6; lane = r2 & 63;
            if (group < 8) {
                int r = (group >> 2) * 64 + (group & 3) * 16 + (lane & 15);
                int c0 = ks * 32 + (lane >> 4) * 8;
                union { f16 e[8]; uint4 u; } t;
                #pragma unroll
                for (int e = 0; e < 8; e++) {
                    int c = c0 + e;
                    t.e[e] = (f16)((c < 131) ? lw[r * 131 + c] : 0.f);
                }
                *(uint4*)&lwf[group * 2560 + ks * 512 + lane * 8] = t.u;
            }
        } else if (idx < 10752) {                     // pwf: 8 groups x 4 ks x 64 lanes
            int j = idx - 8704;
            int group = j >> 8, ks = (j >> 6) & 3, lane = j & 63;
            int i = (group >> 2) * 64 + (group & 3) * 16 + (lane & 15);
            int k0 = ks * 32 + (lane >> 4) * 8;
            union { f16 e[8]; uint4 u; } t;
            #pragma unroll
            for (int e = 0; e < 8; e++) t.e[e] = (f16)pw[i * 128 + k0 + e];
            *(uint4*)&pwf[group * 2048 + ks * 512 + lane * 8] = t.u;
        } else if (idx < 20992) {                     // rpbp: 10240 dense f32
            int j = idx - 10752;
            rpbp[j] = (j < 4 * RPBSZ) ? rpb[j] * LOG2E : 0.f;
        } else if (idx < 21376) {                     // qbs: 384
            int j = idx - 20992;
            qbs[j] = qb[j] * (j < 128 ? QSC : 1.f);
        }
    } else if (b < 216) {
        // b2s[i] = (qb[i] + qw[i,:]·pb) * sc_i ; 16 lanes per output, shuffle-reduce
        int t = (b - 192) * 256 + threadIdx.x;        // [0, 6144)
        int i = t >> 4, l = t & 15;
        if (i < 384) {
            float s = 0.f;
            #pragma unroll
            for (int j = l * 8; j < l * 8 + 8; j++) s += qw[i * 128 + j] * pb[j];
            s += __shfl_xor(s, 1); s += __shfl_xor(s, 2);
            s += __shfl_xor(s, 4); s += __shfl_xor(s, 8);
            if (l == 0) b2s[i] = (qb[i] + s) * (i < 128 ? QSC : 1.f);
        }
    } else {
        // w2f[i][k] = sc_i * sum_j qw[i][j] pw[j][k]  (fragment-packed output)
        const int bw = b - 216;                       // 0..11
        const int m0 = (bw & 1) * 64;                 // k-tile
        const int n0 = (bw >> 1) * 64;                // i-tile
        const int tid = threadIdx.x;
        const int w = tid >> 6, lane = tid & 63, quad = lane >> 4, nn = lane & 15;
        const int krow = m0 + w * 16 + nn;
        f16x8 af[4];
        #pragma unroll
        for (int ks = 0; ks < 4; ks++) {
            union { f16 e[8]; f16x8 v; } t;
            #pragma unroll
            for (int e = 0; e < 8; e++)
                t.e[e] = (f16)pw[(ks * 32 + quad * 8 + e) * 128 + krow];
            af[ks] = t.v;
        }
        f32x4 acc[4] = {};
        #pragma unroll
        for (int nt = 0; nt < 4; nt++) {
            int irow = n0 + nt * 16 + nn;
            #pragma unroll
            for (int ks = 0; ks < 4; ks++) {
                const float* qr = &qw[(size_t)irow * 128 + ks * 32 + quad * 8];
                float4 a = *(const float4*)qr, bq = *(const float4*)(qr + 4);
                PkU u0, u1, u2, u3;
                u0.h = __builtin_amdgcn_cvt_pkrtz(a.x, a.y);
                u1.h = __builtin_amdgcn_cvt_pkrtz(a.z, a.w);
                u2.h = __builtin_amdgcn_cvt_pkrtz(bq.x, bq.y);
                u3.h = __builtin_amdgcn_cvt_pkrtz(bq.z, bq.w);
                union { unsigned u[4]; f16x8 v; } bb;
                bb.u[0] = u0.u; bb.u[1] = u1.u; bb.u[2] = u2.u; bb.u[3] = u3.u;
                acc[nt] = __builtin_amdgcn_mfma_f32_16x16x32_f16(af[ks], bb.v, acc[nt], 0, 0, 0);
            }
        }
        #pragma unroll
        for (int nt = 0; nt < 4; nt++) {
            int i = n0 + nt * 16 + nn;
            int k = m0 + w * 16 + quad * 4;           // 4 consecutive cols, k&7 in {0,4}
            float sc = (i < 128) ? QSC : 1.f;
            PkU p0, p1;
            p0.h = __builtin_amdgcn_cvt_pkrtz(acc[nt][0] * sc, acc[nt][1] * sc);
            p1.h = __builtin_amdgcn_cvt_pkrtz(acc[nt][2] * sc, acc[nt][3] * sc);
            int lane2 = (((k & 31) >> 3) << 4) + (i & 15);
            int faddr = (((i >> 6) << 2) + ((i >> 4) & 3)) * 2048 + (k >> 5) * 512 + lane2 * 8 + (k & 7);
            *(uint2*)&w2f[faddr] = make_uint2(p0.u, p1.u);
        }
    }
}

// ---------- fused fusion+qkv v13: Y in LDS, no yh round-trip; grid (352) ----------
// Phase 1: stage cat (as old fusion_gemm). Phase 2: Y = relu(cat@lwf^T+lb) ->
// Ylds, bit-identical RTZ pack (each wave: chan groups w and w+4). Phase 3: six
// 64-chan qkv tiles read Ylds; epilogues = v10's verified dense-store code.
__global__ __launch_bounds__(256) void fused_fusion_qkv(
    const float* __restrict__ x, const float* __restrict__ cond, const float* __restrict__ mask,
    const f16* __restrict__ lwf, const float* __restrict__ lb,
    const f16* __restrict__ qwf, const float* __restrict__ bias,
    f16* __restrict__ qh, f16* __restrict__ kh2, f16* __restrict__ vh2)
{
    __shared__ __align__(16) f16 Alds[64 * 168];
    __shared__ __align__(16) f16 Ylds[64 * 136];
    __shared__ __align__(16) f16 Rlds[64][72];
    const int m0 = blockIdx.x * 64;
    const int tid = threadIdx.x;
    const int w = tid >> 6, lane = tid & 63, quad = lane >> 4, nn = lane & 15;

    {   // ---- phase 1: stage cat rows (f16) ----
        int r = tid >> 2, cpart = tid & 3;
        size_t pos = m0 + r;
        *(uint4*)&Alds[r * 168 + 128 + cpart * 8] = make_uint4(0, 0, 0, 0);
        const float* xr = x + pos * 128 + cpart * 32;
        #pragma unroll
        for (int t = 0; t < 4; t++) {
            float4 a = *(const float4*)(xr + t * 8);
            float4 b = *(const float4*)(xr + t * 8 + 4);
            PkU p0, p1, p2, p3;
            p0.h = __builtin_amdgcn_cvt_pkrtz(a.x, a.y);
            p1.h = __builtin_amdgcn_cvt_pkrtz(a.z, a.w);
            p2.h = __builtin_amdgcn_cvt_pkrtz(b.x, b.y);
            p3.h = __builtin_amdgcn_cvt_pkrtz(b.z, b.w);
            *(uint4*)&Alds[r * 168 + cpart * 32 + t * 8] = make_uint4(p0.u, p1.u, p2.u, p3.u);
        }
        if (cpart == 0) {
            Alds[r * 168 + 128] = (f16)cond[pos * 2];
            Alds[r * 168 + 129] = (f16)cond[pos * 2 + 1];
            Alds[r * 168 + 130] = (f16)mask[pos];
        }
    }
    __syncthreads();

    // ---- phase 2: Y = relu(cat @ lwf^T + lb) -> Ylds ----
    #pragma unroll
    for (int gi = 0; gi < 2; gi++) {
        const int g = gi * 4 + w;                     // chan group
        const int cb = gi * 64 + w * 16;              // chan base
        const f16* wfb = lwf + (size_t)g * 2560 + lane * 8;
        f16x8 af[5];
        #pragma unroll
        for (int ks = 0; ks < 5; ks++)
            af[ks] = *(const f16x8*)(wfb + ks * 512);
        f32x4 acc[4] = {};
        #pragma unroll
        for (int ks = 0; ks < 5; ks++)
            #pragma unroll
            for (int nt = 0; nt < 4; nt++) {
                f16x8 bf = *(const f16x8*)&Alds[(nt * 16 + nn) * 168 + ks * 32 + quad * 8];
                acc[nt] = __builtin_amdgcn_mfma_f32_16x16x32_f16(af[ks], bf, acc[nt], 0, 0, 0);
            }
        float bv[4];
        #pragma unroll
        for (int r = 0; r < 4; r++) bv[r] = lb[cb + quad * 4 + r];
        #pragma unroll
        for (int nt = 0; nt < 4; nt++) {
            PkU p0, p1;
            p0.h = __builtin_amdgcn_cvt_pkrtz(fmaxf(acc[nt][0] + bv[0], 0.f), fmaxf(acc[nt][1] + bv[1], 0.f));
            p1.h = __builtin_amdgcn_cvt_pkrtz(fmaxf(acc[nt][2] + bv[2], 0.f), fmaxf(acc[nt][3] + bv[3], 0.f));
            *(uint2*)&Ylds[(nt * 16 + nn) * 136 + cb + quad * 4] = make_uint2(p0.u, p1.u);
        }
    }
    __syncthreads();

    // ---- phase 3: six 64-chan qkv tiles from Ylds ----
    #pragma unroll 1
    for (int t = 0; t < 6; t++) {
        const int n0 = t * 64;
        const f16* wfb = qwf + ((size_t)t * 4 + w) * 2048 + lane * 8;
        f16x8 af[4];
        #pragma unroll
        for (int ks = 0; ks < 4; ks++)
            af[ks] = *(const f16x8*)(wfb + ks * 512);
        f32x4 acc[4] = {};
        #pragma unroll
        for (int ks = 0; ks < 4; ks++)
            #pragma unroll
            for (int nt = 0; nt < 4; nt++) {
                f16x8 bf = *(const f16x8*)&Ylds[(nt * 16 + nn) * 136 + ks * 32 + quad * 8];
                acc[nt] = __builtin_amdgcn_mfma_f32_16x16x32_f16(af[ks], bf, acc[nt], 0, 0, 0);
            }
        float bv[4];
        #pragma unroll
        for (int r = 0; r < 4; r++) bv[r] = bias[n0 + w * 16 + quad * 4 + r];

        __syncthreads();                              // Rlds reuse guard
        if (n0 < 256) {   // Q/K: RTZ pack
            #pragma unroll
            for (int nt = 0; nt < 4; nt++) {
                PkU p0, p1;
                p0.h = __builtin_amdgcn_cvt_pkrtz(acc[nt][0] + bv[0], acc[nt][1] + bv[1]);
                p1.h = __builtin_amdgcn_cvt_pkrtz(acc[nt][2] + bv[2], acc[nt][3] + bv[3]);
                *(uint2*)&Rlds[nt * 16 + nn][w * 16 + quad * 4] = make_uint2(p0.u, p1.u);
            }
        } else {          // V: RNE casts
            #pragma unroll
            for (int nt = 0; nt < 4; nt++) {
                union { f16 e[4]; uint2 u; } tt;
                #pragma unroll
                for (int r = 0; r < 4; r++) tt.e[r] = (f16)(acc[nt][r] + bv[r]);
                *(uint2*)&Rlds[nt * 16 + nn][w * 16 + quad * 4] = tt.u;
            }
        }
        __syncthreads();

        if (n0 < 128) {                               // ---- Q: qh[pos][128]
            #pragma unroll
            for (int it = 0; it < 2; it++) {
                int idx = it * 256 + tid;
                int pl = idx >> 3, oct = idx & 7;
                *(uint4*)&qh[(size_t)(m0 + pl) * 128 + n0 + oct * 8] = *(uint4*)&Rlds[pl][oct * 8];
            }
        } else if (n0 < 256) {                        // ---- K: kh2[aa][h][j][ch32]
            #pragma unroll
            for (int it = 0; it < 2; it++) {
                int idx = it * 256 + tid;
                int pl = idx >> 3, oct = idx & 7;
                f16x8 v = *(const f16x8*)&Rlds[pl][oct * 8];
                int pos = m0 + pl, aa = pos / 88, j = pos - aa * 88;
                int ch = n0 - 128 + oct * 8;
                int h = ch >> 5, c32 = ch & 31;
                *(uint4*)&kh2[((size_t)(aa * 4 + h) * 88 + j) * 32 + c32] = *(uint4*)&v;
            }
        } else {                                      // ---- V: vh2[aa][h][half][g][ch16][jr]
            #pragma unroll
            for (int it = 0; it < 2; it++) {
                int idx = it * 256 + tid;
                int pq = idx >> 5, cp = idx & 31;
                union { f16 e[8]; uint4 u; } tt;
                #pragma unroll
                for (int cc = 0; cc < 2; cc++)
                    #pragma unroll
                    for (int jj = 0; jj < 4; jj++)
                        tt.e[cc * 4 + jj] = Rlds[pq * 4 + jj][cp * 2 + cc];
                int pos = m0 + pq * 4, aa = pos / 88, j = pos - aa * 88;
                int ch = n0 - 256 + cp * 2;
                int h = ch >> 5, c = ch & 31, half = c >> 4, c16 = c & 15;
                *(uint4*)&vh2[(size_t)(aa * 4 + h) * 2816 + half * 1408 + (j >> 2) * 64 + c16 * 4] = tt.u;
            }
        }
    }
}

// ---------- qkv GEMM (standalone, for ao input): frag-packed W + LDS-staged stores ----------
__global__ __launch_bounds__(256) void gemm_qkv(
    const f16* __restrict__ A, const f16* __restrict__ Wf, const float* __restrict__ bias,
    f16* __restrict__ qh, f16* __restrict__ kh2, f16* __restrict__ vh2)
{
    __shared__ __align__(16) f16 Alds[64 * 136];
    __shared__ __align__(16) f16 Rlds[64][72];
    const int m0 = blockIdx.x * 64, n0 = blockIdx.y * 64;
    const int tid = threadIdx.x;
    const int w = tid >> 6, lane = tid & 63, quad = lane >> 4, nn = lane & 15;

    for (int i = tid; i < 1024; i += 256) {
        int r = i >> 4, c = i & 15;
        *(uint4*)&Alds[r * 136 + c * 8] = *(const uint4*)&A[(size_t)(m0 + r) * 128 + c * 8];
    }
    __syncthreads();

    const f16* wfb = Wf + ((size_t)(n0 >> 6) * 4 + w) * 2048 + lane * 8;
    f16x8 af[4];
    #pragma unroll
    for (int ks = 0; ks < 4; ks++)
        af[ks] = *(const f16x8*)(wfb + ks * 512);
    f32x4 acc[4] = {};
    #pragma unroll
    for (int ks = 0; ks < 4; ks++)
        #pragma unroll
        for (int nt = 0; nt < 4; nt++) {
            f16x8 bf = *(const f16x8*)&Alds[(nt * 16 + nn) * 136 + ks * 32 + quad * 8];
            acc[nt] = __builtin_amdgcn_mfma_f32_16x16x32_f16(af[ks], bf, acc[nt], 0, 0, 0);
        }
    float bv[4];
    #pragma unroll
    for (int r = 0; r < 4; r++) bv[r] = bias[n0 + w * 16 + quad * 4 + r];

    if (n0 < 256) {   // Q/K: RTZ pack
        #pragma unroll
        for (int nt = 0; nt < 4; nt++) {
            PkU p0, p1;
            p0.h = __builtin_amdgcn_cvt_pkrtz(acc[nt][0] + bv[0], acc[nt][1] + bv[1]);
            p1.h = __builtin_amdgcn_cvt_pkrtz(acc[nt][2] + bv[2], acc[nt][3] + bv[3]);
            *(uint2*)&Rlds[nt * 16 + nn][w * 16 + quad * 4] = make_uint2(p0.u, p1.u);
        }
    } else {          // V: RNE casts
        #pragma unroll
        for (int nt = 0; nt < 4; nt++) {
            union { f16 e[4]; uint2 u; } t;
            #pragma unroll
            for (int r = 0; r < 4; r++) t.e[r] = (f16)(acc[nt][r] + bv[r]);
            *(uint2*)&Rlds[nt * 16 + nn][w * 16 + quad * 4] = t.u;
        }
    }
    __syncthreads();

    if (n0 < 128) {                                   // ---- Q: qh[pos][128]
        #pragma unroll
        for (int it = 0; it < 2; it++) {
            int idx = it * 256 + tid;
            int pl = idx >> 3, oct = idx & 7;
            f16x8 v = *(const f16x8*)&Rlds[pl][oct * 8];
            *(uint4*)&qh[(size_t)(m0 + pl) * 128 + n0 + oct * 8] = *(uint4*)&v;
        }
    } else if (n0 < 256) {                            // ---- K: kh2[aa][h][j][ch32]
        #pragma unroll
        for (int it = 0; it < 2; it++) {
            int idx = it * 256 + tid;
            int pl = idx >> 3, oct = idx & 7;
            f16x8 v = *(const f16x8*)&Rlds[pl][oct * 8];
            int pos = m0 + pl, aa = pos / 88, j = pos - aa * 88;
            int ch = n0 - 128 + oct * 8;
            int h = ch >> 5, c32 = ch & 31;
            *(uint4*)&kh2[((size_t)(aa * 4 + h) * 88 + j) * 32 + c32] = *(uint4*)&v;
        }
    } else {                                          // ---- V: vh2[aa][h][half][g][ch16][jr]
        #pragma unroll
        for (int it = 0; it < 2; it++) {
            int idx = it * 256 + tid;
            int pq = idx >> 5, cp = idx & 31;
            union { f16 e[8]; uint4 u; } t;
            #pragma unroll
            for (int cc = 0; cc < 2; cc++)
                #pragma unroll
                for (int jj = 0; jj < 4; jj++)
                    t.e[cc * 4 + jj] = Rlds[pq * 4 + jj][cp * 2 + cc];
            int pos = m0 + pq * 4, aa = pos / 88, j = pos - aa * 88;
            int ch = n0 - 256 + cp * 2;
            int h = ch >> 5, c = ch & 31, half = c >> 4, c16 = c & 15;
            *(uint4*)&vh2[(size_t)(aa * 4 + h) * 2816 + half * 1408 + (j >> 2) * 64 + c16 * 4] = t.u;
        }
    }
}

// ---------- final projection: frag-packed W + LDS-staged dense f32 stores ----------
__global__ __launch_bounds__(256) void gemm_out(
    const f16* __restrict__ A, const f16* __restrict__ Wf, const float* __restrict__ bias,
    float* __restrict__ outp)
{
    __shared__ __align__(16) f16 Alds[64 * 136];
    __shared__ __align__(16) float Rldsf[64][68];
    const int m0 = blockIdx.x * 64, n0 = blockIdx.y * 64;
    const int tid = threadIdx.x;
    const int w = tid >> 6, lane = tid & 63, quad = lane >> 4, nn = lane & 15;

    for (int i = tid; i < 1024; i += 256) {
        int r = i >> 4, c = i & 15;
        *(uint4*)&Alds[r * 136 + c * 8] = *(const uint4*)&A[(size_t)(m0 + r) * 128 + c * 8];
    }
    __syncthreads();

    const f16* wfb = Wf + ((size_t)(n0 >> 6) * 4 + w) * 2048 + lane * 8;
    f16x8 af[4];
    #pragma unroll
    for (int ks = 0; ks < 4; ks++)
        af[ks] = *(const f16x8*)(wfb + ks * 512);
    f32x4 acc[4] = {};
    #pragma unroll
    for (int ks = 0; ks < 4; ks++)
        #pragma unroll
        for (int nt = 0; nt < 4; nt++) {
            f16x8 bf = *(const f16x8*)&Alds[(nt * 16 + nn) * 136 + ks * 32 + quad * 8];
            acc[nt] = __builtin_amdgcn_mfma_f32_16x16x32_f16(af[ks], bf, acc[nt], 0, 0, 0);
        }
    float bv[4];
    #pragma unroll
    for (int r = 0; r < 4; r++) bv[r] = bias[n0 + w * 16 + quad * 4 + r];
    #pragma unroll
    for (int nt = 0; nt < 4; nt++) {
        f32x4 vv;
        #pragma unroll
        for (int r = 0; r < 4; r++) vv[r] = acc[nt][r] + bv[r];
        *(f32x4*)&Rldsf[nt * 16 + nn][w * 16 + quad * 4] = vv;
    }
    __syncthreads();
    #pragma unroll
    for (int it = 0; it < 4; it++) {
        int idx = it * 256 + tid;
        int pl = idx >> 4, part = idx & 15;
        *(f32x4*)&outp[(size_t)(m0 + pl) * 128 + n0 + part * 4] = *(const f32x4*)&Rldsf[pl][part * 4];
    }
}

// ---------- MFMA neighborhood attention v12 (unchanged): 2 heads per block ----------
__global__ __launch_bounds__(256, 3) void attn_mfma(
    const f16* __restrict__ qh,    // [N][128] Q, pre-scaled by QSC
    const f16* __restrict__ kh2,   // [aa][h][j][ch32]
    const f16* __restrict__ vh2,   // [aa][h][half][g][ch16][jr]
    const float* __restrict__ rpbp,
    f16* __restrict__ ao)          // [N][128]
{
    const int bx = ((blockIdx.x & 7) << 3) + (blockIdx.x >> 3);   // XCD-contiguous i-tiles
    const int i0 = bx * 4;
    const int j0 = blockIdx.y * 8;
    const int tid = threadIdx.x;
    const int w = tid >> 6, lane = tid & 63;
    const int quad = lane >> 4, nn = lane & 15;
    const int kh = w & 1;                  // key-row half within head-group
    const int hs = w >> 1;                 // head-sub within block
    const int h  = blockIdx.z * 2 + hs;

    const int ri0 = min(max(i0 - 12, 0), TT - 28);         // 28-row key span
    const int rj0 = min(max(j0 - 12, 0), PP - WIN) & ~3;   // 4-aligned for vh2

    __shared__ __align__(16) float Olds[2][64][28];   // [head-sub] kh=1 partials

    int si_[2];
    unsigned pm_[2][4];            // packed-f16 column masks per output word
    f16x8 qf[2];
    const float* rpq[2];
    const float* rp_h = rpbp + h * RPBSZ;
    const int aa0 = ri0 + kh * 14; // this wave's first key row (14 rows/wave)

    #pragma unroll
    for (int q = 0; q < 2; q++) {
        int ql = q * 16 + nn;
        int qi = i0 + (ql >> 3), qj = j0 + (ql & 7);
        int si = min(max(qi - 12, 0), TT - WIN);
        int sj = min(max(qj - 12, 0), PP - WIN);
        si_[q] = si;
        unsigned cm = 0x1FFFFFFu << (sj - rj0);       // shift <= 7
        #pragma unroll
        for (int t = 0; t < 4; t++) {
            int k0 = (t >> 1) * 16 + quad * 4 + (t & 1) * 2;
            pm_[q][t] = (((cm >> k0) & 1u) ? 0xFFFFu : 0u)
                      | (((cm >> (k0 + 1)) & 1u) ? 0xFFFF0000u : 0u);
        }
        qf[q] = *(const f16x8*)&qh[(size_t)(qi * PP + qj) * 128 + h * HD + quad * 8];
        rpq[q] = rp_h + (aa0 - qi + 24) * RPBW + (rj0 - qj + 24) + quad * 4;
    }

    const int b0 = min(rj0 + nn, PP - 1);
    const int b1 = min(rj0 + 16 + nn, PP - 1);
    const f16x4 ones4 = {(f16)1.f, (f16)1.f, (f16)1.f, (f16)1.f};

    // dense per-lane base pointers (advance by KVROW per key row)
    const f16* kb = kh2 + (size_t)(aa0 * 4 + h) * 2816 + quad * 8;
    const f16* vb = vh2 + (size_t)(aa0 * 4 + h) * 2816 + ((rj0 >> 2) + quad) * 64 + nn * 4;

    f32x4 O[2][2] = {};            // [qset][ch-half]; regs = queries, lane nn = channel
    f32x4 lacc[2] = {};
    union PB { unsigned u[2]; f16x4 v; };
    PB pa_[2], pb_[2];             // pending P (row aa-1), masked, packed
    f32x4 za_[2], zb_[2];          // rpb C-init for current row

    // ---- prologue: row aa0 -> S/exp only (its PV runs in iter c=1) ----
    int aa = aa0;
    f16x8 kf0 = *(const f16x8*)(kb + (size_t)b0 * 32);
    f16x8 kf1 = *(const f16x8*)(kb + (size_t)b1 * 32);
    f16x4 vfA0 = *(const f16x4u*)vb;                  // keys  0-15, ch lo
    f16x4 vfB0 = *(const f16x4u*)(vb + 256);          // keys 16-31, ch lo
    f16x4 vfA1 = *(const f16x4u*)(vb + 1408);         // keys  0-15, ch hi
    f16x4 vfB1 = *(const f16x4u*)(vb + 1664);         // keys 16-31, ch hi
    #pragma unroll
    for (int q = 0; q < 2; q++) {
        za_[q] = *(const f32x4u*)rpq[q];
        zb_[q] = *(const f32x4u*)(rpq[q] + 16);
        rpq[q] += RPBW;
    }
    #pragma unroll
    for (int q = 0; q < 2; q++) {
        f32x4 s0 = __builtin_amdgcn_mfma_f32_16x16x32_f16(kf0, qf[q], za_[q], 0, 0, 0);
        f32x4 s1 = __builtin_amdgcn_mfma_f32_16x16x32_f16(kf1, qf[q], zb_[q], 0, 0, 0);
        bool rv = (unsigned)(aa - si_[q]) <= 24u;
        float p[8];
        #pragma unroll
        for (int r = 0; r < 4; r++) { p[r] = EXP2(s0[r]); p[r + 4] = EXP2(s1[r]); }
        PkU u0, u1, u2, u3;
        u0.h = __builtin_amdgcn_cvt_pkrtz(p[0], p[1]);
        u1.h = __builtin_amdgcn_cvt_pkrtz(p[2], p[3]);
        u2.h = __builtin_amdgcn_cvt_pkrtz(p[4], p[5]);
        u3.h = __builtin_amdgcn_cvt_pkrtz(p[6], p[7]);
        pa_[q].u[0] = rv ? (u0.u & pm_[q][0]) : 0u;
        pa_[q].u[1] = rv ? (u1.u & pm_[q][1]) : 0u;
        pb_[q].u[0] = rv ? (u2.u & pm_[q][2]) : 0u;
        pb_[q].u[1] = rv ? (u3.u & pm_[q][3]) : 0u;
    }
    // prefetch K for row aa0+1
    kb += KVROW;
    f16x8 nkf0 = *(const f16x8*)(kb + (size_t)b0 * 32);
    f16x8 nkf1 = *(const f16x8*)(kb + (size_t)b1 * 32);

    // ---- fully-unrolled pipelined loop: rows aa0+1 .. aa0+13 ----
    #pragma unroll
    for (int c = 1; c < 14; ++c) {
        aa = aa0 + c;
        kf0 = nkf0; kf1 = nkf1;                       // K(aa), prefetched last iter

        // (a) issue rpb loads for row aa (oldest in VMEM queue -> S wait is cheap)
        #pragma unroll
        for (int q = 0; q < 2; q++) {
            za_[q] = *(const f32x4u*)rpq[q];
            zb_[q] = *(const f32x4u*)(rpq[q] + 16);
            rpq[q] += RPBW;
        }

        // (b) PV for row aa-1 (pure-MFMA cluster; setprio keeps the pipe fed)
        __builtin_amdgcn_s_setprio(1);
        #pragma unroll
        for (int q = 0; q < 2; q++) {
            O[q][0] = __builtin_amdgcn_mfma_f32_16x16x16f16(pa_[q].v, vfA0, O[q][0], 0, 0, 0);
            O[q][0] = __builtin_amdgcn_mfma_f32_16x16x16f16(pb_[q].v, vfB0, O[q][0], 0, 0, 0);
            O[q][1] = __builtin_amdgcn_mfma_f32_16x16x16f16(pa_[q].v, vfA1, O[q][1], 0, 0, 0);
            O[q][1] = __builtin_amdgcn_mfma_f32_16x16x16f16(pb_[q].v, vfB1, O[q][1], 0, 0, 0);
            lacc[q] = __builtin_amdgcn_mfma_f32_16x16x16f16(pa_[q].v, ones4, lacc[q], 0, 0, 0);
            lacc[q] = __builtin_amdgcn_mfma_f32_16x16x16f16(pb_[q].v, ones4, lacc[q], 0, 0, 0);
        }
        __builtin_amdgcn_s_setprio(0);

        // (c) issue V loads for row aa (consumed by next iter's PV) - dense 512B each
        vb += KVROW;
        vfA0 = *(const f16x4u*)vb;
        vfB0 = *(const f16x4u*)(vb + 256);
        vfA1 = *(const f16x4u*)(vb + 1408);
        vfB1 = *(const f16x4u*)(vb + 1664);

        // (d) issue K prefetch for row aa+1 (last iter reads padded row: unused)
        kb += KVROW;
        nkf0 = *(const f16x8*)(kb + (size_t)b0 * 32);
        nkf1 = *(const f16x8*)(kb + (size_t)b1 * 32);

        // (e) S + exp for row aa -> pending P (pa_/pb_ free: consumed in (b))
        #pragma unroll
        for (int q = 0; q < 2; q++) {
            f32x4 s0 = __builtin_amdgcn_mfma_f32_16x16x32_f16(kf0, qf[q], za_[q], 0, 0, 0);
            f32x4 s1 = __builtin_amdgcn_mfma_f32_16x16x32_f16(kf1, qf[q], zb_[q], 0, 0, 0);
            bool rv = (unsigned)(aa - si_[q]) <= 24u;
            float p[8];
            #pragma unroll
            for (int r = 0; r < 4; r++) { p[r] = EXP2(s0[r]); p[r + 4] = EXP2(s1[r]); }
            PkU u0, u1, u2, u3;
            u0.h = __builtin_amdgcn_cvt_pkrtz(p[0], p[1]);
            u1.h = __builtin_amdgcn_cvt_pkrtz(p[2], p[3]);
            u2.h = __builtin_amdgcn_cvt_pkrtz(p[4], p[5]);
            u3.h = __builtin_amdgcn_cvt_pkrtz(p[6], p[7]);
            pa_[q].u[0] = rv ? (u0.u & pm_[q][0]) : 0u;
            pa_[q].u[1] = rv ? (u1.u & pm_[q][1]) : 0u;
            pb_[q].u[0] = rv ? (u2.u & pm_[q][2]) : 0u;
            pb_[q].u[1] = rv ? (u3.u & pm_[q][3]) : 0u;
        }
    }

    // ---- epilogue PV: last row (aa0+13) ----
    #pragma unroll
    for (int q = 0; q < 2; q++) {
        O[q][0] = __builtin_amdgcn_mfma_f32_16x16x16f16(pa_[q].v, vfA0, O[q][0], 0, 0, 0);
        O[q][0] = __builtin_amdgcn_mfma_f32_16x16x16f16(pb_[q].v, vfB0, O[q][0], 0, 0, 0);
        O[q][1] = __builtin_amdgcn_mfma_f32_16x16x16f16(pa_[q].v, vfA1, O[q][1], 0, 0, 0);
        O[q][1] = __builtin_amdgcn_mfma_f32_16x16x16f16(pb_[q].v, vfB1, O[q][1], 0, 0, 0);
        lacc[q] = __builtin_amdgcn_mfma_f32_16x16x16f16(pa_[q].v, ones4, lacc[q], 0, 0, 0);
        lacc[q] = __builtin_amdgcn_mfma_f32_16x16x16f16(pb_[q].v, ones4, lacc[q], 0, 0, 0);
    }

    // ---- merge (per head-pair): kh=1 wave stores, kh=0 wave adds and finishes ----
    if (kh) {
        float* ob = &Olds[hs][lane][0];
        #pragma unroll
        for (int q = 0; q < 2; q++) {
            *(f32x4*)&ob[q * 12]     = O[q][0];
            *(f32x4*)&ob[q * 12 + 4] = O[q][1];
            *(f32x4*)&ob[q * 12 + 8] = lacc[q];
        }
    }
    __syncthreads();
    if (!kh) {
        const float* ob = &Olds[hs][lane][0];
        #pragma unroll
        for (int q = 0; q < 2; q++) {
            f32x4 o0 = O[q][0] + *(const f32x4*)&ob[q * 12];
            f32x4 o1 = O[q][1] + *(const f32x4*)&ob[q * 12 + 4];
            f32x4 la = lacc[q] + *(const f32x4*)&ob[q * 12 + 8];
            #pragma unroll
            for (int r = 0; r < 4; r++) {
                float li = 1.f / la[r];
                int ql = q * 16 + quad * 4 + r;
                int qi = i0 + (ql >> 3), qj = j0 + (ql & 7);
                size_t base = (size_t)(qi * PP + qj) * CC + h * HD;
                ao[base + nn]      = (f16)(o0[r] * li);
                ao[base + 16 + nn] = (f16)(o1[r] * li);
            }
        }
    }
}

extern "C" void kernel_launch(void* const* d_in, const int* in_sizes, int n_in,
                              void* d_out, int out_size, void* d_ws, size_t ws_size,
                              hipStream_t stream) {
    (void)in_sizes; (void)n_in; (void)out_size; (void)ws_size;
    const float* x    = (const float*)d_in[0];
    const float* cond = (const float*)d_in[1];
    const float* mask = (const float*)d_in[2];
    const float* lw   = (const float*)d_in[3];
    const float* lb   = (const float*)d_in[4];
    const float* qw   = (const float*)d_in[5];
    const float* qb   = (const float*)d_in[6];
    const float* rpb  = (const float*)d_in[7];
    const float* pw   = (const float*)d_in[8];
    const float* pb   = (const float*)d_in[9];
    float* outp       = (float*)d_out;

    float* ws   = (float*)d_ws;
    float* qbs  = ws;                 // 384
    float* b2s  = qbs + 384;          // 384
    float* rpbp = b2s + 384;          // 10240 padded
    f16* lwf  = (f16*)(rpbp + 10240);             // 128*160 fragment-packed
    f16* qwf  = lwf + 20480;                      // 384*128 fragment-packed
    f16* pwf  = qwf + 49152;                      // 128*128 fragment-packed
    f16* w2f  = pwf + 16384;                      // 384*128 fragment-packed
    f16* yh   = w2f + 49152;                      // NN*128 (unused in v13, kept for layout)
    f16* qh   = yh + (size_t)NN * 128;            // NN*128 Q
    f16* kh2  = qh + (size_t)NN * 128;            // 258 rows * 11264
    f16* vh2  = kh2 + (size_t)KVAARWS * KVROW;    // 258 rows * 11264
    f16* ao   = vh2 + (size_t)KVAARWS * KVROW;    // NN*128

    prep<<<228, 256, 0, stream>>>(lw, qw, pw, qb, pb, rpb, lwf, qwf, pwf, w2f, qbs, b2s, rpbp);
    fused_fusion_qkv<<<352, 256, 0, stream>>>(x, cond, mask, lwf, lb, qwf, qbs, qh, kh2, vh2);
    attn_mfma<<<dim3(TT / 4, PP / 8, HEADS / 2), 256, 0, stream>>>(qh, kh2, vh2, rpbp, ao);
    gemm_qkv<<<dim3(352, 6), 256, 0, stream>>>(ao, w2f, b2s, qh, kh2, vh2);   // fused proj+qkv
    attn_mfma<<<dim3(TT / 4, PP / 8, HEADS / 2), 256, 0, stream>>>(qh, kh2, vh2, rpbp, ao);
    gemm_out<<<dim3(352, 2), 256, 0, stream>>>(ao, pwf, pb, outp);
}

// Round 13
// 174.187 us; speedup vs baseline: 3.8607x; 1.0382x over previous
//
#include <hip/hip_runtime.h>
#include <hip/hip_fp16.h>

#define TT 256
#define PP 88
#define CC 128
#define NN (TT * PP)          // 22528 positions
#define HEADS 4
#define HD 32
#define WIN 25
#define RPBW 49
#define RPBSZ (RPBW * RPBW)   // 2401
#define SCALE 0.17677669529663687f   // 1/sqrt(32)
#define LOG2E 1.4426950408889634f
#define QSC (SCALE * LOG2E)          // fold exp->exp2 into Q path

// K layout: kh2[aa][h][j:88][ch32]   -> row stride (aa) = 11264, (aa,h) block = 2816
// V layout: vh2[aa][h][half:2][g:22][ch16][jr:4] -> same strides; dense 512B per attn load
#define KVROW 11264           // f16 elems per aa row (4 heads x 2816)
#define KVAARWS 258           // aa rows allocated (256 + prefetch/overshoot pad)

#if __has_builtin(__builtin_amdgcn_exp2f)
#define EXP2(x) __builtin_amdgcn_exp2f(x)
#else
#define EXP2(x) exp2f(x)
#endif

typedef _Float16 f16;
typedef f16 f16x8 __attribute__((ext_vector_type(8)));
typedef f16 f16x8u __attribute__((ext_vector_type(8), aligned(4)));
typedef f16 f16x4 __attribute__((ext_vector_type(4)));
typedef f16 f16x4u __attribute__((ext_vector_type(4), aligned(4)));
typedef float f32x4 __attribute__((ext_vector_type(4)));
typedef float f32x4u __attribute__((ext_vector_type(4), aligned(4)));
typedef __fp16 hf16x2 __attribute__((ext_vector_type(2)));
union PkU { hf16x2 h; unsigned u; };

// Fragment-packed W layout (for all MFMA af loads): output row i, col k:
//   group = (i>>6)*4 + ((i>>4)&3), ks = k>>5, lane = ((k&31)>>3)*16 + (i&15)
//   faddr = group*(KS*512) + ks*512 + lane*8 + (k&7)      [KS = #32-col blocks]
// Inverse (used by vectorized prep): i = (group>>2)*64 + (group&3)*16 + (lane&15),
//   k = ks*32 + (lane>>4)*8 + e, e=0..7  -> 8 consecutive k = 8 consecutive faddr.

// ---------- prep v13: VECTORIZED repack (dense uint4 stores) + b2s + MFMA wcomb ----------
__global__ __launch_bounds__(256) void prep(
    const float* __restrict__ lw, const float* __restrict__ qw,
    const float* __restrict__ pw, const float* __restrict__ qb,
    const float* __restrict__ pb, const float* __restrict__ rpb,
    f16* __restrict__ lwf, f16* __restrict__ qwf, f16* __restrict__ pwf,
    f16* __restrict__ w2f, float* __restrict__ qbs, float* __restrict__ b2s,
    float* __restrict__ rpbp)
{
    const int b = blockIdx.x;
    if (b < 192) {
        int idx = b * 256 + threadIdx.x;              // [0, 49152)
        if (idx < 6144) {                             // qwf: 24 groups x 4 ks x 64 lanes
            int group = idx >> 8, ks = (idx >> 6) & 3, lane = idx & 63;
            int i = (group >> 2) * 64 + (group & 3) * 16 + (lane & 15);
            int k0 = ks * 32 + (lane >> 4) * 8;
            float sc = (i < 128) ? QSC : 1.f;
            union { f16 e[8]; uint4 u; } t;
            #pragma unroll
            for (int e = 0; e < 8; e++) t.e[e] = (f16)(qw[i * 128 + k0 + e] * sc);
            *(uint4*)&qwf[group * 2048 + ks * 512 + lane * 8] = t.u;
        } else if (idx < 8704) {                      // lwf: 8 groups x 5 ks x 64 lanes
            int j = idx - 6144;
            int group = j / 320; int r2 = j - group * 320; int ks = r2 >> 6, lane = r2 & 63;
            if (group < 8) {
                int r = (group >> 2) * 64 + (group & 3) * 16 + (lane & 15);
                int c0 = ks * 32 + (lane >> 4) * 8;
                union { f16 e[8]; uint4 u; } t;
                #pragma unroll
                for (int e = 0; e < 8; e++) {
                    int c = c0 + e;
                    t.e[e] = (f16)((c < 131) ? lw[r * 131 + c] : 0.f);
                }
                *(uint4*)&lwf[group * 2560 + ks * 512 + lane * 8] = t.u;
            }
        } else if (idx < 10752) {                     // pwf: 8 groups x 4 ks x 64 lanes
            int j = idx - 8704;
            int group = j >> 8, ks = (j >> 6) & 3, lane = j & 63;
            int i = (group >> 2) * 64 + (group & 3) * 16 + (lane & 15);
            int k0 = ks * 32 + (lane >> 4) * 8;
            union { f16 e[8]; uint4 u; } t;
            #pragma unroll
            for (int e = 0; e < 8; e++) t.e[e] = (f16)pw[i * 128 + k0 + e];
            *(uint4*)&pwf[group * 2048 + ks * 512 + lane * 8] = t.u;
        } else if (idx < 20992) {                     // rpbp: 10240 dense f32
            int j = idx - 10752;
            rpbp[j] = (j < 4 * RPBSZ) ? rpb[j] * LOG2E : 0.f;
        } else if (idx < 21376) {                     // qbs: 384
            int j = idx - 20992;
            qbs[j] = qb[j] * (j < 128 ? QSC : 1.f);
        }
    } else if (b < 216) {
        // b2s[i] = (qb[i] + qw[i,:]·pb) * sc_i ; 16 lanes per output, shuffle-reduce
        int t = (b - 192) * 256 + threadIdx.x;        // [0, 6144)
        int i = t >> 4, l = t & 15;
        if (i < 384) {
            float s = 0.f;
            #pragma unroll
            for (int j = l * 8; j < l * 8 + 8; j++) s += qw[i * 128 + j] * pb[j];
            s += __shfl_xor(s, 1); s += __shfl_xor(s, 2);
            s += __shfl_xor(s, 4); s += __shfl_xor(s, 8);
            if (l == 0) b2s[i] = (qb[i] + s) * (i < 128 ? QSC : 1.f);
        }
    } else {
        // w2f[i][k] = sc_i * sum_j qw[i][j] pw[j][k]  (fragment-packed output)
        const int bw = b - 216;                       // 0..11
        const int m0 = (bw & 1) * 64;                 // k-tile
        const int n0 = (bw >> 1) * 64;                // i-tile
        const int tid = threadIdx.x;
        const int w = tid >> 6, lane = tid & 63, quad = lane >> 4, nn = lane & 15;
        const int krow = m0 + w * 16 + nn;
        f16x8 af[4];
        #pragma unroll
        for (int ks = 0; ks < 4; ks++) {
            union { f16 e[8]; f16x8 v; } t;
            #pragma unroll
            for (int e = 0; e < 8; e++)
                t.e[e] = (f16)pw[(ks * 32 + quad * 8 + e) * 128 + krow];
            af[ks] = t.v;
        }
        f32x4 acc[4] = {};
        #pragma unroll
        for (int nt = 0; nt < 4; nt++) {
            int irow = n0 + nt * 16 + nn;
            #pragma unroll
            for (int ks = 0; ks < 4; ks++) {
                const float* qr = &qw[(size_t)irow * 128 + ks * 32 + quad * 8];
                float4 a = *(const float4*)qr, bq = *(const float4*)(qr + 4);
                PkU u0, u1, u2, u3;
                u0.h = __builtin_amdgcn_cvt_pkrtz(a.x, a.y);
                u1.h = __builtin_amdgcn_cvt_pkrtz(a.z, a.w);
                u2.h = __builtin_amdgcn_cvt_pkrtz(bq.x, bq.y);
                u3.h = __builtin_amdgcn_cvt_pkrtz(bq.z, bq.w);
                union { unsigned u[4]; f16x8 v; } bb;
                bb.u[0] = u0.u; bb.u[1] = u1.u; bb.u[2] = u2.u; bb.u[3] = u3.u;
                acc[nt] = __builtin_amdgcn_mfma_f32_16x16x32_f16(af[ks], bb.v, acc[nt], 0, 0, 0);
            }
        }
        #pragma unroll
        for (int nt = 0; nt < 4; nt++) {
            int i = n0 + nt * 16 + nn;
            int k = m0 + w * 16 + quad * 4;           // 4 consecutive cols, k&7 in {0,4}
            float sc = (i < 128) ? QSC : 1.f;
            PkU p0, p1;
            p0.h = __builtin_amdgcn_cvt_pkrtz(acc[nt][0] * sc, acc[nt][1] * sc);
            p1.h = __builtin_amdgcn_cvt_pkrtz(acc[nt][2] * sc, acc[nt][3] * sc);
            int lane2 = (((k & 31) >> 3) << 4) + (i & 15);
            int faddr = (((i >> 6) << 2) + ((i >> 4) & 3)) * 2048 + (k >> 5) * 512 + lane2 * 8 + (k & 7);
            *(uint2*)&w2f[faddr] = make_uint2(p0.u, p1.u);
        }
    }
}

// ---------- fused fusion+qkv v13 (unchanged): Y in LDS, no yh round-trip; grid (352) ----------
__global__ __launch_bounds__(256) void fused_fusion_qkv(
    const float* __restrict__ x, const float* __restrict__ cond, const float* __restrict__ mask,
    const f16* __restrict__ lwf, const float* __restrict__ lb,
    const f16* __restrict__ qwf, const float* __restrict__ bias,
    f16* __restrict__ qh, f16* __restrict__ kh2, f16* __restrict__ vh2)
{
    __shared__ __align__(16) f16 Alds[64 * 168];
    __shared__ __align__(16) f16 Ylds[64 * 136];
    __shared__ __align__(16) f16 Rlds[64][72];
    const int m0 = blockIdx.x * 64;
    const int tid = threadIdx.x;
    const int w = tid >> 6, lane = tid & 63, quad = lane >> 4, nn = lane & 15;

    {   // ---- phase 1: stage cat rows (f16) ----
        int r = tid >> 2, cpart = tid & 3;
        size_t pos = m0 + r;
        *(uint4*)&Alds[r * 168 + 128 + cpart * 8] = make_uint4(0, 0, 0, 0);
        const float* xr = x + pos * 128 + cpart * 32;
        #pragma unroll
        for (int t = 0; t < 4; t++) {
            float4 a = *(const float4*)(xr + t * 8);
            float4 b = *(const float4*)(xr + t * 8 + 4);
            PkU p0, p1, p2, p3;
            p0.h = __builtin_amdgcn_cvt_pkrtz(a.x, a.y);
            p1.h = __builtin_amdgcn_cvt_pkrtz(a.z, a.w);
            p2.h = __builtin_amdgcn_cvt_pkrtz(b.x, b.y);
            p3.h = __builtin_amdgcn_cvt_pkrtz(b.z, b.w);
            *(uint4*)&Alds[r * 168 + cpart * 32 + t * 8] = make_uint4(p0.u, p1.u, p2.u, p3.u);
        }
        if (cpart == 0) {
            Alds[r * 168 + 128] = (f16)cond[pos * 2];
            Alds[r * 168 + 129] = (f16)cond[pos * 2 + 1];
            Alds[r * 168 + 130] = (f16)mask[pos];
        }
    }
    __syncthreads();

    // ---- phase 2: Y = relu(cat @ lwf^T + lb) -> Ylds ----
    #pragma unroll
    for (int gi = 0; gi < 2; gi++) {
        const int g = gi * 4 + w;                     // chan group
        const int cb = gi * 64 + w * 16;              // chan base
        const f16* wfb = lwf + (size_t)g * 2560 + lane * 8;
        f16x8 af[5];
        #pragma unroll
        for (int ks = 0; ks < 5; ks++)
            af[ks] = *(const f16x8*)(wfb + ks * 512);
        f32x4 acc[4] = {};
        #pragma unroll
        for (int ks = 0; ks < 5; ks++)
            #pragma unroll
            for (int nt = 0; nt < 4; nt++) {
                f16x8 bf = *(const f16x8*)&Alds[(nt * 16 + nn) * 168 + ks * 32 + quad * 8];
                acc[nt] = __builtin_amdgcn_mfma_f32_16x16x32_f16(af[ks], bf, acc[nt], 0, 0, 0);
            }
        float bv[4];
        #pragma unroll
        for (int r = 0; r < 4; r++) bv[r] = lb[cb + quad * 4 + r];
        #pragma unroll
        for (int nt = 0; nt < 4; nt++) {
            PkU p0, p1;
            p0.h = __builtin_amdgcn_cvt_pkrtz(fmaxf(acc[nt][0] + bv[0], 0.f), fmaxf(acc[nt][1] + bv[1], 0.f));
            p1.h = __builtin_amdgcn_cvt_pkrtz(fmaxf(acc[nt][2] + bv[2], 0.f), fmaxf(acc[nt][3] + bv[3], 0.f));
            *(uint2*)&Ylds[(nt * 16 + nn) * 136 + cb + quad * 4] = make_uint2(p0.u, p1.u);
        }
    }
    __syncthreads();

    // ---- phase 3: six 64-chan qkv tiles from Ylds ----
    #pragma unroll 1
    for (int t = 0; t < 6; t++) {
        const int n0 = t * 64;
        const f16* wfb = qwf + ((size_t)t * 4 + w) * 2048 + lane * 8;
        f16x8 af[4];
        #pragma unroll
        for (int ks = 0; ks < 4; ks++)
            af[ks] = *(const f16x8*)(wfb + ks * 512);
        f32x4 acc[4] = {};
        #pragma unroll
        for (int ks = 0; ks < 4; ks++)
            #pragma unroll
            for (int nt = 0; nt < 4; nt++) {
                f16x8 bf = *(const f16x8*)&Ylds[(nt * 16 + nn) * 136 + ks * 32 + quad * 8];
                acc[nt] = __builtin_amdgcn_mfma_f32_16x16x32_f16(af[ks], bf, acc[nt], 0, 0, 0);
            }
        float bv[4];
        #pragma unroll
        for (int r = 0; r < 4; r++) bv[r] = bias[n0 + w * 16 + quad * 4 + r];

        __syncthreads();                              // Rlds reuse guard
        if (n0 < 256) {   // Q/K: RTZ pack
            #pragma unroll
            for (int nt = 0; nt < 4; nt++) {
                PkU p0, p1;
                p0.h = __builtin_amdgcn_cvt_pkrtz(acc[nt][0] + bv[0], acc[nt][1] + bv[1]);
                p1.h = __builtin_amdgcn_cvt_pkrtz(acc[nt][2] + bv[2], acc[nt][3] + bv[3]);
                *(uint2*)&Rlds[nt * 16 + nn][w * 16 + quad * 4] = make_uint2(p0.u, p1.u);
            }
        } else {          // V: RNE casts
            #pragma unroll
            for (int nt = 0; nt < 4; nt++) {
                union { f16 e[4]; uint2 u; } tt;
                #pragma unroll
                for (int r = 0; r < 4; r++) tt.e[r] = (f16)(acc[nt][r] + bv[r]);
                *(uint2*)&Rlds[nt * 16 + nn][w * 16 + quad * 4] = tt.u;
            }
        }
        __syncthreads();

        if (n0 < 128) {                               // ---- Q: qh[pos][128]
            #pragma unroll
            for (int it = 0; it < 2; it++) {
                int idx = it * 256 + tid;
                int pl = idx >> 3, oct = idx & 7;
                *(uint4*)&qh[(size_t)(m0 + pl) * 128 + n0 + oct * 8] = *(uint4*)&Rlds[pl][oct * 8];
            }
        } else if (n0 < 256) {                        // ---- K: kh2[aa][h][j][ch32]
            #pragma unroll
            for (int it = 0; it < 2; it++) {
                int idx = it * 256 + tid;
                int pl = idx >> 3, oct = idx & 7;
                f16x8 v = *(const f16x8*)&Rlds[pl][oct * 8];
                int pos = m0 + pl, aa = pos / 88, j = pos - aa * 88;
                int ch = n0 - 128 + oct * 8;
                int h = ch >> 5, c32 = ch & 31;
                *(uint4*)&kh2[((size_t)(aa * 4 + h) * 88 + j) * 32 + c32] = *(uint4*)&v;
            }
        } else {                                      // ---- V: vh2[aa][h][half][g][ch16][jr]
            #pragma unroll
            for (int it = 0; it < 2; it++) {
                int idx = it * 256 + tid;
                int pq = idx >> 5, cp = idx & 31;
                union { f16 e[8]; uint4 u; } tt;
                #pragma unroll
                for (int cc = 0; cc < 2; cc++)
                    #pragma unroll
                    for (int jj = 0; jj < 4; jj++)
                        tt.e[cc * 4 + jj] = Rlds[pq * 4 + jj][cp * 2 + cc];
                int pos = m0 + pq * 4, aa = pos / 88, j = pos - aa * 88;
                int ch = n0 - 256 + cp * 2;
                int h = ch >> 5, c = ch & 31, half = c >> 4, c16 = c & 15;
                *(uint4*)&vh2[(size_t)(aa * 4 + h) * 2816 + half * 1408 + (j >> 2) * 64 + c16 * 4] = tt.u;
            }
        }
    }
}

// ---------- qkv GEMM (standalone, for ao input): frag-packed W + LDS-staged stores ----------
__global__ __launch_bounds__(256) void gemm_qkv(
    const f16* __restrict__ A, const f16* __restrict__ Wf, const float* __restrict__ bias,
    f16* __restrict__ qh, f16* __restrict__ kh2, f16* __restrict__ vh2)
{
    __shared__ __align__(16) f16 Alds[64 * 136];
    __shared__ __align__(16) f16 Rlds[64][72];
    const int m0 = blockIdx.x * 64, n0 = blockIdx.y * 64;
    const int tid = threadIdx.x;
    const int w = tid >> 6, lane = tid & 63, quad = lane >> 4, nn = lane & 15;

    for (int i = tid; i < 1024; i += 256) {
        int r = i >> 4, c = i & 15;
        *(uint4*)&Alds[r * 136 + c * 8] = *(const uint4*)&A[(size_t)(m0 + r) * 128 + c * 8];
    }
    __syncthreads();

    const f16* wfb = Wf + ((size_t)(n0 >> 6) * 4 + w) * 2048 + lane * 8;
    f16x8 af[4];
    #pragma unroll
    for (int ks = 0; ks < 4; ks++)
        af[ks] = *(const f16x8*)(wfb + ks * 512);
    f32x4 acc[4] = {};
    #pragma unroll
    for (int ks = 0; ks < 4; ks++)
        #pragma unroll
        for (int nt = 0; nt < 4; nt++) {
            f16x8 bf = *(const f16x8*)&Alds[(nt * 16 + nn) * 136 + ks * 32 + quad * 8];
            acc[nt] = __builtin_amdgcn_mfma_f32_16x16x32_f16(af[ks], bf, acc[nt], 0, 0, 0);
        }
    float bv[4];
    #pragma unroll
    for (int r = 0; r < 4; r++) bv[r] = bias[n0 + w * 16 + quad * 4 + r];

    if (n0 < 256) {   // Q/K: RTZ pack
        #pragma unroll
        for (int nt = 0; nt < 4; nt++) {
            PkU p0, p1;
            p0.h = __builtin_amdgcn_cvt_pkrtz(acc[nt][0] + bv[0], acc[nt][1] + bv[1]);
            p1.h = __builtin_amdgcn_cvt_pkrtz(acc[nt][2] + bv[2], acc[nt][3] + bv[3]);
            *(uint2*)&Rlds[nt * 16 + nn][w * 16 + quad * 4] = make_uint2(p0.u, p1.u);
        }
    } else {          // V: RNE casts
        #pragma unroll
        for (int nt = 0; nt < 4; nt++) {
            union { f16 e[4]; uint2 u; } t;
            #pragma unroll
            for (int r = 0; r < 4; r++) t.e[r] = (f16)(acc[nt][r] + bv[r]);
            *(uint2*)&Rlds[nt * 16 + nn][w * 16 + quad * 4] = t.u;
        }
    }
    __syncthreads();

    if (n0 < 128) {                                   // ---- Q: qh[pos][128]
        #pragma unroll
        for (int it = 0; it < 2; it++) {
            int idx = it * 256 + tid;
            int pl = idx >> 3, oct = idx & 7;
            f16x8 v = *(const f16x8*)&Rlds[pl][oct * 8];
            *(uint4*)&qh[(size_t)(m0 + pl) * 128 + n0 + oct * 8] = *(uint4*)&v;
        }
    } else if (n0 < 256) {                            // ---- K: kh2[aa][h][j][ch32]
        #pragma unroll
        for (int it = 0; it < 2; it++) {
            int idx = it * 256 + tid;
            int pl = idx >> 3, oct = idx & 7;
            f16x8 v = *(const f16x8*)&Rlds[pl][oct * 8];
            int pos = m0 + pl, aa = pos / 88, j = pos - aa * 88;
            int ch = n0 - 128 + oct * 8;
            int h = ch >> 5, c32 = ch & 31;
            *(uint4*)&kh2[((size_t)(aa * 4 + h) * 88 + j) * 32 + c32] = *(uint4*)&v;
        }
    } else {                                          // ---- V: vh2[aa][h][half][g][ch16][jr]
        #pragma unroll
        for (int it = 0; it < 2; it++) {
            int idx = it * 256 + tid;
            int pq = idx >> 5, cp = idx & 31;
            union { f16 e[8]; uint4 u; } t;
            #pragma unroll
            for (int cc = 0; cc < 2; cc++)
                #pragma unroll
                for (int jj = 0; jj < 4; jj++)
                    t.e[cc * 4 + jj] = Rlds[pq * 4 + jj][cp * 2 + cc];
            int pos = m0 + pq * 4, aa = pos / 88, j = pos - aa * 88;
            int ch = n0 - 256 + cp * 2;
            int h = ch >> 5, c = ch & 31, half = c >> 4, c16 = c & 15;
            *(uint4*)&vh2[(size_t)(aa * 4 + h) * 2816 + half * 1408 + (j >> 2) * 64 + c16 * 4] = t.u;
        }
    }
}

// ---------- final projection: frag-packed W + LDS-staged dense f32 stores ----------
__global__ __launch_bounds__(256) void gemm_out(
    const f16* __restrict__ A, const f16* __restrict__ Wf, const float* __restrict__ bias,
    float* __restrict__ outp)
{
    __shared__ __align__(16) f16 Alds[64 * 136];
    __shared__ __align__(16) float Rldsf[64][68];
    const int m0 = blockIdx.x * 64, n0 = blockIdx.y * 64;
    const int tid = threadIdx.x;
    const int w = tid >> 6, lane = tid & 63, quad = lane >> 4, nn = lane & 15;

    for (int i = tid; i < 1024; i += 256) {
        int r = i >> 4, c = i & 15;
        *(uint4*)&Alds[r * 136 + c * 8] = *(const uint4*)&A[(size_t)(m0 + r) * 128 + c * 8];
    }
    __syncthreads();

    const f16* wfb = Wf + ((size_t)(n0 >> 6) * 4 + w) * 2048 + lane * 8;
    f16x8 af[4];
    #pragma unroll
    for (int ks = 0; ks < 4; ks++)
        af[ks] = *(const f16x8*)(wfb + ks * 512);
    f32x4 acc[4] = {};
    #pragma unroll
    for (int ks = 0; ks < 4; ks++)
        #pragma unroll
        for (int nt = 0; nt < 4; nt++) {
            f16x8 bf = *(const f16x8*)&Alds[(nt * 16 + nn) * 136 + ks * 32 + quad * 8];
            acc[nt] = __builtin_amdgcn_mfma_f32_16x16x32_f16(af[ks], bf, acc[nt], 0, 0, 0);
        }
    float bv[4];
    #pragma unroll
    for (int r = 0; r < 4; r++) bv[r] = bias[n0 + w * 16 + quad * 4 + r];
    #pragma unroll
    for (int nt = 0; nt < 4; nt++) {
        f32x4 vv;
        #pragma unroll
        for (int r = 0; r < 4; r++) vv[r] = acc[nt][r] + bv[r];
        *(f32x4*)&Rldsf[nt * 16 + nn][w * 16 + quad * 4] = vv;
    }
    __syncthreads();
    #pragma unroll
    for (int it = 0; it < 4; it++) {
        int idx = it * 256 + tid;
        int pl = idx >> 4, part = idx & 15;
        *(f32x4*)&outp[(size_t)(m0 + pl) * 128 + n0 + part * 4] = *(const f32x4*)&Rldsf[pl][part * 4];
    }
}

// ---------- MFMA neighborhood attention v14: rpb staged in LDS ----------
// v12 structure (2 heads/block, 4 waves, register PV, coalesced kh2/vh2, full
// unroll, setprio). Change: the per-head rpb slice (32 rows x 49 f32, +8-float
// guard for the verified worst-case -3 col index at j-edge tiles) is staged in
// LDS once per block; the 4 in-loop za/zb reads (previously ~10-16-segment
// VMEM gathers, the last non-dense access in the hot loop) become LDS reads
// with identical index arithmetic (+49/iter pointer bump). Staged garbage rows
// (clamped/overshoot sources) are exactly the rows already masked by rv/pm ->
// numerics bit-identical.
__global__ __launch_bounds__(256, 3) void attn_mfma(
    const f16* __restrict__ qh,    // [N][128] Q, pre-scaled by QSC
    const f16* __restrict__ kh2,   // [aa][h][j][ch32]
    const f16* __restrict__ vh2,   // [aa][h][half][g][ch16][jr]
    const float* __restrict__ rpbp,
    f16* __restrict__ ao)          // [N][128]
{
    const int bx = ((blockIdx.x & 7) << 3) + (blockIdx.x >> 3);   // XCD-contiguous i-tiles
    const int i0 = bx * 4;
    const int j0 = blockIdx.y * 8;
    const int tid = threadIdx.x;
    const int w = tid >> 6, lane = tid & 63;
    const int quad = lane >> 4, nn = lane & 15;
    const int kh = w & 1;                  // key-row half within head-group
    const int hs = w >> 1;                 // head-sub within block
    const int h  = blockIdx.z * 2 + hs;

    const int ri0 = min(max(i0 - 12, 0), TT - 28);         // 28-row key span
    const int rj0 = min(max(j0 - 12, 0), PP - WIN) & ~3;   // 4-aligned for vh2

    __shared__ __align__(16) float Olds[2][64][28];   // [head-sub] kh=1 partials
    __shared__ __align__(16) float RpbL[2][1576];     // 8 guard + 32 rows x 49 cols

    // ---- stage rpb slices for both heads (rows rowbase..rowbase+31) ----
    const int rowbase = ri0 - i0 + 21;                // = min needed row (aa_min - qi_max + 24)
    {
        const int sb = rowbase * RPBW;
        #pragma unroll
        for (int hh = 0; hh < 2; hh++) {
            const int hg = blockIdx.z * 2 + hh;
            for (int idx = tid; idx < 1568; idx += 256) {
                int s = hg * RPBSZ + sb + idx;
                s = min(max(s, 0), 10239);            // clamped rows are masked in-loop
                RpbL[hh][8 + idx] = rpbp[s];
            }
        }
    }

    int si_[2];
    unsigned pm_[2][4];            // packed-f16 column masks per output word
    f16x8 qf[2];
    const float* rpq[2];
    const int aa0 = ri0 + kh * 14; // this wave's first key row (14 rows/wave)

    #pragma unroll
    for (int q = 0; q < 2; q++) {
        int ql = q * 16 + nn;
        int qi = i0 + (ql >> 3), qj = j0 + (ql & 7);
        int si = min(max(qi - 12, 0), TT - WIN);
        int sj = min(max(qj - 12, 0), PP - WIN);
        si_[q] = si;
        unsigned cm = 0x1FFFFFFu << (sj - rj0);       // shift <= 7
        #pragma unroll
        for (int t = 0; t < 4; t++) {
            int k0 = (t >> 1) * 16 + quad * 4 + (t & 1) * 2;
            pm_[q][t] = (((cm >> k0) & 1u) ? 0xFFFFu : 0u)
                      | (((cm >> (k0 + 1)) & 1u) ? 0xFFFF0000u : 0u);
        }
        qf[q] = *(const f16x8*)&qh[(size_t)(qi * PP + qj) * 128 + h * HD + quad * 8];
        // LDS pointer: lrow0 = (aa0 - qi + 24) - rowbase in [0,17]; col >= -3 absorbed by +8 guard
        rpq[q] = &RpbL[hs][8 + ((aa0 - qi + 24) - rowbase) * RPBW + (rj0 - qj + 24) + quad * 4];
    }

    const int b0 = min(rj0 + nn, PP - 1);
    const int b1 = min(rj0 + 16 + nn, PP - 1);
    const f16x4 ones4 = {(f16)1.f, (f16)1.f, (f16)1.f, (f16)1.f};

    // dense per-lane base pointers (advance by KVROW per key row)
    const f16* kb = kh2 + (size_t)(aa0 * 4 + h) * 2816 + quad * 8;
    const f16* vb = vh2 + (size_t)(aa0 * 4 + h) * 2816 + ((rj0 >> 2) + quad) * 64 + nn * 4;

    f32x4 O[2][2] = {};            // [qset][ch-half]; regs = queries, lane nn = channel
    f32x4 lacc[2] = {};
    union PB { unsigned u[2]; f16x4 v; };
    PB pa_[2], pb_[2];             // pending P (row aa-1), masked, packed
    f32x4 za_[2], zb_[2];          // rpb C-init for current row

    __syncthreads();               // rpb staging visible to all waves

    // ---- prologue: row aa0 -> S/exp only (its PV runs in iter c=1) ----
    int aa = aa0;
    f16x8 kf0 = *(const f16x8*)(kb + (size_t)b0 * 32);
    f16x8 kf1 = *(const f16x8*)(kb + (size_t)b1 * 32);
    f16x4 vfA0 = *(const f16x4u*)vb;                  // keys  0-15, ch lo
    f16x4 vfB0 = *(const f16x4u*)(vb + 256);          // keys 16-31, ch lo
    f16x4 vfA1 = *(const f16x4u*)(vb + 1408);         // keys  0-15, ch hi
    f16x4 vfB1 = *(const f16x4u*)(vb + 1664);         // keys 16-31, ch hi
    #pragma unroll
    for (int q = 0; q < 2; q++) {
        za_[q] = *(const f32x4u*)rpq[q];
        zb_[q] = *(const f32x4u*)(rpq[q] + 16);
        rpq[q] += RPBW;
    }
    #pragma unroll
    for (int q = 0; q < 2; q++) {
        f32x4 s0 = __builtin_amdgcn_mfma_f32_16x16x32_f16(kf0, qf[q], za_[q], 0, 0, 0);
        f32x4 s1 = __builtin_amdgcn_mfma_f32_16x16x32_f16(kf1, qf[q], zb_[q], 0, 0, 0);
        bool rv = (unsigned)(aa - si_[q]) <= 24u;
        float p[8];
        #pragma unroll
        for (int r = 0; r < 4; r++) { p[r] = EXP2(s0[r]); p[r + 4] = EXP2(s1[r]); }
        PkU u0, u1, u2, u3;
        u0.h = __builtin_amdgcn_cvt_pkrtz(p[0], p[1]);
        u1.h = __builtin_amdgcn_cvt_pkrtz(p[2], p[3]);
        u2.h = __builtin_amdgcn_cvt_pkrtz(p[4], p[5]);
        u3.h = __builtin_amdgcn_cvt_pkrtz(p[6], p[7]);
        pa_[q].u[0] = rv ? (u0.u & pm_[q][0]) : 0u;
        pa_[q].u[1] = rv ? (u1.u & pm_[q][1]) : 0u;
        pb_[q].u[0] = rv ? (u2.u & pm_[q][2]) : 0u;
        pb_[q].u[1] = rv ? (u3.u & pm_[q][3]) : 0u;
    }
    // prefetch K for row aa0+1
    kb += KVROW;
    f16x8 nkf0 = *(const f16x8*)(kb + (size_t)b0 * 32);
    f16x8 nkf1 = *(const f16x8*)(kb + (size_t)b1 * 32);

    // ---- fully-unrolled pipelined loop: rows aa0+1 .. aa0+13 ----
    #pragma unroll
    for (int c = 1; c < 14; ++c) {
        aa = aa0 + c;
        kf0 = nkf0; kf1 = nkf1;                       // K(aa), prefetched last iter

        // (a) issue rpb LDS reads for row aa
        #pragma unroll
        for (int q = 0; q < 2; q++) {
            za_[q] = *(const f32x4u*)rpq[q];
            zb_[q] = *(const f32x4u*)(rpq[q] + 16);
            rpq[q] += RPBW;
        }

        // (b) PV for row aa-1 (pure-MFMA cluster; setprio keeps the pipe fed)
        __builtin_amdgcn_s_setprio(1);
        #pragma unroll
        for (int q = 0; q < 2; q++) {
            O[q][0] = __builtin_amdgcn_mfma_f32_16x16x16f16(pa_[q].v, vfA0, O[q][0], 0, 0, 0);
            O[q][0] = __builtin_amdgcn_mfma_f32_16x16x16f16(pb_[q].v, vfB0, O[q][0], 0, 0, 0);
            O[q][1] = __builtin_amdgcn_mfma_f32_16x16x16f16(pa_[q].v, vfA1, O[q][1], 0, 0, 0);
            O[q][1] = __builtin_amdgcn_mfma_f32_16x16x16f16(pb_[q].v, vfB1, O[q][1], 0, 0, 0);
            lacc[q] = __builtin_amdgcn_mfma_f32_16x16x16f16(pa_[q].v, ones4, lacc[q], 0, 0, 0);
            lacc[q] = __builtin_amdgcn_mfma_f32_16x16x16f16(pb_[q].v, ones4, lacc[q], 0, 0, 0);
        }
        __builtin_amdgcn_s_setprio(0);

        // (c) issue V loads for row aa (consumed by next iter's PV) - dense 512B each
        vb += KVROW;
        vfA0 = *(const f16x4u*)vb;
        vfB0 = *(const f16x4u*)(vb + 256);
        vfA1 = *(const f16x4u*)(vb + 1408);
        vfB1 = *(const f16x4u*)(vb + 1664);

        // (d) issue K prefetch for row aa+1 (last iter reads padded row: unused)
        kb += KVROW;
        nkf0 = *(const f16x8*)(kb + (size_t)b0 * 32);
        nkf1 = *(const f16x8*)(kb + (size_t)b1 * 32);

        // (e) S + exp for row aa -> pending P (pa_/pb_ free: consumed in (b))
        #pragma unroll
        for (int q = 0; q < 2; q++) {
            f32x4 s0 = __builtin_amdgcn_mfma_f32_16x16x32_f16(kf0, qf[q], za_[q], 0, 0, 0);
            f32x4 s1 = __builtin_amdgcn_mfma_f32_16x16x32_f16(kf1, qf[q], zb_[q], 0, 0, 0);
            bool rv = (unsigned)(aa - si_[q]) <= 24u;
            float p[8];
            #pragma unroll
            for (int r = 0; r < 4; r++) { p[r] = EXP2(s0[r]); p[r + 4] = EXP2(s1[r]); }
            PkU u0, u1, u2, u3;
            u0.h = __builtin_amdgcn_cvt_pkrtz(p[0], p[1]);
            u1.h = __builtin_amdgcn_cvt_pkrtz(p[2], p[3]);
            u2.h = __builtin_amdgcn_cvt_pkrtz(p[4], p[5]);
            u3.h = __builtin_amdgcn_cvt_pkrtz(p[6], p[7]);
            pa_[q].u[0] = rv ? (u0.u & pm_[q][0]) : 0u;
            pa_[q].u[1] = rv ? (u1.u & pm_[q][1]) : 0u;
            pb_[q].u[0] = rv ? (u2.u & pm_[q][2]) : 0u;
            pb_[q].u[1] = rv ? (u3.u & pm_[q][3]) : 0u;
        }
    }

    // ---- epilogue PV: last row (aa0+13) ----
    #pragma unroll
    for (int q = 0; q < 2; q++) {
        O[q][0] = __builtin_amdgcn_mfma_f32_16x16x16f16(pa_[q].v, vfA0, O[q][0], 0, 0, 0);
        O[q][0] = __builtin_amdgcn_mfma_f32_16x16x16f16(pb_[q].v, vfB0, O[q][0], 0, 0, 0);
        O[q][1] = __builtin_amdgcn_mfma_f32_16x16x16f16(pa_[q].v, vfA1, O[q][1], 0, 0, 0);
        O[q][1] = __builtin_amdgcn_mfma_f32_16x16x16f16(pb_[q].v, vfB1, O[q][1], 0, 0, 0);
        lacc[q] = __builtin_amdgcn_mfma_f32_16x16x16f16(pa_[q].v, ones4, lacc[q], 0, 0, 0);
        lacc[q] = __builtin_amdgcn_mfma_f32_16x16x16f16(pb_[q].v, ones4, lacc[q], 0, 0, 0);
    }

    // ---- merge (per head-pair): kh=1 wave stores, kh=0 wave adds and finishes ----
    if (kh) {
        float* ob = &Olds[hs][lane][0];
        #pragma unroll
        for (int q = 0; q < 2; q++) {
            *(f32x4*)&ob[q * 12]     = O[q][0];
            *(f32x4*)&ob[q * 12 + 4] = O[q][1];
            *(f32x4*)&ob[q * 12 + 8] = lacc[q];
        }
    }
    __syncthreads();
    if (!kh) {
        const float* ob = &Olds[hs][lane][0];
        #pragma unroll
        for (int q = 0; q < 2; q++) {
            f32x4 o0 = O[q][0] + *(const f32x4*)&ob[q * 12];
            f32x4 o1 = O[q][1] + *(const f32x4*)&ob[q * 12 + 4];
            f32x4 la = lacc[q] + *(const f32x4*)&ob[q * 12 + 8];
            #pragma unroll
            for (int r = 0; r < 4; r++) {
                float li = 1.f / la[r];
                int ql = q * 16 + quad * 4 + r;
                int qi = i0 + (ql >> 3), qj = j0 + (ql & 7);
                size_t base = (size_t)(qi * PP + qj) * CC + h * HD;
                ao[base + nn]      = (f16)(o0[r] * li);
                ao[base + 16 + nn] = (f16)(o1[r] * li);
            }
        }
    }
}

extern "C" void kernel_launch(void* const* d_in, const int* in_sizes, int n_in,
                              void* d_out, int out_size, void* d_ws, size_t ws_size,
                              hipStream_t stream) {
    (void)in_sizes; (void)n_in; (void)out_size; (void)ws_size;
    const float* x    = (const float*)d_in[0];
    const float* cond = (const float*)d_in[1];
    const float* mask = (const float*)d_in[2];
    const float* lw   = (const float*)d_in[3];
    const float* lb   = (const float*)d_in[4];
    const float* qw   = (const float*)d_in[5];
    const float* qb   = (const float*)d_in[6];
    const float* rpb  = (const float*)d_in[7];
    const float* pw   = (const float*)d_in[8];
    const float* pb   = (const float*)d_in[9];
    float* outp       = (float*)d_out;

    float* ws   = (float*)d_ws;
    float* qbs  = ws;                 // 384
    float* b2s  = qbs + 384;          // 384
    float* rpbp = b2s + 384;          // 10240 padded
    f16* lwf  = (f16*)(rpbp + 10240);             // 128*160 fragment-packed
    f16* qwf  = lwf + 20480;                      // 384*128 fragment-packed
    f16* pwf  = qwf + 49152;                      // 128*128 fragment-packed
    f16* w2f  = pwf + 16384;                      // 384*128 fragment-packed
    f16* yh   = w2f + 49152;                      // NN*128 (unused, kept for layout)
    f16* qh   = yh + (size_t)NN * 128;            // NN*128 Q
    f16* kh2  = qh + (size_t)NN * 128;            // 258 rows * 11264
    f16* vh2  = kh2 + (size_t)KVAARWS * KVROW;    // 258 rows * 11264
    f16* ao   = vh2 + (size_t)KVAARWS * KVROW;    // NN*128

    prep<<<228, 256, 0, stream>>>(lw, qw, pw, qb, pb, rpb, lwf, qwf, pwf, w2f, qbs, b2s, rpbp);
    fused_fusion_qkv<<<352, 256, 0, stream>>>(x, cond, mask, lwf, lb, qwf, qbs, qh, kh2, vh2);
    attn_mfma<<<dim3(TT / 4, PP / 8, HEADS / 2), 256, 0, stream>>>(qh, kh2, vh2, rpbp, ao);
    gemm_qkv<<<dim3(352, 6), 256, 0, stream>>>(ao, w2f, b2s, qh, kh2, vh2);   // fused proj+qkv
    attn_mfma<<<dim3(TT / 4, PP / 8, HEADS / 2), 256, 0, stream>>>(qh, kh2, vh2, rpbp, ao);
    gemm_out<<<dim3(352, 2), 256, 0, stream>>>(ao, pwf, pb, outp);
}

// Round 14
// 173.082 us; speedup vs baseline: 3.8854x; 1.0064x over previous
//
#include <hip/hip_runtime.h>
#include <hip/hip_fp16.h>

#define TT 256
#define PP 88
#define CC 128
#define NN (TT * PP)          // 22528 positions
#define HEADS 4
#define HD 32
#define WIN 25
#define RPBW 49
#define RPBSZ (RPBW * RPBW)   // 2401
#define SCALE 0.17677669529663687f   // 1/sqrt(32)
#define LOG2E 1.4426950408889634f
#define QSC (SCALE * LOG2E)          // fold exp->exp2 into Q path

// K layout: kh2[aa][h][j:88][ch32]   -> row stride (aa) = 11264, (aa,h) block = 2816
// V layout: vh2[aa][h][half:2][g:22][ch16][jr:4] -> same strides; dense 512B per attn load
#define KVROW 11264           // f16 elems per aa row (4 heads x 2816)
#define KVAARWS 258           // aa rows allocated (256 + prefetch/overshoot pad)

#if __has_builtin(__builtin_amdgcn_exp2f)
#define EXP2(x) __builtin_amdgcn_exp2f(x)
#else
#define EXP2(x) exp2f(x)
#endif

typedef _Float16 f16;
typedef f16 f16x8 __attribute__((ext_vector_type(8)));
typedef f16 f16x8u __attribute__((ext_vector_type(8), aligned(4)));
typedef f16 f16x4 __attribute__((ext_vector_type(4)));
typedef f16 f16x4u __attribute__((ext_vector_type(4), aligned(4)));
typedef float f32x4 __attribute__((ext_vector_type(4)));
typedef float f32x4u __attribute__((ext_vector_type(4), aligned(4)));
typedef __fp16 hf16x2 __attribute__((ext_vector_type(2)));
union PkU { hf16x2 h; unsigned u; };

// Fragment-packed W layout (for all MFMA af loads): output row i, col k:
//   group = (i>>6)*4 + ((i>>4)&3), ks = k>>5, lane = ((k&31)>>3)*16 + (i&15)
//   faddr = group*(KS*512) + ks*512 + lane*8 + (k&7)      [KS = #32-col blocks]
// Inverse (used by vectorized prep): i = (group>>2)*64 + (group&3)*16 + (lane&15),
//   k = ks*32 + (lane>>4)*8 + e, e=0..7  -> 8 consecutive k = 8 consecutive faddr.

// ---------- prep v13: VECTORIZED repack (dense uint4 stores) + b2s + MFMA wcomb ----------
__global__ __launch_bounds__(256) void prep(
    const float* __restrict__ lw, const float* __restrict__ qw,
    const float* __restrict__ pw, const float* __restrict__ qb,
    const float* __restrict__ pb, const float* __restrict__ rpb,
    f16* __restrict__ lwf, f16* __restrict__ qwf, f16* __restrict__ pwf,
    f16* __restrict__ w2f, float* __restrict__ qbs, float* __restrict__ b2s,
    float* __restrict__ rpbp)
{
    const int b = blockIdx.x;
    if (b < 192) {
        int idx = b * 256 + threadIdx.x;              // [0, 49152)
        if (idx < 6144) {                             // qwf: 24 groups x 4 ks x 64 lanes
            int group = idx >> 8, ks = (idx >> 6) & 3, lane = idx & 63;
            int i = (group >> 2) * 64 + (group & 3) * 16 + (lane & 15);
            int k0 = ks * 32 + (lane >> 4) * 8;
            float sc = (i < 128) ? QSC : 1.f;
            union { f16 e[8]; uint4 u; } t;
            #pragma unroll
            for (int e = 0; e < 8; e++) t.e[e] = (f16)(qw[i * 128 + k0 + e] * sc);
            *(uint4*)&qwf[group * 2048 + ks * 512 + lane * 8] = t.u;
        } else if (idx < 8704) {                      // lwf: 8 groups x 5 ks x 64 lanes
            int j = idx - 6144;
            int group = j / 320; int r2 = j - group * 320; int ks = r2 >> 6, lane = r2 & 63;
            if (group < 8) {
                int r = (group >> 2) * 64 + (group & 3) * 16 + (lane & 15);
                int c0 = ks * 32 + (lane >> 4) * 8;
                union { f16 e[8]; uint4 u; } t;
                #pragma unroll
                for (int e = 0; e < 8; e++) {
                    int c = c0 + e;
                    t.e[e] = (f16)((c < 131) ? lw[r * 131 + c] : 0.f);
                }
                *(uint4*)&lwf[group * 2560 + ks * 512 + lane * 8] = t.u;
            }
        } else if (idx < 10752) {                     // pwf: 8 groups x 4 ks x 64 lanes
            int j = idx - 8704;
            int group = j >> 8, ks = (j >> 6) & 3, lane = j & 63;
            int i = (group >> 2) * 64 + (group & 3) * 16 + (lane & 15);
            int k0 = ks * 32 + (lane >> 4) * 8;
            union { f16 e[8]; uint4 u; } t;
            #pragma unroll
            for (int e = 0; e < 8; e++) t.e[e] = (f16)pw[i * 128 + k0 + e];
            *(uint4*)&pwf[group * 2048 + ks * 512 + lane * 8] = t.u;
        } else if (idx < 20992) {                     // rpbp: 10240 dense f32
            int j = idx - 10752;
            rpbp[j] = (j < 4 * RPBSZ) ? rpb[j] * LOG2E : 0.f;
        } else if (idx < 21376) {                     // qbs: 384
            int j = idx - 20992;
            qbs[j] = qb[j] * (j < 128 ? QSC : 1.f);
        }
    } else if (b < 216) {
        // b2s[i] = (qb[i] + qw[i,:]·pb) * sc_i ; 16 lanes per output, shuffle-reduce
        int t = (b - 192) * 256 + threadIdx.x;        // [0, 6144)
        int i = t >> 4, l = t & 15;
        if (i < 384) {
            float s = 0.f;
            #pragma unroll
            for (int j = l * 8; j < l * 8 + 8; j++) s += qw[i * 128 + j] * pb[j];
            s += __shfl_xor(s, 1); s += __shfl_xor(s, 2);
            s += __shfl_xor(s, 4); s += __shfl_xor(s, 8);
            if (l == 0) b2s[i] = (qb[i] + s) * (i < 128 ? QSC : 1.f);
        }
    } else {
        // w2f[i][k] = sc_i * sum_j qw[i][j] pw[j][k]  (fragment-packed output)
        const int bw = b - 216;                       // 0..11
        const int m0 = (bw & 1) * 64;                 // k-tile
        const int n0 = (bw >> 1) * 64;                // i-tile
        const int tid = threadIdx.x;
        const int w = tid >> 6, lane = tid & 63, quad = lane >> 4, nn = lane & 15;
        const int krow = m0 + w * 16 + nn;
        f16x8 af[4];
        #pragma unroll
        for (int ks = 0; ks < 4; ks++) {
            union { f16 e[8]; f16x8 v; } t;
            #pragma unroll
            for (int e = 0; e < 8; e++)
                t.e[e] = (f16)pw[(ks * 32 + quad * 8 + e) * 128 + krow];
            af[ks] = t.v;
        }
        f32x4 acc[4] = {};
        #pragma unroll
        for (int nt = 0; nt < 4; nt++) {
            int irow = n0 + nt * 16 + nn;
            #pragma unroll
            for (int ks = 0; ks < 4; ks++) {
                const float* qr = &qw[(size_t)irow * 128 + ks * 32 + quad * 8];
                float4 a = *(const float4*)qr, bq = *(const float4*)(qr + 4);
                PkU u0, u1, u2, u3;
                u0.h = __builtin_amdgcn_cvt_pkrtz(a.x, a.y);
                u1.h = __builtin_amdgcn_cvt_pkrtz(a.z, a.w);
                u2.h = __builtin_amdgcn_cvt_pkrtz(bq.x, bq.y);
                u3.h = __builtin_amdgcn_cvt_pkrtz(bq.z, bq.w);
                union { unsigned u[4]; f16x8 v; } bb;
                bb.u[0] = u0.u; bb.u[1] = u1.u; bb.u[2] = u2.u; bb.u[3] = u3.u;
                acc[nt] = __builtin_amdgcn_mfma_f32_16x16x32_f16(af[ks], bb.v, acc[nt], 0, 0, 0);
            }
        }
        #pragma unroll
        for (int nt = 0; nt < 4; nt++) {
            int i = n0 + nt * 16 + nn;
            int k = m0 + w * 16 + quad * 4;           // 4 consecutive cols, k&7 in {0,4}
            float sc = (i < 128) ? QSC : 1.f;
            PkU p0, p1;
            p0.h = __builtin_amdgcn_cvt_pkrtz(acc[nt][0] * sc, acc[nt][1] * sc);
            p1.h = __builtin_amdgcn_cvt_pkrtz(acc[nt][2] * sc, acc[nt][3] * sc);
            int lane2 = (((k & 31) >> 3) << 4) + (i & 15);
            int faddr = (((i >> 6) << 2) + ((i >> 4) & 3)) * 2048 + (k >> 5) * 512 + lane2 * 8 + (k & 7);
            *(uint2*)&w2f[faddr] = make_uint2(p0.u, p1.u);
        }
    }
}

// ---------- fused fusion+qkv v13 (unchanged): Y in LDS, no yh round-trip; grid (352) ----------
__global__ __launch_bounds__(256) void fused_fusion_qkv(
    const float* __restrict__ x, const float* __restrict__ cond, const float* __restrict__ mask,
    const f16* __restrict__ lwf, const float* __restrict__ lb,
    const f16* __restrict__ qwf, const float* __restrict__ bias,
    f16* __restrict__ qh, f16* __restrict__ kh2, f16* __restrict__ vh2)
{
    __shared__ __align__(16) f16 Alds[64 * 168];
    __shared__ __align__(16) f16 Ylds[64 * 136];
    __shared__ __align__(16) f16 Rlds[64][72];
    const int m0 = blockIdx.x * 64;
    const int tid = threadIdx.x;
    const int w = tid >> 6, lane = tid & 63, quad = lane >> 4, nn = lane & 15;

    {   // ---- phase 1: stage cat rows (f16) ----
        int r = tid >> 2, cpart = tid & 3;
        size_t pos = m0 + r;
        *(uint4*)&Alds[r * 168 + 128 + cpart * 8] = make_uint4(0, 0, 0, 0);
        const float* xr = x + pos * 128 + cpart * 32;
        #pragma unroll
        for (int t = 0; t < 4; t++) {
            float4 a = *(const float4*)(xr + t * 8);
            float4 b = *(const float4*)(xr + t * 8 + 4);
            PkU p0, p1, p2, p3;
            p0.h = __builtin_amdgcn_cvt_pkrtz(a.x, a.y);
            p1.h = __builtin_amdgcn_cvt_pkrtz(a.z, a.w);
            p2.h = __builtin_amdgcn_cvt_pkrtz(b.x, b.y);
            p3.h = __builtin_amdgcn_cvt_pkrtz(b.z, b.w);
            *(uint4*)&Alds[r * 168 + cpart * 32 + t * 8] = make_uint4(p0.u, p1.u, p2.u, p3.u);
        }
        if (cpart == 0) {
            Alds[r * 168 + 128] = (f16)cond[pos * 2];
            Alds[r * 168 + 129] = (f16)cond[pos * 2 + 1];
            Alds[r * 168 + 130] = (f16)mask[pos];
        }
    }
    __syncthreads();

    // ---- phase 2: Y = relu(cat @ lwf^T + lb) -> Ylds ----
    #pragma unroll
    for (int gi = 0; gi < 2; gi++) {
        const int g = gi * 4 + w;                     // chan group
        const int cb = gi * 64 + w * 16;              // chan base
        const f16* wfb = lwf + (size_t)g * 2560 + lane * 8;
        f16x8 af[5];
        #pragma unroll
        for (int ks = 0; ks < 5; ks++)
            af[ks] = *(const f16x8*)(wfb + ks * 512);
        f32x4 acc[4] = {};
        #pragma unroll
        for (int ks = 0; ks < 5; ks++)
            #pragma unroll
            for (int nt = 0; nt < 4; nt++) {
                f16x8 bf = *(const f16x8*)&Alds[(nt * 16 + nn) * 168 + ks * 32 + quad * 8];
                acc[nt] = __builtin_amdgcn_mfma_f32_16x16x32_f16(af[ks], bf, acc[nt], 0, 0, 0);
            }
        float bv[4];
        #pragma unroll
        for (int r = 0; r < 4; r++) bv[r] = lb[cb + quad * 4 + r];
        #pragma unroll
        for (int nt = 0; nt < 4; nt++) {
            PkU p0, p1;
            p0.h = __builtin_amdgcn_cvt_pkrtz(fmaxf(acc[nt][0] + bv[0], 0.f), fmaxf(acc[nt][1] + bv[1], 0.f));
            p1.h = __builtin_amdgcn_cvt_pkrtz(fmaxf(acc[nt][2] + bv[2], 0.f), fmaxf(acc[nt][3] + bv[3], 0.f));
            *(uint2*)&Ylds[(nt * 16 + nn) * 136 + cb + quad * 4] = make_uint2(p0.u, p1.u);
        }
    }
    __syncthreads();

    // ---- phase 3: six 64-chan qkv tiles from Ylds ----
    #pragma unroll 1
    for (int t = 0; t < 6; t++) {
        const int n0 = t * 64;
        const f16* wfb = qwf + ((size_t)t * 4 + w) * 2048 + lane * 8;
        f16x8 af[4];
        #pragma unroll
        for (int ks = 0; ks < 4; ks++)
            af[ks] = *(const f16x8*)(wfb + ks * 512);
        f32x4 acc[4] = {};
        #pragma unroll
        for (int ks = 0; ks < 4; ks++)
            #pragma unroll
            for (int nt = 0; nt < 4; nt++) {
                f16x8 bf = *(const f16x8*)&Ylds[(nt * 16 + nn) * 136 + ks * 32 + quad * 8];
                acc[nt] = __builtin_amdgcn_mfma_f32_16x16x32_f16(af[ks], bf, acc[nt], 0, 0, 0);
            }
        float bv[4];
        #pragma unroll
        for (int r = 0; r < 4; r++) bv[r] = bias[n0 + w * 16 + quad * 4 + r];

        __syncthreads();                              // Rlds reuse guard
        if (n0 < 256) {   // Q/K: RTZ pack
            #pragma unroll
            for (int nt = 0; nt < 4; nt++) {
                PkU p0, p1;
                p0.h = __builtin_amdgcn_cvt_pkrtz(acc[nt][0] + bv[0], acc[nt][1] + bv[1]);
                p1.h = __builtin_amdgcn_cvt_pkrtz(acc[nt][2] + bv[2], acc[nt][3] + bv[3]);
                *(uint2*)&Rlds[nt * 16 + nn][w * 16 + quad * 4] = make_uint2(p0.u, p1.u);
            }
        } else {          // V: RNE casts
            #pragma unroll
            for (int nt = 0; nt < 4; nt++) {
                union { f16 e[4]; uint2 u; } tt;
                #pragma unroll
                for (int r = 0; r < 4; r++) tt.e[r] = (f16)(acc[nt][r] + bv[r]);
                *(uint2*)&Rlds[nt * 16 + nn][w * 16 + quad * 4] = tt.u;
            }
        }
        __syncthreads();

        if (n0 < 128) {                               // ---- Q: qh[pos][128]
            #pragma unroll
            for (int it = 0; it < 2; it++) {
                int idx = it * 256 + tid;
                int pl = idx >> 3, oct = idx & 7;
                *(uint4*)&qh[(size_t)(m0 + pl) * 128 + n0 + oct * 8] = *(uint4*)&Rlds[pl][oct * 8];
            }
        } else if (n0 < 256) {                        // ---- K: kh2[aa][h][j][ch32]
            #pragma unroll
            for (int it = 0; it < 2; it++) {
                int idx = it * 256 + tid;
                int pl = idx >> 3, oct = idx & 7;
                f16x8 v = *(const f16x8*)&Rlds[pl][oct * 8];
                int pos = m0 + pl, aa = pos / 88, j = pos - aa * 88;
                int ch = n0 - 128 + oct * 8;
                int h = ch >> 5, c32 = ch & 31;
                *(uint4*)&kh2[((size_t)(aa * 4 + h) * 88 + j) * 32 + c32] = *(uint4*)&v;
            }
        } else {                                      // ---- V: vh2[aa][h][half][g][ch16][jr]
            #pragma unroll
            for (int it = 0; it < 2; it++) {
                int idx = it * 256 + tid;
                int pq = idx >> 5, cp = idx & 31;
                union { f16 e[8]; uint4 u; } tt;
                #pragma unroll
                for (int cc = 0; cc < 2; cc++)
                    #pragma unroll
                    for (int jj = 0; jj < 4; jj++)
                        tt.e[cc * 4 + jj] = Rlds[pq * 4 + jj][cp * 2 + cc];
                int pos = m0 + pq * 4, aa = pos / 88, j = pos - aa * 88;
                int ch = n0 - 256 + cp * 2;
                int h = ch >> 5, c = ch & 31, half = c >> 4, c16 = c & 15;
                *(uint4*)&vh2[(size_t)(aa * 4 + h) * 2816 + half * 1408 + (j >> 2) * 64 + c16 * 4] = tt.u;
            }
        }
    }
}

// ---------- qkv GEMM (standalone, for ao input): frag-packed W + LDS-staged stores ----------
__global__ __launch_bounds__(256) void gemm_qkv(
    const f16* __restrict__ A, const f16* __restrict__ Wf, const float* __restrict__ bias,
    f16* __restrict__ qh, f16* __restrict__ kh2, f16* __restrict__ vh2)
{
    __shared__ __align__(16) f16 Alds[64 * 136];
    __shared__ __align__(16) f16 Rlds[64][72];
    const int m0 = blockIdx.x * 64, n0 = blockIdx.y * 64;
    const int tid = threadIdx.x;
    const int w = tid >> 6, lane = tid & 63, quad = lane >> 4, nn = lane & 15;

    for (int i = tid; i < 1024; i += 256) {
        int r = i >> 4, c = i & 15;
        *(uint4*)&Alds[r * 136 + c * 8] = *(const uint4*)&A[(size_t)(m0 + r) * 128 + c * 8];
    }
    __syncthreads();

    const f16* wfb = Wf + ((size_t)(n0 >> 6) * 4 + w) * 2048 + lane * 8;
    f16x8 af[4];
    #pragma unroll
    for (int ks = 0; ks < 4; ks++)
        af[ks] = *(const f16x8*)(wfb + ks * 512);
    f32x4 acc[4] = {};
    #pragma unroll
    for (int ks = 0; ks < 4; ks++)
        #pragma unroll
        for (int nt = 0; nt < 4; nt++) {
            f16x8 bf = *(const f16x8*)&Alds[(nt * 16 + nn) * 136 + ks * 32 + quad * 8];
            acc[nt] = __builtin_amdgcn_mfma_f32_16x16x32_f16(af[ks], bf, acc[nt], 0, 0, 0);
        }
    float bv[4];
    #pragma unroll
    for (int r = 0; r < 4; r++) bv[r] = bias[n0 + w * 16 + quad * 4 + r];

    if (n0 < 256) {   // Q/K: RTZ pack
        #pragma unroll
        for (int nt = 0; nt < 4; nt++) {
            PkU p0, p1;
            p0.h = __builtin_amdgcn_cvt_pkrtz(acc[nt][0] + bv[0], acc[nt][1] + bv[1]);
            p1.h = __builtin_amdgcn_cvt_pkrtz(acc[nt][2] + bv[2], acc[nt][3] + bv[3]);
            *(uint2*)&Rlds[nt * 16 + nn][w * 16 + quad * 4] = make_uint2(p0.u, p1.u);
        }
    } else {          // V: RNE casts
        #pragma unroll
        for (int nt = 0; nt < 4; nt++) {
            union { f16 e[4]; uint2 u; } t;
            #pragma unroll
            for (int r = 0; r < 4; r++) t.e[r] = (f16)(acc[nt][r] + bv[r]);
            *(uint2*)&Rlds[nt * 16 + nn][w * 16 + quad * 4] = t.u;
        }
    }
    __syncthreads();

    if (n0 < 128) {                                   // ---- Q: qh[pos][128]
        #pragma unroll
        for (int it = 0; it < 2; it++) {
            int idx = it * 256 + tid;
            int pl = idx >> 3, oct = idx & 7;
            f16x8 v = *(const f16x8*)&Rlds[pl][oct * 8];
            *(uint4*)&qh[(size_t)(m0 + pl) * 128 + n0 + oct * 8] = *(uint4*)&v;
        }
    } else if (n0 < 256) {                            // ---- K: kh2[aa][h][j][ch32]
        #pragma unroll
        for (int it = 0; it < 2; it++) {
            int idx = it * 256 + tid;
            int pl = idx >> 3, oct = idx & 7;
            f16x8 v = *(const f16x8*)&Rlds[pl][oct * 8];
            int pos = m0 + pl, aa = pos / 88, j = pos - aa * 88;
            int ch = n0 - 128 + oct * 8;
            int h = ch >> 5, c32 = ch & 31;
            *(uint4*)&kh2[((size_t)(aa * 4 + h) * 88 + j) * 32 + c32] = *(uint4*)&v;
        }
    } else {                                          // ---- V: vh2[aa][h][half][g][ch16][jr]
        #pragma unroll
        for (int it = 0; it < 2; it++) {
            int idx = it * 256 + tid;
            int pq = idx >> 5, cp = idx & 31;
            union { f16 e[8]; uint4 u; } t;
            #pragma unroll
            for (int cc = 0; cc < 2; cc++)
                #pragma unroll
                for (int jj = 0; jj < 4; jj++)
                    t.e[cc * 4 + jj] = Rlds[pq * 4 + jj][cp * 2 + cc];
            int pos = m0 + pq * 4, aa = pos / 88, j = pos - aa * 88;
            int ch = n0 - 256 + cp * 2;
            int h = ch >> 5, c = ch & 31, half = c >> 4, c16 = c & 15;
            *(uint4*)&vh2[(size_t)(aa * 4 + h) * 2816 + half * 1408 + (j >> 2) * 64 + c16 * 4] = t.u;
        }
    }
}

// ---------- final projection: frag-packed W + LDS-staged dense f32 stores ----------
__global__ __launch_bounds__(256) void gemm_out(
    const f16* __restrict__ A, const f16* __restrict__ Wf, const float* __restrict__ bias,
    float* __restrict__ outp)
{
    __shared__ __align__(16) f16 Alds[64 * 136];
    __shared__ __align__(16) float Rldsf[64][68];
    const int m0 = blockIdx.x * 64, n0 = blockIdx.y * 64;
    const int tid = threadIdx.x;
    const int w = tid >> 6, lane = tid & 63, quad = lane >> 4, nn = lane & 15;

    for (int i = tid; i < 1024; i += 256) {
        int r = i >> 4, c = i & 15;
        *(uint4*)&Alds[r * 136 + c * 8] = *(const uint4*)&A[(size_t)(m0 + r) * 128 + c * 8];
    }
    __syncthreads();

    const f16* wfb = Wf + ((size_t)(n0 >> 6) * 4 + w) * 2048 + lane * 8;
    f16x8 af[4];
    #pragma unroll
    for (int ks = 0; ks < 4; ks++)
        af[ks] = *(const f16x8*)(wfb + ks * 512);
    f32x4 acc[4] = {};
    #pragma unroll
    for (int ks = 0; ks < 4; ks++)
        #pragma unroll
        for (int nt = 0; nt < 4; nt++) {
            f16x8 bf = *(const f16x8*)&Alds[(nt * 16 + nn) * 136 + ks * 32 + quad * 8];
            acc[nt] = __builtin_amdgcn_mfma_f32_16x16x32_f16(af[ks], bf, acc[nt], 0, 0, 0);
        }
    float bv[4];
    #pragma unroll
    for (int r = 0; r < 4; r++) bv[r] = bias[n0 + w * 16 + quad * 4 + r];
    #pragma unroll
    for (int nt = 0; nt < 4; nt++) {
        f32x4 vv;
        #pragma unroll
        for (int r = 0; r < 4; r++) vv[r] = acc[nt][r] + bv[r];
        *(f32x4*)&Rldsf[nt * 16 + nn][w * 16 + quad * 4] = vv;
    }
    __syncthreads();
    #pragma unroll
    for (int it = 0; it < 4; it++) {
        int idx = it * 256 + tid;
        int pl = idx >> 4, part = idx & 15;
        *(f32x4*)&outp[(size_t)(m0 + pl) * 128 + n0 + part * 4] = *(const f32x4*)&Rldsf[pl][part * 4];
    }
}

// ---------- MFMA neighborhood attention v15: rpb-in-LDS + double-buffered V ----------
// v14 structure (2 heads/block, rpb staged in LDS, register PV, coalesced
// kh2/vh2, full unroll, setprio). Change: V fragments double-buffered - vcur
// (consumed by this iteration's PV) / vnxt (in flight). Phase (c) now rotates
// vcur <- vnxt and issues V(aa+1), giving V a FULL iteration of latency cover
// (was ~half: loaded at (c), consumed at next (b) -> only (d)+(e) ~120cy of
// cover < L2 latency). K already had full-iteration cover. +8 VGPR (56 -> ~70,
// far from any cliff). Last-iteration overshoot reads row aa0+14 <= 256 < 258
// allocated (same guarantee as the existing K prefetch).
__global__ __launch_bounds__(256, 3) void attn_mfma(
    const f16* __restrict__ qh,    // [N][128] Q, pre-scaled by QSC
    const f16* __restrict__ kh2,   // [aa][h][j][ch32]
    const f16* __restrict__ vh2,   // [aa][h][half][g][ch16][jr]
    const float* __restrict__ rpbp,
    f16* __restrict__ ao)          // [N][128]
{
    const int bx = ((blockIdx.x & 7) << 3) + (blockIdx.x >> 3);   // XCD-contiguous i-tiles
    const int i0 = bx * 4;
    const int j0 = blockIdx.y * 8;
    const int tid = threadIdx.x;
    const int w = tid >> 6, lane = tid & 63;
    const int quad = lane >> 4, nn = lane & 15;
    const int kh = w & 1;                  // key-row half within head-group
    const int hs = w >> 1;                 // head-sub within block
    const int h  = blockIdx.z * 2 + hs;

    const int ri0 = min(max(i0 - 12, 0), TT - 28);         // 28-row key span
    const int rj0 = min(max(j0 - 12, 0), PP - WIN) & ~3;   // 4-aligned for vh2

    __shared__ __align__(16) float Olds[2][64][28];   // [head-sub] kh=1 partials
    __shared__ __align__(16) float RpbL[2][1576];     // 8 guard + 32 rows x 49 cols

    // ---- stage rpb slices for both heads (rows rowbase..rowbase+31) ----
    const int rowbase = ri0 - i0 + 21;                // = min needed row (aa_min - qi_max + 24)
    {
        const int sb = rowbase * RPBW;
        #pragma unroll
        for (int hh = 0; hh < 2; hh++) {
            const int hg = blockIdx.z * 2 + hh;
            for (int idx = tid; idx < 1568; idx += 256) {
                int s = hg * RPBSZ + sb + idx;
                s = min(max(s, 0), 10239);            // clamped rows are masked in-loop
                RpbL[hh][8 + idx] = rpbp[s];
            }
        }
    }

    int si_[2];
    unsigned pm_[2][4];            // packed-f16 column masks per output word
    f16x8 qf[2];
    const float* rpq[2];
    const int aa0 = ri0 + kh * 14; // this wave's first key row (14 rows/wave)

    #pragma unroll
    for (int q = 0; q < 2; q++) {
        int ql = q * 16 + nn;
        int qi = i0 + (ql >> 3), qj = j0 + (ql & 7);
        int si = min(max(qi - 12, 0), TT - WIN);
        int sj = min(max(qj - 12, 0), PP - WIN);
        si_[q] = si;
        unsigned cm = 0x1FFFFFFu << (sj - rj0);       // shift <= 7
        #pragma unroll
        for (int t = 0; t < 4; t++) {
            int k0 = (t >> 1) * 16 + quad * 4 + (t & 1) * 2;
            pm_[q][t] = (((cm >> k0) & 1u) ? 0xFFFFu : 0u)
                      | (((cm >> (k0 + 1)) & 1u) ? 0xFFFF0000u : 0u);
        }
        qf[q] = *(const f16x8*)&qh[(size_t)(qi * PP + qj) * 128 + h * HD + quad * 8];
        // LDS pointer: lrow0 = (aa0 - qi + 24) - rowbase in [0,17]; col >= -3 absorbed by +8 guard
        rpq[q] = &RpbL[hs][8 + ((aa0 - qi + 24) - rowbase) * RPBW + (rj0 - qj + 24) + quad * 4];
    }

    const int b0 = min(rj0 + nn, PP - 1);
    const int b1 = min(rj0 + 16 + nn, PP - 1);
    const f16x4 ones4 = {(f16)1.f, (f16)1.f, (f16)1.f, (f16)1.f};

    // dense per-lane base pointers (advance by KVROW per key row)
    const f16* kb = kh2 + (size_t)(aa0 * 4 + h) * 2816 + quad * 8;
    const f16* vb = vh2 + (size_t)(aa0 * 4 + h) * 2816 + ((rj0 >> 2) + quad) * 64 + nn * 4;

    f32x4 O[2][2] = {};            // [qset][ch-half]; regs = queries, lane nn = channel
    f32x4 lacc[2] = {};
    union PB { unsigned u[2]; f16x4 v; };
    PB pa_[2], pb_[2];             // pending P (row aa-1), masked, packed
    f32x4 za_[2], zb_[2];          // rpb C-init for current row

    __syncthreads();               // rpb staging visible to all waves

    // ---- prologue: row aa0 -> S/exp only (its PV runs in iter c=1) ----
    int aa = aa0;
    f16x8 kf0 = *(const f16x8*)(kb + (size_t)b0 * 32);
    f16x8 kf1 = *(const f16x8*)(kb + (size_t)b1 * 32);
    // V(aa0) -> current buffer
    f16x4 vcA0 = *(const f16x4u*)vb;                  // keys  0-15, ch lo
    f16x4 vcB0 = *(const f16x4u*)(vb + 256);          // keys 16-31, ch lo
    f16x4 vcA1 = *(const f16x4u*)(vb + 1408);         // keys  0-15, ch hi
    f16x4 vcB1 = *(const f16x4u*)(vb + 1664);         // keys 16-31, ch hi
    // V(aa0+1) -> next buffer (full-iteration cover)
    f16x4 vnA0 = *(const f16x4u*)(vb + KVROW);
    f16x4 vnB0 = *(const f16x4u*)(vb + KVROW + 256);
    f16x4 vnA1 = *(const f16x4u*)(vb + KVROW + 1408);
    f16x4 vnB1 = *(const f16x4u*)(vb + KVROW + 1664);
    #pragma unroll
    for (int q = 0; q < 2; q++) {
        za_[q] = *(const f32x4u*)rpq[q];
        zb_[q] = *(const f32x4u*)(rpq[q] + 16);
        rpq[q] += RPBW;
    }
    #pragma unroll
    for (int q = 0; q < 2; q++) {
        f32x4 s0 = __builtin_amdgcn_mfma_f32_16x16x32_f16(kf0, qf[q], za_[q], 0, 0, 0);
        f32x4 s1 = __builtin_amdgcn_mfma_f32_16x16x32_f16(kf1, qf[q], zb_[q], 0, 0, 0);
        bool rv = (unsigned)(aa - si_[q]) <= 24u;
        float p[8];
        #pragma unroll
        for (int r = 0; r < 4; r++) { p[r] = EXP2(s0[r]); p[r + 4] = EXP2(s1[r]); }
        PkU u0, u1, u2, u3;
        u0.h = __builtin_amdgcn_cvt_pkrtz(p[0], p[1]);
        u1.h = __builtin_amdgcn_cvt_pkrtz(p[2], p[3]);
        u2.h = __builtin_amdgcn_cvt_pkrtz(p[4], p[5]);
        u3.h = __builtin_amdgcn_cvt_pkrtz(p[6], p[7]);
        pa_[q].u[0] = rv ? (u0.u & pm_[q][0]) : 0u;
        pa_[q].u[1] = rv ? (u1.u & pm_[q][1]) : 0u;
        pb_[q].u[0] = rv ? (u2.u & pm_[q][2]) : 0u;
        pb_[q].u[1] = rv ? (u3.u & pm_[q][3]) : 0u;
    }
    // prefetch K for row aa0+1
    kb += KVROW;
    f16x8 nkf0 = *(const f16x8*)(kb + (size_t)b0 * 32);
    f16x8 nkf1 = *(const f16x8*)(kb + (size_t)b1 * 32);

    // ---- fully-unrolled pipelined loop: rows aa0+1 .. aa0+13 ----
    #pragma unroll
    for (int c = 1; c < 14; ++c) {
        aa = aa0 + c;
        kf0 = nkf0; kf1 = nkf1;                       // K(aa), prefetched last iter

        // (a) issue rpb LDS reads for row aa
        #pragma unroll
        for (int q = 0; q < 2; q++) {
            za_[q] = *(const f32x4u*)rpq[q];
            zb_[q] = *(const f32x4u*)(rpq[q] + 16);
            rpq[q] += RPBW;
        }

        // (b) PV for row aa-1 using vcur (pure-MFMA cluster; setprio keeps pipe fed)
        __builtin_amdgcn_s_setprio(1);
        #pragma unroll
        for (int q = 0; q < 2; q++) {
            O[q][0] = __builtin_amdgcn_mfma_f32_16x16x16f16(pa_[q].v, vcA0, O[q][0], 0, 0, 0);
            O[q][0] = __builtin_amdgcn_mfma_f32_16x16x16f16(pb_[q].v, vcB0, O[q][0], 0, 0, 0);
            O[q][1] = __builtin_amdgcn_mfma_f32_16x16x16f16(pa_[q].v, vcA1, O[q][1], 0, 0, 0);
            O[q][1] = __builtin_amdgcn_mfma_f32_16x16x16f16(pb_[q].v, vcB1, O[q][1], 0, 0, 0);
            lacc[q] = __builtin_amdgcn_mfma_f32_16x16x16f16(pa_[q].v, ones4, lacc[q], 0, 0, 0);
            lacc[q] = __builtin_amdgcn_mfma_f32_16x16x16f16(pb_[q].v, ones4, lacc[q], 0, 0, 0);
        }
        __builtin_amdgcn_s_setprio(0);

        // (c) rotate V buffers; issue V(aa+1) (full iteration of cover)
        vcA0 = vnA0; vcB0 = vnB0; vcA1 = vnA1; vcB1 = vnB1;
        vb += KVROW;
        vnA0 = *(const f16x4u*)(vb + KVROW);
        vnB0 = *(const f16x4u*)(vb + KVROW + 256);
        vnA1 = *(const f16x4u*)(vb + KVROW + 1408);
        vnB1 = *(const f16x4u*)(vb + KVROW + 1664);

        // (d) issue K prefetch for row aa+1 (last iter reads padded row: unused)
        kb += KVROW;
        nkf0 = *(const f16x8*)(kb + (size_t)b0 * 32);
        nkf1 = *(const f16x8*)(kb + (size_t)b1 * 32);

        // (e) S + exp for row aa -> pending P (pa_/pb_ free: consumed in (b))
        #pragma unroll
        for (int q = 0; q < 2; q++) {
            f32x4 s0 = __builtin_amdgcn_mfma_f32_16x16x32_f16(kf0, qf[q], za_[q], 0, 0, 0);
            f32x4 s1 = __builtin_amdgcn_mfma_f32_16x16x32_f16(kf1, qf[q], zb_[q], 0, 0, 0);
            bool rv = (unsigned)(aa - si_[q]) <= 24u;
            float p[8];
            #pragma unroll
            for (int r = 0; r < 4; r++) { p[r] = EXP2(s0[r]); p[r + 4] = EXP2(s1[r]); }
            PkU u0, u1, u2, u3;
            u0.h = __builtin_amdgcn_cvt_pkrtz(p[0], p[1]);
            u1.h = __builtin_amdgcn_cvt_pkrtz(p[2], p[3]);
            u2.h = __builtin_amdgcn_cvt_pkrtz(p[4], p[5]);
            u3.h = __builtin_amdgcn_cvt_pkrtz(p[6], p[7]);
            pa_[q].u[0] = rv ? (u0.u & pm_[q][0]) : 0u;
            pa_[q].u[1] = rv ? (u1.u & pm_[q][1]) : 0u;
            pb_[q].u[0] = rv ? (u2.u & pm_[q][2]) : 0u;
            pb_[q].u[1] = rv ? (u3.u & pm_[q][3]) : 0u;
        }
    }

    // ---- epilogue PV: last row (aa0+13) uses vcur ----
    #pragma unroll
    for (int q = 0; q < 2; q++) {
        O[q][0] = __builtin_amdgcn_mfma_f32_16x16x16f16(pa_[q].v, vcA0, O[q][0], 0, 0, 0);
        O[q][0] = __builtin_amdgcn_mfma_f32_16x16x16f16(pb_[q].v, vcB0, O[q][0], 0, 0, 0);
        O[q][1] = __builtin_amdgcn_mfma_f32_16x16x16f16(pa_[q].v, vcA1, O[q][1], 0, 0, 0);
        O[q][1] = __builtin_amdgcn_mfma_f32_16x16x16f16(pb_[q].v, vcB1, O[q][1], 0, 0, 0);
        lacc[q] = __builtin_amdgcn_mfma_f32_16x16x16f16(pa_[q].v, ones4, lacc[q], 0, 0, 0);
        lacc[q] = __builtin_amdgcn_mfma_f32_16x16x16f16(pb_[q].v, ones4, lacc[q], 0, 0, 0);
    }

    // ---- merge (per head-pair): kh=1 wave stores, kh=0 wave adds and finishes ----
    if (kh) {
        float* ob = &Olds[hs][lane][0];
        #pragma unroll
        for (int q = 0; q < 2; q++) {
            *(f32x4*)&ob[q * 12]     = O[q][0];
            *(f32x4*)&ob[q * 12 + 4] = O[q][1];
            *(f32x4*)&ob[q * 12 + 8] = lacc[q];
        }
    }
    __syncthreads();
    if (!kh) {
        const float* ob = &Olds[hs][lane][0];
        #pragma unroll
        for (int q = 0; q < 2; q++) {
            f32x4 o0 = O[q][0] + *(const f32x4*)&ob[q * 12];
            f32x4 o1 = O[q][1] + *(const f32x4*)&ob[q * 12 + 4];
            f32x4 la = lacc[q] + *(const f32x4*)&ob[q * 12 + 8];
            #pragma unroll
            for (int r = 0; r < 4; r++) {
                float li = 1.f / la[r];
                int ql = q * 16 + quad * 4 + r;
                int qi = i0 + (ql >> 3), qj = j0 + (ql & 7);
                size_t base = (size_t)(qi * PP + qj) * CC + h * HD;
                ao[base + nn]      = (f16)(o0[r] * li);
                ao[base + 16 + nn] = (f16)(o1[r] * li);
            }
        }
    }
}

extern "C" void kernel_launch(void* const* d_in, const int* in_sizes, int n_in,
                              void* d_out, int out_size, void* d_ws, size_t ws_size,
                              hipStream_t stream) {
    (void)in_sizes; (void)n_in; (void)out_size; (void)ws_size;
    const float* x    = (const float*)d_in[0];
    const float* cond = (const float*)d_in[1];
    const float* mask = (const float*)d_in[2];
    const float* lw   = (const float*)d_in[3];
    const float* lb   = (const float*)d_in[4];
    const float* qw   = (const float*)d_in[5];
    const float* qb   = (const float*)d_in[6];
    const float* rpb  = (const float*)d_in[7];
    const float* pw   = (const float*)d_in[8];
    const float* pb   = (const float*)d_in[9];
    float* outp       = (float*)d_out;

    float* ws   = (float*)d_ws;
    float* qbs  = ws;                 // 384
    float* b2s  = qbs + 384;          // 384
    float* rpbp = b2s + 384;          // 10240 padded
    f16* lwf  = (f16*)(rpbp + 10240);             // 128*160 fragment-packed
    f16* qwf  = lwf + 20480;                      // 384*128 fragment-packed
    f16* pwf  = qwf + 49152;                      // 128*128 fragment-packed
    f16* w2f  = pwf + 16384;                      // 384*128 fragment-packed
    f16* yh   = w2f + 49152;                      // NN*128 (unused, kept for layout)
    f16* qh   = yh + (size_t)NN * 128;            // NN*128 Q
    f16* kh2  = qh + (size_t)NN * 128;            // 258 rows * 11264
    f16* vh2  = kh2 + (size_t)KVAARWS * KVROW;    // 258 rows * 11264
    f16* ao   = vh2 + (size_t)KVAARWS * KVROW;    // NN*128

    prep<<<228, 256, 0, stream>>>(lw, qw, pw, qb, pb, rpb, lwf, qwf, pwf, w2f, qbs, b2s, rpbp);
    fused_fusion_qkv<<<352, 256, 0, stream>>>(x, cond, mask, lwf, lb, qwf, qbs, qh, kh2, vh2);
    attn_mfma<<<dim3(TT / 4, PP / 8, HEADS / 2), 256, 0, stream>>>(qh, kh2, vh2, rpbp, ao);
    gemm_qkv<<<dim3(352, 6), 256, 0, stream>>>(ao, w2f, b2s, qh, kh2, vh2);   // fused proj+qkv
    attn_mfma<<<dim3(TT / 4, PP / 8, HEADS / 2), 256, 0, stream>>>(qh, kh2, vh2, rpbp, ao);
    gemm_out<<<dim3(352, 2), 256, 0, stream>>>(ao, pwf, pb, outp);
}